// Round 1
// baseline (6132.188 us; speedup 1.0000x reference)
//
#include <hip/hip_runtime.h>

// Problem constants
// B=4, N=4096, C=768, H=12, D=64, M=64, PNP=11, SCALE=1/8

// ---------------------------------------------------------------------------
// K1: QKV GEMM  Y = X(16384x768) @ W^T(2304x768) + b, scatter to q/k/v (B,H,N,D)
// ---------------------------------------------------------------------------
__global__ __launch_bounds__(256) void gemm_qkv(
    const float* __restrict__ X, const float* __restrict__ W,
    const float* __restrict__ bias,
    float* __restrict__ q, float* __restrict__ k, float* __restrict__ v)
{
    __shared__ float As[16][65];
    __shared__ float Bs[16][65];
    const int tid = threadIdx.x;
    const int brow = blockIdx.y << 6;
    const int bcol = blockIdx.x << 6;
    const int tx = tid & 15, ty = tid >> 4;
    const int lr = tid >> 2, lc = (tid & 3) << 2;
    float acc[4][4] = {};
    for (int k0 = 0; k0 < 768; k0 += 16) {
        float4 a = *(const float4*)(X + (size_t)(brow + lr) * 768 + k0 + lc);
        float4 b = *(const float4*)(W + (size_t)(bcol + lr) * 768 + k0 + lc);
        As[lc + 0][lr] = a.x; As[lc + 1][lr] = a.y; As[lc + 2][lr] = a.z; As[lc + 3][lr] = a.w;
        Bs[lc + 0][lr] = b.x; Bs[lc + 1][lr] = b.y; Bs[lc + 2][lr] = b.z; Bs[lc + 3][lr] = b.w;
        __syncthreads();
        #pragma unroll
        for (int kk = 0; kk < 16; ++kk) {
            float av[4], bv[4];
            #pragma unroll
            for (int i = 0; i < 4; ++i) av[i] = As[kk][(ty << 2) + i];
            #pragma unroll
            for (int j = 0; j < 4; ++j) bv[j] = Bs[kk][(tx << 2) + j];
            #pragma unroll
            for (int i = 0; i < 4; ++i)
                #pragma unroll
                for (int j = 0; j < 4; ++j)
                    acc[i][j] += av[i] * bv[j];
        }
        __syncthreads();
    }
    #pragma unroll
    for (int i = 0; i < 4; ++i) {
        int r = brow + (ty << 2) + i;
        int b = r >> 12, n = r & 4095;
        #pragma unroll
        for (int j = 0; j < 4; ++j) {
            int c = bcol + (tx << 2) + j;
            float val = acc[i][j] + bias[c];
            int t = c / 768;
            int rem = c - t * 768;
            int h = rem >> 6, d = rem & 63;
            size_t idx = (((size_t)(b * 12 + h) << 12) + n) * 64 + d;
            if (t == 0)      q[idx] = val * 0.125f;
            else if (t == 1) k[idx] = val;
            else             v[idx] = val;
        }
    }
}

// ---------------------------------------------------------------------------
// K2: sc_max[b,h,m] = max_n  sum_d q_m[m,d]*k[n,d]   (h < 11)
// ---------------------------------------------------------------------------
__global__ __launch_bounds__(256) void sc_max_kernel(
    const float* __restrict__ q, const float* __restrict__ k,
    float* __restrict__ scm)
{
    int bh = blockIdx.x;            // 0..43
    int b = bh / 11, h = bh - b * 11;
    size_t base = ((size_t)(b * 12 + h)) << 12;  // row index base
    const float* qb = q + base * 64;
    const float* kb = k + base * 64;
    __shared__ float qm[64][65];
    __shared__ float kt[64][65];
    __shared__ float red[4][64];
    int tid = threadIdx.x;
    for (int e = tid; e < 4096; e += 256) {
        int mm = e >> 6, d = e & 63;
        qm[mm][d] = qb[((size_t)mm << 12) + d];   // q row n = m*64
    }
    int m = tid & 63, g = tid >> 6;
    float best = -1e30f;
    for (int n0 = 0; n0 < 4096; n0 += 64) {
        for (int e = tid; e < 1024; e += 256) {
            int rr = e >> 4, c = (e & 15) << 2;
            float4 k4 = *(const float4*)(kb + ((size_t)(n0 + rr) << 6) + c);
            kt[rr][c] = k4.x; kt[rr][c + 1] = k4.y; kt[rr][c + 2] = k4.z; kt[rr][c + 3] = k4.w;
        }
        __syncthreads();
        for (int nn = g; nn < 64; nn += 4) {
            float s = 0.f;
            #pragma unroll
            for (int d = 0; d < 64; ++d) s += qm[m][d] * kt[nn][d];
            best = fmaxf(best, s);
        }
        __syncthreads();
    }
    red[g][m] = best;
    __syncthreads();
    if (tid < 64) {
        float v0 = fmaxf(fmaxf(red[0][tid], red[1][tid]),
                         fmaxf(red[2][tid], red[3][tid]));
        scm[(bh << 6) + tid] = v0;
    }
}

// ---------------------------------------------------------------------------
// K3a: eB[b,h,m,l] = exp(clip(q_m[m]·k_m[l] - scmax[m], -88, inf))
// ---------------------------------------------------------------------------
__global__ __launch_bounds__(256) void eb_kernel(
    const float* __restrict__ q, const float* __restrict__ k,
    const float* __restrict__ scm, float* __restrict__ eB)
{
    int bh = blockIdx.x;
    int b = bh / 11, h = bh - b * 11;
    size_t base = ((size_t)(b * 12 + h)) << 12;
    const float* qb = q + base * 64;
    const float* kb = k + base * 64;
    __shared__ float qm[64][65], km[64][65];
    int tid = threadIdx.x;
    for (int e = tid; e < 4096; e += 256) {
        int mm = e >> 6, d = e & 63;
        qm[mm][d] = qb[((size_t)mm << 12) + d];
        km[mm][d] = kb[((size_t)mm << 12) + d];
    }
    __syncthreads();
    int m = tid >> 2, l0 = tid & 3;
    float smax = scm[(bh << 6) + m];
    for (int l = l0; l < 64; l += 4) {
        float s = 0.f;
        #pragma unroll
        for (int d = 0; d < 64; ++d) s += qm[m][d] * km[l][d];
        eB[((size_t)bh << 12) + (m << 6) + l] = expf(fmaxf(s - smax, -88.f));
    }
}

// ---------------------------------------------------------------------------
// K3b: per-head norms: denom[h] = max_{b,m} rowsum(eB) * max_{b,l} colsum(eB)
// ---------------------------------------------------------------------------
__global__ __launch_bounds__(256) void norms_kernel(
    const float* __restrict__ eB, float* __restrict__ denom)
{
    int h = blockIdx.x;             // 0..10
    int tid = threadIdx.x;          // 256 = 4 batches x 64
    int b = tid >> 6, idx = tid & 63;
    int bh = b * 11 + h;
    const float* E = eB + ((size_t)bh << 12);
    float rs = 0.f, cs = 0.f;
    #pragma unroll 4
    for (int l = 0; l < 64; ++l) rs += E[(idx << 6) + l];
    #pragma unroll 4
    for (int m = 0; m < 64; ++m) cs += E[(m << 6) + idx];
    __shared__ float r1[256], r2[256];
    r1[tid] = rs; r2[tid] = cs;
    __syncthreads();
    for (int s = 128; s > 0; s >>= 1) {
        if (tid < s) {
            r1[tid] = fmaxf(r1[tid], r1[tid + s]);
            r2[tid] = fmaxf(r2[tid], r2[tid + s]);
        }
        __syncthreads();
    }
    if (tid == 0) denom[h] = r1[0] * r2[0];
}

// ---------------------------------------------------------------------------
// K3c: pinv via 6 Newton iterations, one block per (b,h), all in LDS
// ---------------------------------------------------------------------------
__global__ __launch_bounds__(256) void pinv_kernel(
    const float* __restrict__ eB, const float* __restrict__ denom,
    float* __restrict__ pi_)
{
    int bh = blockIdx.x;
    int h = bh % 11;
    __shared__ float X[64][65], Z[64][65], XZ[64][65], TA[64][65], TB[64][65];
    int tid = threadIdx.x;
    float dn = denom[h];
    for (int e = tid; e < 4096; e += 256) {
        int m = e >> 6, l = e & 63;
        float xv = eB[((size_t)bh << 12) + e];
        X[m][l] = xv;
        Z[l][m] = xv / dn;          // z0 = x^T / (colmax*rowmax)
    }
    __syncthreads();
    int m = tid >> 2, l0 = tid & 3;
    for (int it = 0; it < 6; ++it) {
        for (int l = l0; l < 64; l += 4) {
            float s = 0.f;
            #pragma unroll
            for (int kk = 0; kk < 64; ++kk) s += X[m][kk] * Z[kk][l];
            XZ[m][l] = s;
        }
        __syncthreads();
        for (int l = l0; l < 64; l += 4) {          // TA = XZ@(7I - XZ)
            float s = 0.f;
            #pragma unroll
            for (int kk = 0; kk < 64; ++kk) s += XZ[m][kk] * XZ[kk][l];
            TA[m][l] = 7.f * XZ[m][l] - s;
        }
        __syncthreads();
        for (int l = l0; l < 64; l += 4) {          // TB = XZ@(15I - TA)
            float s = 0.f;
            #pragma unroll
            for (int kk = 0; kk < 64; ++kk) s += XZ[m][kk] * TA[kk][l];
            TB[m][l] = 15.f * XZ[m][l] - s;
        }
        __syncthreads();
        for (int l = l0; l < 64; l += 4) {          // TA = Z@(13I - TB)
            float s = 0.f;
            #pragma unroll
            for (int kk = 0; kk < 64; ++kk) s += Z[m][kk] * TB[kk][l];
            TA[m][l] = 13.f * Z[m][l] - s;
        }
        __syncthreads();
        for (int l = l0; l < 64; l += 4) Z[m][l] = 0.25f * TA[m][l];
        __syncthreads();
    }
    for (int e = tid; e < 4096; e += 256)
        pi_[((size_t)bh << 12) + e] = Z[e >> 6][e & 63];
}

// ---------------------------------------------------------------------------
// K4: W[b,h,m,j] = sum_n exp(SC[m,n]-scmax[m]) * vaug[n,j]   (j<65, streamed)
// ---------------------------------------------------------------------------
__global__ __launch_bounds__(256) void w_kernel(
    const float* __restrict__ q, const float* __restrict__ k,
    const float* __restrict__ v, const float* __restrict__ scm,
    float* __restrict__ Wb)
{
    int bh = blockIdx.x;
    int b = bh / 11, h = bh - b * 11;
    size_t base = ((size_t)(b * 12 + h)) << 12;
    const float* qb = q + base * 64;
    const float* kb = k + base * 64;
    const float* vb = v + base * 64;
    __shared__ float qm[64][65], kt[64][65], S[64][65], vt[64][66];
    int tid = threadIdx.x;
    int m = tid & 63, g = tid >> 6;
    for (int e = tid; e < 4096; e += 256) {
        int mm = e >> 6, d = e & 63;
        qm[mm][d] = qb[((size_t)mm << 12) + d];
    }
    float smax = scm[(bh << 6) + m];
    float acc[17];
    #pragma unroll
    for (int t = 0; t < 17; ++t) acc[t] = 0.f;
    for (int n0 = 0; n0 < 4096; n0 += 64) {
        for (int e = tid; e < 1024; e += 256) {
            int rr = e >> 4, c = (e & 15) << 2;
            float4 k4 = *(const float4*)(kb + ((size_t)(n0 + rr) << 6) + c);
            kt[rr][c] = k4.x; kt[rr][c + 1] = k4.y; kt[rr][c + 2] = k4.z; kt[rr][c + 3] = k4.w;
            float4 v4 = *(const float4*)(vb + ((size_t)(n0 + rr) << 6) + c);
            vt[rr][c] = v4.x; vt[rr][c + 1] = v4.y; vt[rr][c + 2] = v4.z; vt[rr][c + 3] = v4.w;
        }
        if (tid < 64) vt[tid][64] = 1.0f;
        __syncthreads();
        for (int nn = g; nn < 64; nn += 4) {
            float s = 0.f;
            #pragma unroll
            for (int d = 0; d < 64; ++d) s += qm[m][d] * kt[nn][d];
            S[m][nn] = expf(s - smax);
        }
        __syncthreads();
        #pragma unroll
        for (int t = 0; t < 17; ++t) {
            int j = g + (t << 2);
            if (j > 64) break;
            float s = 0.f;
            #pragma unroll
            for (int nn = 0; nn < 64; ++nn) s += S[m][nn] * vt[nn][j];
            acc[t] += s;
        }
        __syncthreads();
    }
    #pragma unroll
    for (int t = 0; t < 17; ++t) {
        int j = g + (t << 2);
        if (j > 64) break;
        Wb[(size_t)((bh << 6) + m) * 65 + j] = acc[t];
    }
}

// ---------------------------------------------------------------------------
// K5: T = pi @ W  (64x64 @ 64x65, one block per bh)
// ---------------------------------------------------------------------------
__global__ __launch_bounds__(256) void pw_kernel(
    const float* __restrict__ pi_, const float* __restrict__ Wb,
    float* __restrict__ Tb)
{
    int bh = blockIdx.x;
    __shared__ float P[64][65];
    __shared__ float Wl[64][66];
    int tid = threadIdx.x;
    for (int e = tid; e < 4096; e += 256)
        P[e >> 6][e & 63] = pi_[((size_t)bh << 12) + e];
    for (int e = tid; e < 64 * 65; e += 256) {
        int l = e / 65, j = e - l * 65;
        Wl[l][j] = Wb[(size_t)((bh << 6) + l) * 65 + j];
    }
    __syncthreads();
    int m = tid & 63, g = tid >> 6;
    #pragma unroll
    for (int t = 0; t < 17; ++t) {
        int j = g + (t << 2);
        if (j > 64) break;
        float s = 0.f;
        #pragma unroll
        for (int l = 0; l < 64; ++l) s += P[m][l] * Wl[l][j];
        Tb[(size_t)((bh << 6) + m) * 65 + j] = s;
    }
}

// ---------------------------------------------------------------------------
// K6: out_p tile: eA = exp(q·k_m^T - rowmax); prod = eA@T; ctx = prod/den
// ---------------------------------------------------------------------------
__global__ __launch_bounds__(256) void outp_kernel(
    const float* __restrict__ q, const float* __restrict__ k,
    const float* __restrict__ Tb, float* __restrict__ ctx)
{
    int bh = blockIdx.y;
    int b = bh / 11, h = bh - b * 11;
    int n0 = blockIdx.x << 6;
    size_t base = ((size_t)(b * 12 + h)) << 12;
    const float* qb = q + base * 64;
    const float* kb = k + base * 64;
    __shared__ float qt[64][65];
    __shared__ float kmprod[64][66];   // k_m tile, reused as prod
    __shared__ float S[64][65];
    __shared__ float Tl[64][66];
    __shared__ float red[4][64];
    int tid = threadIdx.x;
    for (int e = tid; e < 4096; e += 256) {
        int rr = e >> 6, d = e & 63;
        qt[rr][d] = qb[((size_t)(n0 + rr) << 6) + d];
        kmprod[rr][d] = kb[((size_t)rr << 12) + d];
    }
    for (int e = tid; e < 64 * 65; e += 256) {
        int mm = e / 65, j = e - mm * 65;
        Tl[mm][j] = Tb[(size_t)((bh << 6) + mm) * 65 + j];
    }
    __syncthreads();
    int r = tid & 63, g = tid >> 6;
    for (int m = g; m < 64; m += 4) {
        float s = 0.f;
        #pragma unroll
        for (int d = 0; d < 64; ++d) s += qt[r][d] * kmprod[m][d];
        S[r][m] = s;
    }
    float pm = -1e30f;
    for (int m = g; m < 64; m += 4) pm = fmaxf(pm, S[r][m]);
    red[g][r] = pm;
    __syncthreads();
    float rmax = fmaxf(fmaxf(red[0][r], red[1][r]), fmaxf(red[2][r], red[3][r]));
    for (int m = g; m < 64; m += 4) S[r][m] = expf(S[r][m] - rmax);
    __syncthreads();
    #pragma unroll
    for (int t = 0; t < 17; ++t) {
        int j = g + (t << 2);
        if (j > 64) break;
        float s = 0.f;
        #pragma unroll
        for (int m = 0; m < 64; ++m) s += S[r][m] * Tl[m][j];
        kmprod[r][j] = s;
    }
    __syncthreads();
    float dnm = fmaxf(kmprod[r][64], 1e-8f);
    float inv = 1.0f / dnm;
    size_t obase = ((size_t)b * 4096 + (size_t)(n0 + r)) * 768 + h * 64;
    for (int d = g; d < 64; d += 4)
        ctx[obase + d] = kmprod[r][d] * inv;
}

// ---------------------------------------------------------------------------
// K7: softmax head (h=11), flash-style online softmax, fp32
// ---------------------------------------------------------------------------
__global__ __launch_bounds__(256) void softmax_head_kernel(
    const float* __restrict__ q, const float* __restrict__ k,
    const float* __restrict__ v, float* __restrict__ ctx)
{
    int b = blockIdx.y;
    int n0 = blockIdx.x << 6;
    size_t base = ((size_t)(b * 12 + 11)) << 12;
    const float* qb = q + base * 64;
    const float* kb = k + base * 64;
    const float* vb = v + base * 64;
    __shared__ float qt[64][65], kt[64][65], P[64][65], vt[64][65];
    __shared__ float red[4][64], rowm[64], rowl[64];
    int tid = threadIdx.x;
    int r = tid & 63, g = tid >> 6;
    for (int e = tid; e < 4096; e += 256) {
        int rr = e >> 6, d = e & 63;
        qt[rr][d] = qb[((size_t)(n0 + rr) << 6) + d];
    }
    if (tid < 64) { rowm[tid] = -1e30f; rowl[tid] = 0.f; }
    float acc[16];
    #pragma unroll
    for (int i = 0; i < 16; ++i) acc[i] = 0.f;
    for (int m0 = 0; m0 < 4096; m0 += 64) {
        for (int e = tid; e < 1024; e += 256) {
            int rr = e >> 4, c = (e & 15) << 2;
            float4 k4 = *(const float4*)(kb + ((size_t)(m0 + rr) << 6) + c);
            kt[rr][c] = k4.x; kt[rr][c + 1] = k4.y; kt[rr][c + 2] = k4.z; kt[rr][c + 3] = k4.w;
            float4 v4 = *(const float4*)(vb + ((size_t)(m0 + rr) << 6) + c);
            vt[rr][c] = v4.x; vt[rr][c + 1] = v4.y; vt[rr][c + 2] = v4.z; vt[rr][c + 3] = v4.w;
        }
        __syncthreads();
        float pmx = -1e30f;
        int mbase = g << 4;
        #pragma unroll 4
        for (int i = 0; i < 16; ++i) {
            int mm = mbase + i;
            float s = 0.f;
            #pragma unroll
            for (int d = 0; d < 64; ++d) s += qt[r][d] * kt[mm][d];
            P[r][mm] = s;
            pmx = fmaxf(pmx, s);
        }
        red[g][r] = pmx;
        __syncthreads();
        float nm = fmaxf(rowm[r], fmaxf(fmaxf(red[0][r], red[1][r]),
                                        fmaxf(red[2][r], red[3][r])));
        float fac = expf(rowm[r] - nm);
        __syncthreads();
        if (g == 0) rowm[r] = nm;
        float ps = 0.f;
        #pragma unroll 4
        for (int i = 0; i < 16; ++i) {
            int mm = mbase + i;
            float ev = expf(P[r][mm] - nm);
            P[r][mm] = ev;
            ps += ev;
        }
        red[g][r] = ps;
        __syncthreads();
        if (g == 0) rowl[r] = rowl[r] * fac + red[0][r] + red[1][r] + red[2][r] + red[3][r];
        #pragma unroll 4
        for (int i = 0; i < 16; ++i) {
            int d = (g << 4) + i;
            float s = 0.f;
            #pragma unroll
            for (int mm = 0; mm < 64; ++mm) s += P[r][mm] * vt[mm][d];
            acc[i] = acc[i] * fac + s;
        }
        __syncthreads();
    }
    float inv = 1.0f / rowl[r];
    size_t obase = ((size_t)b * 4096 + (size_t)(n0 + r)) * 768 + 11 * 64;
    #pragma unroll
    for (int i = 0; i < 16; ++i)
        ctx[obase + (g << 4) + i] = acc[i] * inv;
}

// ---------------------------------------------------------------------------
// K8: proj GEMM  out = ctx(16384x768) @ proj_w^T(768x768) + proj_b
// ---------------------------------------------------------------------------
__global__ __launch_bounds__(256) void gemm_proj(
    const float* __restrict__ X, const float* __restrict__ W,
    const float* __restrict__ bias, float* __restrict__ out)
{
    __shared__ float As[16][65];
    __shared__ float Bs[16][65];
    const int tid = threadIdx.x;
    const int brow = blockIdx.y << 6;
    const int bcol = blockIdx.x << 6;
    const int tx = tid & 15, ty = tid >> 4;
    const int lr = tid >> 2, lc = (tid & 3) << 2;
    float acc[4][4] = {};
    for (int k0 = 0; k0 < 768; k0 += 16) {
        float4 a = *(const float4*)(X + (size_t)(brow + lr) * 768 + k0 + lc);
        float4 b = *(const float4*)(W + (size_t)(bcol + lr) * 768 + k0 + lc);
        As[lc + 0][lr] = a.x; As[lc + 1][lr] = a.y; As[lc + 2][lr] = a.z; As[lc + 3][lr] = a.w;
        Bs[lc + 0][lr] = b.x; Bs[lc + 1][lr] = b.y; Bs[lc + 2][lr] = b.z; Bs[lc + 3][lr] = b.w;
        __syncthreads();
        #pragma unroll
        for (int kk = 0; kk < 16; ++kk) {
            float av[4], bv[4];
            #pragma unroll
            for (int i = 0; i < 4; ++i) av[i] = As[kk][(ty << 2) + i];
            #pragma unroll
            for (int j = 0; j < 4; ++j) bv[j] = Bs[kk][(tx << 2) + j];
            #pragma unroll
            for (int i = 0; i < 4; ++i)
                #pragma unroll
                for (int j = 0; j < 4; ++j)
                    acc[i][j] += av[i] * bv[j];
        }
        __syncthreads();
    }
    #pragma unroll
    for (int i = 0; i < 4; ++i) {
        int r = brow + (ty << 2) + i;
        #pragma unroll
        for (int j = 0; j < 4; ++j) {
            int c = bcol + (tx << 2) + j;
            out[(size_t)r * 768 + c] = acc[i][j] + bias[c];
        }
    }
}

// ---------------------------------------------------------------------------
extern "C" void kernel_launch(void* const* d_in, const int* in_sizes, int n_in,
                              void* d_out, int out_size, void* d_ws, size_t ws_size,
                              hipStream_t stream)
{
    const float* x      = (const float*)d_in[0];
    const float* qkv_w  = (const float*)d_in[1];
    const float* qkv_b  = (const float*)d_in[2];
    const float* proj_w = (const float*)d_in[3];
    const float* proj_b = (const float*)d_in[4];
    float* out = (float*)d_out;

    float* ws  = (float*)d_ws;
    const size_t QKV = (size_t)4 * 12 * 4096 * 64;   // 12,582,912
    float* q    = ws;
    float* k    = q + QKV;
    float* v    = k + QKV;
    float* ctx  = v + QKV;                            // 12,582,912
    float* scm  = ctx + QKV;                          // 44*64 (pad 4096)
    float* eB   = scm + 4096;                         // 44*4096
    float* den  = eB + 44 * 4096;                     // 11 (pad 64)
    float* pi_  = den + 64;                           // 44*4096
    float* Wb   = pi_ + 44 * 4096;                    // 44*64*65
    float* Tb   = Wb + 44 * 64 * 65;                  // 44*64*65

    gemm_qkv<<<dim3(36, 256), 256, 0, stream>>>(x, qkv_w, qkv_b, q, k, v);
    sc_max_kernel<<<44, 256, 0, stream>>>(q, k, scm);
    eb_kernel<<<44, 256, 0, stream>>>(q, k, scm, eB);
    norms_kernel<<<11, 256, 0, stream>>>(eB, den);
    pinv_kernel<<<44, 256, 0, stream>>>(eB, den, pi_);
    w_kernel<<<44, 256, 0, stream>>>(q, k, v, scm, Wb);
    pw_kernel<<<44, 256, 0, stream>>>(pi_, Wb, Tb);
    outp_kernel<<<dim3(64, 44), 256, 0, stream>>>(q, k, Tb, ctx);
    softmax_head_kernel<<<dim3(64, 4), 256, 0, stream>>>(q, k, v, ctx);
    gemm_proj<<<dim3(12, 256), 256, 0, stream>>>(ctx, proj_w, proj_b, out);
}

// Round 2
// 3804.468 us; speedup vs baseline: 1.6118x; 1.6118x over previous
//
#include <hip/hip_runtime.h>

// B=4, N=4096, C=768, H=12, D=64, M=64, PNP=11, SCALE=1/8

// ---------------------------------------------------------------------------
// K1: QKV GEMM  Y = X(16384x768) @ W^T(2304x768) + b, scatter to q/k/v (B,H,N,D)
// 128x128 tile, 8x8 per thread, fp32
// ---------------------------------------------------------------------------
__global__ __launch_bounds__(256) void gemm_qkv(
    const float* __restrict__ X, const float* __restrict__ W,
    const float* __restrict__ bias,
    float* __restrict__ q, float* __restrict__ k, float* __restrict__ v)
{
    __shared__ float As[16][132];
    __shared__ float Bs[16][132];
    const int tid = threadIdx.x;
    const int brow = blockIdx.y << 7;
    const int bcol = blockIdx.x << 7;
    const int tx = tid & 15, ty = tid >> 4;
    const int lr = tid >> 1, lc8 = (tid & 1) << 3;
    const float* Xr = X + (size_t)(brow + lr) * 768 + lc8;
    const float* Wr = W + (size_t)(bcol + lr) * 768 + lc8;
    float acc[8][8] = {};
    for (int k0 = 0; k0 < 768; k0 += 16) {
        float4 a0 = *(const float4*)(Xr + k0);
        float4 a1 = *(const float4*)(Xr + k0 + 4);
        float4 b0 = *(const float4*)(Wr + k0);
        float4 b1 = *(const float4*)(Wr + k0 + 4);
        __syncthreads();
        As[lc8+0][lr]=a0.x; As[lc8+1][lr]=a0.y; As[lc8+2][lr]=a0.z; As[lc8+3][lr]=a0.w;
        As[lc8+4][lr]=a1.x; As[lc8+5][lr]=a1.y; As[lc8+6][lr]=a1.z; As[lc8+7][lr]=a1.w;
        Bs[lc8+0][lr]=b0.x; Bs[lc8+1][lr]=b0.y; Bs[lc8+2][lr]=b0.z; Bs[lc8+3][lr]=b0.w;
        Bs[lc8+4][lr]=b1.x; Bs[lc8+5][lr]=b1.y; Bs[lc8+6][lr]=b1.z; Bs[lc8+7][lr]=b1.w;
        __syncthreads();
        #pragma unroll
        for (int kk = 0; kk < 16; ++kk) {
            float4 x0 = *(const float4*)&As[kk][ty << 3];
            float4 x1 = *(const float4*)&As[kk][(ty << 3) + 4];
            float4 y0 = *(const float4*)&Bs[kk][tx << 3];
            float4 y1 = *(const float4*)&Bs[kk][(tx << 3) + 4];
            float av[8] = {x0.x,x0.y,x0.z,x0.w,x1.x,x1.y,x1.z,x1.w};
            float bv[8] = {y0.x,y0.y,y0.z,y0.w,y1.x,y1.y,y1.z,y1.w};
            #pragma unroll
            for (int i = 0; i < 8; ++i)
                #pragma unroll
                for (int j = 0; j < 8; ++j)
                    acc[i][j] += av[i] * bv[j];
        }
    }
    // column metadata (same for all i)
    int cj[8], tj[8], hj[8], dj[8];
    float bj[8];
    #pragma unroll
    for (int j = 0; j < 8; ++j) {
        int c = bcol + (tx << 3) + j;
        cj[j] = c;
        int t = c / 768;
        int rem = c - t * 768;
        tj[j] = t; hj[j] = rem >> 6; dj[j] = rem & 63;
        bj[j] = bias[c];
    }
    #pragma unroll
    for (int i = 0; i < 8; ++i) {
        int r = brow + (ty << 3) + i;
        int b = r >> 12, n = r & 4095;
        #pragma unroll
        for (int j = 0; j < 8; ++j) {
            float val = acc[i][j] + bj[j];
            size_t idx = (((size_t)(b * 12 + hj[j]) << 12) + n) * 64 + dj[j];
            if (tj[j] == 0)      q[idx] = val * 0.125f;
            else if (tj[j] == 1) k[idx] = val;
            else                 v[idx] = val;
        }
    }
}

// ---------------------------------------------------------------------------
// K2a: partial sc_max over an n-chunk of 512: scmp[(bh*8+chunk)*64+m]
// ---------------------------------------------------------------------------
__global__ __launch_bounds__(256) void scmax_part(
    const float* __restrict__ q, const float* __restrict__ k,
    float* __restrict__ scmp)
{
    int chunk = blockIdx.x;          // 0..7
    int bh = blockIdx.y;             // 0..43
    int b = bh / 11, h = bh - b * 11;
    size_t base = ((size_t)(b * 12 + h)) << 12;
    const float* qb = q + base * 64;
    const float* kb = k + base * 64;
    __shared__ float qm[64][65];
    __shared__ float kt[64][65];
    __shared__ float red[4][64];
    int tid = threadIdx.x;
    for (int e = tid; e < 4096; e += 256) {
        int mm = e >> 6, d = e & 63;
        qm[mm][d] = qb[((size_t)mm << 12) + d];   // landmark rows n = m*64
    }
    int m = tid & 63, g = tid >> 6;
    float best = -1e30f;
    for (int t = 0; t < 8; ++t) {
        int n0 = (chunk << 9) + (t << 6);
        for (int e = tid; e < 1024; e += 256) {
            int rr = e >> 4, c = (e & 15) << 2;
            float4 k4 = *(const float4*)(kb + ((size_t)(n0 + rr) << 6) + c);
            kt[rr][c] = k4.x; kt[rr][c+1] = k4.y; kt[rr][c+2] = k4.z; kt[rr][c+3] = k4.w;
        }
        __syncthreads();
        for (int nn = g; nn < 64; nn += 4) {
            float s = 0.f;
            #pragma unroll
            for (int d = 0; d < 64; ++d) s += qm[m][d] * kt[nn][d];
            best = fmaxf(best, s);
        }
        __syncthreads();
    }
    red[g][m] = best;
    __syncthreads();
    if (tid < 64) {
        float v0 = fmaxf(fmaxf(red[0][tid], red[1][tid]),
                         fmaxf(red[2][tid], red[3][tid]));
        scmp[((bh << 3) + chunk) * 64 + tid] = v0;
    }
}

// K2b: reduce partial maxes: scm[bh*64+m] = max_c scmp
__global__ __launch_bounds__(256) void scmax_reduce(
    const float* __restrict__ scmp, float* __restrict__ scm)
{
    int gid = blockIdx.x * 256 + threadIdx.x;   // 0..2815
    if (gid >= 44 * 64) return;
    int bh = gid >> 6, m = gid & 63;
    float v0 = -1e30f;
    #pragma unroll
    for (int c = 0; c < 8; ++c)
        v0 = fmaxf(v0, scmp[((bh << 3) + c) * 64 + m]);
    scm[(bh << 6) + m] = v0;
}

// ---------------------------------------------------------------------------
// K3a: eB[b,h,m,l] = exp(clip(q_m[m]·k_m[l] - scmax[m], -88, inf))
// ---------------------------------------------------------------------------
__global__ __launch_bounds__(256) void eb_kernel(
    const float* __restrict__ q, const float* __restrict__ k,
    const float* __restrict__ scm, float* __restrict__ eB)
{
    int bh = blockIdx.x;
    int b = bh / 11, h = bh - b * 11;
    size_t base = ((size_t)(b * 12 + h)) << 12;
    const float* qb = q + base * 64;
    const float* kb = k + base * 64;
    __shared__ float qm[64][65], km[64][65];
    int tid = threadIdx.x;
    for (int e = tid; e < 4096; e += 256) {
        int mm = e >> 6, d = e & 63;
        qm[mm][d] = qb[((size_t)mm << 12) + d];
        km[mm][d] = kb[((size_t)mm << 12) + d];
    }
    __syncthreads();
    int m = tid >> 2, l0 = tid & 3;
    float smax = scm[(bh << 6) + m];
    for (int l = l0; l < 64; l += 4) {
        float s = 0.f;
        #pragma unroll
        for (int d = 0; d < 64; ++d) s += qm[m][d] * km[l][d];
        eB[((size_t)bh << 12) + (m << 6) + l] = expf(fmaxf(s - smax, -88.f));
    }
}

// ---------------------------------------------------------------------------
// K3b: per-head norms: denom[h] = max_{b,m} rowsum(eB) * max_{b,l} colsum(eB)
// ---------------------------------------------------------------------------
__global__ __launch_bounds__(256) void norms_kernel(
    const float* __restrict__ eB, float* __restrict__ denom)
{
    int h = blockIdx.x;
    int tid = threadIdx.x;
    int b = tid >> 6, idx = tid & 63;
    int bh = b * 11 + h;
    const float* E = eB + ((size_t)bh << 12);
    float rs = 0.f, cs = 0.f;
    #pragma unroll 4
    for (int l = 0; l < 64; ++l) rs += E[(idx << 6) + l];
    #pragma unroll 4
    for (int m = 0; m < 64; ++m) cs += E[(m << 6) + idx];
    __shared__ float r1[256], r2[256];
    r1[tid] = rs; r2[tid] = cs;
    __syncthreads();
    for (int s = 128; s > 0; s >>= 1) {
        if (tid < s) {
            r1[tid] = fmaxf(r1[tid], r1[tid + s]);
            r2[tid] = fmaxf(r2[tid], r2[tid + s]);
        }
        __syncthreads();
    }
    if (tid == 0) denom[h] = r1[0] * r2[0];
}

// ---------------------------------------------------------------------------
// K3c: pinv via 6 Newton iterations, one block per (b,h), all in LDS
// ---------------------------------------------------------------------------
__global__ __launch_bounds__(256) void pinv_kernel(
    const float* __restrict__ eB, const float* __restrict__ denom,
    float* __restrict__ pi_)
{
    int bh = blockIdx.x;
    int h = bh % 11;
    __shared__ float X[64][65], Z[64][65], XZ[64][65], TA[64][65], TB[64][65];
    int tid = threadIdx.x;
    float dn = denom[h];
    for (int e = tid; e < 4096; e += 256) {
        int m = e >> 6, l = e & 63;
        float xv = eB[((size_t)bh << 12) + e];
        X[m][l] = xv;
        Z[l][m] = xv / dn;
    }
    __syncthreads();
    int m = tid >> 2, l0 = tid & 3;
    for (int it = 0; it < 6; ++it) {
        for (int l = l0; l < 64; l += 4) {
            float s = 0.f;
            #pragma unroll
            for (int kk = 0; kk < 64; ++kk) s += X[m][kk] * Z[kk][l];
            XZ[m][l] = s;
        }
        __syncthreads();
        for (int l = l0; l < 64; l += 4) {
            float s = 0.f;
            #pragma unroll
            for (int kk = 0; kk < 64; ++kk) s += XZ[m][kk] * XZ[kk][l];
            TA[m][l] = 7.f * XZ[m][l] - s;
        }
        __syncthreads();
        for (int l = l0; l < 64; l += 4) {
            float s = 0.f;
            #pragma unroll
            for (int kk = 0; kk < 64; ++kk) s += XZ[m][kk] * TA[kk][l];
            TB[m][l] = 15.f * XZ[m][l] - s;
        }
        __syncthreads();
        for (int l = l0; l < 64; l += 4) {
            float s = 0.f;
            #pragma unroll
            for (int kk = 0; kk < 64; ++kk) s += Z[m][kk] * TB[kk][l];
            TA[m][l] = 13.f * Z[m][l] - s;
        }
        __syncthreads();
        for (int l = l0; l < 64; l += 4) Z[m][l] = 0.25f * TA[m][l];
        __syncthreads();
    }
    for (int e = tid; e < 4096; e += 256)
        pi_[((size_t)bh << 12) + e] = Z[e >> 6][e & 63];
}

// ---------------------------------------------------------------------------
// K4a: partial W over an n-chunk of 512
// ---------------------------------------------------------------------------
__global__ __launch_bounds__(256) void w_part(
    const float* __restrict__ q, const float* __restrict__ k,
    const float* __restrict__ v, const float* __restrict__ scm,
    float* __restrict__ wpart)
{
    int chunk = blockIdx.x;          // 0..7
    int bh = blockIdx.y;             // 0..43
    int b = bh / 11, h = bh - b * 11;
    size_t base = ((size_t)(b * 12 + h)) << 12;
    const float* qb = q + base * 64;
    const float* kb = k + base * 64;
    const float* vb = v + base * 64;
    __shared__ float qm[64][65], kt[64][65], S[64][65], vt[64][66];
    int tid = threadIdx.x;
    int m = tid & 63, g = tid >> 6;
    for (int e = tid; e < 4096; e += 256) {
        int mm = e >> 6, d = e & 63;
        qm[mm][d] = qb[((size_t)mm << 12) + d];
    }
    float smax = scm[(bh << 6) + m];
    float acc[17];
    #pragma unroll
    for (int t = 0; t < 17; ++t) acc[t] = 0.f;
    for (int tt = 0; tt < 8; ++tt) {
        int n0 = (chunk << 9) + (tt << 6);
        for (int e = tid; e < 1024; e += 256) {
            int rr = e >> 4, c = (e & 15) << 2;
            float4 k4 = *(const float4*)(kb + ((size_t)(n0 + rr) << 6) + c);
            kt[rr][c] = k4.x; kt[rr][c+1] = k4.y; kt[rr][c+2] = k4.z; kt[rr][c+3] = k4.w;
            float4 v4 = *(const float4*)(vb + ((size_t)(n0 + rr) << 6) + c);
            vt[rr][c] = v4.x; vt[rr][c+1] = v4.y; vt[rr][c+2] = v4.z; vt[rr][c+3] = v4.w;
        }
        if (tid < 64) vt[tid][64] = 1.0f;
        __syncthreads();
        for (int nn = g; nn < 64; nn += 4) {
            float s = 0.f;
            #pragma unroll
            for (int d = 0; d < 64; ++d) s += qm[m][d] * kt[nn][d];
            S[m][nn] = expf(s - smax);
        }
        __syncthreads();
        #pragma unroll
        for (int t = 0; t < 17; ++t) {
            int j = g + (t << 2);
            if (j > 64) break;
            float s = 0.f;
            #pragma unroll
            for (int nn = 0; nn < 64; ++nn) s += S[m][nn] * vt[nn][j];
            acc[t] += s;
        }
        __syncthreads();
    }
    size_t obase = (size_t)((bh << 3) + chunk) * 4160 + (size_t)m * 65;
    #pragma unroll
    for (int t = 0; t < 17; ++t) {
        int j = g + (t << 2);
        if (j > 64) break;
        wpart[obase + j] = acc[t];
    }
}

// K4b: Wb[bh] = sum over 8 chunks
__global__ __launch_bounds__(256) void w_reduce(
    const float* __restrict__ wpart, float* __restrict__ Wb)
{
    int bh = blockIdx.x;
    int tid = threadIdx.x;
    for (int e = tid; e < 4160; e += 256) {
        float s = 0.f;
        #pragma unroll
        for (int c = 0; c < 8; ++c)
            s += wpart[(size_t)((bh << 3) + c) * 4160 + e];
        Wb[(size_t)bh * 4160 + e] = s;
    }
}

// ---------------------------------------------------------------------------
// K5: T = pi @ W  (64x64 @ 64x65, one block per bh)
// ---------------------------------------------------------------------------
__global__ __launch_bounds__(256) void pw_kernel(
    const float* __restrict__ pi_, const float* __restrict__ Wb,
    float* __restrict__ Tb)
{
    int bh = blockIdx.x;
    __shared__ float P[64][65];
    __shared__ float Wl[64][66];
    int tid = threadIdx.x;
    for (int e = tid; e < 4096; e += 256)
        P[e >> 6][e & 63] = pi_[((size_t)bh << 12) + e];
    for (int e = tid; e < 64 * 65; e += 256) {
        int l = e / 65, j = e - l * 65;
        Wl[l][j] = Wb[(size_t)bh * 4160 + e];
    }
    __syncthreads();
    int m = tid & 63, g = tid >> 6;
    #pragma unroll
    for (int t = 0; t < 17; ++t) {
        int j = g + (t << 2);
        if (j > 64) break;
        float s = 0.f;
        #pragma unroll
        for (int l = 0; l < 64; ++l) s += P[m][l] * Wl[l][j];
        Tb[(size_t)((bh << 6) + m) * 65 + j] = s;
    }
}

// ---------------------------------------------------------------------------
// K6: out_p tile: eA = exp(q·k_m^T - rowmax); prod = eA@T; ctx = prod/den
// ---------------------------------------------------------------------------
__global__ __launch_bounds__(256) void outp_kernel(
    const float* __restrict__ q, const float* __restrict__ k,
    const float* __restrict__ Tb, float* __restrict__ ctx)
{
    int bh = blockIdx.y;
    int b = bh / 11, h = bh - b * 11;
    int n0 = blockIdx.x << 6;
    size_t base = ((size_t)(b * 12 + h)) << 12;
    const float* qb = q + base * 64;
    const float* kb = k + base * 64;
    __shared__ float qt[64][65];
    __shared__ float kmprod[64][66];
    __shared__ float S[64][65];
    __shared__ float Tl[64][66];
    __shared__ float red[4][64];
    int tid = threadIdx.x;
    for (int e = tid; e < 4096; e += 256) {
        int rr = e >> 6, d = e & 63;
        qt[rr][d] = qb[((size_t)(n0 + rr) << 6) + d];
        kmprod[rr][d] = kb[((size_t)rr << 12) + d];
    }
    for (int e = tid; e < 64 * 65; e += 256) {
        int mm = e / 65, j = e - mm * 65;
        Tl[mm][j] = Tb[(size_t)((bh << 6) + mm) * 65 + j];
    }
    __syncthreads();
    int r = tid & 63, g = tid >> 6;
    for (int m = g; m < 64; m += 4) {
        float s = 0.f;
        #pragma unroll
        for (int d = 0; d < 64; ++d) s += qt[r][d] * kmprod[m][d];
        S[r][m] = s;
    }
    float pm = -1e30f;
    for (int m = g; m < 64; m += 4) pm = fmaxf(pm, S[r][m]);
    red[g][r] = pm;
    __syncthreads();
    float rmax = fmaxf(fmaxf(red[0][r], red[1][r]), fmaxf(red[2][r], red[3][r]));
    for (int m = g; m < 64; m += 4) S[r][m] = expf(S[r][m] - rmax);
    __syncthreads();
    #pragma unroll
    for (int t = 0; t < 17; ++t) {
        int j = g + (t << 2);
        if (j > 64) break;
        float s = 0.f;
        #pragma unroll
        for (int m = 0; m < 64; ++m) s += S[r][m] * Tl[m][j];
        kmprod[r][j] = s;
    }
    __syncthreads();
    float dnm = fmaxf(kmprod[r][64], 1e-8f);
    float inv = 1.0f / dnm;
    size_t obase = ((size_t)b * 4096 + (size_t)(n0 + r)) * 768 + h * 64;
    for (int d = g; d < 64; d += 4)
        ctx[obase + d] = kmprod[r][d] * inv;
}

// ---------------------------------------------------------------------------
// K7a: softmax head (h=11) flash partial over a KV chunk of 1024
// grid (64 tiles, 4 chunks, 4 batches)
// ---------------------------------------------------------------------------
__global__ __launch_bounds__(256) void softmax_part(
    const float* __restrict__ q, const float* __restrict__ k,
    const float* __restrict__ v,
    float* __restrict__ pacc, float* __restrict__ pm, float* __restrict__ pl)
{
    int bx = blockIdx.x;            // q tile
    int cy = blockIdx.y;            // kv chunk
    int b  = blockIdx.z;
    int n0 = bx << 6;
    size_t base = ((size_t)(b * 12 + 11)) << 12;
    const float* qb = q + base * 64;
    const float* kb = k + base * 64;
    const float* vb = v + base * 64;
    __shared__ float qt[64][65], kt[64][65], P[64][65], vt[64][65];
    __shared__ float red[4][64], rowm[64], rowl[64];
    int tid = threadIdx.x;
    int r = tid & 63, g = tid >> 6;
    for (int e = tid; e < 4096; e += 256) {
        int rr = e >> 6, d = e & 63;
        qt[rr][d] = qb[((size_t)(n0 + rr) << 6) + d];
    }
    if (tid < 64) { rowm[tid] = -1e30f; rowl[tid] = 0.f; }
    float acc[16];
    #pragma unroll
    for (int i = 0; i < 16; ++i) acc[i] = 0.f;
    for (int t = 0; t < 16; ++t) {
        int m0 = (cy << 10) + (t << 6);
        for (int e = tid; e < 1024; e += 256) {
            int rr = e >> 4, c = (e & 15) << 2;
            float4 k4 = *(const float4*)(kb + ((size_t)(m0 + rr) << 6) + c);
            kt[rr][c] = k4.x; kt[rr][c+1] = k4.y; kt[rr][c+2] = k4.z; kt[rr][c+3] = k4.w;
            float4 v4 = *(const float4*)(vb + ((size_t)(m0 + rr) << 6) + c);
            vt[rr][c] = v4.x; vt[rr][c+1] = v4.y; vt[rr][c+2] = v4.z; vt[rr][c+3] = v4.w;
        }
        __syncthreads();
        float pmx = -1e30f;
        int mbase = g << 4;
        #pragma unroll 4
        for (int i = 0; i < 16; ++i) {
            int mm = mbase + i;
            float s = 0.f;
            #pragma unroll
            for (int d = 0; d < 64; ++d) s += qt[r][d] * kt[mm][d];
            P[r][mm] = s;
            pmx = fmaxf(pmx, s);
        }
        red[g][r] = pmx;
        __syncthreads();
        float nm = fmaxf(rowm[r], fmaxf(fmaxf(red[0][r], red[1][r]),
                                        fmaxf(red[2][r], red[3][r])));
        float fac = expf(rowm[r] - nm);
        __syncthreads();
        if (g == 0) rowm[r] = nm;
        float ps = 0.f;
        #pragma unroll 4
        for (int i = 0; i < 16; ++i) {
            int mm = mbase + i;
            float ev = expf(P[r][mm] - nm);
            P[r][mm] = ev;
            ps += ev;
        }
        red[g][r] = ps;
        __syncthreads();
        if (g == 0) rowl[r] = rowl[r] * fac + red[0][r] + red[1][r] + red[2][r] + red[3][r];
        #pragma unroll 4
        for (int i = 0; i < 16; ++i) {
            int d = (g << 4) + i;
            float s = 0.f;
            #pragma unroll
            for (int mm = 0; mm < 64; ++mm) s += P[r][mm] * vt[mm][d];
            acc[i] = acc[i] * fac + s;
        }
        __syncthreads();
    }
    // write partials (unnormalized)
    int slot = (b * 4 + cy) * 64 + bx;
    size_t abase = (size_t)slot * 4096 + (size_t)r * 64 + (g << 4);
    #pragma unroll
    for (int i = 0; i < 16; ++i) pacc[abase + i] = acc[i];
    if (tid < 64) {
        pm[(size_t)slot * 64 + tid] = rowm[tid];
        pl[(size_t)slot * 64 + tid] = rowl[tid];
    }
}

// K7b: merge 4 chunk partials -> ctx head 11
__global__ __launch_bounds__(256) void softmax_merge(
    const float* __restrict__ pacc, const float* __restrict__ pm,
    const float* __restrict__ pl, float* __restrict__ ctx)
{
    int bx = blockIdx.x;            // q tile
    int b  = blockIdx.y;
    int tid = threadIdx.x;
    int r = tid & 63, g = tid >> 6;
    float mc[4];
    float mt = -1e30f;
    #pragma unroll
    for (int c = 0; c < 4; ++c) {
        mc[c] = pm[(size_t)((b * 4 + c) * 64 + bx) * 64 + r];
        mt = fmaxf(mt, mc[c]);
    }
    float fac[4], lt = 0.f;
    #pragma unroll
    for (int c = 0; c < 4; ++c) {
        fac[c] = expf(mc[c] - mt);
        lt += fac[c] * pl[(size_t)((b * 4 + c) * 64 + bx) * 64 + r];
    }
    float inv = 1.0f / lt;
    size_t obase = ((size_t)b * 4096 + (size_t)((bx << 6) + r)) * 768 + 11 * 64 + (g << 4);
    #pragma unroll
    for (int i = 0; i < 16; ++i) {
        float s = 0.f;
        #pragma unroll
        for (int c = 0; c < 4; ++c)
            s += fac[c] * pacc[(size_t)((b * 4 + c) * 64 + bx) * 4096 + (size_t)r * 64 + (g << 4) + i];
        ctx[obase + i] = s * inv;
    }
}

// ---------------------------------------------------------------------------
// K8: proj GEMM  out = ctx(16384x768) @ proj_w^T(768x768) + proj_b, 128x128
// ---------------------------------------------------------------------------
__global__ __launch_bounds__(256) void gemm_proj(
    const float* __restrict__ X, const float* __restrict__ W,
    const float* __restrict__ bias, float* __restrict__ out)
{
    __shared__ float As[16][132];
    __shared__ float Bs[16][132];
    const int tid = threadIdx.x;
    const int brow = blockIdx.y << 7;
    const int bcol = blockIdx.x << 7;
    const int tx = tid & 15, ty = tid >> 4;
    const int lr = tid >> 1, lc8 = (tid & 1) << 3;
    const float* Xr = X + (size_t)(brow + lr) * 768 + lc8;
    const float* Wr = W + (size_t)(bcol + lr) * 768 + lc8;
    float acc[8][8] = {};
    for (int k0 = 0; k0 < 768; k0 += 16) {
        float4 a0 = *(const float4*)(Xr + k0);
        float4 a1 = *(const float4*)(Xr + k0 + 4);
        float4 b0 = *(const float4*)(Wr + k0);
        float4 b1 = *(const float4*)(Wr + k0 + 4);
        __syncthreads();
        As[lc8+0][lr]=a0.x; As[lc8+1][lr]=a0.y; As[lc8+2][lr]=a0.z; As[lc8+3][lr]=a0.w;
        As[lc8+4][lr]=a1.x; As[lc8+5][lr]=a1.y; As[lc8+6][lr]=a1.z; As[lc8+7][lr]=a1.w;
        Bs[lc8+0][lr]=b0.x; Bs[lc8+1][lr]=b0.y; Bs[lc8+2][lr]=b0.z; Bs[lc8+3][lr]=b0.w;
        Bs[lc8+4][lr]=b1.x; Bs[lc8+5][lr]=b1.y; Bs[lc8+6][lr]=b1.z; Bs[lc8+7][lr]=b1.w;
        __syncthreads();
        #pragma unroll
        for (int kk = 0; kk < 16; ++kk) {
            float4 x0 = *(const float4*)&As[kk][ty << 3];
            float4 x1 = *(const float4*)&As[kk][(ty << 3) + 4];
            float4 y0 = *(const float4*)&Bs[kk][tx << 3];
            float4 y1 = *(const float4*)&Bs[kk][(tx << 3) + 4];
            float av[8] = {x0.x,x0.y,x0.z,x0.w,x1.x,x1.y,x1.z,x1.w};
            float bv[8] = {y0.x,y0.y,y0.z,y0.w,y1.x,y1.y,y1.z,y1.w};
            #pragma unroll
            for (int i = 0; i < 8; ++i)
                #pragma unroll
                for (int j = 0; j < 8; ++j)
                    acc[i][j] += av[i] * bv[j];
        }
    }
    #pragma unroll
    for (int i = 0; i < 8; ++i) {
        int r = brow + (ty << 3) + i;
        #pragma unroll
        for (int j = 0; j < 8; ++j) {
            int c = bcol + (tx << 3) + j;
            out[(size_t)r * 768 + c] = acc[i][j] + bias[c];
        }
    }
}

// ---------------------------------------------------------------------------
extern "C" void kernel_launch(void* const* d_in, const int* in_sizes, int n_in,
                              void* d_out, int out_size, void* d_ws, size_t ws_size,
                              hipStream_t stream)
{
    const float* x      = (const float*)d_in[0];
    const float* qkv_w  = (const float*)d_in[1];
    const float* qkv_b  = (const float*)d_in[2];
    const float* proj_w = (const float*)d_in[3];
    const float* proj_b = (const float*)d_in[4];
    float* out = (float*)d_out;

    float* ws  = (float*)d_ws;
    const size_t QKV = (size_t)4 * 12 * 4096 * 64;   // 12,582,912
    float* q    = ws;
    float* k    = q + QKV;
    float* v    = k + QKV;
    float* ctx  = v + QKV;
    float* scm  = ctx + QKV;                          // 44*64 (pad 4096)
    float* eB   = scm + 4096;                         // 44*4096
    float* den  = eB + 44 * 4096;                     // 11 (pad 64)
    float* pi_  = den + 64;                           // 44*4096
    float* Wb   = pi_ + 44 * 4096;                    // 44*4160
    float* Tb   = Wb + 44 * 4160;                     // 44*64*65

    // scratch in d_out (dead before gemm_proj writes the real output)
    float* pacc  = out;                               // 4*4*64*4096 = 4,194,304
    float* pm    = pacc + 4194304;                    // 65,536
    float* pl    = pm + 65536;                        // 65,536
    float* wpart = pl + 65536;                        // 44*8*4160 = 1,464,320
    float* scmp  = wpart + 1464320;                   // 44*8*64 = 22,528
    // total 5,812,224 floats < out_size (12,582,912)

    gemm_qkv<<<dim3(18, 128), 256, 0, stream>>>(x, qkv_w, qkv_b, q, k, v);
    scmax_part<<<dim3(8, 44), 256, 0, stream>>>(q, k, scmp);
    scmax_reduce<<<11, 256, 0, stream>>>(scmp, scm);
    eb_kernel<<<44, 256, 0, stream>>>(q, k, scm, eB);
    norms_kernel<<<11, 256, 0, stream>>>(eB, den);
    pinv_kernel<<<44, 256, 0, stream>>>(eB, den, pi_);
    w_part<<<dim3(8, 44), 256, 0, stream>>>(q, k, v, scm, wpart);
    w_reduce<<<44, 256, 0, stream>>>(wpart, Wb);
    pw_kernel<<<44, 256, 0, stream>>>(pi_, Wb, Tb);
    outp_kernel<<<dim3(64, 44), 256, 0, stream>>>(q, k, Tb, ctx);
    softmax_part<<<dim3(64, 4, 4), 256, 0, stream>>>(q, k, v, pacc, pm, pl);
    softmax_merge<<<dim3(64, 4), 256, 0, stream>>>(pacc, pm, pl, ctx);
    gemm_proj<<<dim3(6, 128), 256, 0, stream>>>(ctx, proj_w, proj_b, out);
}

// Round 3
// 1686.527 us; speedup vs baseline: 3.6360x; 2.2558x over previous
//
#include <hip/hip_runtime.h>

// B=4, N=4096, C=768, H=12, D=64, M=64, PNP=11, SCALE=1/8

typedef __attribute__((ext_vector_type(8))) short short8;
typedef __attribute__((ext_vector_type(4))) float f32x4;

static __device__ __forceinline__ unsigned short f2bf(float f) {
    union { float f; unsigned u; } x; x.f = f;
    unsigned r = x.u + 0x7fffu + ((x.u >> 16) & 1u);   // RNE
    return (unsigned short)(r >> 16);
}

// ---------------------------------------------------------------------------
// K1: QKV GEMM  Y = X(16384x768) @ W^T(2304x768) + b, scatter to q/k/v (B,H,N,D)
// 128x128 tile, 8x8 per thread, fp32  (numerically critical path: stays fp32)
// ---------------------------------------------------------------------------
__global__ __launch_bounds__(256) void gemm_qkv(
    const float* __restrict__ X, const float* __restrict__ W,
    const float* __restrict__ bias,
    float* __restrict__ q, float* __restrict__ k, float* __restrict__ v)
{
    __shared__ float As[16][132];
    __shared__ float Bs[16][132];
    const int tid = threadIdx.x;
    const int brow = blockIdx.y << 7;
    const int bcol = blockIdx.x << 7;
    const int tx = tid & 15, ty = tid >> 4;
    const int lr = tid >> 1, lc8 = (tid & 1) << 3;
    const float* Xr = X + (size_t)(brow + lr) * 768 + lc8;
    const float* Wr = W + (size_t)(bcol + lr) * 768 + lc8;
    float acc[8][8] = {};
    for (int k0 = 0; k0 < 768; k0 += 16) {
        float4 a0 = *(const float4*)(Xr + k0);
        float4 a1 = *(const float4*)(Xr + k0 + 4);
        float4 b0 = *(const float4*)(Wr + k0);
        float4 b1 = *(const float4*)(Wr + k0 + 4);
        __syncthreads();
        As[lc8+0][lr]=a0.x; As[lc8+1][lr]=a0.y; As[lc8+2][lr]=a0.z; As[lc8+3][lr]=a0.w;
        As[lc8+4][lr]=a1.x; As[lc8+5][lr]=a1.y; As[lc8+6][lr]=a1.z; As[lc8+7][lr]=a1.w;
        Bs[lc8+0][lr]=b0.x; Bs[lc8+1][lr]=b0.y; Bs[lc8+2][lr]=b0.z; Bs[lc8+3][lr]=b0.w;
        Bs[lc8+4][lr]=b1.x; Bs[lc8+5][lr]=b1.y; Bs[lc8+6][lr]=b1.z; Bs[lc8+7][lr]=b1.w;
        __syncthreads();
        #pragma unroll
        for (int kk = 0; kk < 16; ++kk) {
            float4 x0 = *(const float4*)&As[kk][ty << 3];
            float4 x1 = *(const float4*)&As[kk][(ty << 3) + 4];
            float4 y0 = *(const float4*)&Bs[kk][tx << 3];
            float4 y1 = *(const float4*)&Bs[kk][(tx << 3) + 4];
            float av[8] = {x0.x,x0.y,x0.z,x0.w,x1.x,x1.y,x1.z,x1.w};
            float bv[8] = {y0.x,y0.y,y0.z,y0.w,y1.x,y1.y,y1.z,y1.w};
            #pragma unroll
            for (int i = 0; i < 8; ++i)
                #pragma unroll
                for (int j = 0; j < 8; ++j)
                    acc[i][j] += av[i] * bv[j];
        }
    }
    int tj[8], hj[8], dj[8];
    float bj[8];
    #pragma unroll
    for (int j = 0; j < 8; ++j) {
        int c = bcol + (tx << 3) + j;
        int t = c / 768;
        int rem = c - t * 768;
        tj[j] = t; hj[j] = rem >> 6; dj[j] = rem & 63;
        bj[j] = bias[c];
    }
    #pragma unroll
    for (int i = 0; i < 8; ++i) {
        int r = brow + (ty << 3) + i;
        int b = r >> 12, n = r & 4095;
        #pragma unroll
        for (int j = 0; j < 8; ++j) {
            float val = acc[i][j] + bj[j];
            size_t idx = (((size_t)(b * 12 + hj[j]) << 12) + n) * 64 + dj[j];
            if (tj[j] == 0)      q[idx] = val * 0.125f;
            else if (tj[j] == 1) k[idx] = val;
            else                 v[idx] = val;
        }
    }
}

// ---------------------------------------------------------------------------
// K2: fused flash pass for SC: online max + W-partial per 512-n chunk (fp32)
// grid (8 chunks, 44 bh). 4x4 register tiles, transposed LDS, float4 reads.
// ---------------------------------------------------------------------------
__global__ __launch_bounds__(256) void wflash(
    const float* __restrict__ q, const float* __restrict__ k,
    const float* __restrict__ v,
    float* __restrict__ wacc, float* __restrict__ wl, float* __restrict__ wm)
{
    int chunk = blockIdx.x;
    int bh = blockIdx.y;
    int b = bh / 11, h = bh - b * 11;
    size_t base = ((size_t)(b * 12 + h)) << 12;
    const float* qb = q + base * 64;
    const float* kb = k + base * 64;
    const float* vb = v + base * 64;
    __shared__ float qmT[64][68];   // [d][m] landmarks transposed
    __shared__ float ktT[64][68];   // [d][n]
    __shared__ float vt [64][68];   // [n][j]
    __shared__ float pT [64][68];   // [n][m]
    __shared__ float rmax[64][16];
    __shared__ float mrun[64], fac[64];
    int tid = threadIdx.x;
    int tx = tid & 15, ty = tid >> 4;
    int rr = tid >> 2, dg = (tid & 3) << 4;
    {   // landmarks: q row n = m*64
        const float* qrow = qb + ((size_t)rr << 12) + dg;
        #pragma unroll
        for (int i = 0; i < 16; i += 4) {
            float4 f = *(const float4*)(qrow + i);
            qmT[dg+i][rr] = f.x; qmT[dg+i+1][rr] = f.y;
            qmT[dg+i+2][rr] = f.z; qmT[dg+i+3][rr] = f.w;
        }
    }
    if (tid < 64) mrun[tid] = -1e30f;
    float acc4[4][4] = {};
    float lsum[4] = {};
    for (int t = 0; t < 8; ++t) {
        int n0 = (chunk << 9) + (t << 6);
        __syncthreads();   // prev tile's pT/vt reads done; qmT visible
        const float* krow = kb + (((size_t)(n0 + rr)) << 6) + dg;
        #pragma unroll
        for (int i = 0; i < 16; i += 4) {
            float4 f = *(const float4*)(krow + i);
            ktT[dg+i][rr] = f.x; ktT[dg+i+1][rr] = f.y;
            ktT[dg+i+2][rr] = f.z; ktT[dg+i+3][rr] = f.w;
        }
        const float* vrow = vb + (((size_t)(n0 + rr)) << 6) + dg;
        #pragma unroll
        for (int i = 0; i < 16; i += 4)
            *(float4*)&vt[rr][dg + i] = *(const float4*)(vrow + i);
        __syncthreads();
        float s4[4][4];
        #pragma unroll
        for (int i = 0; i < 4; ++i)
            #pragma unroll
            for (int j = 0; j < 4; ++j) s4[i][j] = 0.f;
        #pragma unroll 4
        for (int d = 0; d < 64; ++d) {
            float4 a  = *(const float4*)&qmT[d][ty << 2];
            float4 bb = *(const float4*)&ktT[d][tx << 2];
            float av[4] = {a.x,a.y,a.z,a.w};
            float bv[4] = {bb.x,bb.y,bb.z,bb.w};
            #pragma unroll
            for (int i = 0; i < 4; ++i)
                #pragma unroll
                for (int j = 0; j < 4; ++j)
                    s4[i][j] += av[i] * bv[j];
        }
        #pragma unroll
        for (int i = 0; i < 4; ++i) {
            float tm = fmaxf(fmaxf(s4[i][0], s4[i][1]), fmaxf(s4[i][2], s4[i][3]));
            rmax[(ty << 2) + i][tx] = tm;
        }
        __syncthreads();
        if (tid < 64) {
            float mx = rmax[tid][0];
            #pragma unroll
            for (int c = 1; c < 16; ++c) mx = fmaxf(mx, rmax[tid][c]);
            float mn = fmaxf(mrun[tid], mx);
            fac[tid] = expf(mrun[tid] - mn);
            mrun[tid] = mn;
        }
        __syncthreads();
        #pragma unroll
        for (int i = 0; i < 4; ++i) {
            int m = (ty << 2) + i;
            float f = fac[m], mr = mrun[m];
            float ls = lsum[i] * f;
            #pragma unroll
            for (int j = 0; j < 4; ++j) {
                acc4[i][j] *= f;
                float p = expf(s4[i][j] - mr);
                ls += p;
                pT[(tx << 2) + j][m] = p;
            }
            lsum[i] = ls;
        }
        __syncthreads();
        #pragma unroll 4
        for (int n = 0; n < 64; ++n) {
            float4 pp = *(const float4*)&pT[n][ty << 2];
            float4 vv = *(const float4*)&vt[n][tx << 2];
            float pa[4] = {pp.x,pp.y,pp.z,pp.w};
            float va[4] = {vv.x,vv.y,vv.z,vv.w};
            #pragma unroll
            for (int i = 0; i < 4; ++i)
                #pragma unroll
                for (int j = 0; j < 4; ++j)
                    acc4[i][j] += pa[i] * va[j];
        }
    }
    int cidx = (bh << 3) + chunk;
    #pragma unroll
    for (int i = 0; i < 4; ++i)
        #pragma unroll
        for (int j = 0; j < 4; ++j)
            wacc[((size_t)cidx << 12) + ((size_t)((ty << 2) + i) << 6) + (tx << 2) + j] = acc4[i][j];
    __syncthreads();
    #pragma unroll
    for (int i = 0; i < 4; ++i) rmax[(ty << 2) + i][tx] = lsum[i];
    __syncthreads();
    if (tid < 64) {
        float s = 0.f;
        #pragma unroll
        for (int c = 0; c < 16; ++c) s += rmax[tid][c];
        wl[cidx * 64 + tid] = s;
        wm[cidx * 64 + tid] = mrun[tid];
    }
}

// K2b: merge chunk partials -> Wb (65 cols, col 64 = ones-column) + scm
__global__ __launch_bounds__(256) void wmerge(
    const float* __restrict__ wacc, const float* __restrict__ wl,
    const float* __restrict__ wm,
    float* __restrict__ Wb, float* __restrict__ scm)
{
    int bh = blockIdx.x;
    int tid = threadIdx.x;
    __shared__ float fcs[8][64];
    if (tid < 64) {
        float mx = -1e30f;
        #pragma unroll
        for (int c = 0; c < 8; ++c)
            mx = fmaxf(mx, wm[((bh << 3) + c) * 64 + tid]);
        scm[(bh << 6) + tid] = mx;
        #pragma unroll
        for (int c = 0; c < 8; ++c)
            fcs[c][tid] = expf(wm[((bh << 3) + c) * 64 + tid] - mx);
    }
    __syncthreads();
    for (int e = tid; e < 4096; e += 256) {
        int m = e >> 6, j = e & 63;
        float s = 0.f;
        #pragma unroll
        for (int c = 0; c < 8; ++c)
            s += fcs[c][m] * wacc[((size_t)((bh << 3) + c) << 12) + e];
        Wb[(size_t)bh * 4160 + m * 65 + j] = s;
    }
    if (tid < 64) {
        float s = 0.f;
        #pragma unroll
        for (int c = 0; c < 8; ++c)
            s += fcs[c][tid] * wl[((bh << 3) + c) * 64 + tid];
        Wb[(size_t)bh * 4160 + tid * 65 + 64] = s;
    }
}

// ---------------------------------------------------------------------------
// K3a: eB[b,h,m,l] = exp(clip(q_m[m]·k_m[l] - scmax[m], -88, inf))  (fp32)
// ---------------------------------------------------------------------------
__global__ __launch_bounds__(256) void eb_kernel(
    const float* __restrict__ q, const float* __restrict__ k,
    const float* __restrict__ scm, float* __restrict__ eB)
{
    int bh = blockIdx.x;
    int b = bh / 11, h = bh - b * 11;
    size_t base = ((size_t)(b * 12 + h)) << 12;
    const float* qb = q + base * 64;
    const float* kb = k + base * 64;
    __shared__ float qm[64][65], km[64][65];
    int tid = threadIdx.x;
    for (int e = tid; e < 4096; e += 256) {
        int mm = e >> 6, d = e & 63;
        qm[mm][d] = qb[((size_t)mm << 12) + d];
        km[mm][d] = kb[((size_t)mm << 12) + d];
    }
    __syncthreads();
    int m = tid >> 2, l0 = tid & 3;
    float smax = scm[(bh << 6) + m];
    for (int l = l0; l < 64; l += 4) {
        float s = 0.f;
        #pragma unroll
        for (int d = 0; d < 64; ++d) s += qm[m][d] * km[l][d];
        eB[((size_t)bh << 12) + (m << 6) + l] = expf(fmaxf(s - smax, -88.f));
    }
}

// ---------------------------------------------------------------------------
// K3b: per-head norms
// ---------------------------------------------------------------------------
__global__ __launch_bounds__(256) void norms_kernel(
    const float* __restrict__ eB, float* __restrict__ denom)
{
    int h = blockIdx.x;
    int tid = threadIdx.x;
    int b = tid >> 6, idx = tid & 63;
    int bh = b * 11 + h;
    const float* E = eB + ((size_t)bh << 12);
    float rs = 0.f, cs = 0.f;
    #pragma unroll 4
    for (int l = 0; l < 64; ++l) rs += E[(idx << 6) + l];
    #pragma unroll 4
    for (int m = 0; m < 64; ++m) cs += E[(m << 6) + idx];
    __shared__ float r1[256], r2[256];
    r1[tid] = rs; r2[tid] = cs;
    __syncthreads();
    for (int s = 128; s > 0; s >>= 1) {
        if (tid < s) {
            r1[tid] = fmaxf(r1[tid], r1[tid + s]);
            r2[tid] = fmaxf(r2[tid], r2[tid + s]);
        }
        __syncthreads();
    }
    if (tid == 0) denom[h] = r1[0] * r2[0];
}

// ---------------------------------------------------------------------------
// K3c: pinv via 6 Newton iterations (fp32, unchanged — numerically critical)
// ---------------------------------------------------------------------------
__global__ __launch_bounds__(256) void pinv_kernel(
    const float* __restrict__ eB, const float* __restrict__ denom,
    float* __restrict__ pi_)
{
    int bh = blockIdx.x;
    int h = bh % 11;
    __shared__ float X[64][65], Z[64][65], XZ[64][65], TA[64][65], TB[64][65];
    int tid = threadIdx.x;
    float dn = denom[h];
    for (int e = tid; e < 4096; e += 256) {
        int m = e >> 6, l = e & 63;
        float xv = eB[((size_t)bh << 12) + e];
        X[m][l] = xv;
        Z[l][m] = xv / dn;
    }
    __syncthreads();
    int m = tid >> 2, l0 = tid & 3;
    for (int it = 0; it < 6; ++it) {
        for (int l = l0; l < 64; l += 4) {
            float s = 0.f;
            #pragma unroll
            for (int kk = 0; kk < 64; ++kk) s += X[m][kk] * Z[kk][l];
            XZ[m][l] = s;
        }
        __syncthreads();
        for (int l = l0; l < 64; l += 4) {
            float s = 0.f;
            #pragma unroll
            for (int kk = 0; kk < 64; ++kk) s += XZ[m][kk] * XZ[kk][l];
            TA[m][l] = 7.f * XZ[m][l] - s;
        }
        __syncthreads();
        for (int l = l0; l < 64; l += 4) {
            float s = 0.f;
            #pragma unroll
            for (int kk = 0; kk < 64; ++kk) s += XZ[m][kk] * TA[kk][l];
            TB[m][l] = 15.f * XZ[m][l] - s;
        }
        __syncthreads();
        for (int l = l0; l < 64; l += 4) {
            float s = 0.f;
            #pragma unroll
            for (int kk = 0; kk < 64; ++kk) s += Z[m][kk] * TB[kk][l];
            TA[m][l] = 13.f * Z[m][l] - s;
        }
        __syncthreads();
        for (int l = l0; l < 64; l += 4) Z[m][l] = 0.25f * TA[m][l];
        __syncthreads();
    }
    for (int e = tid; e < 4096; e += 256)
        pi_[((size_t)bh << 12) + e] = Z[e >> 6][e & 63];
}

// ---------------------------------------------------------------------------
// K5: T = pi @ W  (64x64 @ 64x65)
// ---------------------------------------------------------------------------
__global__ __launch_bounds__(256) void pw_kernel(
    const float* __restrict__ pi_, const float* __restrict__ Wb,
    float* __restrict__ Tb)
{
    int bh = blockIdx.x;
    __shared__ float P[64][65];
    __shared__ float Wl[64][66];
    int tid = threadIdx.x;
    for (int e = tid; e < 4096; e += 256)
        P[e >> 6][e & 63] = pi_[((size_t)bh << 12) + e];
    for (int e = tid; e < 64 * 65; e += 256) {
        int l = e / 65, j = e - l * 65;
        Wl[l][j] = Wb[(size_t)bh * 4160 + e];
    }
    __syncthreads();
    int m = tid & 63, g = tid >> 6;
    #pragma unroll
    for (int t = 0; t < 17; ++t) {
        int j = g + (t << 2);
        if (j > 64) break;
        float s = 0.f;
        #pragma unroll
        for (int l = 0; l < 64; ++l) s += P[m][l] * Wl[l][j];
        Tb[(size_t)((bh << 6) + m) * 65 + j] = s;
    }
}

// ---------------------------------------------------------------------------
// K6: out_p tile (register-tiled fp32): eA = exp(S-rowmax); prod = eA@T; /den
// ---------------------------------------------------------------------------
__global__ __launch_bounds__(256) void outp_kernel(
    const float* __restrict__ q, const float* __restrict__ k,
    const float* __restrict__ Tb, float* __restrict__ ctx)
{
    int bh = blockIdx.y;
    int b = bh / 11, h = bh - b * 11;
    int n0 = blockIdx.x << 6;
    size_t base = ((size_t)(b * 12 + h)) << 12;
    const float* qb = q + base * 64;
    const float* kb = k + base * 64;
    __shared__ float qtT[64][68];   // [d][r]
    __shared__ float kmT[64][68];   // [d][m]
    __shared__ float pT [64][68];   // [m][r]
    __shared__ float Tl [64][68];   // [m][j] j<65
    __shared__ float rmax[64][17];
    int tid = threadIdx.x;
    int tx = tid & 15, ty = tid >> 4;
    int rr = tid >> 2, dg = (tid & 3) << 4;
    {
        const float* qrow = qb + (((size_t)(n0 + rr)) << 6) + dg;
        const float* krow = kb + ((size_t)rr << 12) + dg;
        #pragma unroll
        for (int i = 0; i < 16; i += 4) {
            float4 f = *(const float4*)(qrow + i);
            qtT[dg+i][rr] = f.x; qtT[dg+i+1][rr] = f.y;
            qtT[dg+i+2][rr] = f.z; qtT[dg+i+3][rr] = f.w;
            float4 g2 = *(const float4*)(krow + i);
            kmT[dg+i][rr] = g2.x; kmT[dg+i+1][rr] = g2.y;
            kmT[dg+i+2][rr] = g2.z; kmT[dg+i+3][rr] = g2.w;
        }
    }
    for (int e = tid; e < 4160; e += 256) {
        int m = e / 65, j = e - m * 65;
        Tl[m][j] = Tb[(size_t)((bh << 6) + m) * 65 + j];
    }
    __syncthreads();
    float s4[4][4];
    #pragma unroll
    for (int i = 0; i < 4; ++i)
        #pragma unroll
        for (int j = 0; j < 4; ++j) s4[i][j] = 0.f;
    #pragma unroll 4
    for (int d = 0; d < 64; ++d) {
        float4 a  = *(const float4*)&qtT[d][ty << 2];
        float4 bb = *(const float4*)&kmT[d][tx << 2];
        float av[4] = {a.x,a.y,a.z,a.w};
        float bv[4] = {bb.x,bb.y,bb.z,bb.w};
        #pragma unroll
        for (int i = 0; i < 4; ++i)
            #pragma unroll
            for (int j = 0; j < 4; ++j)
                s4[i][j] += av[i] * bv[j];
    }
    #pragma unroll
    for (int i = 0; i < 4; ++i) {
        float tm = fmaxf(fmaxf(s4[i][0], s4[i][1]), fmaxf(s4[i][2], s4[i][3]));
        rmax[(ty << 2) + i][tx] = tm;
    }
    __syncthreads();
    if (tid < 64) {
        float mx = rmax[tid][0];
        #pragma unroll
        for (int c = 1; c < 16; ++c) mx = fmaxf(mx, rmax[tid][c]);
        rmax[tid][16] = mx;
    }
    __syncthreads();
    #pragma unroll
    for (int i = 0; i < 4; ++i) {
        float mr = rmax[(ty << 2) + i][16];
        #pragma unroll
        for (int j = 0; j < 4; ++j)
            pT[(tx << 2) + j][(ty << 2) + i] = expf(s4[i][j] - mr);
    }
    __syncthreads();
    float acc[4][4] = {};
    float c64[4] = {};
    #pragma unroll 4
    for (int m = 0; m < 64; ++m) {
        float4 pp = *(const float4*)&pT[m][ty << 2];
        float4 tt = *(const float4*)&Tl[m][tx << 2];
        float t64 = Tl[m][64];
        float pa[4] = {pp.x,pp.y,pp.z,pp.w};
        float ta[4] = {tt.x,tt.y,tt.z,tt.w};
        #pragma unroll
        for (int i = 0; i < 4; ++i) {
            #pragma unroll
            for (int j = 0; j < 4; ++j)
                acc[i][j] += pa[i] * ta[j];
            c64[i] += pa[i] * t64;
        }
    }
    #pragma unroll
    for (int i = 0; i < 4; ++i) {
        float inv = 1.0f / fmaxf(c64[i], 1e-8f);
        size_t obase = ((size_t)b * 4096 + (size_t)(n0 + (ty << 2) + i)) * 768 + h * 64 + (tx << 2);
        #pragma unroll
        for (int j = 0; j < 4; ++j)
            ctx[obase + j] = acc[i][j] * inv;
    }
}

// ---------------------------------------------------------------------------
// K7: softmax head (h=11) — bf16 MFMA flash attention, full KV sweep
// grid (64 q-tiles, 4 batches), 256 thr = 4 waves, wave owns 16 q rows
// ---------------------------------------------------------------------------
__global__ __launch_bounds__(256) void flash_h11(
    const float* __restrict__ q, const float* __restrict__ k,
    const float* __restrict__ v, float* __restrict__ ctx)
{
    int b = blockIdx.y;
    int n0 = blockIdx.x << 6;
    size_t base = ((size_t)(b * 12 + 11)) << 12;
    const float* qb = q + base * 64;
    const float* kb = k + base * 64;
    const float* vb = v + base * 64;
    __shared__ unsigned short qs[64][72];
    __shared__ unsigned short ks[64][72];
    __shared__ unsigned short vts[64][72];     // [d][n] (V transposed)
    __shared__ unsigned short ps[4][16][72];   // per-wave P
    int tid = threadIdx.x;
    int wv = tid >> 6, ln = tid & 63;
    int rr = tid >> 2, dg = (tid & 3) << 4;
    // Q tile -> bf16 LDS
    for (int e = tid * 4; e < 4096; e += 1024) {
        int r2 = e >> 6, d = e & 63;
        float4 f = *(const float4*)(qb + (((size_t)(n0 + r2)) << 6) + d);
        qs[r2][d] = f2bf(f.x); qs[r2][d+1] = f2bf(f.y);
        qs[r2][d+2] = f2bf(f.z); qs[r2][d+3] = f2bf(f.w);
    }
    __syncthreads();
    const int arow = (wv << 4) + (ln & 15);
    const int ak0 = (ln >> 4) << 3;           // 0,8,16,24
    short8 aq0 = *(short8*)&qs[arow][ak0];
    short8 aq1 = *(short8*)&qs[arow][ak0 + 32];
    f32x4 o_acc[4] = {};
    float mr[4] = {-1e30f, -1e30f, -1e30f, -1e30f};
    float lr[4] = {};
    for (int m0 = 0; m0 < 4096; m0 += 64) {
        __syncthreads();
        {   // K -> bf16 LDS, V -> bf16 LDS transposed
            const float* krow = kb + (((size_t)(m0 + rr)) << 6) + dg;
            const float* vrow = vb + (((size_t)(m0 + rr)) << 6) + dg;
            #pragma unroll
            for (int i = 0; i < 16; i += 4) {
                float4 f = *(const float4*)(krow + i);
                ks[rr][dg+i] = f2bf(f.x); ks[rr][dg+i+1] = f2bf(f.y);
                ks[rr][dg+i+2] = f2bf(f.z); ks[rr][dg+i+3] = f2bf(f.w);
                float4 g2 = *(const float4*)(vrow + i);
                vts[dg+i][rr] = f2bf(g2.x); vts[dg+i+1][rr] = f2bf(g2.y);
                vts[dg+i+2][rr] = f2bf(g2.z); vts[dg+i+3][rr] = f2bf(g2.w);
            }
        }
        __syncthreads();
        // S = Q·K^T  (4 col-blocks of 16)
        f32x4 s_acc[4];
        #pragma unroll
        for (int jb = 0; jb < 4; ++jb) {
            f32x4 z = {};
            short8 bk0 = *(short8*)&ks[(jb << 4) + (ln & 15)][ak0];
            short8 bk1 = *(short8*)&ks[(jb << 4) + (ln & 15)][ak0 + 32];
            z = __builtin_amdgcn_mfma_f32_16x16x32_bf16(aq0, bk0, z, 0, 0, 0);
            z = __builtin_amdgcn_mfma_f32_16x16x32_bf16(aq1, bk1, z, 0, 0, 0);
            s_acc[jb] = z;
        }
        // online softmax: lane holds S[(ln>>4)*4+r][jb*16+(ln&15)]
        float mx[4];
        #pragma unroll
        for (int r = 0; r < 4; ++r)
            mx[r] = fmaxf(fmaxf(s_acc[0][r], s_acc[1][r]),
                          fmaxf(s_acc[2][r], s_acc[3][r]));
        #pragma unroll
        for (int off = 1; off < 16; off <<= 1)
            #pragma unroll
            for (int r = 0; r < 4; ++r)
                mx[r] = fmaxf(mx[r], __shfl_xor(mx[r], off, 64));
        float fac[4];
        #pragma unroll
        for (int r = 0; r < 4; ++r) {
            float mn = fmaxf(mr[r], mx[r]);
            fac[r] = expf(mr[r] - mn);
            mr[r] = mn;
        }
        float rs[4] = {};
        #pragma unroll
        for (int jb = 0; jb < 4; ++jb)
            #pragma unroll
            for (int r = 0; r < 4; ++r) {
                float p = expf(s_acc[jb][r] - mr[r]);
                rs[r] += p;
                ps[wv][((ln >> 4) << 2) + r][(jb << 4) + (ln & 15)] = f2bf(p);
            }
        #pragma unroll
        for (int off = 1; off < 16; off <<= 1)
            #pragma unroll
            for (int r = 0; r < 4; ++r)
                rs[r] += __shfl_xor(rs[r], off, 64);
        #pragma unroll
        for (int r = 0; r < 4; ++r) lr[r] = lr[r] * fac[r] + rs[r];
        // rescale O
        #pragma unroll
        for (int jb = 0; jb < 4; ++jb)
            #pragma unroll
            for (int r = 0; r < 4; ++r)
                o_acc[jb][r] *= fac[r];
        // O += P·V  (A = P from ps, B = V from vts)
        short8 pa0 = *(short8*)&ps[wv][ln & 15][ak0];
        short8 pa1 = *(short8*)&ps[wv][ln & 15][ak0 + 32];
        #pragma unroll
        for (int jb = 0; jb < 4; ++jb) {
            short8 bv0 = *(short8*)&vts[(jb << 4) + (ln & 15)][ak0];
            short8 bv1 = *(short8*)&vts[(jb << 4) + (ln & 15)][ak0 + 32];
            f32x4 z = o_acc[jb];
            z = __builtin_amdgcn_mfma_f32_16x16x32_bf16(pa0, bv0, z, 0, 0, 0);
            z = __builtin_amdgcn_mfma_f32_16x16x32_bf16(pa1, bv1, z, 0, 0, 0);
            o_acc[jb] = z;
        }
    }
    float invl[4];
    #pragma unroll
    for (int r = 0; r < 4; ++r) invl[r] = 1.0f / lr[r];
    #pragma unroll
    for (int jb = 0; jb < 4; ++jb)
        #pragma unroll
        for (int r = 0; r < 4; ++r) {
            int row_q = (wv << 4) + ((ln >> 4) << 2) + r;
            int col_d = (jb << 4) + (ln & 15);
            ctx[((size_t)b * 4096 + n0 + row_q) * 768 + 11 * 64 + col_d] =
                o_acc[jb][r] * invl[r];
        }
}

// ---------------------------------------------------------------------------
// K8: proj GEMM  out = ctx(16384x768) @ proj_w^T + proj_b (fp32 128x128)
// ---------------------------------------------------------------------------
__global__ __launch_bounds__(256) void gemm_proj(
    const float* __restrict__ X, const float* __restrict__ W,
    const float* __restrict__ bias, float* __restrict__ out)
{
    __shared__ float As[16][132];
    __shared__ float Bs[16][132];
    const int tid = threadIdx.x;
    const int brow = blockIdx.y << 7;
    const int bcol = blockIdx.x << 7;
    const int tx = tid & 15, ty = tid >> 4;
    const int lr = tid >> 1, lc8 = (tid & 1) << 3;
    const float* Xr = X + (size_t)(brow + lr) * 768 + lc8;
    const float* Wr = W + (size_t)(bcol + lr) * 768 + lc8;
    float acc[8][8] = {};
    for (int k0 = 0; k0 < 768; k0 += 16) {
        float4 a0 = *(const float4*)(Xr + k0);
        float4 a1 = *(const float4*)(Xr + k0 + 4);
        float4 b0 = *(const float4*)(Wr + k0);
        float4 b1 = *(const float4*)(Wr + k0 + 4);
        __syncthreads();
        As[lc8+0][lr]=a0.x; As[lc8+1][lr]=a0.y; As[lc8+2][lr]=a0.z; As[lc8+3][lr]=a0.w;
        As[lc8+4][lr]=a1.x; As[lc8+5][lr]=a1.y; As[lc8+6][lr]=a1.z; As[lc8+7][lr]=a1.w;
        Bs[lc8+0][lr]=b0.x; Bs[lc8+1][lr]=b0.y; Bs[lc8+2][lr]=b0.z; Bs[lc8+3][lr]=b0.w;
        Bs[lc8+4][lr]=b1.x; Bs[lc8+5][lr]=b1.y; Bs[lc8+6][lr]=b1.z; Bs[lc8+7][lr]=b1.w;
        __syncthreads();
        #pragma unroll
        for (int kk = 0; kk < 16; ++kk) {
            float4 x0 = *(const float4*)&As[kk][ty << 3];
            float4 x1 = *(const float4*)&As[kk][(ty << 3) + 4];
            float4 y0 = *(const float4*)&Bs[kk][tx << 3];
            float4 y1 = *(const float4*)&Bs[kk][(tx << 3) + 4];
            float av[8] = {x0.x,x0.y,x0.z,x0.w,x1.x,x1.y,x1.z,x1.w};
            float bv[8] = {y0.x,y0.y,y0.z,y0.w,y1.x,y1.y,y1.z,y1.w};
            #pragma unroll
            for (int i = 0; i < 8; ++i)
                #pragma unroll
                for (int j = 0; j < 8; ++j)
                    acc[i][j] += av[i] * bv[j];
        }
    }
    #pragma unroll
    for (int i = 0; i < 8; ++i) {
        int r = brow + (ty << 3) + i;
        #pragma unroll
        for (int j = 0; j < 8; ++j) {
            int c = bcol + (tx << 3) + j;
            out[(size_t)r * 768 + c] = acc[i][j] + bias[c];
        }
    }
}

// ---------------------------------------------------------------------------
extern "C" void kernel_launch(void* const* d_in, const int* in_sizes, int n_in,
                              void* d_out, int out_size, void* d_ws, size_t ws_size,
                              hipStream_t stream)
{
    const float* x      = (const float*)d_in[0];
    const float* qkv_w  = (const float*)d_in[1];
    const float* qkv_b  = (const float*)d_in[2];
    const float* proj_w = (const float*)d_in[3];
    const float* proj_b = (const float*)d_in[4];
    float* out = (float*)d_out;

    float* ws  = (float*)d_ws;
    const size_t QKV = (size_t)4 * 12 * 4096 * 64;   // 12,582,912
    float* q    = ws;
    float* k    = q + QKV;
    float* v    = k + QKV;
    float* ctx  = v + QKV;
    float* scm  = ctx + QKV;                          // 44*64 (pad 4096)
    float* eB   = scm + 4096;                         // 44*4096
    float* den  = eB + 44 * 4096;                     // 11 (pad 64)
    float* pi_  = den + 64;                           // 44*4096
    float* Wb   = pi_ + 44 * 4096;                    // 44*4160
    float* Tb   = Wb + 44 * 4160;                     // 44*64*65

    // scratch in d_out (dead before gemm_proj writes the real output)
    float* wacc = out;                                // 352*4096 = 1,441,792
    float* wl   = wacc + 1441792;                     // 22,528
    float* wm   = wl + 22528;                         // 22,528

    gemm_qkv<<<dim3(18, 128), 256, 0, stream>>>(x, qkv_w, qkv_b, q, k, v);
    wflash<<<dim3(8, 44), 256, 0, stream>>>(q, k, v, wacc, wl, wm);
    wmerge<<<44, 256, 0, stream>>>(wacc, wl, wm, Wb, scm);
    eb_kernel<<<44, 256, 0, stream>>>(q, k, scm, eB);
    norms_kernel<<<11, 256, 0, stream>>>(eB, den);
    pinv_kernel<<<44, 256, 0, stream>>>(eB, den, pi_);
    pw_kernel<<<44, 256, 0, stream>>>(pi_, Wb, Tb);
    outp_kernel<<<dim3(64, 44), 256, 0, stream>>>(q, k, Tb, ctx);
    flash_h11<<<dim3(64, 4), 256, 0, stream>>>(q, k, v, ctx);
    gemm_proj<<<dim3(6, 128), 256, 0, stream>>>(ctx, proj_w, proj_b, out);
}

// Round 4
// 1072.616 us; speedup vs baseline: 5.7170x; 1.5724x over previous
//
#include <hip/hip_runtime.h>

// B=4, N=4096, C=768, H=12, D=64, M=64, PNP=11, SCALE=1/8

typedef __attribute__((ext_vector_type(8))) short short8;
typedef __attribute__((ext_vector_type(4))) float f32x4;
typedef __attribute__((ext_vector_type(4))) unsigned short ushort4v;

static __device__ __forceinline__ unsigned short f2bf(float f) {
    union { float f; unsigned u; } x; x.f = f;
    unsigned r = x.u + 0x7fffu + ((x.u >> 16) & 1u);   // RNE
    return (unsigned short)(r >> 16);
}

static __device__ __forceinline__ void bfsplit(float x, unsigned short& h, unsigned short& l) {
    unsigned short hh = f2bf(x);
    union { unsigned u; float f; } t; t.u = (unsigned)hh << 16;
    h = hh;
    l = f2bf(x - t.f);    // exact residual (Sterbenz), RNE to bf16
}

// ---------------------------------------------------------------------------
// K0: split fp32 array into bf16 (hi, lo) pair arrays. memory-bound.
// ---------------------------------------------------------------------------
__global__ __launch_bounds__(256) void preconv(
    const float* __restrict__ in, unsigned short* __restrict__ hi,
    unsigned short* __restrict__ lo, int n4)
{
    for (int i = blockIdx.x * 256 + threadIdx.x; i < n4; i += gridDim.x * 256) {
        float4 f = *(const float4*)(in + (size_t)i * 4);
        float vs[4] = {f.x, f.y, f.z, f.w};
        ushort4v h, l;
        #pragma unroll
        for (int j = 0; j < 4; ++j) {
            unsigned short hh, ll;
            bfsplit(vs[j], hh, ll);
            h[j] = hh; l[j] = ll;
        }
        *(ushort4v*)(hi + (size_t)i * 4) = h;
        *(ushort4v*)(lo + (size_t)i * 4) = l;
    }
}

// ---------------------------------------------------------------------------
// K1: QKV GEMM via bf16x3-split MFMA.  C = X(16384x768) @ W^T(2304x768) + b
// 128x128 tile, BK=32, 4 waves (2x2), each wave 64x64 via 4x4 16x16x32 frags.
// Epilogue scatters to q/k/v in (B,H,N,D), q scaled by 1/8.
// ---------------------------------------------------------------------------
__global__ __launch_bounds__(256, 2) void gemm_qkv_mfma(
    const unsigned short* __restrict__ Xh, const unsigned short* __restrict__ Xl,
    const unsigned short* __restrict__ Wh, const unsigned short* __restrict__ Wl,
    const float* __restrict__ bias,
    float* __restrict__ q, float* __restrict__ k, float* __restrict__ v)
{
    __shared__ unsigned short Ah[128][40], Al[128][40], Bh[128][40], Bl[128][40];
    const int tid = threadIdx.x;
    const int brow = blockIdx.y << 7, bcol = blockIdx.x << 7;
    const int ln = tid & 63, wv = tid >> 6;
    const int wr = (wv >> 1) << 6, wc = (wv & 1) << 6;
    const int srow = tid >> 1, sk = (tid & 1) << 4;
    const size_t ag = (size_t)(brow + srow) * 768 + sk;
    const size_t bg = (size_t)(bcol + srow) * 768 + sk;
    const int fr = ln & 15, fk = (ln >> 4) << 3;

    f32x4 acc[4][4] = {};
    for (int k0 = 0; k0 < 768; k0 += 32) {
        short8 xh0 = *(const short8*)(Xh + ag + k0);
        short8 xh1 = *(const short8*)(Xh + ag + k0 + 8);
        short8 xl0 = *(const short8*)(Xl + ag + k0);
        short8 xl1 = *(const short8*)(Xl + ag + k0 + 8);
        short8 wh0 = *(const short8*)(Wh + bg + k0);
        short8 wh1 = *(const short8*)(Wh + bg + k0 + 8);
        short8 wl0 = *(const short8*)(Wl + bg + k0);
        short8 wl1 = *(const short8*)(Wl + bg + k0 + 8);
        __syncthreads();
        *(short8*)&Ah[srow][sk] = xh0; *(short8*)&Ah[srow][sk + 8] = xh1;
        *(short8*)&Al[srow][sk] = xl0; *(short8*)&Al[srow][sk + 8] = xl1;
        *(short8*)&Bh[srow][sk] = wh0; *(short8*)&Bh[srow][sk + 8] = wh1;
        *(short8*)&Bl[srow][sk] = wl0; *(short8*)&Bl[srow][sk + 8] = wl1;
        __syncthreads();
        short8 ah[4], al[4], bh[4], bl[4];
        #pragma unroll
        for (int i = 0; i < 4; ++i) {
            ah[i] = *(short8*)&Ah[wr + (i << 4) + fr][fk];
            al[i] = *(short8*)&Al[wr + (i << 4) + fr][fk];
        }
        #pragma unroll
        for (int j = 0; j < 4; ++j) {
            bh[j] = *(short8*)&Bh[wc + (j << 4) + fr][fk];
            bl[j] = *(short8*)&Bl[wc + (j << 4) + fr][fk];
        }
        #pragma unroll
        for (int i = 0; i < 4; ++i)
            #pragma unroll
            for (int j = 0; j < 4; ++j) {
                acc[i][j] = __builtin_amdgcn_mfma_f32_16x16x32_bf16(ah[i], bh[j], acc[i][j], 0, 0, 0);
                acc[i][j] = __builtin_amdgcn_mfma_f32_16x16x32_bf16(ah[i], bl[j], acc[i][j], 0, 0, 0);
                acc[i][j] = __builtin_amdgcn_mfma_f32_16x16x32_bf16(al[i], bh[j], acc[i][j], 0, 0, 0);
            }
    }
    const int fg = ln >> 4;
    #pragma unroll
    for (int j = 0; j < 4; ++j) {
        int c = bcol + wc + (j << 4) + fr;
        float bb = bias[c];
        int t = c / 768;
        int rem = c - t * 768;
        int h = rem >> 6, d = rem & 63;
        #pragma unroll
        for (int i = 0; i < 4; ++i)
            #pragma unroll
            for (int r = 0; r < 4; ++r) {
                int row = brow + wr + (i << 4) + (fg << 2) + r;
                int b = row >> 12, n = row & 4095;
                float val = acc[i][j][r] + bb;
                size_t idx = (((size_t)(b * 12 + h) << 12) + n) * 64 + d;
                if (t == 0)      q[idx] = val * 0.125f;
                else if (t == 1) k[idx] = val;
                else             v[idx] = val;
            }
    }
}

// ---------------------------------------------------------------------------
// K2: fused flash pass for SC: online max + W-partial per 512-n chunk (fp32)
// ---------------------------------------------------------------------------
__global__ __launch_bounds__(256) void wflash(
    const float* __restrict__ q, const float* __restrict__ k,
    const float* __restrict__ v,
    float* __restrict__ wacc, float* __restrict__ wl, float* __restrict__ wm)
{
    int chunk = blockIdx.x;
    int bh = blockIdx.y;
    int b = bh / 11, h = bh - b * 11;
    size_t base = ((size_t)(b * 12 + h)) << 12;
    const float* qb = q + base * 64;
    const float* kb = k + base * 64;
    const float* vb = v + base * 64;
    __shared__ float qmT[64][68];
    __shared__ float ktT[64][68];
    __shared__ float vt [64][68];
    __shared__ float pT [64][68];
    __shared__ float rmax[64][16];
    __shared__ float mrun[64], fac[64];
    int tid = threadIdx.x;
    int tx = tid & 15, ty = tid >> 4;
    int rr = tid >> 2, dg = (tid & 3) << 4;
    {
        const float* qrow = qb + ((size_t)rr << 12) + dg;
        #pragma unroll
        for (int i = 0; i < 16; i += 4) {
            float4 f = *(const float4*)(qrow + i);
            qmT[dg+i][rr] = f.x; qmT[dg+i+1][rr] = f.y;
            qmT[dg+i+2][rr] = f.z; qmT[dg+i+3][rr] = f.w;
        }
    }
    if (tid < 64) mrun[tid] = -1e30f;
    float acc4[4][4] = {};
    float lsum[4] = {};
    for (int t = 0; t < 8; ++t) {
        int n0 = (chunk << 9) + (t << 6);
        __syncthreads();
        const float* krow = kb + (((size_t)(n0 + rr)) << 6) + dg;
        #pragma unroll
        for (int i = 0; i < 16; i += 4) {
            float4 f = *(const float4*)(krow + i);
            ktT[dg+i][rr] = f.x; ktT[dg+i+1][rr] = f.y;
            ktT[dg+i+2][rr] = f.z; ktT[dg+i+3][rr] = f.w;
        }
        const float* vrow = vb + (((size_t)(n0 + rr)) << 6) + dg;
        #pragma unroll
        for (int i = 0; i < 16; i += 4)
            *(float4*)&vt[rr][dg + i] = *(const float4*)(vrow + i);
        __syncthreads();
        float s4[4][4];
        #pragma unroll
        for (int i = 0; i < 4; ++i)
            #pragma unroll
            for (int j = 0; j < 4; ++j) s4[i][j] = 0.f;
        #pragma unroll 4
        for (int d = 0; d < 64; ++d) {
            float4 a  = *(const float4*)&qmT[d][ty << 2];
            float4 bb = *(const float4*)&ktT[d][tx << 2];
            float av[4] = {a.x,a.y,a.z,a.w};
            float bv[4] = {bb.x,bb.y,bb.z,bb.w};
            #pragma unroll
            for (int i = 0; i < 4; ++i)
                #pragma unroll
                for (int j = 0; j < 4; ++j)
                    s4[i][j] += av[i] * bv[j];
        }
        #pragma unroll
        for (int i = 0; i < 4; ++i) {
            float tm = fmaxf(fmaxf(s4[i][0], s4[i][1]), fmaxf(s4[i][2], s4[i][3]));
            rmax[(ty << 2) + i][tx] = tm;
        }
        __syncthreads();
        if (tid < 64) {
            float mx = rmax[tid][0];
            #pragma unroll
            for (int c = 1; c < 16; ++c) mx = fmaxf(mx, rmax[tid][c]);
            float mn = fmaxf(mrun[tid], mx);
            fac[tid] = expf(mrun[tid] - mn);
            mrun[tid] = mn;
        }
        __syncthreads();
        #pragma unroll
        for (int i = 0; i < 4; ++i) {
            int m = (ty << 2) + i;
            float f = fac[m], mr = mrun[m];
            float ls = lsum[i] * f;
            #pragma unroll
            for (int j = 0; j < 4; ++j) {
                acc4[i][j] *= f;
                float p = expf(s4[i][j] - mr);
                ls += p;
                pT[(tx << 2) + j][m] = p;
            }
            lsum[i] = ls;
        }
        __syncthreads();
        #pragma unroll 4
        for (int n = 0; n < 64; ++n) {
            float4 pp = *(const float4*)&pT[n][ty << 2];
            float4 vv = *(const float4*)&vt[n][tx << 2];
            float pa[4] = {pp.x,pp.y,pp.z,pp.w};
            float va[4] = {vv.x,vv.y,vv.z,vv.w};
            #pragma unroll
            for (int i = 0; i < 4; ++i)
                #pragma unroll
                for (int j = 0; j < 4; ++j)
                    acc4[i][j] += pa[i] * va[j];
        }
    }
    int cidx = (bh << 3) + chunk;
    #pragma unroll
    for (int i = 0; i < 4; ++i)
        #pragma unroll
        for (int j = 0; j < 4; ++j)
            wacc[((size_t)cidx << 12) + ((size_t)((ty << 2) + i) << 6) + (tx << 2) + j] = acc4[i][j];
    __syncthreads();
    #pragma unroll
    for (int i = 0; i < 4; ++i) rmax[(ty << 2) + i][tx] = lsum[i];
    __syncthreads();
    if (tid < 64) {
        float s = 0.f;
        #pragma unroll
        for (int c = 0; c < 16; ++c) s += rmax[tid][c];
        wl[cidx * 64 + tid] = s;
        wm[cidx * 64 + tid] = mrun[tid];
    }
}

// K2b: merge chunk partials -> Wb (65 cols, col 64 = ones-column) + scm
__global__ __launch_bounds__(256) void wmerge(
    const float* __restrict__ wacc, const float* __restrict__ wl,
    const float* __restrict__ wm,
    float* __restrict__ Wb, float* __restrict__ scm)
{
    int bh = blockIdx.x;
    int tid = threadIdx.x;
    __shared__ float fcs[8][64];
    if (tid < 64) {
        float mx = -1e30f;
        #pragma unroll
        for (int c = 0; c < 8; ++c)
            mx = fmaxf(mx, wm[((bh << 3) + c) * 64 + tid]);
        scm[(bh << 6) + tid] = mx;
        #pragma unroll
        for (int c = 0; c < 8; ++c)
            fcs[c][tid] = expf(wm[((bh << 3) + c) * 64 + tid] - mx);
    }
    __syncthreads();
    for (int e = tid; e < 4096; e += 256) {
        int m = e >> 6, j = e & 63;
        float s = 0.f;
        #pragma unroll
        for (int c = 0; c < 8; ++c)
            s += fcs[c][m] * wacc[((size_t)((bh << 3) + c) << 12) + e];
        Wb[(size_t)bh * 4160 + m * 65 + j] = s;
    }
    if (tid < 64) {
        float s = 0.f;
        #pragma unroll
        for (int c = 0; c < 8; ++c)
            s += fcs[c][tid] * wl[((bh << 3) + c) * 64 + tid];
        Wb[(size_t)bh * 4160 + tid * 65 + 64] = s;
    }
}

// ---------------------------------------------------------------------------
// K3a: eB (fp32)
// ---------------------------------------------------------------------------
__global__ __launch_bounds__(256) void eb_kernel(
    const float* __restrict__ q, const float* __restrict__ k,
    const float* __restrict__ scm, float* __restrict__ eB)
{
    int bh = blockIdx.x;
    int b = bh / 11, h = bh - b * 11;
    size_t base = ((size_t)(b * 12 + h)) << 12;
    const float* qb = q + base * 64;
    const float* kb = k + base * 64;
    __shared__ float qm[64][65], km[64][65];
    int tid = threadIdx.x;
    for (int e = tid; e < 4096; e += 256) {
        int mm = e >> 6, d = e & 63;
        qm[mm][d] = qb[((size_t)mm << 12) + d];
        km[mm][d] = kb[((size_t)mm << 12) + d];
    }
    __syncthreads();
    int m = tid >> 2, l0 = tid & 3;
    float smax = scm[(bh << 6) + m];
    for (int l = l0; l < 64; l += 4) {
        float s = 0.f;
        #pragma unroll
        for (int d = 0; d < 64; ++d) s += qm[m][d] * km[l][d];
        eB[((size_t)bh << 12) + (m << 6) + l] = expf(fmaxf(s - smax, -88.f));
    }
}

// ---------------------------------------------------------------------------
// K3b: per-head norms
// ---------------------------------------------------------------------------
__global__ __launch_bounds__(256) void norms_kernel(
    const float* __restrict__ eB, float* __restrict__ denom)
{
    int h = blockIdx.x;
    int tid = threadIdx.x;
    int b = tid >> 6, idx = tid & 63;
    int bh = b * 11 + h;
    const float* E = eB + ((size_t)bh << 12);
    float rs = 0.f, cs = 0.f;
    #pragma unroll 4
    for (int l = 0; l < 64; ++l) rs += E[(idx << 6) + l];
    #pragma unroll 4
    for (int m = 0; m < 64; ++m) cs += E[(m << 6) + idx];
    __shared__ float r1[256], r2[256];
    r1[tid] = rs; r2[tid] = cs;
    __syncthreads();
    for (int s = 128; s > 0; s >>= 1) {
        if (tid < s) {
            r1[tid] = fmaxf(r1[tid], r1[tid + s]);
            r2[tid] = fmaxf(r2[tid], r2[tid + s]);
        }
        __syncthreads();
    }
    if (tid == 0) denom[h] = r1[0] * r2[0];
}

// ---------------------------------------------------------------------------
// K3c: pinv via 6 Newton iterations (fp32, numerically critical)
// ---------------------------------------------------------------------------
__global__ __launch_bounds__(256) void pinv_kernel(
    const float* __restrict__ eB, const float* __restrict__ denom,
    float* __restrict__ pi_)
{
    int bh = blockIdx.x;
    int h = bh % 11;
    __shared__ float X[64][65], Z[64][65], XZ[64][65], TA[64][65], TB[64][65];
    int tid = threadIdx.x;
    float dn = denom[h];
    for (int e = tid; e < 4096; e += 256) {
        int m = e >> 6, l = e & 63;
        float xv = eB[((size_t)bh << 12) + e];
        X[m][l] = xv;
        Z[l][m] = xv / dn;
    }
    __syncthreads();
    int m = tid >> 2, l0 = tid & 3;
    for (int it = 0; it < 6; ++it) {
        for (int l = l0; l < 64; l += 4) {
            float s = 0.f;
            #pragma unroll
            for (int kk = 0; kk < 64; ++kk) s += X[m][kk] * Z[kk][l];
            XZ[m][l] = s;
        }
        __syncthreads();
        for (int l = l0; l < 64; l += 4) {
            float s = 0.f;
            #pragma unroll
            for (int kk = 0; kk < 64; ++kk) s += XZ[m][kk] * XZ[kk][l];
            TA[m][l] = 7.f * XZ[m][l] - s;
        }
        __syncthreads();
        for (int l = l0; l < 64; l += 4) {
            float s = 0.f;
            #pragma unroll
            for (int kk = 0; kk < 64; ++kk) s += XZ[m][kk] * TA[kk][l];
            TB[m][l] = 15.f * XZ[m][l] - s;
        }
        __syncthreads();
        for (int l = l0; l < 64; l += 4) {
            float s = 0.f;
            #pragma unroll
            for (int kk = 0; kk < 64; ++kk) s += Z[m][kk] * TB[kk][l];
            TA[m][l] = 13.f * Z[m][l] - s;
        }
        __syncthreads();
        for (int l = l0; l < 64; l += 4) Z[m][l] = 0.25f * TA[m][l];
        __syncthreads();
    }
    for (int e = tid; e < 4096; e += 256)
        pi_[((size_t)bh << 12) + e] = Z[e >> 6][e & 63];
}

// ---------------------------------------------------------------------------
// K5: T = pi @ W  (64x64 @ 64x65)
// ---------------------------------------------------------------------------
__global__ __launch_bounds__(256) void pw_kernel(
    const float* __restrict__ pi_, const float* __restrict__ Wb,
    float* __restrict__ Tb)
{
    int bh = blockIdx.x;
    __shared__ float P[64][65];
    __shared__ float Wl[64][66];
    int tid = threadIdx.x;
    for (int e = tid; e < 4096; e += 256)
        P[e >> 6][e & 63] = pi_[((size_t)bh << 12) + e];
    for (int e = tid; e < 64 * 65; e += 256) {
        int l = e / 65, j = e - l * 65;
        Wl[l][j] = Wb[(size_t)bh * 4160 + e];
    }
    __syncthreads();
    int m = tid & 63, g = tid >> 6;
    #pragma unroll
    for (int t = 0; t < 17; ++t) {
        int j = g + (t << 2);
        if (j > 64) break;
        float s = 0.f;
        #pragma unroll
        for (int l = 0; l < 64; ++l) s += P[m][l] * Wl[l][j];
        Tb[(size_t)((bh << 6) + m) * 65 + j] = s;
    }
}

// ---------------------------------------------------------------------------
// K6: out_p tile (register-tiled fp32) -> ctx_hi/ctx_lo (bf16 split)
// ---------------------------------------------------------------------------
__global__ __launch_bounds__(256) void outp_kernel(
    const float* __restrict__ q, const float* __restrict__ k,
    const float* __restrict__ Tb,
    unsigned short* __restrict__ ctxh, unsigned short* __restrict__ ctxl)
{
    int bh = blockIdx.y;
    int b = bh / 11, h = bh - b * 11;
    int n0 = blockIdx.x << 6;
    size_t base = ((size_t)(b * 12 + h)) << 12;
    const float* qb = q + base * 64;
    const float* kb = k + base * 64;
    __shared__ float qtT[64][68];
    __shared__ float kmT[64][68];
    __shared__ float pT [64][68];
    __shared__ float Tl [64][68];
    __shared__ float rmax[64][17];
    int tid = threadIdx.x;
    int tx = tid & 15, ty = tid >> 4;
    int rr = tid >> 2, dg = (tid & 3) << 4;
    {
        const float* qrow = qb + (((size_t)(n0 + rr)) << 6) + dg;
        const float* krow = kb + ((size_t)rr << 12) + dg;
        #pragma unroll
        for (int i = 0; i < 16; i += 4) {
            float4 f = *(const float4*)(qrow + i);
            qtT[dg+i][rr] = f.x; qtT[dg+i+1][rr] = f.y;
            qtT[dg+i+2][rr] = f.z; qtT[dg+i+3][rr] = f.w;
            float4 g2 = *(const float4*)(krow + i);
            kmT[dg+i][rr] = g2.x; kmT[dg+i+1][rr] = g2.y;
            kmT[dg+i+2][rr] = g2.z; kmT[dg+i+3][rr] = g2.w;
        }
    }
    for (int e = tid; e < 4160; e += 256) {
        int m = e / 65, j = e - m * 65;
        Tl[m][j] = Tb[(size_t)((bh << 6) + m) * 65 + j];
    }
    __syncthreads();
    float s4[4][4];
    #pragma unroll
    for (int i = 0; i < 4; ++i)
        #pragma unroll
        for (int j = 0; j < 4; ++j) s4[i][j] = 0.f;
    #pragma unroll 4
    for (int d = 0; d < 64; ++d) {
        float4 a  = *(const float4*)&qtT[d][ty << 2];
        float4 bb = *(const float4*)&kmT[d][tx << 2];
        float av[4] = {a.x,a.y,a.z,a.w};
        float bv[4] = {bb.x,bb.y,bb.z,bb.w};
        #pragma unroll
        for (int i = 0; i < 4; ++i)
            #pragma unroll
            for (int j = 0; j < 4; ++j)
                s4[i][j] += av[i] * bv[j];
    }
    #pragma unroll
    for (int i = 0; i < 4; ++i) {
        float tm = fmaxf(fmaxf(s4[i][0], s4[i][1]), fmaxf(s4[i][2], s4[i][3]));
        rmax[(ty << 2) + i][tx] = tm;
    }
    __syncthreads();
    if (tid < 64) {
        float mx = rmax[tid][0];
        #pragma unroll
        for (int c = 1; c < 16; ++c) mx = fmaxf(mx, rmax[tid][c]);
        rmax[tid][16] = mx;
    }
    __syncthreads();
    #pragma unroll
    for (int i = 0; i < 4; ++i) {
        float mr = rmax[(ty << 2) + i][16];
        #pragma unroll
        for (int j = 0; j < 4; ++j)
            pT[(tx << 2) + j][(ty << 2) + i] = expf(s4[i][j] - mr);
    }
    __syncthreads();
    float acc[4][4] = {};
    float c64[4] = {};
    #pragma unroll 4
    for (int m = 0; m < 64; ++m) {
        float4 pp = *(const float4*)&pT[m][ty << 2];
        float4 tt = *(const float4*)&Tl[m][tx << 2];
        float t64 = Tl[m][64];
        float pa[4] = {pp.x,pp.y,pp.z,pp.w};
        float ta[4] = {tt.x,tt.y,tt.z,tt.w};
        #pragma unroll
        for (int i = 0; i < 4; ++i) {
            #pragma unroll
            for (int j = 0; j < 4; ++j)
                acc[i][j] += pa[i] * ta[j];
            c64[i] += pa[i] * t64;
        }
    }
    #pragma unroll
    for (int i = 0; i < 4; ++i) {
        float inv = 1.0f / fmaxf(c64[i], 1e-8f);
        size_t obase = ((size_t)b * 4096 + (size_t)(n0 + (ty << 2) + i)) * 768 + h * 64 + (tx << 2);
        #pragma unroll
        for (int j = 0; j < 4; ++j) {
            unsigned short hh, ll;
            bfsplit(acc[i][j] * inv, hh, ll);
            ctxh[obase + j] = hh; ctxl[obase + j] = ll;
        }
    }
}

// ---------------------------------------------------------------------------
// K7: softmax head (h=11) — bf16 MFMA flash attention -> ctx_hi/ctx_lo
// ---------------------------------------------------------------------------
__global__ __launch_bounds__(256) void flash_h11(
    const float* __restrict__ q, const float* __restrict__ k,
    const float* __restrict__ v,
    unsigned short* __restrict__ ctxh, unsigned short* __restrict__ ctxl)
{
    int b = blockIdx.y;
    int n0 = blockIdx.x << 6;
    size_t base = ((size_t)(b * 12 + 11)) << 12;
    const float* qb = q + base * 64;
    const float* kb = k + base * 64;
    const float* vb = v + base * 64;
    __shared__ unsigned short qs[64][72];
    __shared__ unsigned short ks[64][72];
    __shared__ unsigned short vts[64][72];
    __shared__ unsigned short ps[4][16][72];
    int tid = threadIdx.x;
    int wv = tid >> 6, ln = tid & 63;
    int rr = tid >> 2, dg = (tid & 3) << 4;
    for (int e = tid * 4; e < 4096; e += 1024) {
        int r2 = e >> 6, d = e & 63;
        float4 f = *(const float4*)(qb + (((size_t)(n0 + r2)) << 6) + d);
        qs[r2][d] = f2bf(f.x); qs[r2][d+1] = f2bf(f.y);
        qs[r2][d+2] = f2bf(f.z); qs[r2][d+3] = f2bf(f.w);
    }
    __syncthreads();
    const int arow = (wv << 4) + (ln & 15);
    const int ak0 = (ln >> 4) << 3;
    short8 aq0 = *(short8*)&qs[arow][ak0];
    short8 aq1 = *(short8*)&qs[arow][ak0 + 32];
    f32x4 o_acc[4] = {};
    float mr[4] = {-1e30f, -1e30f, -1e30f, -1e30f};
    float lr[4] = {};
    for (int m0 = 0; m0 < 4096; m0 += 64) {
        __syncthreads();
        {
            const float* krow = kb + (((size_t)(m0 + rr)) << 6) + dg;
            const float* vrow = vb + (((size_t)(m0 + rr)) << 6) + dg;
            #pragma unroll
            for (int i = 0; i < 16; i += 4) {
                float4 f = *(const float4*)(krow + i);
                ks[rr][dg+i] = f2bf(f.x); ks[rr][dg+i+1] = f2bf(f.y);
                ks[rr][dg+i+2] = f2bf(f.z); ks[rr][dg+i+3] = f2bf(f.w);
                float4 g2 = *(const float4*)(vrow + i);
                vts[dg+i][rr] = f2bf(g2.x); vts[dg+i+1][rr] = f2bf(g2.y);
                vts[dg+i+2][rr] = f2bf(g2.z); vts[dg+i+3][rr] = f2bf(g2.w);
            }
        }
        __syncthreads();
        f32x4 s_acc[4];
        #pragma unroll
        for (int jb = 0; jb < 4; ++jb) {
            f32x4 z = {};
            short8 bk0 = *(short8*)&ks[(jb << 4) + (ln & 15)][ak0];
            short8 bk1 = *(short8*)&ks[(jb << 4) + (ln & 15)][ak0 + 32];
            z = __builtin_amdgcn_mfma_f32_16x16x32_bf16(aq0, bk0, z, 0, 0, 0);
            z = __builtin_amdgcn_mfma_f32_16x16x32_bf16(aq1, bk1, z, 0, 0, 0);
            s_acc[jb] = z;
        }
        float mx[4];
        #pragma unroll
        for (int r = 0; r < 4; ++r)
            mx[r] = fmaxf(fmaxf(s_acc[0][r], s_acc[1][r]),
                          fmaxf(s_acc[2][r], s_acc[3][r]));
        #pragma unroll
        for (int off = 1; off < 16; off <<= 1)
            #pragma unroll
            for (int r = 0; r < 4; ++r)
                mx[r] = fmaxf(mx[r], __shfl_xor(mx[r], off, 64));
        float fac[4];
        #pragma unroll
        for (int r = 0; r < 4; ++r) {
            float mn = fmaxf(mr[r], mx[r]);
            fac[r] = expf(mr[r] - mn);
            mr[r] = mn;
        }
        float rs[4] = {};
        #pragma unroll
        for (int jb = 0; jb < 4; ++jb)
            #pragma unroll
            for (int r = 0; r < 4; ++r) {
                float p = expf(s_acc[jb][r] - mr[r]);
                rs[r] += p;
                ps[wv][((ln >> 4) << 2) + r][(jb << 4) + (ln & 15)] = f2bf(p);
            }
        #pragma unroll
        for (int off = 1; off < 16; off <<= 1)
            #pragma unroll
            for (int r = 0; r < 4; ++r)
                rs[r] += __shfl_xor(rs[r], off, 64);
        #pragma unroll
        for (int r = 0; r < 4; ++r) lr[r] = lr[r] * fac[r] + rs[r];
        #pragma unroll
        for (int jb = 0; jb < 4; ++jb)
            #pragma unroll
            for (int r = 0; r < 4; ++r)
                o_acc[jb][r] *= fac[r];
        short8 pa0 = *(short8*)&ps[wv][ln & 15][ak0];
        short8 pa1 = *(short8*)&ps[wv][ln & 15][ak0 + 32];
        #pragma unroll
        for (int jb = 0; jb < 4; ++jb) {
            short8 bv0 = *(short8*)&vts[(jb << 4) + (ln & 15)][ak0];
            short8 bv1 = *(short8*)&vts[(jb << 4) + (ln & 15)][ak0 + 32];
            f32x4 z = o_acc[jb];
            z = __builtin_amdgcn_mfma_f32_16x16x32_bf16(pa0, bv0, z, 0, 0, 0);
            z = __builtin_amdgcn_mfma_f32_16x16x32_bf16(pa1, bv1, z, 0, 0, 0);
            o_acc[jb] = z;
        }
    }
    float invl[4];
    #pragma unroll
    for (int r = 0; r < 4; ++r) invl[r] = 1.0f / lr[r];
    #pragma unroll
    for (int jb = 0; jb < 4; ++jb)
        #pragma unroll
        for (int r = 0; r < 4; ++r) {
            int row_q = (wv << 4) + ((ln >> 4) << 2) + r;
            int col_d = (jb << 4) + (ln & 15);
            size_t idx = ((size_t)b * 4096 + n0 + row_q) * 768 + 11 * 64 + col_d;
            unsigned short hh, ll;
            bfsplit(o_acc[jb][r] * invl[r], hh, ll);
            ctxh[idx] = hh; ctxl[idx] = ll;
        }
}

// ---------------------------------------------------------------------------
// K8: proj GEMM via bf16x3 MFMA: out = ctx(16384x768) @ proj_w^T + proj_b
// ---------------------------------------------------------------------------
__global__ __launch_bounds__(256, 2) void gemm_proj_mfma(
    const unsigned short* __restrict__ Xh, const unsigned short* __restrict__ Xl,
    const unsigned short* __restrict__ Wh, const unsigned short* __restrict__ Wl,
    const float* __restrict__ bias, float* __restrict__ out)
{
    __shared__ unsigned short Ah[128][40], Al[128][40], Bh[128][40], Bl[128][40];
    const int tid = threadIdx.x;
    const int brow = blockIdx.y << 7, bcol = blockIdx.x << 7;
    const int ln = tid & 63, wv = tid >> 6;
    const int wr = (wv >> 1) << 6, wc = (wv & 1) << 6;
    const int srow = tid >> 1, sk = (tid & 1) << 4;
    const size_t ag = (size_t)(brow + srow) * 768 + sk;
    const size_t bg = (size_t)(bcol + srow) * 768 + sk;
    const int fr = ln & 15, fk = (ln >> 4) << 3;

    f32x4 acc[4][4] = {};
    for (int k0 = 0; k0 < 768; k0 += 32) {
        short8 xh0 = *(const short8*)(Xh + ag + k0);
        short8 xh1 = *(const short8*)(Xh + ag + k0 + 8);
        short8 xl0 = *(const short8*)(Xl + ag + k0);
        short8 xl1 = *(const short8*)(Xl + ag + k0 + 8);
        short8 wh0 = *(const short8*)(Wh + bg + k0);
        short8 wh1 = *(const short8*)(Wh + bg + k0 + 8);
        short8 wl0 = *(const short8*)(Wl + bg + k0);
        short8 wl1 = *(const short8*)(Wl + bg + k0 + 8);
        __syncthreads();
        *(short8*)&Ah[srow][sk] = xh0; *(short8*)&Ah[srow][sk + 8] = xh1;
        *(short8*)&Al[srow][sk] = xl0; *(short8*)&Al[srow][sk + 8] = xl1;
        *(short8*)&Bh[srow][sk] = wh0; *(short8*)&Bh[srow][sk + 8] = wh1;
        *(short8*)&Bl[srow][sk] = wl0; *(short8*)&Bl[srow][sk + 8] = wl1;
        __syncthreads();
        short8 ah[4], al[4], bh[4], bl[4];
        #pragma unroll
        for (int i = 0; i < 4; ++i) {
            ah[i] = *(short8*)&Ah[wr + (i << 4) + fr][fk];
            al[i] = *(short8*)&Al[wr + (i << 4) + fr][fk];
        }
        #pragma unroll
        for (int j = 0; j < 4; ++j) {
            bh[j] = *(short8*)&Bh[wc + (j << 4) + fr][fk];
            bl[j] = *(short8*)&Bl[wc + (j << 4) + fr][fk];
        }
        #pragma unroll
        for (int i = 0; i < 4; ++i)
            #pragma unroll
            for (int j = 0; j < 4; ++j) {
                acc[i][j] = __builtin_amdgcn_mfma_f32_16x16x32_bf16(ah[i], bh[j], acc[i][j], 0, 0, 0);
                acc[i][j] = __builtin_amdgcn_mfma_f32_16x16x32_bf16(ah[i], bl[j], acc[i][j], 0, 0, 0);
                acc[i][j] = __builtin_amdgcn_mfma_f32_16x16x32_bf16(al[i], bh[j], acc[i][j], 0, 0, 0);
            }
    }
    const int fg = ln >> 4;
    #pragma unroll
    for (int j = 0; j < 4; ++j) {
        int c = bcol + wc + (j << 4) + fr;
        float bb = bias[c];
        #pragma unroll
        for (int i = 0; i < 4; ++i)
            #pragma unroll
            for (int r = 0; r < 4; ++r) {
                int row = brow + wr + (i << 4) + (fg << 2) + r;
                out[(size_t)row * 768 + c] = acc[i][j][r] + bb;
            }
    }
}

// ---------------------------------------------------------------------------
extern "C" void kernel_launch(void* const* d_in, const int* in_sizes, int n_in,
                              void* d_out, int out_size, void* d_ws, size_t ws_size,
                              hipStream_t stream)
{
    const float* x      = (const float*)d_in[0];
    const float* qkv_w  = (const float*)d_in[1];
    const float* qkv_b  = (const float*)d_in[2];
    const float* proj_w = (const float*)d_in[3];
    const float* proj_b = (const float*)d_in[4];
    float* out = (float*)d_out;

    float* ws  = (float*)d_ws;
    const size_t QKV = (size_t)4 * 12 * 4096 * 64;   // 12,582,912
    float* q    = ws;
    float* k    = q + QKV;
    float* v    = k + QKV;
    unsigned short* ctxh = (unsigned short*)(v + QKV);   // QKV shorts
    unsigned short* ctxl = ctxh + QKV;                    // QKV shorts
    float* scm  = (float*)(ctxl + QKV);
    float* eB   = scm + 4096;
    float* den  = eB + 44 * 4096;
    float* pi_  = den + 64;
    float* Wb   = pi_ + 44 * 4096;
    float* Tb   = Wb + 44 * 4160;
    unsigned short* Whi  = (unsigned short*)(Tb + 44 * 4160);
    unsigned short* Wlo  = Whi + (size_t)2304 * 768;
    unsigned short* Pwhi = Wlo + (size_t)2304 * 768;
    unsigned short* Pwlo = Pwhi + (size_t)768 * 768;

    // d_out scratch phase 1: X hi/lo split (exactly fills d_out; dead after
    // gemm_qkv_mfma). Phase 2: wflash partials (after gemm_qkv completes).
    unsigned short* Xhi = (unsigned short*)out;
    unsigned short* Xlo = Xhi + QKV;
    float* wacc = out;
    float* wl   = wacc + 1441792;
    float* wm   = wl + 22528;

    preconv<<<2048, 256, 0, stream>>>(x, Xhi, Xlo, 3145728);
    preconv<<<1024, 256, 0, stream>>>(qkv_w, Whi, Wlo, 442368);
    preconv<<<512, 256, 0, stream>>>(proj_w, Pwhi, Pwlo, 147456);
    gemm_qkv_mfma<<<dim3(18, 128), 256, 0, stream>>>(Xhi, Xlo, Whi, Wlo, qkv_b, q, k, v);
    wflash<<<dim3(8, 44), 256, 0, stream>>>(q, k, v, wacc, wl, wm);
    wmerge<<<44, 256, 0, stream>>>(wacc, wl, wm, Wb, scm);
    eb_kernel<<<44, 256, 0, stream>>>(q, k, scm, eB);
    norms_kernel<<<11, 256, 0, stream>>>(eB, den);
    pinv_kernel<<<44, 256, 0, stream>>>(eB, den, pi_);
    pw_kernel<<<44, 256, 0, stream>>>(pi_, Wb, Tb);
    outp_kernel<<<dim3(64, 44), 256, 0, stream>>>(q, k, Tb, ctxh, ctxl);
    flash_h11<<<dim3(64, 4), 256, 0, stream>>>(q, k, v, ctxh, ctxl);
    gemm_proj_mfma<<<dim3(6, 128), 256, 0, stream>>>(ctxh, ctxl, Pwhi, Pwlo, proj_b, out);
}

// Round 5
// 723.337 us; speedup vs baseline: 8.4776x; 1.4829x over previous
//
#include <hip/hip_runtime.h>

// B=4, N=4096, C=768, H=12, D=64, M=64, PNP=11, SCALE=1/8

typedef __attribute__((ext_vector_type(8))) short short8;
typedef __attribute__((ext_vector_type(4))) float f32x4;
typedef __attribute__((ext_vector_type(4))) unsigned short ushort4v;

static __device__ __forceinline__ unsigned short f2bf(float f) {
    union { float f; unsigned u; } x; x.f = f;
    unsigned r = x.u + 0x7fffu + ((x.u >> 16) & 1u);   // RNE
    return (unsigned short)(r >> 16);
}

static __device__ __forceinline__ void bfsplit(float x, unsigned short& h, unsigned short& l) {
    unsigned short hh = f2bf(x);
    union { unsigned u; float f; } t; t.u = (unsigned)hh << 16;
    h = hh;
    l = f2bf(x - t.f);    // exact residual, RNE to bf16
}

// ---------------------------------------------------------------------------
// K0: split fp32 array into bf16 (hi, lo) pair arrays. memory-bound.
// ---------------------------------------------------------------------------
__global__ __launch_bounds__(256) void preconv(
    const float* __restrict__ in, unsigned short* __restrict__ hi,
    unsigned short* __restrict__ lo, int n4)
{
    for (int i = blockIdx.x * 256 + threadIdx.x; i < n4; i += gridDim.x * 256) {
        float4 f = *(const float4*)(in + (size_t)i * 4);
        float vs[4] = {f.x, f.y, f.z, f.w};
        ushort4v h, l;
        #pragma unroll
        for (int j = 0; j < 4; ++j) {
            unsigned short hh, ll;
            bfsplit(vs[j], hh, ll);
            h[j] = hh; l[j] = ll;
        }
        *(ushort4v*)(hi + (size_t)i * 4) = h;
        *(ushort4v*)(lo + (size_t)i * 4) = l;
    }
}

// ---------------------------------------------------------------------------
// K1: QKV GEMM via bf16x3-split MFMA (128x128 tile, BK=32, 4 waves)
// ---------------------------------------------------------------------------
__global__ __launch_bounds__(256, 2) void gemm_qkv_mfma(
    const unsigned short* __restrict__ Xh, const unsigned short* __restrict__ Xl,
    const unsigned short* __restrict__ Wh, const unsigned short* __restrict__ Wl,
    const float* __restrict__ bias,
    float* __restrict__ q, float* __restrict__ k, float* __restrict__ v)
{
    __shared__ unsigned short Ah[128][40], Al[128][40], Bh[128][40], Bl[128][40];
    const int tid = threadIdx.x;
    const int brow = blockIdx.y << 7, bcol = blockIdx.x << 7;
    const int ln = tid & 63, wv = tid >> 6;
    const int wr = (wv >> 1) << 6, wc = (wv & 1) << 6;
    const int srow = tid >> 1, sk = (tid & 1) << 4;
    const size_t ag = (size_t)(brow + srow) * 768 + sk;
    const size_t bg = (size_t)(bcol + srow) * 768 + sk;
    const int fr = ln & 15, fk = (ln >> 4) << 3;

    f32x4 acc[4][4] = {};
    for (int k0 = 0; k0 < 768; k0 += 32) {
        short8 xh0 = *(const short8*)(Xh + ag + k0);
        short8 xh1 = *(const short8*)(Xh + ag + k0 + 8);
        short8 xl0 = *(const short8*)(Xl + ag + k0);
        short8 xl1 = *(const short8*)(Xl + ag + k0 + 8);
        short8 wh0 = *(const short8*)(Wh + bg + k0);
        short8 wh1 = *(const short8*)(Wh + bg + k0 + 8);
        short8 wl0 = *(const short8*)(Wl + bg + k0);
        short8 wl1 = *(const short8*)(Wl + bg + k0 + 8);
        __syncthreads();
        *(short8*)&Ah[srow][sk] = xh0; *(short8*)&Ah[srow][sk + 8] = xh1;
        *(short8*)&Al[srow][sk] = xl0; *(short8*)&Al[srow][sk + 8] = xl1;
        *(short8*)&Bh[srow][sk] = wh0; *(short8*)&Bh[srow][sk + 8] = wh1;
        *(short8*)&Bl[srow][sk] = wl0; *(short8*)&Bl[srow][sk + 8] = wl1;
        __syncthreads();
        short8 ah[4], al[4], bh[4], bl[4];
        #pragma unroll
        for (int i = 0; i < 4; ++i) {
            ah[i] = *(short8*)&Ah[wr + (i << 4) + fr][fk];
            al[i] = *(short8*)&Al[wr + (i << 4) + fr][fk];
        }
        #pragma unroll
        for (int j = 0; j < 4; ++j) {
            bh[j] = *(short8*)&Bh[wc + (j << 4) + fr][fk];
            bl[j] = *(short8*)&Bl[wc + (j << 4) + fr][fk];
        }
        #pragma unroll
        for (int i = 0; i < 4; ++i)
            #pragma unroll
            for (int j = 0; j < 4; ++j) {
                acc[i][j] = __builtin_amdgcn_mfma_f32_16x16x32_bf16(ah[i], bh[j], acc[i][j], 0, 0, 0);
                acc[i][j] = __builtin_amdgcn_mfma_f32_16x16x32_bf16(ah[i], bl[j], acc[i][j], 0, 0, 0);
                acc[i][j] = __builtin_amdgcn_mfma_f32_16x16x32_bf16(al[i], bh[j], acc[i][j], 0, 0, 0);
            }
    }
    const int fg = ln >> 4;
    #pragma unroll
    for (int j = 0; j < 4; ++j) {
        int c = bcol + wc + (j << 4) + fr;
        float bb = bias[c];
        int t = c / 768;
        int rem = c - t * 768;
        int h = rem >> 6, d = rem & 63;
        #pragma unroll
        for (int i = 0; i < 4; ++i)
            #pragma unroll
            for (int r = 0; r < 4; ++r) {
                int row = brow + wr + (i << 4) + (fg << 2) + r;
                int b = row >> 12, n = row & 4095;
                float val = acc[i][j][r] + bb;
                size_t idx = (((size_t)(b * 12 + h) << 12) + n) * 64 + d;
                if (t == 0)      q[idx] = val * 0.125f;
                else if (t == 1) k[idx] = val;
                else             v[idx] = val;
            }
    }
}

// ---------------------------------------------------------------------------
// K2: fused flash pass for SC: online max + W-partial per 512-n chunk (fp32)
// ---------------------------------------------------------------------------
__global__ __launch_bounds__(256) void wflash(
    const float* __restrict__ q, const float* __restrict__ k,
    const float* __restrict__ v,
    float* __restrict__ wacc, float* __restrict__ wl, float* __restrict__ wm)
{
    int chunk = blockIdx.x;
    int bh = blockIdx.y;
    int b = bh / 11, h = bh - b * 11;
    size_t base = ((size_t)(b * 12 + h)) << 12;
    const float* qb = q + base * 64;
    const float* kb = k + base * 64;
    const float* vb = v + base * 64;
    __shared__ float qmT[64][68];
    __shared__ float ktT[64][68];
    __shared__ float vt [64][68];
    __shared__ float pT [64][68];
    __shared__ float rmax[64][16];
    __shared__ float mrun[64], fac[64];
    int tid = threadIdx.x;
    int tx = tid & 15, ty = tid >> 4;
    int rr = tid >> 2, dg = (tid & 3) << 4;
    {
        const float* qrow = qb + ((size_t)rr << 12) + dg;
        #pragma unroll
        for (int i = 0; i < 16; i += 4) {
            float4 f = *(const float4*)(qrow + i);
            qmT[dg+i][rr] = f.x; qmT[dg+i+1][rr] = f.y;
            qmT[dg+i+2][rr] = f.z; qmT[dg+i+3][rr] = f.w;
        }
    }
    if (tid < 64) mrun[tid] = -1e30f;
    float acc4[4][4] = {};
    float lsum[4] = {};
    for (int t = 0; t < 8; ++t) {
        int n0 = (chunk << 9) + (t << 6);
        __syncthreads();
        const float* krow = kb + (((size_t)(n0 + rr)) << 6) + dg;
        #pragma unroll
        for (int i = 0; i < 16; i += 4) {
            float4 f = *(const float4*)(krow + i);
            ktT[dg+i][rr] = f.x; ktT[dg+i+1][rr] = f.y;
            ktT[dg+i+2][rr] = f.z; ktT[dg+i+3][rr] = f.w;
        }
        const float* vrow = vb + (((size_t)(n0 + rr)) << 6) + dg;
        #pragma unroll
        for (int i = 0; i < 16; i += 4)
            *(float4*)&vt[rr][dg + i] = *(const float4*)(vrow + i);
        __syncthreads();
        float s4[4][4];
        #pragma unroll
        for (int i = 0; i < 4; ++i)
            #pragma unroll
            for (int j = 0; j < 4; ++j) s4[i][j] = 0.f;
        #pragma unroll 4
        for (int d = 0; d < 64; ++d) {
            float4 a  = *(const float4*)&qmT[d][ty << 2];
            float4 bb = *(const float4*)&ktT[d][tx << 2];
            float av[4] = {a.x,a.y,a.z,a.w};
            float bv[4] = {bb.x,bb.y,bb.z,bb.w};
            #pragma unroll
            for (int i = 0; i < 4; ++i)
                #pragma unroll
                for (int j = 0; j < 4; ++j)
                    s4[i][j] += av[i] * bv[j];
        }
        #pragma unroll
        for (int i = 0; i < 4; ++i) {
            float tm = fmaxf(fmaxf(s4[i][0], s4[i][1]), fmaxf(s4[i][2], s4[i][3]));
            rmax[(ty << 2) + i][tx] = tm;
        }
        __syncthreads();
        if (tid < 64) {
            float mx = rmax[tid][0];
            #pragma unroll
            for (int c = 1; c < 16; ++c) mx = fmaxf(mx, rmax[tid][c]);
            float mn = fmaxf(mrun[tid], mx);
            fac[tid] = expf(mrun[tid] - mn);
            mrun[tid] = mn;
        }
        __syncthreads();
        #pragma unroll
        for (int i = 0; i < 4; ++i) {
            int m = (ty << 2) + i;
            float f = fac[m], mr = mrun[m];
            float ls = lsum[i] * f;
            #pragma unroll
            for (int j = 0; j < 4; ++j) {
                acc4[i][j] *= f;
                float p = expf(s4[i][j] - mr);
                ls += p;
                pT[(tx << 2) + j][m] = p;
            }
            lsum[i] = ls;
        }
        __syncthreads();
        #pragma unroll 4
        for (int n = 0; n < 64; ++n) {
            float4 pp = *(const float4*)&pT[n][ty << 2];
            float4 vv = *(const float4*)&vt[n][tx << 2];
            float pa[4] = {pp.x,pp.y,pp.z,pp.w};
            float va[4] = {vv.x,vv.y,vv.z,vv.w};
            #pragma unroll
            for (int i = 0; i < 4; ++i)
                #pragma unroll
                for (int j = 0; j < 4; ++j)
                    acc4[i][j] += pa[i] * va[j];
        }
    }
    int cidx = (bh << 3) + chunk;
    #pragma unroll
    for (int i = 0; i < 4; ++i)
        #pragma unroll
        for (int j = 0; j < 4; ++j)
            wacc[((size_t)cidx << 12) + ((size_t)((ty << 2) + i) << 6) + (tx << 2) + j] = acc4[i][j];
    __syncthreads();
    #pragma unroll
    for (int i = 0; i < 4; ++i) rmax[(ty << 2) + i][tx] = lsum[i];
    __syncthreads();
    if (tid < 64) {
        float s = 0.f;
        #pragma unroll
        for (int c = 0; c < 16; ++c) s += rmax[tid][c];
        wl[cidx * 64 + tid] = s;
        wm[cidx * 64 + tid] = mrun[tid];
    }
}

// K2b: merge chunk partials -> Wb (65 cols, col 64 = ones-column) + scm
__global__ __launch_bounds__(256) void wmerge(
    const float* __restrict__ wacc, const float* __restrict__ wl,
    const float* __restrict__ wm,
    float* __restrict__ Wb, float* __restrict__ scm)
{
    int bh = blockIdx.x;
    int tid = threadIdx.x;
    __shared__ float fcs[8][64];
    if (tid < 64) {
        float mx = -1e30f;
        #pragma unroll
        for (int c = 0; c < 8; ++c)
            mx = fmaxf(mx, wm[((bh << 3) + c) * 64 + tid]);
        scm[(bh << 6) + tid] = mx;
        #pragma unroll
        for (int c = 0; c < 8; ++c)
            fcs[c][tid] = expf(wm[((bh << 3) + c) * 64 + tid] - mx);
    }
    __syncthreads();
    for (int e = tid; e < 4096; e += 256) {
        int m = e >> 6, j = e & 63;
        float s = 0.f;
        #pragma unroll
        for (int c = 0; c < 8; ++c)
            s += fcs[c][m] * wacc[((size_t)((bh << 3) + c) << 12) + e];
        Wb[(size_t)bh * 4160 + m * 65 + j] = s;
    }
    if (tid < 64) {
        float s = 0.f;
        #pragma unroll
        for (int c = 0; c < 8; ++c)
            s += fcs[c][tid] * wl[((bh << 3) + c) * 64 + tid];
        Wb[(size_t)bh * 4160 + tid * 65 + 64] = s;
    }
}

// ---------------------------------------------------------------------------
// K3a: eB (fp32)
// ---------------------------------------------------------------------------
__global__ __launch_bounds__(256) void eb_kernel(
    const float* __restrict__ q, const float* __restrict__ k,
    const float* __restrict__ scm, float* __restrict__ eB)
{
    int bh = blockIdx.x;
    int b = bh / 11, h = bh - b * 11;
    size_t base = ((size_t)(b * 12 + h)) << 12;
    const float* qb = q + base * 64;
    const float* kb = k + base * 64;
    __shared__ float qm[64][65], km[64][65];
    int tid = threadIdx.x;
    for (int e = tid; e < 4096; e += 256) {
        int mm = e >> 6, d = e & 63;
        qm[mm][d] = qb[((size_t)mm << 12) + d];
        km[mm][d] = kb[((size_t)mm << 12) + d];
    }
    __syncthreads();
    int m = tid >> 2, l0 = tid & 3;
    float smax = scm[(bh << 6) + m];
    for (int l = l0; l < 64; l += 4) {
        float s = 0.f;
        #pragma unroll
        for (int d = 0; d < 64; ++d) s += qm[m][d] * km[l][d];
        eB[((size_t)bh << 12) + (m << 6) + l] = expf(fmaxf(s - smax, -88.f));
    }
}

// ---------------------------------------------------------------------------
// K3b: per-head norms
// ---------------------------------------------------------------------------
__global__ __launch_bounds__(256) void norms_kernel(
    const float* __restrict__ eB, float* __restrict__ denom)
{
    int h = blockIdx.x;
    int tid = threadIdx.x;
    int b = tid >> 6, idx = tid & 63;
    int bh = b * 11 + h;
    const float* E = eB + ((size_t)bh << 12);
    float rs = 0.f, cs = 0.f;
    #pragma unroll 4
    for (int l = 0; l < 64; ++l) rs += E[(idx << 6) + l];
    #pragma unroll 4
    for (int m = 0; m < 64; ++m) cs += E[(m << 6) + idx];
    __shared__ float r1[256], r2[256];
    r1[tid] = rs; r2[tid] = cs;
    __syncthreads();
    for (int s = 128; s > 0; s >>= 1) {
        if (tid < s) {
            r1[tid] = fmaxf(r1[tid], r1[tid + s]);
            r2[tid] = fmaxf(r2[tid], r2[tid + s]);
        }
        __syncthreads();
    }
    if (tid == 0) denom[h] = r1[0] * r2[0];
}

// ---------------------------------------------------------------------------
// K3c: pinv via 6 Newton iterations — bf16x3 MFMA matmuls, one block per bh.
// All 64x64 matrices in LDS as (hi,lo) bf16 pairs, row-major + transposed.
// Linear terms (7/15·XZ, 13·Z) use the lane's own C-fragment registers/Zf.
// ---------------------------------------------------------------------------
__device__ __forceinline__ void mm64x3(
    const unsigned short (&Ahi)[64][72], const unsigned short (&Alo)[64][72],
    const unsigned short (&BThi)[64][72], const unsigned short (&BTlo)[64][72],
    int wr, int wc, int fr, int fk, f32x4 (&acc)[2][2])
{
    #pragma unroll
    for (int ks = 0; ks < 2; ++ks) {
        const int kb = (ks << 5) + fk;
        short8 ah[2], al[2], bh[2], bl[2];
        #pragma unroll
        for (int i = 0; i < 2; ++i) {
            ah[i] = *(const short8*)&Ahi[wr + (i << 4) + fr][kb];
            al[i] = *(const short8*)&Alo[wr + (i << 4) + fr][kb];
            bh[i] = *(const short8*)&BThi[wc + (i << 4) + fr][kb];
            bl[i] = *(const short8*)&BTlo[wc + (i << 4) + fr][kb];
        }
        #pragma unroll
        for (int i = 0; i < 2; ++i)
            #pragma unroll
            for (int j = 0; j < 2; ++j) {
                acc[i][j] = __builtin_amdgcn_mfma_f32_16x16x32_bf16(ah[i], bh[j], acc[i][j], 0, 0, 0);
                acc[i][j] = __builtin_amdgcn_mfma_f32_16x16x32_bf16(ah[i], bl[j], acc[i][j], 0, 0, 0);
                acc[i][j] = __builtin_amdgcn_mfma_f32_16x16x32_bf16(al[i], bh[j], acc[i][j], 0, 0, 0);
            }
    }
}

__global__ __launch_bounds__(256) void pinv_kernel(
    const float* __restrict__ eB, const float* __restrict__ denom,
    float* __restrict__ pi_)
{
    __shared__ unsigned short Xh[64][72],  Xl[64][72];
    __shared__ unsigned short Zh[64][72],  Zl[64][72];
    __shared__ unsigned short ZTh[64][72], ZTl[64][72];
    __shared__ unsigned short Mh[64][72],  Ml[64][72];    // XZ
    __shared__ unsigned short MTh[64][72], MTl[64][72];
    __shared__ unsigned short Th[64][72],  Tbl[64][72];   // TA/TB transposed
    __shared__ float Zf[64][68];
    int bh = blockIdx.x;
    int h = bh % 11;
    int tid = threadIdx.x;
    float dn = denom[h];
    const int ln = tid & 63, wv = tid >> 6;
    const int wr = (wv >> 1) << 5, wc = (wv & 1) << 5;
    const int fr = ln & 15, fk = (ln >> 4) << 3;
    const int rg = (ln >> 4) << 2;

    for (int e = tid; e < 4096; e += 256) {
        int m = e >> 6, l = e & 63;
        float xv = eB[((size_t)bh << 12) + e];
        unsigned short hh, ll;
        bfsplit(xv, hh, ll);
        Xh[m][l] = hh; Xl[m][l] = ll;
        float zv = xv / dn;
        Zf[l][m] = zv;
        bfsplit(zv, hh, ll);
        Zh[l][m] = hh; Zl[l][m] = ll;     // Z row-major
        ZTh[m][l] = hh; ZTl[m][l] = ll;   // Z transposed
    }
    __syncthreads();

    for (int it = 0; it < 6; ++it) {
        // ---- step 1: M = X @ Z  (keep fp32 fragments in registers) ----
        f32x4 mm1[2][2] = {};
        mm64x3(Xh, Xl, ZTh, ZTl, wr, wc, fr, fk, mm1);
        #pragma unroll
        for (int i = 0; i < 2; ++i)
            #pragma unroll
            for (int j = 0; j < 2; ++j)
                #pragma unroll
                for (int r = 0; r < 4; ++r) {
                    int row = wr + (i << 4) + rg + r, col = wc + (j << 4) + fr;
                    unsigned short hh, ll;
                    bfsplit(mm1[i][j][r], hh, ll);
                    Mh[row][col] = hh;  Ml[row][col] = ll;
                    MTh[col][row] = hh; MTl[col][row] = ll;
                }
        __syncthreads();
        // ---- step 2: TA = 7M - M@M  -> Th/Tbl (transposed) ----
        f32x4 a2[2][2] = {};
        mm64x3(Mh, Ml, MTh, MTl, wr, wc, fr, fk, a2);
        #pragma unroll
        for (int i = 0; i < 2; ++i)
            #pragma unroll
            for (int j = 0; j < 2; ++j)
                #pragma unroll
                for (int r = 0; r < 4; ++r) {
                    int row = wr + (i << 4) + rg + r, col = wc + (j << 4) + fr;
                    float val = 7.f * mm1[i][j][r] - a2[i][j][r];
                    unsigned short hh, ll;
                    bfsplit(val, hh, ll);
                    Th[col][row] = hh; Tbl[col][row] = ll;
                }
        __syncthreads();
        // ---- step 3: TB = 15M - M@TA -> Th/Tbl (read then overwrite) ----
        f32x4 a3[2][2] = {};
        mm64x3(Mh, Ml, Th, Tbl, wr, wc, fr, fk, a3);
        __syncthreads();   // all reads of TA complete before overwrite
        #pragma unroll
        for (int i = 0; i < 2; ++i)
            #pragma unroll
            for (int j = 0; j < 2; ++j)
                #pragma unroll
                for (int r = 0; r < 4; ++r) {
                    int row = wr + (i << 4) + rg + r, col = wc + (j << 4) + fr;
                    float val = 15.f * mm1[i][j][r] - a3[i][j][r];
                    unsigned short hh, ll;
                    bfsplit(val, hh, ll);
                    Th[col][row] = hh; Tbl[col][row] = ll;
                }
        __syncthreads();
        // ---- step 4: Znew = 0.25(13Z - Z@TB) ----
        f32x4 a4[2][2] = {};
        mm64x3(Zh, Zl, Th, Tbl, wr, wc, fr, fk, a4);
        float zn[2][2][4];
        #pragma unroll
        for (int i = 0; i < 2; ++i)
            #pragma unroll
            for (int j = 0; j < 2; ++j)
                #pragma unroll
                for (int r = 0; r < 4; ++r) {
                    int row = wr + (i << 4) + rg + r, col = wc + (j << 4) + fr;
                    zn[i][j][r] = 0.25f * (13.f * Zf[row][col] - a4[i][j][r]);
                }
        __syncthreads();   // all reads of Z complete before overwrite
        #pragma unroll
        for (int i = 0; i < 2; ++i)
            #pragma unroll
            for (int j = 0; j < 2; ++j)
                #pragma unroll
                for (int r = 0; r < 4; ++r) {
                    int row = wr + (i << 4) + rg + r, col = wc + (j << 4) + fr;
                    float val = zn[i][j][r];
                    Zf[row][col] = val;
                    unsigned short hh, ll;
                    bfsplit(val, hh, ll);
                    Zh[row][col] = hh;  Zl[row][col] = ll;
                    ZTh[col][row] = hh; ZTl[col][row] = ll;
                }
        __syncthreads();
    }
    for (int e = tid; e < 4096; e += 256)
        pi_[((size_t)bh << 12) + e] = Zf[e >> 6][e & 63];
}

// ---------------------------------------------------------------------------
// K5: T = pi @ W  (64x64 @ 64x65)
// ---------------------------------------------------------------------------
__global__ __launch_bounds__(256) void pw_kernel(
    const float* __restrict__ pi_, const float* __restrict__ Wb,
    float* __restrict__ Tb)
{
    int bh = blockIdx.x;
    __shared__ float P[64][65];
    __shared__ float Wl[64][66];
    int tid = threadIdx.x;
    for (int e = tid; e < 4096; e += 256)
        P[e >> 6][e & 63] = pi_[((size_t)bh << 12) + e];
    for (int e = tid; e < 64 * 65; e += 256) {
        int l = e / 65, j = e - l * 65;
        Wl[l][j] = Wb[(size_t)bh * 4160 + e];
    }
    __syncthreads();
    int m = tid & 63, g = tid >> 6;
    #pragma unroll
    for (int t = 0; t < 17; ++t) {
        int j = g + (t << 2);
        if (j > 64) break;
        float s = 0.f;
        #pragma unroll
        for (int l = 0; l < 64; ++l) s += P[m][l] * Wl[l][j];
        Tb[(size_t)((bh << 6) + m) * 65 + j] = s;
    }
}

// ---------------------------------------------------------------------------
// K6: out_p tile (register-tiled fp32) -> ctx_hi/ctx_lo (bf16 split)
// ---------------------------------------------------------------------------
__global__ __launch_bounds__(256) void outp_kernel(
    const float* __restrict__ q, const float* __restrict__ k,
    const float* __restrict__ Tb,
    unsigned short* __restrict__ ctxh, unsigned short* __restrict__ ctxl)
{
    int bh = blockIdx.y;
    int b = bh / 11, h = bh - b * 11;
    int n0 = blockIdx.x << 6;
    size_t base = ((size_t)(b * 12 + h)) << 12;
    const float* qb = q + base * 64;
    const float* kb = k + base * 64;
    __shared__ float qtT[64][68];
    __shared__ float kmT[64][68];
    __shared__ float pT [64][68];
    __shared__ float Tl [64][68];
    __shared__ float rmax[64][17];
    int tid = threadIdx.x;
    int tx = tid & 15, ty = tid >> 4;
    int rr = tid >> 2, dg = (tid & 3) << 4;
    {
        const float* qrow = qb + (((size_t)(n0 + rr)) << 6) + dg;
        const float* krow = kb + ((size_t)rr << 12) + dg;
        #pragma unroll
        for (int i = 0; i < 16; i += 4) {
            float4 f = *(const float4*)(qrow + i);
            qtT[dg+i][rr] = f.x; qtT[dg+i+1][rr] = f.y;
            qtT[dg+i+2][rr] = f.z; qtT[dg+i+3][rr] = f.w;
            float4 g2 = *(const float4*)(krow + i);
            kmT[dg+i][rr] = g2.x; kmT[dg+i+1][rr] = g2.y;
            kmT[dg+i+2][rr] = g2.z; kmT[dg+i+3][rr] = g2.w;
        }
    }
    for (int e = tid; e < 4160; e += 256) {
        int m = e / 65, j = e - m * 65;
        Tl[m][j] = Tb[(size_t)((bh << 6) + m) * 65 + j];
    }
    __syncthreads();
    float s4[4][4];
    #pragma unroll
    for (int i = 0; i < 4; ++i)
        #pragma unroll
        for (int j = 0; j < 4; ++j) s4[i][j] = 0.f;
    #pragma unroll 4
    for (int d = 0; d < 64; ++d) {
        float4 a  = *(const float4*)&qtT[d][ty << 2];
        float4 bb = *(const float4*)&kmT[d][tx << 2];
        float av[4] = {a.x,a.y,a.z,a.w};
        float bv[4] = {bb.x,bb.y,bb.z,bb.w};
        #pragma unroll
        for (int i = 0; i < 4; ++i)
            #pragma unroll
            for (int j = 0; j < 4; ++j)
                s4[i][j] += av[i] * bv[j];
    }
    #pragma unroll
    for (int i = 0; i < 4; ++i) {
        float tm = fmaxf(fmaxf(s4[i][0], s4[i][1]), fmaxf(s4[i][2], s4[i][3]));
        rmax[(ty << 2) + i][tx] = tm;
    }
    __syncthreads();
    if (tid < 64) {
        float mx = rmax[tid][0];
        #pragma unroll
        for (int c = 1; c < 16; ++c) mx = fmaxf(mx, rmax[tid][c]);
        rmax[tid][16] = mx;
    }
    __syncthreads();
    #pragma unroll
    for (int i = 0; i < 4; ++i) {
        float mr = rmax[(ty << 2) + i][16];
        #pragma unroll
        for (int j = 0; j < 4; ++j)
            pT[(tx << 2) + j][(ty << 2) + i] = expf(s4[i][j] - mr);
    }
    __syncthreads();
    float acc[4][4] = {};
    float c64[4] = {};
    #pragma unroll 4
    for (int m = 0; m < 64; ++m) {
        float4 pp = *(const float4*)&pT[m][ty << 2];
        float4 tt = *(const float4*)&Tl[m][tx << 2];
        float t64 = Tl[m][64];
        float pa[4] = {pp.x,pp.y,pp.z,pp.w};
        float ta[4] = {tt.x,tt.y,tt.z,tt.w};
        #pragma unroll
        for (int i = 0; i < 4; ++i) {
            #pragma unroll
            for (int j = 0; j < 4; ++j)
                acc[i][j] += pa[i] * ta[j];
            c64[i] += pa[i] * t64;
        }
    }
    #pragma unroll
    for (int i = 0; i < 4; ++i) {
        float inv = 1.0f / fmaxf(c64[i], 1e-8f);
        size_t obase = ((size_t)b * 4096 + (size_t)(n0 + (ty << 2) + i)) * 768 + h * 64 + (tx << 2);
        #pragma unroll
        for (int j = 0; j < 4; ++j) {
            unsigned short hh, ll;
            bfsplit(acc[i][j] * inv, hh, ll);
            ctxh[obase + j] = hh; ctxl[obase + j] = ll;
        }
    }
}

// ---------------------------------------------------------------------------
// K7: softmax head (h=11) — bf16 MFMA flash attention -> ctx_hi/ctx_lo
// ---------------------------------------------------------------------------
__global__ __launch_bounds__(256) void flash_h11(
    const float* __restrict__ q, const float* __restrict__ k,
    const float* __restrict__ v,
    unsigned short* __restrict__ ctxh, unsigned short* __restrict__ ctxl)
{
    int b = blockIdx.y;
    int n0 = blockIdx.x << 6;
    size_t base = ((size_t)(b * 12 + 11)) << 12;
    const float* qb = q + base * 64;
    const float* kb = k + base * 64;
    const float* vb = v + base * 64;
    __shared__ unsigned short qs[64][72];
    __shared__ unsigned short ks[64][72];
    __shared__ unsigned short vts[64][72];
    __shared__ unsigned short ps[4][16][72];
    int tid = threadIdx.x;
    int wv = tid >> 6, ln = tid & 63;
    int rr = tid >> 2, dg = (tid & 3) << 4;
    for (int e = tid * 4; e < 4096; e += 1024) {
        int r2 = e >> 6, d = e & 63;
        float4 f = *(const float4*)(qb + (((size_t)(n0 + r2)) << 6) + d);
        qs[r2][d] = f2bf(f.x); qs[r2][d+1] = f2bf(f.y);
        qs[r2][d+2] = f2bf(f.z); qs[r2][d+3] = f2bf(f.w);
    }
    __syncthreads();
    const int arow = (wv << 4) + (ln & 15);
    const int ak0 = (ln >> 4) << 3;
    short8 aq0 = *(short8*)&qs[arow][ak0];
    short8 aq1 = *(short8*)&qs[arow][ak0 + 32];
    f32x4 o_acc[4] = {};
    float mr[4] = {-1e30f, -1e30f, -1e30f, -1e30f};
    float lr[4] = {};
    for (int m0 = 0; m0 < 4096; m0 += 64) {
        __syncthreads();
        {
            const float* krow = kb + (((size_t)(m0 + rr)) << 6) + dg;
            const float* vrow = vb + (((size_t)(m0 + rr)) << 6) + dg;
            #pragma unroll
            for (int i = 0; i < 16; i += 4) {
                float4 f = *(const float4*)(krow + i);
                ks[rr][dg+i] = f2bf(f.x); ks[rr][dg+i+1] = f2bf(f.y);
                ks[rr][dg+i+2] = f2bf(f.z); ks[rr][dg+i+3] = f2bf(f.w);
                float4 g2 = *(const float4*)(vrow + i);
                vts[dg+i][rr] = f2bf(g2.x); vts[dg+i+1][rr] = f2bf(g2.y);
                vts[dg+i+2][rr] = f2bf(g2.z); vts[dg+i+3][rr] = f2bf(g2.w);
            }
        }
        __syncthreads();
        f32x4 s_acc[4];
        #pragma unroll
        for (int jb = 0; jb < 4; ++jb) {
            f32x4 z = {};
            short8 bk0 = *(short8*)&ks[(jb << 4) + (ln & 15)][ak0];
            short8 bk1 = *(short8*)&ks[(jb << 4) + (ln & 15)][ak0 + 32];
            z = __builtin_amdgcn_mfma_f32_16x16x32_bf16(aq0, bk0, z, 0, 0, 0);
            z = __builtin_amdgcn_mfma_f32_16x16x32_bf16(aq1, bk1, z, 0, 0, 0);
            s_acc[jb] = z;
        }
        float mx[4];
        #pragma unroll
        for (int r = 0; r < 4; ++r)
            mx[r] = fmaxf(fmaxf(s_acc[0][r], s_acc[1][r]),
                          fmaxf(s_acc[2][r], s_acc[3][r]));
        #pragma unroll
        for (int off = 1; off < 16; off <<= 1)
            #pragma unroll
            for (int r = 0; r < 4; ++r)
                mx[r] = fmaxf(mx[r], __shfl_xor(mx[r], off, 64));
        float fac[4];
        #pragma unroll
        for (int r = 0; r < 4; ++r) {
            float mn = fmaxf(mr[r], mx[r]);
            fac[r] = expf(mr[r] - mn);
            mr[r] = mn;
        }
        float rs[4] = {};
        #pragma unroll
        for (int jb = 0; jb < 4; ++jb)
            #pragma unroll
            for (int r = 0; r < 4; ++r) {
                float p = expf(s_acc[jb][r] - mr[r]);
                rs[r] += p;
                ps[wv][((ln >> 4) << 2) + r][(jb << 4) + (ln & 15)] = f2bf(p);
            }
        #pragma unroll
        for (int off = 1; off < 16; off <<= 1)
            #pragma unroll
            for (int r = 0; r < 4; ++r)
                rs[r] += __shfl_xor(rs[r], off, 64);
        #pragma unroll
        for (int r = 0; r < 4; ++r) lr[r] = lr[r] * fac[r] + rs[r];
        #pragma unroll
        for (int jb = 0; jb < 4; ++jb)
            #pragma unroll
            for (int r = 0; r < 4; ++r)
                o_acc[jb][r] *= fac[r];
        short8 pa0 = *(short8*)&ps[wv][ln & 15][ak0];
        short8 pa1 = *(short8*)&ps[wv][ln & 15][ak0 + 32];
        #pragma unroll
        for (int jb = 0; jb < 4; ++jb) {
            short8 bv0 = *(short8*)&vts[(jb << 4) + (ln & 15)][ak0];
            short8 bv1 = *(short8*)&vts[(jb << 4) + (ln & 15)][ak0 + 32];
            f32x4 z = o_acc[jb];
            z = __builtin_amdgcn_mfma_f32_16x16x32_bf16(pa0, bv0, z, 0, 0, 0);
            z = __builtin_amdgcn_mfma_f32_16x16x32_bf16(pa1, bv1, z, 0, 0, 0);
            o_acc[jb] = z;
        }
    }
    float invl[4];
    #pragma unroll
    for (int r = 0; r < 4; ++r) invl[r] = 1.0f / lr[r];
    #pragma unroll
    for (int jb = 0; jb < 4; ++jb)
        #pragma unroll
        for (int r = 0; r < 4; ++r) {
            int row_q = (wv << 4) + ((ln >> 4) << 2) + r;
            int col_d = (jb << 4) + (ln & 15);
            size_t idx = ((size_t)b * 4096 + n0 + row_q) * 768 + 11 * 64 + col_d;
            unsigned short hh, ll;
            bfsplit(o_acc[jb][r] * invl[r], hh, ll);
            ctxh[idx] = hh; ctxl[idx] = ll;
        }
}

// ---------------------------------------------------------------------------
// K8: proj GEMM via bf16x3 MFMA: out = ctx(16384x768) @ proj_w^T + proj_b
// ---------------------------------------------------------------------------
__global__ __launch_bounds__(256, 2) void gemm_proj_mfma(
    const unsigned short* __restrict__ Xh, const unsigned short* __restrict__ Xl,
    const unsigned short* __restrict__ Wh, const unsigned short* __restrict__ Wl,
    const float* __restrict__ bias, float* __restrict__ out)
{
    __shared__ unsigned short Ah[128][40], Al[128][40], Bh[128][40], Bl[128][40];
    const int tid = threadIdx.x;
    const int brow = blockIdx.y << 7, bcol = blockIdx.x << 7;
    const int ln = tid & 63, wv = tid >> 6;
    const int wr = (wv >> 1) << 6, wc = (wv & 1) << 6;
    const int srow = tid >> 1, sk = (tid & 1) << 4;
    const size_t ag = (size_t)(brow + srow) * 768 + sk;
    const size_t bg = (size_t)(bcol + srow) * 768 + sk;
    const int fr = ln & 15, fk = (ln >> 4) << 3;

    f32x4 acc[4][4] = {};
    for (int k0 = 0; k0 < 768; k0 += 32) {
        short8 xh0 = *(const short8*)(Xh + ag + k0);
        short8 xh1 = *(const short8*)(Xh + ag + k0 + 8);
        short8 xl0 = *(const short8*)(Xl + ag + k0);
        short8 xl1 = *(const short8*)(Xl + ag + k0 + 8);
        short8 wh0 = *(const short8*)(Wh + bg + k0);
        short8 wh1 = *(const short8*)(Wh + bg + k0 + 8);
        short8 wl0 = *(const short8*)(Wl + bg + k0);
        short8 wl1 = *(const short8*)(Wl + bg + k0 + 8);
        __syncthreads();
        *(short8*)&Ah[srow][sk] = xh0; *(short8*)&Ah[srow][sk + 8] = xh1;
        *(short8*)&Al[srow][sk] = xl0; *(short8*)&Al[srow][sk + 8] = xl1;
        *(short8*)&Bh[srow][sk] = wh0; *(short8*)&Bh[srow][sk + 8] = wh1;
        *(short8*)&Bl[srow][sk] = wl0; *(short8*)&Bl[srow][sk + 8] = wl1;
        __syncthreads();
        short8 ah[4], al[4], bh[4], bl[4];
        #pragma unroll
        for (int i = 0; i < 4; ++i) {
            ah[i] = *(short8*)&Ah[wr + (i << 4) + fr][fk];
            al[i] = *(short8*)&Al[wr + (i << 4) + fr][fk];
        }
        #pragma unroll
        for (int j = 0; j < 4; ++j) {
            bh[j] = *(short8*)&Bh[wc + (j << 4) + fr][fk];
            bl[j] = *(short8*)&Bl[wc + (j << 4) + fr][fk];
        }
        #pragma unroll
        for (int i = 0; i < 4; ++i)
            #pragma unroll
            for (int j = 0; j < 4; ++j) {
                acc[i][j] = __builtin_amdgcn_mfma_f32_16x16x32_bf16(ah[i], bh[j], acc[i][j], 0, 0, 0);
                acc[i][j] = __builtin_amdgcn_mfma_f32_16x16x32_bf16(ah[i], bl[j], acc[i][j], 0, 0, 0);
                acc[i][j] = __builtin_amdgcn_mfma_f32_16x16x32_bf16(al[i], bh[j], acc[i][j], 0, 0, 0);
            }
    }
    const int fg = ln >> 4;
    #pragma unroll
    for (int j = 0; j < 4; ++j) {
        int c = bcol + wc + (j << 4) + fr;
        float bb = bias[c];
        #pragma unroll
        for (int i = 0; i < 4; ++i)
            #pragma unroll
            for (int r = 0; r < 4; ++r) {
                int row = brow + wr + (i << 4) + (fg << 2) + r;
                out[(size_t)row * 768 + c] = acc[i][j][r] + bb;
            }
    }
}

// ---------------------------------------------------------------------------
extern "C" void kernel_launch(void* const* d_in, const int* in_sizes, int n_in,
                              void* d_out, int out_size, void* d_ws, size_t ws_size,
                              hipStream_t stream)
{
    const float* x      = (const float*)d_in[0];
    const float* qkv_w  = (const float*)d_in[1];
    const float* qkv_b  = (const float*)d_in[2];
    const float* proj_w = (const float*)d_in[3];
    const float* proj_b = (const float*)d_in[4];
    float* out = (float*)d_out;

    float* ws  = (float*)d_ws;
    const size_t QKV = (size_t)4 * 12 * 4096 * 64;   // 12,582,912
    float* q    = ws;
    float* k    = q + QKV;
    float* v    = k + QKV;
    unsigned short* ctxh = (unsigned short*)(v + QKV);   // QKV shorts
    unsigned short* ctxl = ctxh + QKV;                    // QKV shorts
    float* scm  = (float*)(ctxl + QKV);
    float* eB   = scm + 4096;
    float* den  = eB + 44 * 4096;
    float* pi_  = den + 64;
    float* Wb   = pi_ + 44 * 4096;
    float* Tb   = Wb + 44 * 4160;
    unsigned short* Whi  = (unsigned short*)(Tb + 44 * 4160);
    unsigned short* Wlo  = Whi + (size_t)2304 * 768;
    unsigned short* Pwhi = Wlo + (size_t)2304 * 768;
    unsigned short* Pwlo = Pwhi + (size_t)768 * 768;

    // d_out scratch phase 1: X hi/lo split (dead after gemm_qkv_mfma).
    // Phase 2: wflash partials.
    unsigned short* Xhi = (unsigned short*)out;
    unsigned short* Xlo = Xhi + QKV;
    float* wacc = out;
    float* wl   = wacc + 1441792;
    float* wm   = wl + 22528;

    preconv<<<2048, 256, 0, stream>>>(x, Xhi, Xlo, 3145728);
    preconv<<<1024, 256, 0, stream>>>(qkv_w, Whi, Wlo, 442368);
    preconv<<<512, 256, 0, stream>>>(proj_w, Pwhi, Pwlo, 147456);
    gemm_qkv_mfma<<<dim3(18, 128), 256, 0, stream>>>(Xhi, Xlo, Whi, Wlo, qkv_b, q, k, v);
    wflash<<<dim3(8, 44), 256, 0, stream>>>(q, k, v, wacc, wl, wm);
    wmerge<<<44, 256, 0, stream>>>(wacc, wl, wm, Wb, scm);
    eb_kernel<<<44, 256, 0, stream>>>(q, k, scm, eB);
    norms_kernel<<<11, 256, 0, stream>>>(eB, den);
    pinv_kernel<<<44, 256, 0, stream>>>(eB, den, pi_);
    pw_kernel<<<44, 256, 0, stream>>>(pi_, Wb, Tb);
    outp_kernel<<<dim3(64, 44), 256, 0, stream>>>(q, k, Tb, ctxh, ctxl);
    flash_h11<<<dim3(64, 4), 256, 0, stream>>>(q, k, v, ctxh, ctxl);
    gemm_proj_mfma<<<dim3(6, 128), 256, 0, stream>>>(ctxh, ctxl, Pwhi, Pwlo, proj_b, out);
}

// Round 6
// 666.728 us; speedup vs baseline: 9.1974x; 1.0849x over previous
//
#include <hip/hip_runtime.h>

// B=4, N=4096, C=768, H=12, D=64, M=64, PNP=11, SCALE=1/8

typedef __attribute__((ext_vector_type(8))) short short8;
typedef __attribute__((ext_vector_type(4))) float f32x4;
typedef __attribute__((ext_vector_type(4))) unsigned short ushort4v;

static __device__ __forceinline__ unsigned short f2bf(float f) {
    union { float f; unsigned u; } x; x.f = f;
    unsigned r = x.u + 0x7fffu + ((x.u >> 16) & 1u);   // RNE
    return (unsigned short)(r >> 16);
}

static __device__ __forceinline__ void bfsplit(float x, unsigned short& h, unsigned short& l) {
    unsigned short hh = f2bf(x);
    union { unsigned u; float f; } t; t.u = (unsigned)hh << 16;
    h = hh;
    l = f2bf(x - t.f);    // exact residual, RNE to bf16
}

// ---------------------------------------------------------------------------
// K0: split fp32 array into bf16 (hi, lo) pair arrays. memory-bound.
// ---------------------------------------------------------------------------
__global__ __launch_bounds__(256) void preconv(
    const float* __restrict__ in, unsigned short* __restrict__ hi,
    unsigned short* __restrict__ lo, int n4)
{
    for (int i = blockIdx.x * 256 + threadIdx.x; i < n4; i += gridDim.x * 256) {
        float4 f = *(const float4*)(in + (size_t)i * 4);
        float vs[4] = {f.x, f.y, f.z, f.w};
        ushort4v h, l;
        #pragma unroll
        for (int j = 0; j < 4; ++j) {
            unsigned short hh, ll;
            bfsplit(vs[j], hh, ll);
            h[j] = hh; l[j] = ll;
        }
        *(ushort4v*)(hi + (size_t)i * 4) = h;
        *(ushort4v*)(lo + (size_t)i * 4) = l;
    }
}

// ---------------------------------------------------------------------------
// K1: QKV GEMM via bf16x3-split MFMA (128x128 tile, BK=32, 4 waves)
// ---------------------------------------------------------------------------
__global__ __launch_bounds__(256, 2) void gemm_qkv_mfma(
    const unsigned short* __restrict__ Xh, const unsigned short* __restrict__ Xl,
    const unsigned short* __restrict__ Wh, const unsigned short* __restrict__ Wl,
    const float* __restrict__ bias,
    float* __restrict__ q, float* __restrict__ k, float* __restrict__ v)
{
    __shared__ unsigned short Ah[128][40], Al[128][40], Bh[128][40], Bl[128][40];
    const int tid = threadIdx.x;
    const int brow = blockIdx.y << 7, bcol = blockIdx.x << 7;
    const int ln = tid & 63, wv = tid >> 6;
    const int wr = (wv >> 1) << 6, wc = (wv & 1) << 6;
    const int srow = tid >> 1, sk = (tid & 1) << 4;
    const size_t ag = (size_t)(brow + srow) * 768 + sk;
    const size_t bg = (size_t)(bcol + srow) * 768 + sk;
    const int fr = ln & 15, fk = (ln >> 4) << 3;

    f32x4 acc[4][4] = {};
    for (int k0 = 0; k0 < 768; k0 += 32) {
        short8 xh0 = *(const short8*)(Xh + ag + k0);
        short8 xh1 = *(const short8*)(Xh + ag + k0 + 8);
        short8 xl0 = *(const short8*)(Xl + ag + k0);
        short8 xl1 = *(const short8*)(Xl + ag + k0 + 8);
        short8 wh0 = *(const short8*)(Wh + bg + k0);
        short8 wh1 = *(const short8*)(Wh + bg + k0 + 8);
        short8 wl0 = *(const short8*)(Wl + bg + k0);
        short8 wl1 = *(const short8*)(Wl + bg + k0 + 8);
        __syncthreads();
        *(short8*)&Ah[srow][sk] = xh0; *(short8*)&Ah[srow][sk + 8] = xh1;
        *(short8*)&Al[srow][sk] = xl0; *(short8*)&Al[srow][sk + 8] = xl1;
        *(short8*)&Bh[srow][sk] = wh0; *(short8*)&Bh[srow][sk + 8] = wh1;
        *(short8*)&Bl[srow][sk] = wl0; *(short8*)&Bl[srow][sk + 8] = wl1;
        __syncthreads();
        short8 ah[4], al[4], bh[4], bl[4];
        #pragma unroll
        for (int i = 0; i < 4; ++i) {
            ah[i] = *(short8*)&Ah[wr + (i << 4) + fr][fk];
            al[i] = *(short8*)&Al[wr + (i << 4) + fr][fk];
        }
        #pragma unroll
        for (int j = 0; j < 4; ++j) {
            bh[j] = *(short8*)&Bh[wc + (j << 4) + fr][fk];
            bl[j] = *(short8*)&Bl[wc + (j << 4) + fr][fk];
        }
        #pragma unroll
        for (int i = 0; i < 4; ++i)
            #pragma unroll
            for (int j = 0; j < 4; ++j) {
                acc[i][j] = __builtin_amdgcn_mfma_f32_16x16x32_bf16(ah[i], bh[j], acc[i][j], 0, 0, 0);
                acc[i][j] = __builtin_amdgcn_mfma_f32_16x16x32_bf16(ah[i], bl[j], acc[i][j], 0, 0, 0);
                acc[i][j] = __builtin_amdgcn_mfma_f32_16x16x32_bf16(al[i], bh[j], acc[i][j], 0, 0, 0);
            }
    }
    const int fg = ln >> 4;
    #pragma unroll
    for (int j = 0; j < 4; ++j) {
        int c = bcol + wc + (j << 4) + fr;
        float bb = bias[c];
        int t = c / 768;
        int rem = c - t * 768;
        int h = rem >> 6, d = rem & 63;
        #pragma unroll
        for (int i = 0; i < 4; ++i)
            #pragma unroll
            for (int r = 0; r < 4; ++r) {
                int row = brow + wr + (i << 4) + (fg << 2) + r;
                int b = row >> 12, n = row & 4095;
                float val = acc[i][j][r] + bb;
                size_t idx = (((size_t)(b * 12 + h) << 12) + n) * 64 + d;
                if (t == 0)      q[idx] = val * 0.125f;
                else if (t == 1) k[idx] = val;
                else             v[idx] = val;
            }
    }
}

// ---------------------------------------------------------------------------
// K2: fused flash pass for SC — bf16x3 MFMA. Online max + W-partial per
// 512-n chunk. 4 waves, each owns 16 landmark rows. grid (8, 44).
// ---------------------------------------------------------------------------
__global__ __launch_bounds__(256) void wflash(
    const float* __restrict__ q, const float* __restrict__ k,
    const float* __restrict__ v,
    float* __restrict__ wacc, float* __restrict__ wl, float* __restrict__ wm)
{
    int chunk = blockIdx.x;
    int bh = blockIdx.y;
    int b = bh / 11, h = bh - b * 11;
    size_t base = ((size_t)(b * 12 + h)) << 12;
    const float* qb = q + base * 64;
    const float* kb = k + base * 64;
    const float* vb = v + base * 64;
    __shared__ unsigned short kh[64][72], kl[64][72];
    __shared__ unsigned short vth[64][72], vtl[64][72];   // V transposed [j][n]
    __shared__ unsigned short ph[4][16][72], pl[4][16][72];
    int tid = threadIdx.x;
    int wv = tid >> 6, ln = tid & 63;
    int rr = tid >> 2, dg = (tid & 3) << 4;
    const int arow = (wv << 4) + (ln & 15);
    const int ak0 = (ln >> 4) << 3;
    const int rg = (ln >> 4) << 2;
    // A-frags: landmark q rows (global n = arow*64), hi/lo, in registers
    short8 aqh0, aql0, aqh1, aql1;
    {
        const float* qrow = qb + ((size_t)arow << 12);
        #pragma unroll
        for (int j = 0; j < 8; ++j) {
            unsigned short hh, ll;
            bfsplit(qrow[ak0 + j], hh, ll);
            aqh0[j] = (short)hh; aql0[j] = (short)ll;
            bfsplit(qrow[ak0 + 32 + j], hh, ll);
            aqh1[j] = (short)hh; aql1[j] = (short)ll;
        }
    }
    f32x4 o_acc[4] = {};
    float mr[4] = {-1e30f, -1e30f, -1e30f, -1e30f};
    float lr[4] = {};
    for (int t = 0; t < 8; ++t) {
        int n0 = (chunk << 9) + (t << 6);
        __syncthreads();
        {   // stage K rows + V transposed, hi/lo bf16
            const float* krow = kb + (((size_t)(n0 + rr)) << 6) + dg;
            const float* vrow = vb + (((size_t)(n0 + rr)) << 6) + dg;
            #pragma unroll
            for (int i = 0; i < 16; i += 4) {
                float4 f = *(const float4*)(krow + i);
                unsigned short hh, ll;
                bfsplit(f.x, hh, ll); kh[rr][dg+i]   = hh; kl[rr][dg+i]   = ll;
                bfsplit(f.y, hh, ll); kh[rr][dg+i+1] = hh; kl[rr][dg+i+1] = ll;
                bfsplit(f.z, hh, ll); kh[rr][dg+i+2] = hh; kl[rr][dg+i+2] = ll;
                bfsplit(f.w, hh, ll); kh[rr][dg+i+3] = hh; kl[rr][dg+i+3] = ll;
                float4 g2 = *(const float4*)(vrow + i);
                bfsplit(g2.x, hh, ll); vth[dg+i][rr]   = hh; vtl[dg+i][rr]   = ll;
                bfsplit(g2.y, hh, ll); vth[dg+i+1][rr] = hh; vtl[dg+i+1][rr] = ll;
                bfsplit(g2.z, hh, ll); vth[dg+i+2][rr] = hh; vtl[dg+i+2][rr] = ll;
                bfsplit(g2.w, hh, ll); vth[dg+i+3][rr] = hh; vtl[dg+i+3][rr] = ll;
            }
        }
        __syncthreads();
        // S = q_m · K^T (x3 split)
        f32x4 s_acc[4];
        #pragma unroll
        for (int jb = 0; jb < 4; ++jb) {
            f32x4 z = {};
            const int brow2 = (jb << 4) + (ln & 15);
            short8 bh0 = *(short8*)&kh[brow2][ak0];
            short8 bh1 = *(short8*)&kh[brow2][ak0 + 32];
            short8 bl0 = *(short8*)&kl[brow2][ak0];
            short8 bl1 = *(short8*)&kl[brow2][ak0 + 32];
            z = __builtin_amdgcn_mfma_f32_16x16x32_bf16(aqh0, bh0, z, 0, 0, 0);
            z = __builtin_amdgcn_mfma_f32_16x16x32_bf16(aqh0, bl0, z, 0, 0, 0);
            z = __builtin_amdgcn_mfma_f32_16x16x32_bf16(aql0, bh0, z, 0, 0, 0);
            z = __builtin_amdgcn_mfma_f32_16x16x32_bf16(aqh1, bh1, z, 0, 0, 0);
            z = __builtin_amdgcn_mfma_f32_16x16x32_bf16(aqh1, bl1, z, 0, 0, 0);
            z = __builtin_amdgcn_mfma_f32_16x16x32_bf16(aql1, bh1, z, 0, 0, 0);
            s_acc[jb] = z;
        }
        // online softmax (per landmark row)
        float mx[4];
        #pragma unroll
        for (int r = 0; r < 4; ++r)
            mx[r] = fmaxf(fmaxf(s_acc[0][r], s_acc[1][r]),
                          fmaxf(s_acc[2][r], s_acc[3][r]));
        #pragma unroll
        for (int off = 1; off < 16; off <<= 1)
            #pragma unroll
            for (int r = 0; r < 4; ++r)
                mx[r] = fmaxf(mx[r], __shfl_xor(mx[r], off, 64));
        float fac[4];
        #pragma unroll
        for (int r = 0; r < 4; ++r) {
            float mn = fmaxf(mr[r], mx[r]);
            fac[r] = expf(mr[r] - mn);
            mr[r] = mn;
        }
        float rs[4] = {};
        #pragma unroll
        for (int jb = 0; jb < 4; ++jb)
            #pragma unroll
            for (int r = 0; r < 4; ++r) {
                float p = expf(s_acc[jb][r] - mr[r]);
                rs[r] += p;
                unsigned short hh, ll;
                bfsplit(p, hh, ll);
                ph[wv][rg + r][(jb << 4) + (ln & 15)] = hh;
                pl[wv][rg + r][(jb << 4) + (ln & 15)] = ll;
            }
        #pragma unroll
        for (int off = 1; off < 16; off <<= 1)
            #pragma unroll
            for (int r = 0; r < 4; ++r)
                rs[r] += __shfl_xor(rs[r], off, 64);
        #pragma unroll
        for (int r = 0; r < 4; ++r) lr[r] = lr[r] * fac[r] + rs[r];
        #pragma unroll
        for (int jb = 0; jb < 4; ++jb)
            #pragma unroll
            for (int r = 0; r < 4; ++r)
                o_acc[jb][r] *= fac[r];
        // O += P · V  (x3 split)
        short8 pah0 = *(short8*)&ph[wv][ln & 15][ak0];
        short8 pah1 = *(short8*)&ph[wv][ln & 15][ak0 + 32];
        short8 pal0 = *(short8*)&pl[wv][ln & 15][ak0];
        short8 pal1 = *(short8*)&pl[wv][ln & 15][ak0 + 32];
        #pragma unroll
        for (int jb = 0; jb < 4; ++jb) {
            const int brow2 = (jb << 4) + (ln & 15);
            short8 bvh0 = *(short8*)&vth[brow2][ak0];
            short8 bvh1 = *(short8*)&vth[brow2][ak0 + 32];
            short8 bvl0 = *(short8*)&vtl[brow2][ak0];
            short8 bvl1 = *(short8*)&vtl[brow2][ak0 + 32];
            f32x4 o = o_acc[jb];
            o = __builtin_amdgcn_mfma_f32_16x16x32_bf16(pah0, bvh0, o, 0, 0, 0);
            o = __builtin_amdgcn_mfma_f32_16x16x32_bf16(pah0, bvl0, o, 0, 0, 0);
            o = __builtin_amdgcn_mfma_f32_16x16x32_bf16(pal0, bvh0, o, 0, 0, 0);
            o = __builtin_amdgcn_mfma_f32_16x16x32_bf16(pah1, bvh1, o, 0, 0, 0);
            o = __builtin_amdgcn_mfma_f32_16x16x32_bf16(pah1, bvl1, o, 0, 0, 0);
            o = __builtin_amdgcn_mfma_f32_16x16x32_bf16(pal1, bvh1, o, 0, 0, 0);
            o_acc[jb] = o;
        }
    }
    int cidx = (bh << 3) + chunk;
    #pragma unroll
    for (int jb = 0; jb < 4; ++jb)
        #pragma unroll
        for (int r = 0; r < 4; ++r) {
            int row = (wv << 4) + rg + r, col = (jb << 4) + (ln & 15);
            wacc[((size_t)cidx << 12) + ((size_t)row << 6) + col] = o_acc[jb][r];
        }
    if ((ln & 15) == 0)
        #pragma unroll
        for (int r = 0; r < 4; ++r) {
            int row = (wv << 4) + rg + r;
            wl[cidx * 64 + row] = lr[r];
            wm[cidx * 64 + row] = mr[r];
        }
}

// K2b: merge chunk partials -> Wb (65 cols, col 64 = ones-column) + scm
__global__ __launch_bounds__(256) void wmerge(
    const float* __restrict__ wacc, const float* __restrict__ wl,
    const float* __restrict__ wm,
    float* __restrict__ Wb, float* __restrict__ scm)
{
    int bh = blockIdx.x;
    int tid = threadIdx.x;
    __shared__ float fcs[8][64];
    if (tid < 64) {
        float mx = -1e30f;
        #pragma unroll
        for (int c = 0; c < 8; ++c)
            mx = fmaxf(mx, wm[((bh << 3) + c) * 64 + tid]);
        scm[(bh << 6) + tid] = mx;
        #pragma unroll
        for (int c = 0; c < 8; ++c)
            fcs[c][tid] = expf(wm[((bh << 3) + c) * 64 + tid] - mx);
    }
    __syncthreads();
    for (int e = tid; e < 4096; e += 256) {
        int m = e >> 6, j = e & 63;
        float s = 0.f;
        #pragma unroll
        for (int c = 0; c < 8; ++c)
            s += fcs[c][m] * wacc[((size_t)((bh << 3) + c) << 12) + e];
        Wb[(size_t)bh * 4160 + m * 65 + j] = s;
    }
    if (tid < 64) {
        float s = 0.f;
        #pragma unroll
        for (int c = 0; c < 8; ++c)
            s += fcs[c][tid] * wl[((bh << 3) + c) * 64 + tid];
        Wb[(size_t)bh * 4160 + tid * 65 + 64] = s;
    }
}

// ---------------------------------------------------------------------------
// K3a: eB (fp32)
// ---------------------------------------------------------------------------
__global__ __launch_bounds__(256) void eb_kernel(
    const float* __restrict__ q, const float* __restrict__ k,
    const float* __restrict__ scm, float* __restrict__ eB)
{
    int bh = blockIdx.x;
    int b = bh / 11, h = bh - b * 11;
    size_t base = ((size_t)(b * 12 + h)) << 12;
    const float* qb = q + base * 64;
    const float* kb = k + base * 64;
    __shared__ float qm[64][65], km[64][65];
    int tid = threadIdx.x;
    for (int e = tid; e < 4096; e += 256) {
        int mm = e >> 6, d = e & 63;
        qm[mm][d] = qb[((size_t)mm << 12) + d];
        km[mm][d] = kb[((size_t)mm << 12) + d];
    }
    __syncthreads();
    int m = tid >> 2, l0 = tid & 3;
    float smax = scm[(bh << 6) + m];
    for (int l = l0; l < 64; l += 4) {
        float s = 0.f;
        #pragma unroll
        for (int d = 0; d < 64; ++d) s += qm[m][d] * km[l][d];
        eB[((size_t)bh << 12) + (m << 6) + l] = expf(fmaxf(s - smax, -88.f));
    }
}

// ---------------------------------------------------------------------------
// K3b: per-head norms
// ---------------------------------------------------------------------------
__global__ __launch_bounds__(256) void norms_kernel(
    const float* __restrict__ eB, float* __restrict__ denom)
{
    int h = blockIdx.x;
    int tid = threadIdx.x;
    int b = tid >> 6, idx = tid & 63;
    int bh = b * 11 + h;
    const float* E = eB + ((size_t)bh << 12);
    float rs = 0.f, cs = 0.f;
    #pragma unroll 4
    for (int l = 0; l < 64; ++l) rs += E[(idx << 6) + l];
    #pragma unroll 4
    for (int m = 0; m < 64; ++m) cs += E[(m << 6) + idx];
    __shared__ float r1[256], r2[256];
    r1[tid] = rs; r2[tid] = cs;
    __syncthreads();
    for (int s = 128; s > 0; s >>= 1) {
        if (tid < s) {
            r1[tid] = fmaxf(r1[tid], r1[tid + s]);
            r2[tid] = fmaxf(r2[tid], r2[tid + s]);
        }
        __syncthreads();
    }
    if (tid == 0) denom[h] = r1[0] * r2[0];
}

// ---------------------------------------------------------------------------
// K3c: pinv via 6 Newton iterations — bf16x3 MFMA matmuls, one block per bh.
// ---------------------------------------------------------------------------
__device__ __forceinline__ void mm64x3(
    const unsigned short (&Ahi)[64][72], const unsigned short (&Alo)[64][72],
    const unsigned short (&BThi)[64][72], const unsigned short (&BTlo)[64][72],
    int wr, int wc, int fr, int fk, f32x4 (&acc)[2][2])
{
    #pragma unroll
    for (int ks = 0; ks < 2; ++ks) {
        const int kb = (ks << 5) + fk;
        short8 ah[2], al[2], bh[2], bl[2];
        #pragma unroll
        for (int i = 0; i < 2; ++i) {
            ah[i] = *(const short8*)&Ahi[wr + (i << 4) + fr][kb];
            al[i] = *(const short8*)&Alo[wr + (i << 4) + fr][kb];
            bh[i] = *(const short8*)&BThi[wc + (i << 4) + fr][kb];
            bl[i] = *(const short8*)&BTlo[wc + (i << 4) + fr][kb];
        }
        #pragma unroll
        for (int i = 0; i < 2; ++i)
            #pragma unroll
            for (int j = 0; j < 2; ++j) {
                acc[i][j] = __builtin_amdgcn_mfma_f32_16x16x32_bf16(ah[i], bh[j], acc[i][j], 0, 0, 0);
                acc[i][j] = __builtin_amdgcn_mfma_f32_16x16x32_bf16(ah[i], bl[j], acc[i][j], 0, 0, 0);
                acc[i][j] = __builtin_amdgcn_mfma_f32_16x16x32_bf16(al[i], bh[j], acc[i][j], 0, 0, 0);
            }
    }
}

__global__ __launch_bounds__(256) void pinv_kernel(
    const float* __restrict__ eB, const float* __restrict__ denom,
    float* __restrict__ pi_)
{
    __shared__ unsigned short Xh[64][72],  Xl[64][72];
    __shared__ unsigned short Zh[64][72],  Zl[64][72];
    __shared__ unsigned short ZTh[64][72], ZTl[64][72];
    __shared__ unsigned short Mh[64][72],  Ml[64][72];    // XZ
    __shared__ unsigned short MTh[64][72], MTl[64][72];
    __shared__ unsigned short Th[64][72],  Tbl[64][72];   // TA/TB transposed
    __shared__ float Zf[64][68];
    int bh = blockIdx.x;
    int h = bh % 11;
    int tid = threadIdx.x;
    float dn = denom[h];
    const int ln = tid & 63, wv = tid >> 6;
    const int wr = (wv >> 1) << 5, wc = (wv & 1) << 5;
    const int fr = ln & 15, fk = (ln >> 4) << 3;
    const int rg = (ln >> 4) << 2;

    for (int e = tid; e < 4096; e += 256) {
        int m = e >> 6, l = e & 63;
        float xv = eB[((size_t)bh << 12) + e];
        unsigned short hh, ll;
        bfsplit(xv, hh, ll);
        Xh[m][l] = hh; Xl[m][l] = ll;
        float zv = xv / dn;
        Zf[l][m] = zv;
        bfsplit(zv, hh, ll);
        Zh[l][m] = hh; Zl[l][m] = ll;
        ZTh[m][l] = hh; ZTl[m][l] = ll;
    }
    __syncthreads();

    for (int it = 0; it < 6; ++it) {
        f32x4 mm1[2][2] = {};
        mm64x3(Xh, Xl, ZTh, ZTl, wr, wc, fr, fk, mm1);
        #pragma unroll
        for (int i = 0; i < 2; ++i)
            #pragma unroll
            for (int j = 0; j < 2; ++j)
                #pragma unroll
                for (int r = 0; r < 4; ++r) {
                    int row = wr + (i << 4) + rg + r, col = wc + (j << 4) + fr;
                    unsigned short hh, ll;
                    bfsplit(mm1[i][j][r], hh, ll);
                    Mh[row][col] = hh;  Ml[row][col] = ll;
                    MTh[col][row] = hh; MTl[col][row] = ll;
                }
        __syncthreads();
        f32x4 a2[2][2] = {};
        mm64x3(Mh, Ml, MTh, MTl, wr, wc, fr, fk, a2);
        #pragma unroll
        for (int i = 0; i < 2; ++i)
            #pragma unroll
            for (int j = 0; j < 2; ++j)
                #pragma unroll
                for (int r = 0; r < 4; ++r) {
                    int row = wr + (i << 4) + rg + r, col = wc + (j << 4) + fr;
                    float val = 7.f * mm1[i][j][r] - a2[i][j][r];
                    unsigned short hh, ll;
                    bfsplit(val, hh, ll);
                    Th[col][row] = hh; Tbl[col][row] = ll;
                }
        __syncthreads();
        f32x4 a3[2][2] = {};
        mm64x3(Mh, Ml, Th, Tbl, wr, wc, fr, fk, a3);
        __syncthreads();
        #pragma unroll
        for (int i = 0; i < 2; ++i)
            #pragma unroll
            for (int j = 0; j < 2; ++j)
                #pragma unroll
                for (int r = 0; r < 4; ++r) {
                    int row = wr + (i << 4) + rg + r, col = wc + (j << 4) + fr;
                    float val = 15.f * mm1[i][j][r] - a3[i][j][r];
                    unsigned short hh, ll;
                    bfsplit(val, hh, ll);
                    Th[col][row] = hh; Tbl[col][row] = ll;
                }
        __syncthreads();
        f32x4 a4[2][2] = {};
        mm64x3(Zh, Zl, Th, Tbl, wr, wc, fr, fk, a4);
        float zn[2][2][4];
        #pragma unroll
        for (int i = 0; i < 2; ++i)
            #pragma unroll
            for (int j = 0; j < 2; ++j)
                #pragma unroll
                for (int r = 0; r < 4; ++r) {
                    int row = wr + (i << 4) + rg + r, col = wc + (j << 4) + fr;
                    zn[i][j][r] = 0.25f * (13.f * Zf[row][col] - a4[i][j][r]);
                }
        __syncthreads();
        #pragma unroll
        for (int i = 0; i < 2; ++i)
            #pragma unroll
            for (int j = 0; j < 2; ++j)
                #pragma unroll
                for (int r = 0; r < 4; ++r) {
                    int row = wr + (i << 4) + rg + r, col = wc + (j << 4) + fr;
                    float val = zn[i][j][r];
                    Zf[row][col] = val;
                    unsigned short hh, ll;
                    bfsplit(val, hh, ll);
                    Zh[row][col] = hh;  Zl[row][col] = ll;
                    ZTh[col][row] = hh; ZTl[col][row] = ll;
                }
        __syncthreads();
    }
    for (int e = tid; e < 4096; e += 256)
        pi_[((size_t)bh << 12) + e] = Zf[e >> 6][e & 63];
}

// ---------------------------------------------------------------------------
// K5: T = pi @ W  (64x64 @ 64x65)
// ---------------------------------------------------------------------------
__global__ __launch_bounds__(256) void pw_kernel(
    const float* __restrict__ pi_, const float* __restrict__ Wb,
    float* __restrict__ Tb)
{
    int bh = blockIdx.x;
    __shared__ float P[64][65];
    __shared__ float Wl[64][66];
    int tid = threadIdx.x;
    for (int e = tid; e < 4096; e += 256)
        P[e >> 6][e & 63] = pi_[((size_t)bh << 12) + e];
    for (int e = tid; e < 64 * 65; e += 256) {
        int l = e / 65, j = e - l * 65;
        Wl[l][j] = Wb[(size_t)bh * 4160 + e];
    }
    __syncthreads();
    int m = tid & 63, g = tid >> 6;
    #pragma unroll
    for (int t = 0; t < 17; ++t) {
        int j = g + (t << 2);
        if (j > 64) break;
        float s = 0.f;
        #pragma unroll
        for (int l = 0; l < 64; ++l) s += P[m][l] * Wl[l][j];
        Tb[(size_t)((bh << 6) + m) * 65 + j] = s;
    }
}

// ---------------------------------------------------------------------------
// K6: out_p — bf16x3 MFMA: eA = exp(q·k_m^T − rowmax); O = eA@T; /den
// grid (64, 44), 4 waves each own 16 q rows.
// ---------------------------------------------------------------------------
__global__ __launch_bounds__(256) void outp_kernel(
    const float* __restrict__ q, const float* __restrict__ k,
    const float* __restrict__ Tb,
    unsigned short* __restrict__ ctxh, unsigned short* __restrict__ ctxl)
{
    int bh = blockIdx.y;
    int b = bh / 11, h = bh - b * 11;
    int n0 = blockIdx.x << 6;
    size_t base = ((size_t)(b * 12 + h)) << 12;
    const float* qb = q + base * 64;
    const float* kb = k + base * 64;
    __shared__ unsigned short kmh[64][72], kml[64][72];
    __shared__ unsigned short tth[64][72], ttl[64][72];   // T^T [j][m], j<64
    __shared__ unsigned short ph[4][16][72], pl[4][16][72];
    __shared__ float t64[64];
    int tid = threadIdx.x;
    int wv = tid >> 6, ln = tid & 63;
    int rr = tid >> 2, dg = (tid & 3) << 4;
    const int arow = (wv << 4) + (ln & 15);
    const int ak0 = (ln >> 4) << 3;
    const int rg = (ln >> 4) << 2;
    {   // stage k_m (landmark rows) hi/lo
        const float* krow = kb + ((size_t)rr << 12) + dg;
        #pragma unroll
        for (int i = 0; i < 16; i += 4) {
            float4 f = *(const float4*)(krow + i);
            unsigned short hh, ll;
            bfsplit(f.x, hh, ll); kmh[rr][dg+i]   = hh; kml[rr][dg+i]   = ll;
            bfsplit(f.y, hh, ll); kmh[rr][dg+i+1] = hh; kml[rr][dg+i+1] = ll;
            bfsplit(f.z, hh, ll); kmh[rr][dg+i+2] = hh; kml[rr][dg+i+2] = ll;
            bfsplit(f.w, hh, ll); kmh[rr][dg+i+3] = hh; kml[rr][dg+i+3] = ll;
        }
    }
    for (int e = tid; e < 4096; e += 256) {   // stage T^T hi/lo
        int m = e >> 6, j = e & 63;
        float tv = Tb[(size_t)((bh << 6) + m) * 65 + j];
        unsigned short hh, ll;
        bfsplit(tv, hh, ll);
        tth[j][m] = hh; ttl[j][m] = ll;
    }
    if (tid < 64) t64[tid] = Tb[(size_t)((bh << 6) + tid) * 65 + 64];
    // A-frags: q rows n0+arow, hi/lo in registers
    short8 aqh0, aql0, aqh1, aql1;
    {
        const float* qrow = qb + (((size_t)(n0 + arow)) << 6);
        #pragma unroll
        for (int j = 0; j < 8; ++j) {
            unsigned short hh, ll;
            bfsplit(qrow[ak0 + j], hh, ll);
            aqh0[j] = (short)hh; aql0[j] = (short)ll;
            bfsplit(qrow[ak0 + 32 + j], hh, ll);
            aqh1[j] = (short)hh; aql1[j] = (short)ll;
        }
    }
    __syncthreads();
    // S = q · k_m^T (x3)
    f32x4 s_acc[4];
    #pragma unroll
    for (int jb = 0; jb < 4; ++jb) {
        f32x4 z = {};
        const int brow2 = (jb << 4) + (ln & 15);
        short8 bh0 = *(short8*)&kmh[brow2][ak0];
        short8 bh1 = *(short8*)&kmh[brow2][ak0 + 32];
        short8 bl0 = *(short8*)&kml[brow2][ak0];
        short8 bl1 = *(short8*)&kml[brow2][ak0 + 32];
        z = __builtin_amdgcn_mfma_f32_16x16x32_bf16(aqh0, bh0, z, 0, 0, 0);
        z = __builtin_amdgcn_mfma_f32_16x16x32_bf16(aqh0, bl0, z, 0, 0, 0);
        z = __builtin_amdgcn_mfma_f32_16x16x32_bf16(aql0, bh0, z, 0, 0, 0);
        z = __builtin_amdgcn_mfma_f32_16x16x32_bf16(aqh1, bh1, z, 0, 0, 0);
        z = __builtin_amdgcn_mfma_f32_16x16x32_bf16(aqh1, bl1, z, 0, 0, 0);
        z = __builtin_amdgcn_mfma_f32_16x16x32_bf16(aql1, bh1, z, 0, 0, 0);
        s_acc[jb] = z;
    }
    // full row max
    float mx[4];
    #pragma unroll
    for (int r = 0; r < 4; ++r)
        mx[r] = fmaxf(fmaxf(s_acc[0][r], s_acc[1][r]),
                      fmaxf(s_acc[2][r], s_acc[3][r]));
    #pragma unroll
    for (int off = 1; off < 16; off <<= 1)
        #pragma unroll
        for (int r = 0; r < 4; ++r)
            mx[r] = fmaxf(mx[r], __shfl_xor(mx[r], off, 64));
    // eA = exp(S − mx); den (fp32); store eA hi/lo
    float den[4] = {};
    #pragma unroll
    for (int jb = 0; jb < 4; ++jb) {
        float tj = t64[(jb << 4) + (ln & 15)];
        #pragma unroll
        for (int r = 0; r < 4; ++r) {
            float p = expf(s_acc[jb][r] - mx[r]);
            den[r] += p * tj;
            unsigned short hh, ll;
            bfsplit(p, hh, ll);
            ph[wv][rg + r][(jb << 4) + (ln & 15)] = hh;
            pl[wv][rg + r][(jb << 4) + (ln & 15)] = ll;
        }
    }
    #pragma unroll
    for (int off = 1; off < 16; off <<= 1)
        #pragma unroll
        for (int r = 0; r < 4; ++r)
            den[r] += __shfl_xor(den[r], off, 64);
    // O = eA @ T (cols 0..63, x3)
    short8 pah0 = *(short8*)&ph[wv][ln & 15][ak0];
    short8 pah1 = *(short8*)&ph[wv][ln & 15][ak0 + 32];
    short8 pal0 = *(short8*)&pl[wv][ln & 15][ak0];
    short8 pal1 = *(short8*)&pl[wv][ln & 15][ak0 + 32];
    f32x4 o_acc[4] = {};
    #pragma unroll
    for (int jb = 0; jb < 4; ++jb) {
        const int brow2 = (jb << 4) + (ln & 15);
        short8 bth0 = *(short8*)&tth[brow2][ak0];
        short8 bth1 = *(short8*)&tth[brow2][ak0 + 32];
        short8 btl0 = *(short8*)&ttl[brow2][ak0];
        short8 btl1 = *(short8*)&ttl[brow2][ak0 + 32];
        f32x4 o = o_acc[jb];
        o = __builtin_amdgcn_mfma_f32_16x16x32_bf16(pah0, bth0, o, 0, 0, 0);
        o = __builtin_amdgcn_mfma_f32_16x16x32_bf16(pah0, btl0, o, 0, 0, 0);
        o = __builtin_amdgcn_mfma_f32_16x16x32_bf16(pal0, bth0, o, 0, 0, 0);
        o = __builtin_amdgcn_mfma_f32_16x16x32_bf16(pah1, bth1, o, 0, 0, 0);
        o = __builtin_amdgcn_mfma_f32_16x16x32_bf16(pah1, btl1, o, 0, 0, 0);
        o = __builtin_amdgcn_mfma_f32_16x16x32_bf16(pal1, bth1, o, 0, 0, 0);
        o_acc[jb] = o;
    }
    float inv[4];
    #pragma unroll
    for (int r = 0; r < 4; ++r) inv[r] = 1.0f / fmaxf(den[r], 1e-8f);
    #pragma unroll
    for (int jb = 0; jb < 4; ++jb)
        #pragma unroll
        for (int r = 0; r < 4; ++r) {
            int row = n0 + (wv << 4) + rg + r;
            int col = (jb << 4) + (ln & 15);
            size_t idx = ((size_t)b * 4096 + row) * 768 + h * 64 + col;
            unsigned short hh, ll;
            bfsplit(o_acc[jb][r] * inv[r], hh, ll);
            ctxh[idx] = hh; ctxl[idx] = ll;
        }
}

// ---------------------------------------------------------------------------
// K7: softmax head (h=11) — bf16 MFMA flash attention -> ctx_hi/ctx_lo
// ---------------------------------------------------------------------------
__global__ __launch_bounds__(256) void flash_h11(
    const float* __restrict__ q, const float* __restrict__ k,
    const float* __restrict__ v,
    unsigned short* __restrict__ ctxh, unsigned short* __restrict__ ctxl)
{
    int b = blockIdx.y;
    int n0 = blockIdx.x << 6;
    size_t base = ((size_t)(b * 12 + 11)) << 12;
    const float* qb = q + base * 64;
    const float* kb = k + base * 64;
    const float* vb = v + base * 64;
    __shared__ unsigned short qs[64][72];
    __shared__ unsigned short ks[64][72];
    __shared__ unsigned short vts[64][72];
    __shared__ unsigned short ps[4][16][72];
    int tid = threadIdx.x;
    int wv = tid >> 6, ln = tid & 63;
    int rr = tid >> 2, dg = (tid & 3) << 4;
    for (int e = tid * 4; e < 4096; e += 1024) {
        int r2 = e >> 6, d = e & 63;
        float4 f = *(const float4*)(qb + (((size_t)(n0 + r2)) << 6) + d);
        qs[r2][d] = f2bf(f.x); qs[r2][d+1] = f2bf(f.y);
        qs[r2][d+2] = f2bf(f.z); qs[r2][d+3] = f2bf(f.w);
    }
    __syncthreads();
    const int arow = (wv << 4) + (ln & 15);
    const int ak0 = (ln >> 4) << 3;
    short8 aq0 = *(short8*)&qs[arow][ak0];
    short8 aq1 = *(short8*)&qs[arow][ak0 + 32];
    f32x4 o_acc[4] = {};
    float mr[4] = {-1e30f, -1e30f, -1e30f, -1e30f};
    float lr[4] = {};
    for (int m0 = 0; m0 < 4096; m0 += 64) {
        __syncthreads();
        {
            const float* krow = kb + (((size_t)(m0 + rr)) << 6) + dg;
            const float* vrow = vb + (((size_t)(m0 + rr)) << 6) + dg;
            #pragma unroll
            for (int i = 0; i < 16; i += 4) {
                float4 f = *(const float4*)(krow + i);
                ks[rr][dg+i] = f2bf(f.x); ks[rr][dg+i+1] = f2bf(f.y);
                ks[rr][dg+i+2] = f2bf(f.z); ks[rr][dg+i+3] = f2bf(f.w);
                float4 g2 = *(const float4*)(vrow + i);
                vts[dg+i][rr] = f2bf(g2.x); vts[dg+i+1][rr] = f2bf(g2.y);
                vts[dg+i+2][rr] = f2bf(g2.z); vts[dg+i+3][rr] = f2bf(g2.w);
            }
        }
        __syncthreads();
        f32x4 s_acc[4];
        #pragma unroll
        for (int jb = 0; jb < 4; ++jb) {
            f32x4 z = {};
            short8 bk0 = *(short8*)&ks[(jb << 4) + (ln & 15)][ak0];
            short8 bk1 = *(short8*)&ks[(jb << 4) + (ln & 15)][ak0 + 32];
            z = __builtin_amdgcn_mfma_f32_16x16x32_bf16(aq0, bk0, z, 0, 0, 0);
            z = __builtin_amdgcn_mfma_f32_16x16x32_bf16(aq1, bk1, z, 0, 0, 0);
            s_acc[jb] = z;
        }
        float mx[4];
        #pragma unroll
        for (int r = 0; r < 4; ++r)
            mx[r] = fmaxf(fmaxf(s_acc[0][r], s_acc[1][r]),
                          fmaxf(s_acc[2][r], s_acc[3][r]));
        #pragma unroll
        for (int off = 1; off < 16; off <<= 1)
            #pragma unroll
            for (int r = 0; r < 4; ++r)
                mx[r] = fmaxf(mx[r], __shfl_xor(mx[r], off, 64));
        float fac[4];
        #pragma unroll
        for (int r = 0; r < 4; ++r) {
            float mn = fmaxf(mr[r], mx[r]);
            fac[r] = expf(mr[r] - mn);
            mr[r] = mn;
        }
        float rs[4] = {};
        #pragma unroll
        for (int jb = 0; jb < 4; ++jb)
            #pragma unroll
            for (int r = 0; r < 4; ++r) {
                float p = expf(s_acc[jb][r] - mr[r]);
                rs[r] += p;
                ps[wv][((ln >> 4) << 2) + r][(jb << 4) + (ln & 15)] = f2bf(p);
            }
        #pragma unroll
        for (int off = 1; off < 16; off <<= 1)
            #pragma unroll
            for (int r = 0; r < 4; ++r)
                rs[r] += __shfl_xor(rs[r], off, 64);
        #pragma unroll
        for (int r = 0; r < 4; ++r) lr[r] = lr[r] * fac[r] + rs[r];
        #pragma unroll
        for (int jb = 0; jb < 4; ++jb)
            #pragma unroll
            for (int r = 0; r < 4; ++r)
                o_acc[jb][r] *= fac[r];
        short8 pa0 = *(short8*)&ps[wv][ln & 15][ak0];
        short8 pa1 = *(short8*)&ps[wv][ln & 15][ak0 + 32];
        #pragma unroll
        for (int jb = 0; jb < 4; ++jb) {
            short8 bv0 = *(short8*)&vts[(jb << 4) + (ln & 15)][ak0];
            short8 bv1 = *(short8*)&vts[(jb << 4) + (ln & 15)][ak0 + 32];
            f32x4 z = o_acc[jb];
            z = __builtin_amdgcn_mfma_f32_16x16x32_bf16(pa0, bv0, z, 0, 0, 0);
            z = __builtin_amdgcn_mfma_f32_16x16x32_bf16(pa1, bv1, z, 0, 0, 0);
            o_acc[jb] = z;
        }
    }
    float invl[4];
    #pragma unroll
    for (int r = 0; r < 4; ++r) invl[r] = 1.0f / lr[r];
    #pragma unroll
    for (int jb = 0; jb < 4; ++jb)
        #pragma unroll
        for (int r = 0; r < 4; ++r) {
            int row_q = (wv << 4) + ((ln >> 4) << 2) + r;
            int col_d = (jb << 4) + (ln & 15);
            size_t idx = ((size_t)b * 4096 + n0 + row_q) * 768 + 11 * 64 + col_d;
            unsigned short hh, ll;
            bfsplit(o_acc[jb][r] * invl[r], hh, ll);
            ctxh[idx] = hh; ctxl[idx] = ll;
        }
}

// ---------------------------------------------------------------------------
// K8: proj GEMM via bf16x3 MFMA: out = ctx(16384x768) @ proj_w^T + proj_b
// ---------------------------------------------------------------------------
__global__ __launch_bounds__(256, 2) void gemm_proj_mfma(
    const unsigned short* __restrict__ Xh, const unsigned short* __restrict__ Xl,
    const unsigned short* __restrict__ Wh, const unsigned short* __restrict__ Wl,
    const float* __restrict__ bias, float* __restrict__ out)
{
    __shared__ unsigned short Ah[128][40], Al[128][40], Bh[128][40], Bl[128][40];
    const int tid = threadIdx.x;
    const int brow = blockIdx.y << 7, bcol = blockIdx.x << 7;
    const int ln = tid & 63, wv = tid >> 6;
    const int wr = (wv >> 1) << 6, wc = (wv & 1) << 6;
    const int srow = tid >> 1, sk = (tid & 1) << 4;
    const size_t ag = (size_t)(brow + srow) * 768 + sk;
    const size_t bg = (size_t)(bcol + srow) * 768 + sk;
    const int fr = ln & 15, fk = (ln >> 4) << 3;

    f32x4 acc[4][4] = {};
    for (int k0 = 0; k0 < 768; k0 += 32) {
        short8 xh0 = *(const short8*)(Xh + ag + k0);
        short8 xh1 = *(const short8*)(Xh + ag + k0 + 8);
        short8 xl0 = *(const short8*)(Xl + ag + k0);
        short8 xl1 = *(const short8*)(Xl + ag + k0 + 8);
        short8 wh0 = *(const short8*)(Wh + bg + k0);
        short8 wh1 = *(const short8*)(Wh + bg + k0 + 8);
        short8 wl0 = *(const short8*)(Wl + bg + k0);
        short8 wl1 = *(const short8*)(Wl + bg + k0 + 8);
        __syncthreads();
        *(short8*)&Ah[srow][sk] = xh0; *(short8*)&Ah[srow][sk + 8] = xh1;
        *(short8*)&Al[srow][sk] = xl0; *(short8*)&Al[srow][sk + 8] = xl1;
        *(short8*)&Bh[srow][sk] = wh0; *(short8*)&Bh[srow][sk + 8] = wh1;
        *(short8*)&Bl[srow][sk] = wl0; *(short8*)&Bl[srow][sk + 8] = wl1;
        __syncthreads();
        short8 ah[4], al[4], bh[4], bl[4];
        #pragma unroll
        for (int i = 0; i < 4; ++i) {
            ah[i] = *(short8*)&Ah[wr + (i << 4) + fr][fk];
            al[i] = *(short8*)&Al[wr + (i << 4) + fr][fk];
        }
        #pragma unroll
        for (int j = 0; j < 4; ++j) {
            bh[j] = *(short8*)&Bh[wc + (j << 4) + fr][fk];
            bl[j] = *(short8*)&Bl[wc + (j << 4) + fr][fk];
        }
        #pragma unroll
        for (int i = 0; i < 4; ++i)
            #pragma unroll
            for (int j = 0; j < 4; ++j) {
                acc[i][j] = __builtin_amdgcn_mfma_f32_16x16x32_bf16(ah[i], bh[j], acc[i][j], 0, 0, 0);
                acc[i][j] = __builtin_amdgcn_mfma_f32_16x16x32_bf16(ah[i], bl[j], acc[i][j], 0, 0, 0);
                acc[i][j] = __builtin_amdgcn_mfma_f32_16x16x32_bf16(al[i], bh[j], acc[i][j], 0, 0, 0);
            }
    }
    const int fg = ln >> 4;
    #pragma unroll
    for (int j = 0; j < 4; ++j) {
        int c = bcol + wc + (j << 4) + fr;
        float bb = bias[c];
        #pragma unroll
        for (int i = 0; i < 4; ++i)
            #pragma unroll
            for (int r = 0; r < 4; ++r) {
                int row = brow + wr + (i << 4) + (fg << 2) + r;
                out[(size_t)row * 768 + c] = acc[i][j][r] + bb;
            }
    }
}

// ---------------------------------------------------------------------------
extern "C" void kernel_launch(void* const* d_in, const int* in_sizes, int n_in,
                              void* d_out, int out_size, void* d_ws, size_t ws_size,
                              hipStream_t stream)
{
    const float* x      = (const float*)d_in[0];
    const float* qkv_w  = (const float*)d_in[1];
    const float* qkv_b  = (const float*)d_in[2];
    const float* proj_w = (const float*)d_in[3];
    const float* proj_b = (const float*)d_in[4];
    float* out = (float*)d_out;

    float* ws  = (float*)d_ws;
    const size_t QKV = (size_t)4 * 12 * 4096 * 64;   // 12,582,912
    float* q    = ws;
    float* k    = q + QKV;
    float* v    = k + QKV;
    unsigned short* ctxh = (unsigned short*)(v + QKV);   // QKV shorts
    unsigned short* ctxl = ctxh + QKV;                    // QKV shorts
    float* scm  = (float*)(ctxl + QKV);
    float* eB   = scm + 4096;
    float* den  = eB + 44 * 4096;
    float* pi_  = den + 64;
    float* Wb   = pi_ + 44 * 4096;
    float* Tb   = Wb + 44 * 4160;
    unsigned short* Whi  = (unsigned short*)(Tb + 44 * 4160);
    unsigned short* Wlo  = Whi + (size_t)2304 * 768;
    unsigned short* Pwhi = Wlo + (size_t)2304 * 768;
    unsigned short* Pwlo = Pwhi + (size_t)768 * 768;

    // d_out scratch phase 1: X hi/lo split (dead after gemm_qkv_mfma).
    // Phase 2: wflash partials.
    unsigned short* Xhi = (unsigned short*)out;
    unsigned short* Xlo = Xhi + QKV;
    float* wacc = out;
    float* wl   = wacc + 1441792;
    float* wm   = wl + 22528;

    preconv<<<2048, 256, 0, stream>>>(x, Xhi, Xlo, 3145728);
    preconv<<<1024, 256, 0, stream>>>(qkv_w, Whi, Wlo, 442368);
    preconv<<<512, 256, 0, stream>>>(proj_w, Pwhi, Pwlo, 147456);
    gemm_qkv_mfma<<<dim3(18, 128), 256, 0, stream>>>(Xhi, Xlo, Whi, Wlo, qkv_b, q, k, v);
    wflash<<<dim3(8, 44), 256, 0, stream>>>(q, k, v, wacc, wl, wm);
    wmerge<<<44, 256, 0, stream>>>(wacc, wl, wm, Wb, scm);
    eb_kernel<<<44, 256, 0, stream>>>(q, k, scm, eB);
    norms_kernel<<<11, 256, 0, stream>>>(eB, den);
    pinv_kernel<<<44, 256, 0, stream>>>(eB, den, pi_);
    pw_kernel<<<44, 256, 0, stream>>>(pi_, Wb, Tb);
    outp_kernel<<<dim3(64, 44), 256, 0, stream>>>(q, k, Tb, ctxh, ctxl);
    flash_h11<<<dim3(64, 4), 256, 0, stream>>>(q, k, v, ctxh, ctxl);
    gemm_proj_mfma<<<dim3(6, 128), 256, 0, stream>>>(ctxh, ctxl, Pwhi, Pwlo, proj_b, out);
}

// Round 7
// 495.579 us; speedup vs baseline: 12.3738x; 1.3454x over previous
//
#include <hip/hip_runtime.h>

// B=4, N=4096, C=768, H=12, D=64, M=64, PNP=11, SCALE=1/8

typedef __attribute__((ext_vector_type(8))) short short8;
typedef __attribute__((ext_vector_type(4))) float f32x4;
typedef __attribute__((ext_vector_type(4))) unsigned short ushort4v;

static __device__ __forceinline__ unsigned short f2bf(float f) {
    union { float f; unsigned u; } x; x.f = f;
    unsigned r = x.u + 0x7fffu + ((x.u >> 16) & 1u);   // RNE
    return (unsigned short)(r >> 16);
}

static __device__ __forceinline__ void bfsplit(float x, unsigned short& h, unsigned short& l) {
    unsigned short hh = f2bf(x);
    union { unsigned u; float f; } t; t.u = (unsigned)hh << 16;
    h = hh;
    l = f2bf(x - t.f);    // exact residual, RNE to bf16
}

// ---------------------------------------------------------------------------
// K0: split fp32 array into bf16 (hi, lo) pair arrays. memory-bound.
// ---------------------------------------------------------------------------
__global__ __launch_bounds__(256) void preconv(
    const float* __restrict__ in, unsigned short* __restrict__ hi,
    unsigned short* __restrict__ lo, int n4)
{
    for (int i = blockIdx.x * 256 + threadIdx.x; i < n4; i += gridDim.x * 256) {
        float4 f = *(const float4*)(in + (size_t)i * 4);
        float vs[4] = {f.x, f.y, f.z, f.w};
        ushort4v h, l;
        #pragma unroll
        for (int j = 0; j < 4; ++j) {
            unsigned short hh, ll;
            bfsplit(vs[j], hh, ll);
            h[j] = hh; l[j] = ll;
        }
        *(ushort4v*)(hi + (size_t)i * 4) = h;
        *(ushort4v*)(lo + (size_t)i * 4) = l;
    }
}

// ---------------------------------------------------------------------------
// K1: QKV GEMM via bf16x3-split MFMA. 128x128 tile, BK=32, 4 waves.
// Unpadded XOR-swizzled LDS (chunk ^ (row&3)); XCD-aware block swizzle.
// ---------------------------------------------------------------------------
__global__ __launch_bounds__(256, 2) void gemm_qkv_mfma(
    const unsigned short* __restrict__ Xh, const unsigned short* __restrict__ Xl,
    const unsigned short* __restrict__ Wh, const unsigned short* __restrict__ Wl,
    const float* __restrict__ bias,
    float* __restrict__ q, float* __restrict__ k, float* __restrict__ v)
{
    __shared__ unsigned short Ah[4096], Al[4096], Bh[4096], Bl[4096]; // [128][32] swizzled
    const int tid = threadIdx.x;
    // XCD swizzle: nwg=2304 (%8==0), 288 blocks per XCD contiguous
    const int bid = blockIdx.x;
    const int swz = (bid & 7) * 288 + (bid >> 3);
    const int brow = (swz / 18) << 7, bcol = (swz % 18) << 7;
    const int ln = tid & 63, wv = tid >> 6;
    const int wr = (wv >> 1) << 6, wc = (wv & 1) << 6;
    const int srow = tid >> 1, sc = (tid & 1) << 1;     // 2 chunks of 8 shorts
    const size_t ag = (size_t)(brow + srow) * 768 + (sc << 3);
    const size_t bg = (size_t)(bcol + srow) * 768 + (sc << 3);
    const int fr = ln & 15, fc = ln >> 4;               // fragment row / chunk
    const int i0 = srow * 32 + (((sc + 0) ^ (srow & 3)) << 3);
    const int i1 = srow * 32 + (((sc + 1) ^ (srow & 3)) << 3);

    f32x4 acc[4][4] = {};
    for (int k0 = 0; k0 < 768; k0 += 32) {
        short8 xh0 = *(const short8*)(Xh + ag + k0);
        short8 xh1 = *(const short8*)(Xh + ag + k0 + 8);
        short8 xl0 = *(const short8*)(Xl + ag + k0);
        short8 xl1 = *(const short8*)(Xl + ag + k0 + 8);
        short8 wh0 = *(const short8*)(Wh + bg + k0);
        short8 wh1 = *(const short8*)(Wh + bg + k0 + 8);
        short8 wl0 = *(const short8*)(Wl + bg + k0);
        short8 wl1 = *(const short8*)(Wl + bg + k0 + 8);
        __syncthreads();
        *(short8*)&Ah[i0] = xh0; *(short8*)&Ah[i1] = xh1;
        *(short8*)&Al[i0] = xl0; *(short8*)&Al[i1] = xl1;
        *(short8*)&Bh[i0] = wh0; *(short8*)&Bh[i1] = wh1;
        *(short8*)&Bl[i0] = wl0; *(short8*)&Bl[i1] = wl1;
        __syncthreads();
        short8 ah[4], al[4], bh[4], bl[4];
        #pragma unroll
        for (int i = 0; i < 4; ++i) {
            int ar = wr + (i << 4) + fr;
            int aidx = ar * 32 + ((fc ^ (ar & 3)) << 3);
            ah[i] = *(short8*)&Ah[aidx];
            al[i] = *(short8*)&Al[aidx];
            int br2 = wc + (i << 4) + fr;
            int bidx = br2 * 32 + ((fc ^ (br2 & 3)) << 3);
            bh[i] = *(short8*)&Bh[bidx];
            bl[i] = *(short8*)&Bl[bidx];
        }
        #pragma unroll
        for (int i = 0; i < 4; ++i)
            #pragma unroll
            for (int j = 0; j < 4; ++j) {
                acc[i][j] = __builtin_amdgcn_mfma_f32_16x16x32_bf16(ah[i], bh[j], acc[i][j], 0, 0, 0);
                acc[i][j] = __builtin_amdgcn_mfma_f32_16x16x32_bf16(ah[i], bl[j], acc[i][j], 0, 0, 0);
                acc[i][j] = __builtin_amdgcn_mfma_f32_16x16x32_bf16(al[i], bh[j], acc[i][j], 0, 0, 0);
            }
    }
    const int fg = ln >> 4;
    #pragma unroll
    for (int j = 0; j < 4; ++j) {
        int c = bcol + wc + (j << 4) + fr;
        float bb = bias[c];
        int t = c / 768;
        int rem = c - t * 768;
        int h = rem >> 6, d = rem & 63;
        #pragma unroll
        for (int i = 0; i < 4; ++i)
            #pragma unroll
            for (int r = 0; r < 4; ++r) {
                int row = brow + wr + (i << 4) + (fg << 2) + r;
                int b = row >> 12, n = row & 4095;
                float val = acc[i][j][r] + bb;
                size_t idx = (((size_t)(b * 12 + h) << 12) + n) * 64 + d;
                if (t == 0)      q[idx] = val * 0.125f;
                else if (t == 1) k[idx] = val;
                else             v[idx] = val;
            }
    }
}

// ---------------------------------------------------------------------------
// K2: fused flash pass for SC — bf16x3 MFMA. grid (8, 44).
// ---------------------------------------------------------------------------
__global__ __launch_bounds__(256) void wflash(
    const float* __restrict__ q, const float* __restrict__ k,
    const float* __restrict__ v,
    float* __restrict__ wacc, float* __restrict__ wl, float* __restrict__ wm)
{
    int chunk = blockIdx.x;
    int bh = blockIdx.y;
    int b = bh / 11, h = bh - b * 11;
    size_t base = ((size_t)(b * 12 + h)) << 12;
    const float* qb = q + base * 64;
    const float* kb = k + base * 64;
    const float* vb = v + base * 64;
    __shared__ unsigned short kh[64][72], kl[64][72];
    __shared__ unsigned short vth[64][72], vtl[64][72];
    __shared__ unsigned short ph[4][16][72], pl[4][16][72];
    int tid = threadIdx.x;
    int wv = tid >> 6, ln = tid & 63;
    int rr = tid >> 2, dg = (tid & 3) << 4;
    const int arow = (wv << 4) + (ln & 15);
    const int ak0 = (ln >> 4) << 3;
    const int rg = (ln >> 4) << 2;
    short8 aqh0, aql0, aqh1, aql1;
    {
        const float* qrow = qb + ((size_t)arow << 12);
        #pragma unroll
        for (int j = 0; j < 8; ++j) {
            unsigned short hh, ll;
            bfsplit(qrow[ak0 + j], hh, ll);
            aqh0[j] = (short)hh; aql0[j] = (short)ll;
            bfsplit(qrow[ak0 + 32 + j], hh, ll);
            aqh1[j] = (short)hh; aql1[j] = (short)ll;
        }
    }
    f32x4 o_acc[4] = {};
    float mr[4] = {-1e30f, -1e30f, -1e30f, -1e30f};
    float lr[4] = {};
    for (int t = 0; t < 8; ++t) {
        int n0 = (chunk << 9) + (t << 6);
        __syncthreads();
        {
            const float* krow = kb + (((size_t)(n0 + rr)) << 6) + dg;
            const float* vrow = vb + (((size_t)(n0 + rr)) << 6) + dg;
            #pragma unroll
            for (int i = 0; i < 16; i += 4) {
                float4 f = *(const float4*)(krow + i);
                unsigned short hh, ll;
                bfsplit(f.x, hh, ll); kh[rr][dg+i]   = hh; kl[rr][dg+i]   = ll;
                bfsplit(f.y, hh, ll); kh[rr][dg+i+1] = hh; kl[rr][dg+i+1] = ll;
                bfsplit(f.z, hh, ll); kh[rr][dg+i+2] = hh; kl[rr][dg+i+2] = ll;
                bfsplit(f.w, hh, ll); kh[rr][dg+i+3] = hh; kl[rr][dg+i+3] = ll;
                float4 g2 = *(const float4*)(vrow + i);
                bfsplit(g2.x, hh, ll); vth[dg+i][rr]   = hh; vtl[dg+i][rr]   = ll;
                bfsplit(g2.y, hh, ll); vth[dg+i+1][rr] = hh; vtl[dg+i+1][rr] = ll;
                bfsplit(g2.z, hh, ll); vth[dg+i+2][rr] = hh; vtl[dg+i+2][rr] = ll;
                bfsplit(g2.w, hh, ll); vth[dg+i+3][rr] = hh; vtl[dg+i+3][rr] = ll;
            }
        }
        __syncthreads();
        f32x4 s_acc[4];
        #pragma unroll
        for (int jb = 0; jb < 4; ++jb) {
            f32x4 z = {};
            const int brow2 = (jb << 4) + (ln & 15);
            short8 bh0 = *(short8*)&kh[brow2][ak0];
            short8 bh1 = *(short8*)&kh[brow2][ak0 + 32];
            short8 bl0 = *(short8*)&kl[brow2][ak0];
            short8 bl1 = *(short8*)&kl[brow2][ak0 + 32];
            z = __builtin_amdgcn_mfma_f32_16x16x32_bf16(aqh0, bh0, z, 0, 0, 0);
            z = __builtin_amdgcn_mfma_f32_16x16x32_bf16(aqh0, bl0, z, 0, 0, 0);
            z = __builtin_amdgcn_mfma_f32_16x16x32_bf16(aql0, bh0, z, 0, 0, 0);
            z = __builtin_amdgcn_mfma_f32_16x16x32_bf16(aqh1, bh1, z, 0, 0, 0);
            z = __builtin_amdgcn_mfma_f32_16x16x32_bf16(aqh1, bl1, z, 0, 0, 0);
            z = __builtin_amdgcn_mfma_f32_16x16x32_bf16(aql1, bh1, z, 0, 0, 0);
            s_acc[jb] = z;
        }
        float mx[4];
        #pragma unroll
        for (int r = 0; r < 4; ++r)
            mx[r] = fmaxf(fmaxf(s_acc[0][r], s_acc[1][r]),
                          fmaxf(s_acc[2][r], s_acc[3][r]));
        #pragma unroll
        for (int off = 1; off < 16; off <<= 1)
            #pragma unroll
            for (int r = 0; r < 4; ++r)
                mx[r] = fmaxf(mx[r], __shfl_xor(mx[r], off, 64));
        float fac[4];
        #pragma unroll
        for (int r = 0; r < 4; ++r) {
            float mn = fmaxf(mr[r], mx[r]);
            fac[r] = expf(mr[r] - mn);
            mr[r] = mn;
        }
        float rs[4] = {};
        #pragma unroll
        for (int jb = 0; jb < 4; ++jb)
            #pragma unroll
            for (int r = 0; r < 4; ++r) {
                float p = expf(s_acc[jb][r] - mr[r]);
                rs[r] += p;
                unsigned short hh, ll;
                bfsplit(p, hh, ll);
                ph[wv][rg + r][(jb << 4) + (ln & 15)] = hh;
                pl[wv][rg + r][(jb << 4) + (ln & 15)] = ll;
            }
        #pragma unroll
        for (int off = 1; off < 16; off <<= 1)
            #pragma unroll
            for (int r = 0; r < 4; ++r)
                rs[r] += __shfl_xor(rs[r], off, 64);
        #pragma unroll
        for (int r = 0; r < 4; ++r) lr[r] = lr[r] * fac[r] + rs[r];
        #pragma unroll
        for (int jb = 0; jb < 4; ++jb)
            #pragma unroll
            for (int r = 0; r < 4; ++r)
                o_acc[jb][r] *= fac[r];
        short8 pah0 = *(short8*)&ph[wv][ln & 15][ak0];
        short8 pah1 = *(short8*)&ph[wv][ln & 15][ak0 + 32];
        short8 pal0 = *(short8*)&pl[wv][ln & 15][ak0];
        short8 pal1 = *(short8*)&pl[wv][ln & 15][ak0 + 32];
        #pragma unroll
        for (int jb = 0; jb < 4; ++jb) {
            const int brow2 = (jb << 4) + (ln & 15);
            short8 bvh0 = *(short8*)&vth[brow2][ak0];
            short8 bvh1 = *(short8*)&vth[brow2][ak0 + 32];
            short8 bvl0 = *(short8*)&vtl[brow2][ak0];
            short8 bvl1 = *(short8*)&vtl[brow2][ak0 + 32];
            f32x4 o = o_acc[jb];
            o = __builtin_amdgcn_mfma_f32_16x16x32_bf16(pah0, bvh0, o, 0, 0, 0);
            o = __builtin_amdgcn_mfma_f32_16x16x32_bf16(pah0, bvl0, o, 0, 0, 0);
            o = __builtin_amdgcn_mfma_f32_16x16x32_bf16(pal0, bvh0, o, 0, 0, 0);
            o = __builtin_amdgcn_mfma_f32_16x16x32_bf16(pah1, bvh1, o, 0, 0, 0);
            o = __builtin_amdgcn_mfma_f32_16x16x32_bf16(pah1, bvl1, o, 0, 0, 0);
            o = __builtin_amdgcn_mfma_f32_16x16x32_bf16(pal1, bvh1, o, 0, 0, 0);
            o_acc[jb] = o;
        }
    }
    int cidx = (bh << 3) + chunk;
    #pragma unroll
    for (int jb = 0; jb < 4; ++jb)
        #pragma unroll
        for (int r = 0; r < 4; ++r) {
            int row = (wv << 4) + rg + r, col = (jb << 4) + (ln & 15);
            wacc[((size_t)cidx << 12) + ((size_t)row << 6) + col] = o_acc[jb][r];
        }
    if ((ln & 15) == 0)
        #pragma unroll
        for (int r = 0; r < 4; ++r) {
            int row = (wv << 4) + rg + r;
            wl[cidx * 64 + row] = lr[r];
            wm[cidx * 64 + row] = mr[r];
        }
}

// K2b: merge chunk partials -> Wb (65 cols, col 64 = ones-column) + scm
__global__ __launch_bounds__(256) void wmerge(
    const float* __restrict__ wacc, const float* __restrict__ wl,
    const float* __restrict__ wm,
    float* __restrict__ Wb, float* __restrict__ scm)
{
    int bh = blockIdx.x;
    int tid = threadIdx.x;
    __shared__ float fcs[8][64];
    if (tid < 64) {
        float mx = -1e30f;
        #pragma unroll
        for (int c = 0; c < 8; ++c)
            mx = fmaxf(mx, wm[((bh << 3) + c) * 64 + tid]);
        scm[(bh << 6) + tid] = mx;
        #pragma unroll
        for (int c = 0; c < 8; ++c)
            fcs[c][tid] = expf(wm[((bh << 3) + c) * 64 + tid] - mx);
    }
    __syncthreads();
    for (int e = tid; e < 4096; e += 256) {
        int m = e >> 6, j = e & 63;
        float s = 0.f;
        #pragma unroll
        for (int c = 0; c < 8; ++c)
            s += fcs[c][m] * wacc[((size_t)((bh << 3) + c) << 12) + e];
        Wb[(size_t)bh * 4160 + m * 65 + j] = s;
    }
    if (tid < 64) {
        float s = 0.f;
        #pragma unroll
        for (int c = 0; c < 8; ++c)
            s += fcs[c][tid] * wl[((bh << 3) + c) * 64 + tid];
        Wb[(size_t)bh * 4160 + tid * 65 + 64] = s;
    }
}

// ---------------------------------------------------------------------------
// K3a: eB (fp32)
// ---------------------------------------------------------------------------
__global__ __launch_bounds__(256) void eb_kernel(
    const float* __restrict__ q, const float* __restrict__ k,
    const float* __restrict__ scm, float* __restrict__ eB)
{
    int bh = blockIdx.x;
    int b = bh / 11, h = bh - b * 11;
    size_t base = ((size_t)(b * 12 + h)) << 12;
    const float* qb = q + base * 64;
    const float* kb = k + base * 64;
    __shared__ float qm[64][65], km[64][65];
    int tid = threadIdx.x;
    for (int e = tid; e < 4096; e += 256) {
        int mm = e >> 6, d = e & 63;
        qm[mm][d] = qb[((size_t)mm << 12) + d];
        km[mm][d] = kb[((size_t)mm << 12) + d];
    }
    __syncthreads();
    int m = tid >> 2, l0 = tid & 3;
    float smax = scm[(bh << 6) + m];
    for (int l = l0; l < 64; l += 4) {
        float s = 0.f;
        #pragma unroll
        for (int d = 0; d < 64; ++d) s += qm[m][d] * km[l][d];
        eB[((size_t)bh << 12) + (m << 6) + l] = expf(fmaxf(s - smax, -88.f));
    }
}

// ---------------------------------------------------------------------------
// K3b: per-head norms
// ---------------------------------------------------------------------------
__global__ __launch_bounds__(256) void norms_kernel(
    const float* __restrict__ eB, float* __restrict__ denom)
{
    int h = blockIdx.x;
    int tid = threadIdx.x;
    int b = tid >> 6, idx = tid & 63;
    int bh = b * 11 + h;
    const float* E = eB + ((size_t)bh << 12);
    float rs = 0.f, cs = 0.f;
    #pragma unroll 4
    for (int l = 0; l < 64; ++l) rs += E[(idx << 6) + l];
    #pragma unroll 4
    for (int m = 0; m < 64; ++m) cs += E[(m << 6) + idx];
    __shared__ float r1[256], r2[256];
    r1[tid] = rs; r2[tid] = cs;
    __syncthreads();
    for (int s = 128; s > 0; s >>= 1) {
        if (tid < s) {
            r1[tid] = fmaxf(r1[tid], r1[tid + s]);
            r2[tid] = fmaxf(r2[tid], r2[tid + s]);
        }
        __syncthreads();
    }
    if (tid == 0) denom[h] = r1[0] * r2[0];
}

// ---------------------------------------------------------------------------
// K3c: pinv via 6 Newton iterations — bf16x3 MFMA matmuls, one block per bh.
// ---------------------------------------------------------------------------
__device__ __forceinline__ void mm64x3(
    const unsigned short (&Ahi)[64][72], const unsigned short (&Alo)[64][72],
    const unsigned short (&BThi)[64][72], const unsigned short (&BTlo)[64][72],
    int wr, int wc, int fr, int fk, f32x4 (&acc)[2][2])
{
    #pragma unroll
    for (int ks = 0; ks < 2; ++ks) {
        const int kb = (ks << 5) + fk;
        short8 ah[2], al[2], bh[2], bl[2];
        #pragma unroll
        for (int i = 0; i < 2; ++i) {
            ah[i] = *(const short8*)&Ahi[wr + (i << 4) + fr][kb];
            al[i] = *(const short8*)&Alo[wr + (i << 4) + fr][kb];
            bh[i] = *(const short8*)&BThi[wc + (i << 4) + fr][kb];
            bl[i] = *(const short8*)&BTlo[wc + (i << 4) + fr][kb];
        }
        #pragma unroll
        for (int i = 0; i < 2; ++i)
            #pragma unroll
            for (int j = 0; j < 2; ++j) {
                acc[i][j] = __builtin_amdgcn_mfma_f32_16x16x32_bf16(ah[i], bh[j], acc[i][j], 0, 0, 0);
                acc[i][j] = __builtin_amdgcn_mfma_f32_16x16x32_bf16(ah[i], bl[j], acc[i][j], 0, 0, 0);
                acc[i][j] = __builtin_amdgcn_mfma_f32_16x16x32_bf16(al[i], bh[j], acc[i][j], 0, 0, 0);
            }
    }
}

__global__ __launch_bounds__(256) void pinv_kernel(
    const float* __restrict__ eB, const float* __restrict__ denom,
    float* __restrict__ pi_)
{
    __shared__ unsigned short Xh[64][72],  Xl[64][72];
    __shared__ unsigned short Zh[64][72],  Zl[64][72];
    __shared__ unsigned short ZTh[64][72], ZTl[64][72];
    __shared__ unsigned short Mh[64][72],  Ml[64][72];
    __shared__ unsigned short MTh[64][72], MTl[64][72];
    __shared__ unsigned short Th[64][72],  Tbl[64][72];
    __shared__ float Zf[64][68];
    int bh = blockIdx.x;
    int h = bh % 11;
    int tid = threadIdx.x;
    float dn = denom[h];
    const int ln = tid & 63, wv = tid >> 6;
    const int wr = (wv >> 1) << 5, wc = (wv & 1) << 5;
    const int fr = ln & 15, fk = (ln >> 4) << 3;
    const int rg = (ln >> 4) << 2;

    for (int e = tid; e < 4096; e += 256) {
        int m = e >> 6, l = e & 63;
        float xv = eB[((size_t)bh << 12) + e];
        unsigned short hh, ll;
        bfsplit(xv, hh, ll);
        Xh[m][l] = hh; Xl[m][l] = ll;
        float zv = xv / dn;
        Zf[l][m] = zv;
        bfsplit(zv, hh, ll);
        Zh[l][m] = hh; Zl[l][m] = ll;
        ZTh[m][l] = hh; ZTl[m][l] = ll;
    }
    __syncthreads();

    for (int it = 0; it < 6; ++it) {
        f32x4 mm1[2][2] = {};
        mm64x3(Xh, Xl, ZTh, ZTl, wr, wc, fr, fk, mm1);
        #pragma unroll
        for (int i = 0; i < 2; ++i)
            #pragma unroll
            for (int j = 0; j < 2; ++j)
                #pragma unroll
                for (int r = 0; r < 4; ++r) {
                    int row = wr + (i << 4) + rg + r, col = wc + (j << 4) + fr;
                    unsigned short hh, ll;
                    bfsplit(mm1[i][j][r], hh, ll);
                    Mh[row][col] = hh;  Ml[row][col] = ll;
                    MTh[col][row] = hh; MTl[col][row] = ll;
                }
        __syncthreads();
        f32x4 a2[2][2] = {};
        mm64x3(Mh, Ml, MTh, MTl, wr, wc, fr, fk, a2);
        #pragma unroll
        for (int i = 0; i < 2; ++i)
            #pragma unroll
            for (int j = 0; j < 2; ++j)
                #pragma unroll
                for (int r = 0; r < 4; ++r) {
                    int row = wr + (i << 4) + rg + r, col = wc + (j << 4) + fr;
                    float val = 7.f * mm1[i][j][r] - a2[i][j][r];
                    unsigned short hh, ll;
                    bfsplit(val, hh, ll);
                    Th[col][row] = hh; Tbl[col][row] = ll;
                }
        __syncthreads();
        f32x4 a3[2][2] = {};
        mm64x3(Mh, Ml, Th, Tbl, wr, wc, fr, fk, a3);
        __syncthreads();
        #pragma unroll
        for (int i = 0; i < 2; ++i)
            #pragma unroll
            for (int j = 0; j < 2; ++j)
                #pragma unroll
                for (int r = 0; r < 4; ++r) {
                    int row = wr + (i << 4) + rg + r, col = wc + (j << 4) + fr;
                    float val = 15.f * mm1[i][j][r] - a3[i][j][r];
                    unsigned short hh, ll;
                    bfsplit(val, hh, ll);
                    Th[col][row] = hh; Tbl[col][row] = ll;
                }
        __syncthreads();
        f32x4 a4[2][2] = {};
        mm64x3(Zh, Zl, Th, Tbl, wr, wc, fr, fk, a4);
        float zn[2][2][4];
        #pragma unroll
        for (int i = 0; i < 2; ++i)
            #pragma unroll
            for (int j = 0; j < 2; ++j)
                #pragma unroll
                for (int r = 0; r < 4; ++r) {
                    int row = wr + (i << 4) + rg + r, col = wc + (j << 4) + fr;
                    zn[i][j][r] = 0.25f * (13.f * Zf[row][col] - a4[i][j][r]);
                }
        __syncthreads();
        #pragma unroll
        for (int i = 0; i < 2; ++i)
            #pragma unroll
            for (int j = 0; j < 2; ++j)
                #pragma unroll
                for (int r = 0; r < 4; ++r) {
                    int row = wr + (i << 4) + rg + r, col = wc + (j << 4) + fr;
                    float val = zn[i][j][r];
                    Zf[row][col] = val;
                    unsigned short hh, ll;
                    bfsplit(val, hh, ll);
                    Zh[row][col] = hh;  Zl[row][col] = ll;
                    ZTh[col][row] = hh; ZTl[col][row] = ll;
                }
        __syncthreads();
    }
    for (int e = tid; e < 4096; e += 256)
        pi_[((size_t)bh << 12) + e] = Zf[e >> 6][e & 63];
}

// ---------------------------------------------------------------------------
// K5: T = pi @ W  (64x64 @ 64x65)
// ---------------------------------------------------------------------------
__global__ __launch_bounds__(256) void pw_kernel(
    const float* __restrict__ pi_, const float* __restrict__ Wb,
    float* __restrict__ Tb)
{
    int bh = blockIdx.x;
    __shared__ float P[64][65];
    __shared__ float Wl[64][66];
    int tid = threadIdx.x;
    for (int e = tid; e < 4096; e += 256)
        P[e >> 6][e & 63] = pi_[((size_t)bh << 12) + e];
    for (int e = tid; e < 64 * 65; e += 256) {
        int l = e / 65, j = e - l * 65;
        Wl[l][j] = Wb[(size_t)bh * 4160 + e];
    }
    __syncthreads();
    int m = tid & 63, g = tid >> 6;
    #pragma unroll
    for (int t = 0; t < 17; ++t) {
        int j = g + (t << 2);
        if (j > 64) break;
        float s = 0.f;
        #pragma unroll
        for (int l = 0; l < 64; ++l) s += P[m][l] * Wl[l][j];
        Tb[(size_t)((bh << 6) + m) * 65 + j] = s;
    }
}

// ---------------------------------------------------------------------------
// K6: out_p — bf16x3 MFMA, writes ctx as single bf16 (proj is bf16 now)
// ---------------------------------------------------------------------------
__global__ __launch_bounds__(256) void outp_kernel(
    const float* __restrict__ q, const float* __restrict__ k,
    const float* __restrict__ Tb, unsigned short* __restrict__ ctxh)
{
    int bh = blockIdx.y;
    int b = bh / 11, h = bh - b * 11;
    int n0 = blockIdx.x << 6;
    size_t base = ((size_t)(b * 12 + h)) << 12;
    const float* qb = q + base * 64;
    const float* kb = k + base * 64;
    __shared__ unsigned short kmh[64][72], kml[64][72];
    __shared__ unsigned short tth[64][72], ttl[64][72];
    __shared__ unsigned short ph[4][16][72], pl[4][16][72];
    __shared__ float t64[64];
    int tid = threadIdx.x;
    int wv = tid >> 6, ln = tid & 63;
    int rr = tid >> 2, dg = (tid & 3) << 4;
    const int arow = (wv << 4) + (ln & 15);
    const int ak0 = (ln >> 4) << 3;
    const int rg = (ln >> 4) << 2;
    {
        const float* krow = kb + ((size_t)rr << 12) + dg;
        #pragma unroll
        for (int i = 0; i < 16; i += 4) {
            float4 f = *(const float4*)(krow + i);
            unsigned short hh, ll;
            bfsplit(f.x, hh, ll); kmh[rr][dg+i]   = hh; kml[rr][dg+i]   = ll;
            bfsplit(f.y, hh, ll); kmh[rr][dg+i+1] = hh; kml[rr][dg+i+1] = ll;
            bfsplit(f.z, hh, ll); kmh[rr][dg+i+2] = hh; kml[rr][dg+i+2] = ll;
            bfsplit(f.w, hh, ll); kmh[rr][dg+i+3] = hh; kml[rr][dg+i+3] = ll;
        }
    }
    for (int e = tid; e < 4096; e += 256) {
        int m = e >> 6, j = e & 63;
        float tv = Tb[(size_t)((bh << 6) + m) * 65 + j];
        unsigned short hh, ll;
        bfsplit(tv, hh, ll);
        tth[j][m] = hh; ttl[j][m] = ll;
    }
    if (tid < 64) t64[tid] = Tb[(size_t)((bh << 6) + tid) * 65 + 64];
    short8 aqh0, aql0, aqh1, aql1;
    {
        const float* qrow = qb + (((size_t)(n0 + arow)) << 6);
        #pragma unroll
        for (int j = 0; j < 8; ++j) {
            unsigned short hh, ll;
            bfsplit(qrow[ak0 + j], hh, ll);
            aqh0[j] = (short)hh; aql0[j] = (short)ll;
            bfsplit(qrow[ak0 + 32 + j], hh, ll);
            aqh1[j] = (short)hh; aql1[j] = (short)ll;
        }
    }
    __syncthreads();
    f32x4 s_acc[4];
    #pragma unroll
    for (int jb = 0; jb < 4; ++jb) {
        f32x4 z = {};
        const int brow2 = (jb << 4) + (ln & 15);
        short8 bh0 = *(short8*)&kmh[brow2][ak0];
        short8 bh1 = *(short8*)&kmh[brow2][ak0 + 32];
        short8 bl0 = *(short8*)&kml[brow2][ak0];
        short8 bl1 = *(short8*)&kml[brow2][ak0 + 32];
        z = __builtin_amdgcn_mfma_f32_16x16x32_bf16(aqh0, bh0, z, 0, 0, 0);
        z = __builtin_amdgcn_mfma_f32_16x16x32_bf16(aqh0, bl0, z, 0, 0, 0);
        z = __builtin_amdgcn_mfma_f32_16x16x32_bf16(aql0, bh0, z, 0, 0, 0);
        z = __builtin_amdgcn_mfma_f32_16x16x32_bf16(aqh1, bh1, z, 0, 0, 0);
        z = __builtin_amdgcn_mfma_f32_16x16x32_bf16(aqh1, bl1, z, 0, 0, 0);
        z = __builtin_amdgcn_mfma_f32_16x16x32_bf16(aql1, bh1, z, 0, 0, 0);
        s_acc[jb] = z;
    }
    float mx[4];
    #pragma unroll
    for (int r = 0; r < 4; ++r)
        mx[r] = fmaxf(fmaxf(s_acc[0][r], s_acc[1][r]),
                      fmaxf(s_acc[2][r], s_acc[3][r]));
    #pragma unroll
    for (int off = 1; off < 16; off <<= 1)
        #pragma unroll
        for (int r = 0; r < 4; ++r)
            mx[r] = fmaxf(mx[r], __shfl_xor(mx[r], off, 64));
    float den[4] = {};
    #pragma unroll
    for (int jb = 0; jb < 4; ++jb) {
        float tj = t64[(jb << 4) + (ln & 15)];
        #pragma unroll
        for (int r = 0; r < 4; ++r) {
            float p = expf(s_acc[jb][r] - mx[r]);
            den[r] += p * tj;
            unsigned short hh, ll;
            bfsplit(p, hh, ll);
            ph[wv][rg + r][(jb << 4) + (ln & 15)] = hh;
            pl[wv][rg + r][(jb << 4) + (ln & 15)] = ll;
        }
    }
    #pragma unroll
    for (int off = 1; off < 16; off <<= 1)
        #pragma unroll
        for (int r = 0; r < 4; ++r)
            den[r] += __shfl_xor(den[r], off, 64);
    short8 pah0 = *(short8*)&ph[wv][ln & 15][ak0];
    short8 pah1 = *(short8*)&ph[wv][ln & 15][ak0 + 32];
    short8 pal0 = *(short8*)&pl[wv][ln & 15][ak0];
    short8 pal1 = *(short8*)&pl[wv][ln & 15][ak0 + 32];
    f32x4 o_acc[4] = {};
    #pragma unroll
    for (int jb = 0; jb < 4; ++jb) {
        const int brow2 = (jb << 4) + (ln & 15);
        short8 bth0 = *(short8*)&tth[brow2][ak0];
        short8 bth1 = *(short8*)&tth[brow2][ak0 + 32];
        short8 btl0 = *(short8*)&ttl[brow2][ak0];
        short8 btl1 = *(short8*)&ttl[brow2][ak0 + 32];
        f32x4 o = o_acc[jb];
        o = __builtin_amdgcn_mfma_f32_16x16x32_bf16(pah0, bth0, o, 0, 0, 0);
        o = __builtin_amdgcn_mfma_f32_16x16x32_bf16(pah0, btl0, o, 0, 0, 0);
        o = __builtin_amdgcn_mfma_f32_16x16x32_bf16(pal0, bth0, o, 0, 0, 0);
        o = __builtin_amdgcn_mfma_f32_16x16x32_bf16(pah1, bth1, o, 0, 0, 0);
        o = __builtin_amdgcn_mfma_f32_16x16x32_bf16(pah1, btl1, o, 0, 0, 0);
        o = __builtin_amdgcn_mfma_f32_16x16x32_bf16(pal1, bth1, o, 0, 0, 0);
        o_acc[jb] = o;
    }
    float inv[4];
    #pragma unroll
    for (int r = 0; r < 4; ++r) inv[r] = 1.0f / fmaxf(den[r], 1e-8f);
    #pragma unroll
    for (int jb = 0; jb < 4; ++jb)
        #pragma unroll
        for (int r = 0; r < 4; ++r) {
            int row = n0 + (wv << 4) + rg + r;
            int col = (jb << 4) + (ln & 15);
            ctxh[((size_t)b * 4096 + row) * 768 + h * 64 + col] =
                f2bf(o_acc[jb][r] * inv[r]);
        }
}

// ---------------------------------------------------------------------------
// K7a: softmax head (h=11) flash partial over a 1024-KV chunk. grid (64,4,4).
// ---------------------------------------------------------------------------
__global__ __launch_bounds__(256) void flash_part(
    const float* __restrict__ q, const float* __restrict__ k,
    const float* __restrict__ v,
    float* __restrict__ pacc, float* __restrict__ pm, float* __restrict__ pl)
{
    int bx = blockIdx.x, cy = blockIdx.y, b = blockIdx.z;
    int n0 = bx << 6;
    size_t base = ((size_t)(b * 12 + 11)) << 12;
    const float* qb = q + base * 64;
    const float* kb = k + base * 64;
    const float* vb = v + base * 64;
    __shared__ unsigned short qs[64][72];
    __shared__ unsigned short ks[64][72];
    __shared__ unsigned short vts[64][72];
    __shared__ unsigned short ps[4][16][72];
    int tid = threadIdx.x;
    int wv = tid >> 6, ln = tid & 63;
    int rr = tid >> 2, dg = (tid & 3) << 4;
    for (int e = tid * 4; e < 4096; e += 1024) {
        int r2 = e >> 6, d = e & 63;
        float4 f = *(const float4*)(qb + (((size_t)(n0 + r2)) << 6) + d);
        qs[r2][d] = f2bf(f.x); qs[r2][d+1] = f2bf(f.y);
        qs[r2][d+2] = f2bf(f.z); qs[r2][d+3] = f2bf(f.w);
    }
    __syncthreads();
    const int arow = (wv << 4) + (ln & 15);
    const int ak0 = (ln >> 4) << 3;
    const int rg = (ln >> 4) << 2;
    short8 aq0 = *(short8*)&qs[arow][ak0];
    short8 aq1 = *(short8*)&qs[arow][ak0 + 32];
    f32x4 o_acc[4] = {};
    float mr[4] = {-1e30f, -1e30f, -1e30f, -1e30f};
    float lr[4] = {};
    for (int t = 0; t < 16; ++t) {
        int m0 = (cy << 10) + (t << 6);
        __syncthreads();
        {
            const float* krow = kb + (((size_t)(m0 + rr)) << 6) + dg;
            const float* vrow = vb + (((size_t)(m0 + rr)) << 6) + dg;
            #pragma unroll
            for (int i = 0; i < 16; i += 4) {
                float4 f = *(const float4*)(krow + i);
                ks[rr][dg+i] = f2bf(f.x); ks[rr][dg+i+1] = f2bf(f.y);
                ks[rr][dg+i+2] = f2bf(f.z); ks[rr][dg+i+3] = f2bf(f.w);
                float4 g2 = *(const float4*)(vrow + i);
                vts[dg+i][rr] = f2bf(g2.x); vts[dg+i+1][rr] = f2bf(g2.y);
                vts[dg+i+2][rr] = f2bf(g2.z); vts[dg+i+3][rr] = f2bf(g2.w);
            }
        }
        __syncthreads();
        f32x4 s_acc[4];
        #pragma unroll
        for (int jb = 0; jb < 4; ++jb) {
            f32x4 z = {};
            short8 bk0 = *(short8*)&ks[(jb << 4) + (ln & 15)][ak0];
            short8 bk1 = *(short8*)&ks[(jb << 4) + (ln & 15)][ak0 + 32];
            z = __builtin_amdgcn_mfma_f32_16x16x32_bf16(aq0, bk0, z, 0, 0, 0);
            z = __builtin_amdgcn_mfma_f32_16x16x32_bf16(aq1, bk1, z, 0, 0, 0);
            s_acc[jb] = z;
        }
        float mx[4];
        #pragma unroll
        for (int r = 0; r < 4; ++r)
            mx[r] = fmaxf(fmaxf(s_acc[0][r], s_acc[1][r]),
                          fmaxf(s_acc[2][r], s_acc[3][r]));
        #pragma unroll
        for (int off = 1; off < 16; off <<= 1)
            #pragma unroll
            for (int r = 0; r < 4; ++r)
                mx[r] = fmaxf(mx[r], __shfl_xor(mx[r], off, 64));
        float fac[4];
        #pragma unroll
        for (int r = 0; r < 4; ++r) {
            float mn = fmaxf(mr[r], mx[r]);
            fac[r] = expf(mr[r] - mn);
            mr[r] = mn;
        }
        float rs[4] = {};
        #pragma unroll
        for (int jb = 0; jb < 4; ++jb)
            #pragma unroll
            for (int r = 0; r < 4; ++r) {
                float p = expf(s_acc[jb][r] - mr[r]);
                rs[r] += p;
                ps[wv][rg + r][(jb << 4) + (ln & 15)] = f2bf(p);
            }
        #pragma unroll
        for (int off = 1; off < 16; off <<= 1)
            #pragma unroll
            for (int r = 0; r < 4; ++r)
                rs[r] += __shfl_xor(rs[r], off, 64);
        #pragma unroll
        for (int r = 0; r < 4; ++r) lr[r] = lr[r] * fac[r] + rs[r];
        #pragma unroll
        for (int jb = 0; jb < 4; ++jb)
            #pragma unroll
            for (int r = 0; r < 4; ++r)
                o_acc[jb][r] *= fac[r];
        short8 pa0 = *(short8*)&ps[wv][ln & 15][ak0];
        short8 pa1 = *(short8*)&ps[wv][ln & 15][ak0 + 32];
        #pragma unroll
        for (int jb = 0; jb < 4; ++jb) {
            short8 bv0 = *(short8*)&vts[(jb << 4) + (ln & 15)][ak0];
            short8 bv1 = *(short8*)&vts[(jb << 4) + (ln & 15)][ak0 + 32];
            f32x4 z = o_acc[jb];
            z = __builtin_amdgcn_mfma_f32_16x16x32_bf16(pa0, bv0, z, 0, 0, 0);
            z = __builtin_amdgcn_mfma_f32_16x16x32_bf16(pa1, bv1, z, 0, 0, 0);
            o_acc[jb] = z;
        }
    }
    int slot = (b * 4 + cy) * 64 + bx;
    #pragma unroll
    for (int jb = 0; jb < 4; ++jb)
        #pragma unroll
        for (int r = 0; r < 4; ++r) {
            int row = (wv << 4) + rg + r, col = (jb << 4) + (ln & 15);
            pacc[(size_t)slot * 4096 + (size_t)row * 64 + col] = o_acc[jb][r];
        }
    if ((ln & 15) == 0)
        #pragma unroll
        for (int r = 0; r < 4; ++r) {
            int row = (wv << 4) + rg + r;
            pm[(size_t)slot * 64 + row] = mr[r];
            pl[(size_t)slot * 64 + row] = lr[r];
        }
}

// K7b: merge 4 chunk partials -> ctx head 11 (bf16)
__global__ __launch_bounds__(256) void flash_merge(
    const float* __restrict__ pacc, const float* __restrict__ pm,
    const float* __restrict__ pl, unsigned short* __restrict__ ctxh)
{
    int bx = blockIdx.x, b = blockIdx.y;
    int tid = threadIdx.x, r = tid & 63, g = tid >> 6;
    float mc[4], mt = -1e30f;
    #pragma unroll
    for (int c = 0; c < 4; ++c) {
        mc[c] = pm[(size_t)((b * 4 + c) * 64 + bx) * 64 + r];
        mt = fmaxf(mt, mc[c]);
    }
    float fac[4], lt = 0.f;
    #pragma unroll
    for (int c = 0; c < 4; ++c) {
        fac[c] = expf(mc[c] - mt);
        lt += fac[c] * pl[(size_t)((b * 4 + c) * 64 + bx) * 64 + r];
    }
    float inv = 1.0f / lt;
    size_t obase = ((size_t)b * 4096 + (size_t)((bx << 6) + r)) * 768 + 11 * 64 + (g << 4);
    #pragma unroll
    for (int i = 0; i < 16; ++i) {
        float s = 0.f;
        #pragma unroll
        for (int c = 0; c < 4; ++c)
            s += fac[c] * pacc[(size_t)((b * 4 + c) * 64 + bx) * 4096 + (size_t)r * 64 + (g << 4) + i];
        ctxh[obase + i] = f2bf(s * inv);
    }
}

// ---------------------------------------------------------------------------
// K8: proj GEMM — plain bf16 MFMA (proj does not feed exp/pinv; bf16-safe).
// 128x128 tile, BK=32, swizzled LDS, XCD block swizzle.
// ---------------------------------------------------------------------------
__global__ __launch_bounds__(256, 2) void gemm_proj_mfma(
    const unsigned short* __restrict__ Xh, const unsigned short* __restrict__ Wh,
    const float* __restrict__ bias, float* __restrict__ out)
{
    __shared__ unsigned short Ah[4096], Bh[4096];   // [128][32] swizzled
    const int tid = threadIdx.x;
    const int bid = blockIdx.x;                      // nwg=768 (%8==0), 96/XCD
    const int swz = (bid & 7) * 96 + (bid >> 3);
    const int brow = (swz / 6) << 7, bcol = (swz % 6) << 7;
    const int ln = tid & 63, wv = tid >> 6;
    const int wr = (wv >> 1) << 6, wc = (wv & 1) << 6;
    const int srow = tid >> 1, sc = (tid & 1) << 1;
    const size_t ag = (size_t)(brow + srow) * 768 + (sc << 3);
    const size_t bg = (size_t)(bcol + srow) * 768 + (sc << 3);
    const int fr = ln & 15, fc = ln >> 4;
    const int i0 = srow * 32 + (((sc + 0) ^ (srow & 3)) << 3);
    const int i1 = srow * 32 + (((sc + 1) ^ (srow & 3)) << 3);

    f32x4 acc[4][4] = {};
    for (int k0 = 0; k0 < 768; k0 += 32) {
        short8 xh0 = *(const short8*)(Xh + ag + k0);
        short8 xh1 = *(const short8*)(Xh + ag + k0 + 8);
        short8 wh0 = *(const short8*)(Wh + bg + k0);
        short8 wh1 = *(const short8*)(Wh + bg + k0 + 8);
        __syncthreads();
        *(short8*)&Ah[i0] = xh0; *(short8*)&Ah[i1] = xh1;
        *(short8*)&Bh[i0] = wh0; *(short8*)&Bh[i1] = wh1;
        __syncthreads();
        short8 ah[4], bh[4];
        #pragma unroll
        for (int i = 0; i < 4; ++i) {
            int ar = wr + (i << 4) + fr;
            ah[i] = *(short8*)&Ah[ar * 32 + ((fc ^ (ar & 3)) << 3)];
            int br2 = wc + (i << 4) + fr;
            bh[i] = *(short8*)&Bh[br2 * 32 + ((fc ^ (br2 & 3)) << 3)];
        }
        #pragma unroll
        for (int i = 0; i < 4; ++i)
            #pragma unroll
            for (int j = 0; j < 4; ++j)
                acc[i][j] = __builtin_amdgcn_mfma_f32_16x16x32_bf16(ah[i], bh[j], acc[i][j], 0, 0, 0);
    }
    const int fg = ln >> 4;
    #pragma unroll
    for (int j = 0; j < 4; ++j) {
        int c = bcol + wc + (j << 4) + fr;
        float bb = bias[c];
        #pragma unroll
        for (int i = 0; i < 4; ++i)
            #pragma unroll
            for (int r = 0; r < 4; ++r) {
                int row = brow + wr + (i << 4) + (fg << 2) + r;
                out[(size_t)row * 768 + c] = acc[i][j][r] + bb;
            }
    }
}

// ---------------------------------------------------------------------------
extern "C" void kernel_launch(void* const* d_in, const int* in_sizes, int n_in,
                              void* d_out, int out_size, void* d_ws, size_t ws_size,
                              hipStream_t stream)
{
    const float* x      = (const float*)d_in[0];
    const float* qkv_w  = (const float*)d_in[1];
    const float* qkv_b  = (const float*)d_in[2];
    const float* proj_w = (const float*)d_in[3];
    const float* proj_b = (const float*)d_in[4];
    float* out = (float*)d_out;

    float* ws  = (float*)d_ws;
    const size_t QKV = (size_t)4 * 12 * 4096 * 64;   // 12,582,912
    float* q    = ws;
    float* k    = q + QKV;
    float* v    = k + QKV;
    unsigned short* ctxh = (unsigned short*)(v + QKV);   // QKV ushorts
    float* scm  = (float*)(ctxh + QKV);
    float* eB   = scm + 4096;
    float* den  = eB + 44 * 4096;
    float* pi_  = den + 64;
    float* Wb   = pi_ + 44 * 4096;
    float* Tb   = Wb + 44 * 4160;
    unsigned short* Whi  = (unsigned short*)(Tb + 44 * 4160);
    unsigned short* Wlo  = Whi + (size_t)2304 * 768;
    unsigned short* Pwhi = Wlo + (size_t)2304 * 768;
    unsigned short* Pwlo = Pwhi + (size_t)768 * 768;   // written, unused

    // d_out scratch: phase 1 X hi/lo (dead after gemm_qkv); phase 2 wflash
    // partials (dead after wmerge); phase 3 flash partials (dead after merge).
    unsigned short* Xhi = (unsigned short*)out;
    unsigned short* Xlo = Xhi + QKV;
    float* wacc = out;                    // 1,441,792
    float* wl   = wacc + 1441792;         // 22,528
    float* wm   = wl + 22528;             // 22,528
    float* fpacc = out;                   // 4,194,304 (after wmerge)
    float* fpm   = fpacc + 4194304;       // 65,536
    float* fpl   = fpm + 65536;           // 65,536

    preconv<<<2048, 256, 0, stream>>>(x, Xhi, Xlo, 3145728);
    preconv<<<1024, 256, 0, stream>>>(qkv_w, Whi, Wlo, 442368);
    preconv<<<512, 256, 0, stream>>>(proj_w, Pwhi, Pwlo, 147456);
    gemm_qkv_mfma<<<2304, 256, 0, stream>>>(Xhi, Xlo, Whi, Wlo, qkv_b, q, k, v);
    wflash<<<dim3(8, 44), 256, 0, stream>>>(q, k, v, wacc, wl, wm);
    wmerge<<<44, 256, 0, stream>>>(wacc, wl, wm, Wb, scm);
    eb_kernel<<<44, 256, 0, stream>>>(q, k, scm, eB);
    norms_kernel<<<11, 256, 0, stream>>>(eB, den);
    pinv_kernel<<<44, 256, 0, stream>>>(eB, den, pi_);
    pw_kernel<<<44, 256, 0, stream>>>(pi_, Wb, Tb);
    outp_kernel<<<dim3(64, 44), 256, 0, stream>>>(q, k, Tb, ctxh);
    flash_part<<<dim3(64, 4, 4), 256, 0, stream>>>(q, k, v, fpacc, fpm, fpl);
    flash_merge<<<dim3(64, 4), 256, 0, stream>>>(fpacc, fpm, fpl, ctxh);
    gemm_proj_mfma<<<768, 256, 0, stream>>>(ctxh, Pwhi, proj_b, out);
}

// Round 8
// 480.433 us; speedup vs baseline: 12.7639x; 1.0315x over previous
//
#include <hip/hip_runtime.h>

// B=4, N=4096, C=768, H=12, D=64, M=64, PNP=11, SCALE=1/8

typedef __attribute__((ext_vector_type(8))) short short8;
typedef __attribute__((ext_vector_type(4))) float f32x4;
typedef __attribute__((ext_vector_type(4))) unsigned short ushort4v;

static __device__ __forceinline__ unsigned short f2bf(float f) {
    union { float f; unsigned u; } x; x.f = f;
    unsigned r = x.u + 0x7fffu + ((x.u >> 16) & 1u);   // RNE
    return (unsigned short)(r >> 16);
}

static __device__ __forceinline__ float b2f(unsigned short u) {
    union { unsigned u; float f; } t; t.u = (unsigned)u << 16; return t.f;
}

static __device__ __forceinline__ void bfsplit(float x, unsigned short& h, unsigned short& l) {
    unsigned short hh = f2bf(x);
    union { unsigned u; float f; } t; t.u = (unsigned)hh << 16;
    h = hh;
    l = f2bf(x - t.f);    // exact residual, RNE to bf16
}

// ---------------------------------------------------------------------------
// K0: split fp32 array into bf16 (hi, lo) pair arrays. memory-bound.
// ---------------------------------------------------------------------------
__global__ __launch_bounds__(256) void preconv(
    const float* __restrict__ in, unsigned short* __restrict__ hi,
    unsigned short* __restrict__ lo, int n4)
{
    for (int i = blockIdx.x * 256 + threadIdx.x; i < n4; i += gridDim.x * 256) {
        float4 f = *(const float4*)(in + (size_t)i * 4);
        float vs[4] = {f.x, f.y, f.z, f.w};
        ushort4v h, l;
        #pragma unroll
        for (int j = 0; j < 4; ++j) {
            unsigned short hh, ll;
            bfsplit(vs[j], hh, ll);
            h[j] = hh; l[j] = ll;
        }
        *(ushort4v*)(hi + (size_t)i * 4) = h;
        *(ushort4v*)(lo + (size_t)i * 4) = l;
    }
}

// ---------------------------------------------------------------------------
// K1: QKV GEMM via bf16 split MFMA. 128x128 tile, BK=32, 4 waves.
// q,k column-tiles: x3 split (feed exp paths). v tiles (bcol>=1536): x1 bf16.
// Epilogue: q->(qh,ql)*0.125, k->(kh,kl), v->vh (bf16).
// ---------------------------------------------------------------------------
__global__ __launch_bounds__(256, 2) void gemm_qkv_mfma(
    const unsigned short* __restrict__ Xh, const unsigned short* __restrict__ Xl,
    const unsigned short* __restrict__ Wh, const unsigned short* __restrict__ Wl,
    const float* __restrict__ bias,
    unsigned short* __restrict__ qh, unsigned short* __restrict__ ql,
    unsigned short* __restrict__ kh, unsigned short* __restrict__ kl,
    unsigned short* __restrict__ vh)
{
    __shared__ unsigned short Ah[4096], Al[4096], Bh[4096], Bl[4096]; // [128][32] swizzled
    const int tid = threadIdx.x;
    const int bid = blockIdx.x;                 // nwg=2304 (%8==0)
    const int swz = (bid & 7) * 288 + (bid >> 3);
    const int brow = (swz / 18) << 7, bcol = (swz % 18) << 7;
    const bool isv = (bcol >= 1536);
    const int ln = tid & 63, wv = tid >> 6;
    const int wr = (wv >> 1) << 6, wc = (wv & 1) << 6;
    const int srow = tid >> 1, sc = (tid & 1) << 1;
    const size_t ag = (size_t)(brow + srow) * 768 + (sc << 3);
    const size_t bg = (size_t)(bcol + srow) * 768 + (sc << 3);
    const int fr = ln & 15, fc = ln >> 4;
    const int i0 = srow * 32 + (((sc + 0) ^ (srow & 3)) << 3);
    const int i1 = srow * 32 + (((sc + 1) ^ (srow & 3)) << 3);

    f32x4 acc[4][4] = {};
    for (int k0 = 0; k0 < 768; k0 += 32) {
        short8 xh0 = *(const short8*)(Xh + ag + k0);
        short8 xh1 = *(const short8*)(Xh + ag + k0 + 8);
        short8 wh0 = *(const short8*)(Wh + bg + k0);
        short8 wh1 = *(const short8*)(Wh + bg + k0 + 8);
        short8 xl0, xl1, wl0, wl1;
        if (!isv) {
            xl0 = *(const short8*)(Xl + ag + k0);
            xl1 = *(const short8*)(Xl + ag + k0 + 8);
            wl0 = *(const short8*)(Wl + bg + k0);
            wl1 = *(const short8*)(Wl + bg + k0 + 8);
        }
        __syncthreads();
        *(short8*)&Ah[i0] = xh0; *(short8*)&Ah[i1] = xh1;
        *(short8*)&Bh[i0] = wh0; *(short8*)&Bh[i1] = wh1;
        if (!isv) {
            *(short8*)&Al[i0] = xl0; *(short8*)&Al[i1] = xl1;
            *(short8*)&Bl[i0] = wl0; *(short8*)&Bl[i1] = wl1;
        }
        __syncthreads();
        short8 ah[4], al[4], bh[4], bl[4];
        #pragma unroll
        for (int i = 0; i < 4; ++i) {
            int ar = wr + (i << 4) + fr;
            int aidx = ar * 32 + ((fc ^ (ar & 3)) << 3);
            ah[i] = *(short8*)&Ah[aidx];
            int br2 = wc + (i << 4) + fr;
            int bidx = br2 * 32 + ((fc ^ (br2 & 3)) << 3);
            bh[i] = *(short8*)&Bh[bidx];
            if (!isv) {
                al[i] = *(short8*)&Al[aidx];
                bl[i] = *(short8*)&Bl[bidx];
            }
        }
        #pragma unroll
        for (int i = 0; i < 4; ++i)
            #pragma unroll
            for (int j = 0; j < 4; ++j) {
                acc[i][j] = __builtin_amdgcn_mfma_f32_16x16x32_bf16(ah[i], bh[j], acc[i][j], 0, 0, 0);
                if (!isv) {
                    acc[i][j] = __builtin_amdgcn_mfma_f32_16x16x32_bf16(ah[i], bl[j], acc[i][j], 0, 0, 0);
                    acc[i][j] = __builtin_amdgcn_mfma_f32_16x16x32_bf16(al[i], bh[j], acc[i][j], 0, 0, 0);
                }
            }
    }
    const int fg = ln >> 4;
    #pragma unroll
    for (int j = 0; j < 4; ++j) {
        int c = bcol + wc + (j << 4) + fr;
        float bb = bias[c];
        int t = c / 768;
        int rem = c - t * 768;
        int h = rem >> 6, d = rem & 63;
        #pragma unroll
        for (int i = 0; i < 4; ++i)
            #pragma unroll
            for (int r = 0; r < 4; ++r) {
                int row = brow + wr + (i << 4) + (fg << 2) + r;
                int b = row >> 12, n = row & 4095;
                float val = acc[i][j][r] + bb;
                size_t idx = (((size_t)(b * 12 + h) << 12) + n) * 64 + d;
                unsigned short hh, ll;
                if (t == 0) {
                    bfsplit(val * 0.125f, hh, ll);
                    qh[idx] = hh; ql[idx] = ll;
                } else if (t == 1) {
                    bfsplit(val, hh, ll);
                    kh[idx] = hh; kl[idx] = ll;
                } else {
                    vh[idx] = f2bf(val);
                }
            }
    }
}

// ---------------------------------------------------------------------------
// K2: fused flash pass for SC — MFMA. S: qk x3 split; PV: P hi/lo x V bf16.
// grid (8 chunks, 44 bh).
// ---------------------------------------------------------------------------
__global__ __launch_bounds__(256) void wflash(
    const unsigned short* __restrict__ qh, const unsigned short* __restrict__ ql,
    const unsigned short* __restrict__ khg, const unsigned short* __restrict__ klg,
    const unsigned short* __restrict__ vhg,
    float* __restrict__ wacc, float* __restrict__ wl, float* __restrict__ wm)
{
    int chunk = blockIdx.x;
    int bh = blockIdx.y;
    int b = bh / 11, h = bh - b * 11;
    size_t base = ((size_t)(b * 12 + h)) << 12;   // row base
    __shared__ unsigned short kh_s[64][72], kl_s[64][72];
    __shared__ unsigned short vth[64][72];                 // V^T [d][n], bf16
    __shared__ unsigned short ph[4][16][72], pl[4][16][72];
    int tid = threadIdx.x;
    int wv = tid >> 6, ln = tid & 63;
    int rr = tid >> 2, dg = (tid & 3) << 4;
    const int arow = (wv << 4) + (ln & 15);
    const int ak0 = (ln >> 4) << 3;
    const int rg = (ln >> 4) << 2;
    // A-frags: landmark q rows (n = arow*64), hi/lo straight from split arrays
    short8 aqh0, aql0, aqh1, aql1;
    {
        size_t off = ((base + ((size_t)arow << 6)) << 6) + ak0;
        aqh0 = *(const short8*)(qh + off);
        aqh1 = *(const short8*)(qh + off + 32);
        aql0 = *(const short8*)(ql + off);
        aql1 = *(const short8*)(ql + off + 32);
    }
    f32x4 o_acc[4] = {};
    float mr[4] = {-1e30f, -1e30f, -1e30f, -1e30f};
    float lr[4] = {};
    for (int t = 0; t < 8; ++t) {
        int n0 = (chunk << 9) + (t << 6);
        __syncthreads();
        {   // stage K (hi/lo) rows + V^T (bf16) — pure copies
            size_t off = ((base + n0 + rr) << 6) + dg;
            *(short8*)&kh_s[rr][dg]     = *(const short8*)(khg + off);
            *(short8*)&kh_s[rr][dg + 8] = *(const short8*)(khg + off + 8);
            *(short8*)&kl_s[rr][dg]     = *(const short8*)(klg + off);
            *(short8*)&kl_s[rr][dg + 8] = *(const short8*)(klg + off + 8);
            short8 v0 = *(const short8*)(vhg + off);
            short8 v1 = *(const short8*)(vhg + off + 8);
            #pragma unroll
            for (int i = 0; i < 8; ++i) {
                vth[dg + i][rr]     = (unsigned short)v0[i];
                vth[dg + 8 + i][rr] = (unsigned short)v1[i];
            }
        }
        __syncthreads();
        // S = q_m · K^T (x3 split)
        f32x4 s_acc[4];
        #pragma unroll
        for (int jb = 0; jb < 4; ++jb) {
            f32x4 z = {};
            const int brow2 = (jb << 4) + (ln & 15);
            short8 bh0 = *(short8*)&kh_s[brow2][ak0];
            short8 bh1 = *(short8*)&kh_s[brow2][ak0 + 32];
            short8 bl0 = *(short8*)&kl_s[brow2][ak0];
            short8 bl1 = *(short8*)&kl_s[brow2][ak0 + 32];
            z = __builtin_amdgcn_mfma_f32_16x16x32_bf16(aqh0, bh0, z, 0, 0, 0);
            z = __builtin_amdgcn_mfma_f32_16x16x32_bf16(aqh0, bl0, z, 0, 0, 0);
            z = __builtin_amdgcn_mfma_f32_16x16x32_bf16(aql0, bh0, z, 0, 0, 0);
            z = __builtin_amdgcn_mfma_f32_16x16x32_bf16(aqh1, bh1, z, 0, 0, 0);
            z = __builtin_amdgcn_mfma_f32_16x16x32_bf16(aqh1, bl1, z, 0, 0, 0);
            z = __builtin_amdgcn_mfma_f32_16x16x32_bf16(aql1, bh1, z, 0, 0, 0);
            s_acc[jb] = z;
        }
        float mx[4];
        #pragma unroll
        for (int r = 0; r < 4; ++r)
            mx[r] = fmaxf(fmaxf(s_acc[0][r], s_acc[1][r]),
                          fmaxf(s_acc[2][r], s_acc[3][r]));
        #pragma unroll
        for (int off2 = 1; off2 < 16; off2 <<= 1)
            #pragma unroll
            for (int r = 0; r < 4; ++r)
                mx[r] = fmaxf(mx[r], __shfl_xor(mx[r], off2, 64));
        float fac[4];
        #pragma unroll
        for (int r = 0; r < 4; ++r) {
            float mn = fmaxf(mr[r], mx[r]);
            fac[r] = expf(mr[r] - mn);
            mr[r] = mn;
        }
        float rs[4] = {};
        #pragma unroll
        for (int jb = 0; jb < 4; ++jb)
            #pragma unroll
            for (int r = 0; r < 4; ++r) {
                float p = expf(s_acc[jb][r] - mr[r]);
                rs[r] += p;
                unsigned short hh, ll;
                bfsplit(p, hh, ll);
                ph[wv][rg + r][(jb << 4) + (ln & 15)] = hh;
                pl[wv][rg + r][(jb << 4) + (ln & 15)] = ll;
            }
        #pragma unroll
        for (int off2 = 1; off2 < 16; off2 <<= 1)
            #pragma unroll
            for (int r = 0; r < 4; ++r)
                rs[r] += __shfl_xor(rs[r], off2, 64);
        #pragma unroll
        for (int r = 0; r < 4; ++r) lr[r] = lr[r] * fac[r] + rs[r];
        #pragma unroll
        for (int jb = 0; jb < 4; ++jb)
            #pragma unroll
            for (int r = 0; r < 4; ++r)
                o_acc[jb][r] *= fac[r];
        // O += P · V  (P hi/lo, V bf16: 4 MFMAs per jb)
        short8 pah0 = *(short8*)&ph[wv][ln & 15][ak0];
        short8 pah1 = *(short8*)&ph[wv][ln & 15][ak0 + 32];
        short8 pal0 = *(short8*)&pl[wv][ln & 15][ak0];
        short8 pal1 = *(short8*)&pl[wv][ln & 15][ak0 + 32];
        #pragma unroll
        for (int jb = 0; jb < 4; ++jb) {
            const int brow2 = (jb << 4) + (ln & 15);
            short8 bv0 = *(short8*)&vth[brow2][ak0];
            short8 bv1 = *(short8*)&vth[brow2][ak0 + 32];
            f32x4 o = o_acc[jb];
            o = __builtin_amdgcn_mfma_f32_16x16x32_bf16(pah0, bv0, o, 0, 0, 0);
            o = __builtin_amdgcn_mfma_f32_16x16x32_bf16(pal0, bv0, o, 0, 0, 0);
            o = __builtin_amdgcn_mfma_f32_16x16x32_bf16(pah1, bv1, o, 0, 0, 0);
            o = __builtin_amdgcn_mfma_f32_16x16x32_bf16(pal1, bv1, o, 0, 0, 0);
            o_acc[jb] = o;
        }
    }
    int cidx = (bh << 3) + chunk;
    #pragma unroll
    for (int jb = 0; jb < 4; ++jb)
        #pragma unroll
        for (int r = 0; r < 4; ++r) {
            int row = (wv << 4) + rg + r, col = (jb << 4) + (ln & 15);
            wacc[((size_t)cidx << 12) + ((size_t)row << 6) + col] = o_acc[jb][r];
        }
    if ((ln & 15) == 0)
        #pragma unroll
        for (int r = 0; r < 4; ++r) {
            int row = (wv << 4) + rg + r;
            wl[cidx * 64 + row] = lr[r];
            wm[cidx * 64 + row] = mr[r];
        }
}

// K2b: merge chunk partials -> Wb (65 cols, col 64 = ones-column) + scm
__global__ __launch_bounds__(256) void wmerge(
    const float* __restrict__ wacc, const float* __restrict__ wl,
    const float* __restrict__ wm,
    float* __restrict__ Wb, float* __restrict__ scm)
{
    int bh = blockIdx.x;
    int tid = threadIdx.x;
    __shared__ float fcs[8][64];
    if (tid < 64) {
        float mx = -1e30f;
        #pragma unroll
        for (int c = 0; c < 8; ++c)
            mx = fmaxf(mx, wm[((bh << 3) + c) * 64 + tid]);
        scm[(bh << 6) + tid] = mx;
        #pragma unroll
        for (int c = 0; c < 8; ++c)
            fcs[c][tid] = expf(wm[((bh << 3) + c) * 64 + tid] - mx);
    }
    __syncthreads();
    for (int e = tid; e < 4096; e += 256) {
        int m = e >> 6, j = e & 63;
        float s = 0.f;
        #pragma unroll
        for (int c = 0; c < 8; ++c)
            s += fcs[c][m] * wacc[((size_t)((bh << 3) + c) << 12) + e];
        Wb[(size_t)bh * 4160 + m * 65 + j] = s;
    }
    if (tid < 64) {
        float s = 0.f;
        #pragma unroll
        for (int c = 0; c < 8; ++c)
            s += fcs[c][tid] * wl[((bh << 3) + c) * 64 + tid];
        Wb[(size_t)bh * 4160 + tid * 65 + 64] = s;
    }
}

// ---------------------------------------------------------------------------
// K3a: eB — fp32 reconstructed from (hi,lo) split arrays
// ---------------------------------------------------------------------------
__global__ __launch_bounds__(256) void eb_kernel(
    const unsigned short* __restrict__ qh, const unsigned short* __restrict__ ql,
    const unsigned short* __restrict__ kh, const unsigned short* __restrict__ kl,
    const float* __restrict__ scm, float* __restrict__ eB)
{
    int bh = blockIdx.x;
    int b = bh / 11, h = bh - b * 11;
    size_t base = ((size_t)(b * 12 + h)) << 12;
    __shared__ float qm[64][65], km[64][65];
    int tid = threadIdx.x;
    for (int e = tid; e < 4096; e += 256) {
        int mm = e >> 6, d = e & 63;
        size_t off = ((base + ((size_t)mm << 6)) << 6) + d;
        qm[mm][d] = b2f(qh[off]) + b2f(ql[off]);
        km[mm][d] = b2f(kh[off]) + b2f(kl[off]);
    }
    __syncthreads();
    int m = tid >> 2, l0 = tid & 3;
    float smax = scm[(bh << 6) + m];
    for (int l = l0; l < 64; l += 4) {
        float s = 0.f;
        #pragma unroll
        for (int d = 0; d < 64; ++d) s += qm[m][d] * km[l][d];
        eB[((size_t)bh << 12) + (m << 6) + l] = expf(fmaxf(s - smax, -88.f));
    }
}

// ---------------------------------------------------------------------------
// K3b: per-head norms
// ---------------------------------------------------------------------------
__global__ __launch_bounds__(256) void norms_kernel(
    const float* __restrict__ eB, float* __restrict__ denom)
{
    int h = blockIdx.x;
    int tid = threadIdx.x;
    int b = tid >> 6, idx = tid & 63;
    int bh = b * 11 + h;
    const float* E = eB + ((size_t)bh << 12);
    float rs = 0.f, cs = 0.f;
    #pragma unroll 4
    for (int l = 0; l < 64; ++l) rs += E[(idx << 6) + l];
    #pragma unroll 4
    for (int m = 0; m < 64; ++m) cs += E[(m << 6) + idx];
    __shared__ float r1[256], r2[256];
    r1[tid] = rs; r2[tid] = cs;
    __syncthreads();
    for (int s = 128; s > 0; s >>= 1) {
        if (tid < s) {
            r1[tid] = fmaxf(r1[tid], r1[tid + s]);
            r2[tid] = fmaxf(r2[tid], r2[tid + s]);
        }
        __syncthreads();
    }
    if (tid == 0) denom[h] = r1[0] * r2[0];
}

// ---------------------------------------------------------------------------
// K3c: pinv via 6 Newton iterations — bf16x3 MFMA matmuls, one block per bh.
// ---------------------------------------------------------------------------
__device__ __forceinline__ void mm64x3(
    const unsigned short (&Ahi)[64][72], const unsigned short (&Alo)[64][72],
    const unsigned short (&BThi)[64][72], const unsigned short (&BTlo)[64][72],
    int wr, int wc, int fr, int fk, f32x4 (&acc)[2][2])
{
    #pragma unroll
    for (int ks = 0; ks < 2; ++ks) {
        const int kb = (ks << 5) + fk;
        short8 ah[2], al[2], bh[2], bl[2];
        #pragma unroll
        for (int i = 0; i < 2; ++i) {
            ah[i] = *(const short8*)&Ahi[wr + (i << 4) + fr][kb];
            al[i] = *(const short8*)&Alo[wr + (i << 4) + fr][kb];
            bh[i] = *(const short8*)&BThi[wc + (i << 4) + fr][kb];
            bl[i] = *(const short8*)&BTlo[wc + (i << 4) + fr][kb];
        }
        #pragma unroll
        for (int i = 0; i < 2; ++i)
            #pragma unroll
            for (int j = 0; j < 2; ++j) {
                acc[i][j] = __builtin_amdgcn_mfma_f32_16x16x32_bf16(ah[i], bh[j], acc[i][j], 0, 0, 0);
                acc[i][j] = __builtin_amdgcn_mfma_f32_16x16x32_bf16(ah[i], bl[j], acc[i][j], 0, 0, 0);
                acc[i][j] = __builtin_amdgcn_mfma_f32_16x16x32_bf16(al[i], bh[j], acc[i][j], 0, 0, 0);
            }
    }
}

__global__ __launch_bounds__(256) void pinv_kernel(
    const float* __restrict__ eB, const float* __restrict__ denom,
    float* __restrict__ pi_)
{
    __shared__ unsigned short Xh[64][72],  Xl[64][72];
    __shared__ unsigned short Zh[64][72],  Zl[64][72];
    __shared__ unsigned short ZTh[64][72], ZTl[64][72];
    __shared__ unsigned short Mh[64][72],  Ml[64][72];
    __shared__ unsigned short MTh[64][72], MTl[64][72];
    __shared__ unsigned short Th[64][72],  Tbl[64][72];
    __shared__ float Zf[64][68];
    int bh = blockIdx.x;
    int h = bh % 11;
    int tid = threadIdx.x;
    float dn = denom[h];
    const int ln = tid & 63, wv = tid >> 6;
    const int wr = (wv >> 1) << 5, wc = (wv & 1) << 5;
    const int fr = ln & 15, fk = (ln >> 4) << 3;
    const int rg = (ln >> 4) << 2;

    for (int e = tid; e < 4096; e += 256) {
        int m = e >> 6, l = e & 63;
        float xv = eB[((size_t)bh << 12) + e];
        unsigned short hh, ll;
        bfsplit(xv, hh, ll);
        Xh[m][l] = hh; Xl[m][l] = ll;
        float zv = xv / dn;
        Zf[l][m] = zv;
        bfsplit(zv, hh, ll);
        Zh[l][m] = hh; Zl[l][m] = ll;
        ZTh[m][l] = hh; ZTl[m][l] = ll;
    }
    __syncthreads();

    for (int it = 0; it < 6; ++it) {
        f32x4 mm1[2][2] = {};
        mm64x3(Xh, Xl, ZTh, ZTl, wr, wc, fr, fk, mm1);
        #pragma unroll
        for (int i = 0; i < 2; ++i)
            #pragma unroll
            for (int j = 0; j < 2; ++j)
                #pragma unroll
                for (int r = 0; r < 4; ++r) {
                    int row = wr + (i << 4) + rg + r, col = wc + (j << 4) + fr;
                    unsigned short hh, ll;
                    bfsplit(mm1[i][j][r], hh, ll);
                    Mh[row][col] = hh;  Ml[row][col] = ll;
                    MTh[col][row] = hh; MTl[col][row] = ll;
                }
        __syncthreads();
        f32x4 a2[2][2] = {};
        mm64x3(Mh, Ml, MTh, MTl, wr, wc, fr, fk, a2);
        #pragma unroll
        for (int i = 0; i < 2; ++i)
            #pragma unroll
            for (int j = 0; j < 2; ++j)
                #pragma unroll
                for (int r = 0; r < 4; ++r) {
                    int row = wr + (i << 4) + rg + r, col = wc + (j << 4) + fr;
                    float val = 7.f * mm1[i][j][r] - a2[i][j][r];
                    unsigned short hh, ll;
                    bfsplit(val, hh, ll);
                    Th[col][row] = hh; Tbl[col][row] = ll;
                }
        __syncthreads();
        f32x4 a3[2][2] = {};
        mm64x3(Mh, Ml, Th, Tbl, wr, wc, fr, fk, a3);
        __syncthreads();
        #pragma unroll
        for (int i = 0; i < 2; ++i)
            #pragma unroll
            for (int j = 0; j < 2; ++j)
                #pragma unroll
                for (int r = 0; r < 4; ++r) {
                    int row = wr + (i << 4) + rg + r, col = wc + (j << 4) + fr;
                    float val = 15.f * mm1[i][j][r] - a3[i][j][r];
                    unsigned short hh, ll;
                    bfsplit(val, hh, ll);
                    Th[col][row] = hh; Tbl[col][row] = ll;
                }
        __syncthreads();
        f32x4 a4[2][2] = {};
        mm64x3(Zh, Zl, Th, Tbl, wr, wc, fr, fk, a4);
        float zn[2][2][4];
        #pragma unroll
        for (int i = 0; i < 2; ++i)
            #pragma unroll
            for (int j = 0; j < 2; ++j)
                #pragma unroll
                for (int r = 0; r < 4; ++r) {
                    int row = wr + (i << 4) + rg + r, col = wc + (j << 4) + fr;
                    zn[i][j][r] = 0.25f * (13.f * Zf[row][col] - a4[i][j][r]);
                }
        __syncthreads();
        #pragma unroll
        for (int i = 0; i < 2; ++i)
            #pragma unroll
            for (int j = 0; j < 2; ++j)
                #pragma unroll
                for (int r = 0; r < 4; ++r) {
                    int row = wr + (i << 4) + rg + r, col = wc + (j << 4) + fr;
                    float val = zn[i][j][r];
                    Zf[row][col] = val;
                    unsigned short hh, ll;
                    bfsplit(val, hh, ll);
                    Zh[row][col] = hh;  Zl[row][col] = ll;
                    ZTh[col][row] = hh; ZTl[col][row] = ll;
                }
        __syncthreads();
    }
    for (int e = tid; e < 4096; e += 256)
        pi_[((size_t)bh << 12) + e] = Zf[e >> 6][e & 63];
}

// ---------------------------------------------------------------------------
// K5: T = pi @ W  (64x64 @ 64x65)
// ---------------------------------------------------------------------------
__global__ __launch_bounds__(256) void pw_kernel(
    const float* __restrict__ pi_, const float* __restrict__ Wb,
    float* __restrict__ Tb)
{
    int bh = blockIdx.x;
    __shared__ float P[64][65];
    __shared__ float Wl[64][66];
    int tid = threadIdx.x;
    for (int e = tid; e < 4096; e += 256)
        P[e >> 6][e & 63] = pi_[((size_t)bh << 12) + e];
    for (int e = tid; e < 64 * 65; e += 256) {
        int l = e / 65, j = e - l * 65;
        Wl[l][j] = Wb[(size_t)bh * 4160 + e];
    }
    __syncthreads();
    int m = tid & 63, g = tid >> 6;
    #pragma unroll
    for (int t = 0; t < 17; ++t) {
        int j = g + (t << 2);
        if (j > 64) break;
        float s = 0.f;
        #pragma unroll
        for (int l = 0; l < 64; ++l) s += P[m][l] * Wl[l][j];
        Tb[(size_t)((bh << 6) + m) * 65 + j] = s;
    }
}

// ---------------------------------------------------------------------------
// K6: out_p — MFMA: S x3 from split q,k; eA hi/lo × T hi/lo; ctx bf16
// ---------------------------------------------------------------------------
__global__ __launch_bounds__(256) void outp_kernel(
    const unsigned short* __restrict__ qh, const unsigned short* __restrict__ ql,
    const unsigned short* __restrict__ khg, const unsigned short* __restrict__ klg,
    const float* __restrict__ Tb, unsigned short* __restrict__ ctxh)
{
    int bh = blockIdx.y;
    int b = bh / 11, h = bh - b * 11;
    int n0 = blockIdx.x << 6;
    size_t base = ((size_t)(b * 12 + h)) << 12;
    __shared__ unsigned short kmh[64][72], kml[64][72];
    __shared__ unsigned short tth[64][72], ttl[64][72];
    __shared__ unsigned short ph[4][16][72], pl[4][16][72];
    __shared__ float t64[64];
    int tid = threadIdx.x;
    int wv = tid >> 6, ln = tid & 63;
    int rr = tid >> 2, dg = (tid & 3) << 4;
    const int arow = (wv << 4) + (ln & 15);
    const int ak0 = (ln >> 4) << 3;
    const int rg = (ln >> 4) << 2;
    {   // stage k_m (landmark rows) hi/lo — pure copies
        size_t off = ((base + ((size_t)rr << 6)) << 6) + dg;
        *(short8*)&kmh[rr][dg]     = *(const short8*)(khg + off);
        *(short8*)&kmh[rr][dg + 8] = *(const short8*)(khg + off + 8);
        *(short8*)&kml[rr][dg]     = *(const short8*)(klg + off);
        *(short8*)&kml[rr][dg + 8] = *(const short8*)(klg + off + 8);
    }
    for (int e = tid; e < 4096; e += 256) {
        int m = e >> 6, j = e & 63;
        float tv = Tb[(size_t)((bh << 6) + m) * 65 + j];
        unsigned short hh, ll;
        bfsplit(tv, hh, ll);
        tth[j][m] = hh; ttl[j][m] = ll;
    }
    if (tid < 64) t64[tid] = Tb[(size_t)((bh << 6) + tid) * 65 + 64];
    short8 aqh0, aql0, aqh1, aql1;
    {
        size_t off = ((base + n0 + arow) << 6) + ak0;
        aqh0 = *(const short8*)(qh + off);
        aqh1 = *(const short8*)(qh + off + 32);
        aql0 = *(const short8*)(ql + off);
        aql1 = *(const short8*)(ql + off + 32);
    }
    __syncthreads();
    f32x4 s_acc[4];
    #pragma unroll
    for (int jb = 0; jb < 4; ++jb) {
        f32x4 z = {};
        const int brow2 = (jb << 4) + (ln & 15);
        short8 bh0 = *(short8*)&kmh[brow2][ak0];
        short8 bh1 = *(short8*)&kmh[brow2][ak0 + 32];
        short8 bl0 = *(short8*)&kml[brow2][ak0];
        short8 bl1 = *(short8*)&kml[brow2][ak0 + 32];
        z = __builtin_amdgcn_mfma_f32_16x16x32_bf16(aqh0, bh0, z, 0, 0, 0);
        z = __builtin_amdgcn_mfma_f32_16x16x32_bf16(aqh0, bl0, z, 0, 0, 0);
        z = __builtin_amdgcn_mfma_f32_16x16x32_bf16(aql0, bh0, z, 0, 0, 0);
        z = __builtin_amdgcn_mfma_f32_16x16x32_bf16(aqh1, bh1, z, 0, 0, 0);
        z = __builtin_amdgcn_mfma_f32_16x16x32_bf16(aqh1, bl1, z, 0, 0, 0);
        z = __builtin_amdgcn_mfma_f32_16x16x32_bf16(aql1, bh1, z, 0, 0, 0);
        s_acc[jb] = z;
    }
    float mx[4];
    #pragma unroll
    for (int r = 0; r < 4; ++r)
        mx[r] = fmaxf(fmaxf(s_acc[0][r], s_acc[1][r]),
                      fmaxf(s_acc[2][r], s_acc[3][r]));
    #pragma unroll
    for (int off2 = 1; off2 < 16; off2 <<= 1)
        #pragma unroll
        for (int r = 0; r < 4; ++r)
            mx[r] = fmaxf(mx[r], __shfl_xor(mx[r], off2, 64));
    float den[4] = {};
    #pragma unroll
    for (int jb = 0; jb < 4; ++jb) {
        float tj = t64[(jb << 4) + (ln & 15)];
        #pragma unroll
        for (int r = 0; r < 4; ++r) {
            float p = expf(s_acc[jb][r] - mx[r]);
            den[r] += p * tj;
            unsigned short hh, ll;
            bfsplit(p, hh, ll);
            ph[wv][rg + r][(jb << 4) + (ln & 15)] = hh;
            pl[wv][rg + r][(jb << 4) + (ln & 15)] = ll;
        }
    }
    #pragma unroll
    for (int off2 = 1; off2 < 16; off2 <<= 1)
        #pragma unroll
        for (int r = 0; r < 4; ++r)
            den[r] += __shfl_xor(den[r], off2, 64);
    short8 pah0 = *(short8*)&ph[wv][ln & 15][ak0];
    short8 pah1 = *(short8*)&ph[wv][ln & 15][ak0 + 32];
    short8 pal0 = *(short8*)&pl[wv][ln & 15][ak0];
    short8 pal1 = *(short8*)&pl[wv][ln & 15][ak0 + 32];
    f32x4 o_acc[4] = {};
    #pragma unroll
    for (int jb = 0; jb < 4; ++jb) {
        const int brow2 = (jb << 4) + (ln & 15);
        short8 bth0 = *(short8*)&tth[brow2][ak0];
        short8 bth1 = *(short8*)&tth[brow2][ak0 + 32];
        short8 btl0 = *(short8*)&ttl[brow2][ak0];
        short8 btl1 = *(short8*)&ttl[brow2][ak0 + 32];
        f32x4 o = o_acc[jb];
        o = __builtin_amdgcn_mfma_f32_16x16x32_bf16(pah0, bth0, o, 0, 0, 0);
        o = __builtin_amdgcn_mfma_f32_16x16x32_bf16(pah0, btl0, o, 0, 0, 0);
        o = __builtin_amdgcn_mfma_f32_16x16x32_bf16(pal0, bth0, o, 0, 0, 0);
        o = __builtin_amdgcn_mfma_f32_16x16x32_bf16(pah1, bth1, o, 0, 0, 0);
        o = __builtin_amdgcn_mfma_f32_16x16x32_bf16(pah1, btl1, o, 0, 0, 0);
        o = __builtin_amdgcn_mfma_f32_16x16x32_bf16(pal1, bth1, o, 0, 0, 0);
        o_acc[jb] = o;
    }
    float inv[4];
    #pragma unroll
    for (int r = 0; r < 4; ++r) inv[r] = 1.0f / fmaxf(den[r], 1e-8f);
    #pragma unroll
    for (int jb = 0; jb < 4; ++jb)
        #pragma unroll
        for (int r = 0; r < 4; ++r) {
            int row = n0 + (wv << 4) + rg + r;
            int col = (jb << 4) + (ln & 15);
            ctxh[((size_t)b * 4096 + row) * 768 + h * 64 + col] =
                f2bf(o_acc[jb][r] * inv[r]);
        }
}

// ---------------------------------------------------------------------------
// K7a: softmax head (h=11) flash partial over a 1024-KV chunk. grid (64,4,4).
// Reads bf16 q,k,v directly (hi parts).
// ---------------------------------------------------------------------------
__global__ __launch_bounds__(256) void flash_part(
    const unsigned short* __restrict__ qhg, const unsigned short* __restrict__ khg,
    const unsigned short* __restrict__ vhg,
    float* __restrict__ pacc, float* __restrict__ pm, float* __restrict__ pl)
{
    int bx = blockIdx.x, cy = blockIdx.y, b = blockIdx.z;
    int n0 = bx << 6;
    size_t base = ((size_t)(b * 12 + 11)) << 12;
    __shared__ unsigned short qs[64][72];
    __shared__ unsigned short ks[64][72];
    __shared__ unsigned short vts[64][72];
    __shared__ unsigned short ps[4][16][72];
    int tid = threadIdx.x;
    int wv = tid >> 6, ln = tid & 63;
    int rr = tid >> 2, dg = (tid & 3) << 4;
    {
        size_t off = ((base + n0 + rr) << 6) + dg;
        *(short8*)&qs[rr][dg]     = *(const short8*)(qhg + off);
        *(short8*)&qs[rr][dg + 8] = *(const short8*)(qhg + off + 8);
    }
    __syncthreads();
    const int arow = (wv << 4) + (ln & 15);
    const int ak0 = (ln >> 4) << 3;
    const int rg = (ln >> 4) << 2;
    short8 aq0 = *(short8*)&qs[arow][ak0];
    short8 aq1 = *(short8*)&qs[arow][ak0 + 32];
    f32x4 o_acc[4] = {};
    float mr[4] = {-1e30f, -1e30f, -1e30f, -1e30f};
    float lr[4] = {};
    for (int t = 0; t < 16; ++t) {
        int m0 = (cy << 10) + (t << 6);
        __syncthreads();
        {
            size_t off = ((base + m0 + rr) << 6) + dg;
            *(short8*)&ks[rr][dg]     = *(const short8*)(khg + off);
            *(short8*)&ks[rr][dg + 8] = *(const short8*)(khg + off + 8);
            short8 v0 = *(const short8*)(vhg + off);
            short8 v1 = *(const short8*)(vhg + off + 8);
            #pragma unroll
            for (int i = 0; i < 8; ++i) {
                vts[dg + i][rr]     = (unsigned short)v0[i];
                vts[dg + 8 + i][rr] = (unsigned short)v1[i];
            }
        }
        __syncthreads();
        f32x4 s_acc[4];
        #pragma unroll
        for (int jb = 0; jb < 4; ++jb) {
            f32x4 z = {};
            short8 bk0 = *(short8*)&ks[(jb << 4) + (ln & 15)][ak0];
            short8 bk1 = *(short8*)&ks[(jb << 4) + (ln & 15)][ak0 + 32];
            z = __builtin_amdgcn_mfma_f32_16x16x32_bf16(aq0, bk0, z, 0, 0, 0);
            z = __builtin_amdgcn_mfma_f32_16x16x32_bf16(aq1, bk1, z, 0, 0, 0);
            s_acc[jb] = z;
        }
        float mx[4];
        #pragma unroll
        for (int r = 0; r < 4; ++r)
            mx[r] = fmaxf(fmaxf(s_acc[0][r], s_acc[1][r]),
                          fmaxf(s_acc[2][r], s_acc[3][r]));
        #pragma unroll
        for (int off2 = 1; off2 < 16; off2 <<= 1)
            #pragma unroll
            for (int r = 0; r < 4; ++r)
                mx[r] = fmaxf(mx[r], __shfl_xor(mx[r], off2, 64));
        float fac[4];
        #pragma unroll
        for (int r = 0; r < 4; ++r) {
            float mn = fmaxf(mr[r], mx[r]);
            fac[r] = expf(mr[r] - mn);
            mr[r] = mn;
        }
        float rs[4] = {};
        #pragma unroll
        for (int jb = 0; jb < 4; ++jb)
            #pragma unroll
            for (int r = 0; r < 4; ++r) {
                float p = expf(s_acc[jb][r] - mr[r]);
                rs[r] += p;
                ps[wv][rg + r][(jb << 4) + (ln & 15)] = f2bf(p);
            }
        #pragma unroll
        for (int off2 = 1; off2 < 16; off2 <<= 1)
            #pragma unroll
            for (int r = 0; r < 4; ++r)
                rs[r] += __shfl_xor(rs[r], off2, 64);
        #pragma unroll
        for (int r = 0; r < 4; ++r) lr[r] = lr[r] * fac[r] + rs[r];
        #pragma unroll
        for (int jb = 0; jb < 4; ++jb)
            #pragma unroll
            for (int r = 0; r < 4; ++r)
                o_acc[jb][r] *= fac[r];
        short8 pa0 = *(short8*)&ps[wv][ln & 15][ak0];
        short8 pa1 = *(short8*)&ps[wv][ln & 15][ak0 + 32];
        #pragma unroll
        for (int jb = 0; jb < 4; ++jb) {
            short8 bv0 = *(short8*)&vts[(jb << 4) + (ln & 15)][ak0];
            short8 bv1 = *(short8*)&vts[(jb << 4) + (ln & 15)][ak0 + 32];
            f32x4 z = o_acc[jb];
            z = __builtin_amdgcn_mfma_f32_16x16x32_bf16(pa0, bv0, z, 0, 0, 0);
            z = __builtin_amdgcn_mfma_f32_16x16x32_bf16(pa1, bv1, z, 0, 0, 0);
            o_acc[jb] = z;
        }
    }
    int slot = (b * 4 + cy) * 64 + bx;
    #pragma unroll
    for (int jb = 0; jb < 4; ++jb)
        #pragma unroll
        for (int r = 0; r < 4; ++r) {
            int row = (wv << 4) + rg + r, col = (jb << 4) + (ln & 15);
            pacc[(size_t)slot * 4096 + (size_t)row * 64 + col] = o_acc[jb][r];
        }
    if ((ln & 15) == 0)
        #pragma unroll
        for (int r = 0; r < 4; ++r) {
            int row = (wv << 4) + rg + r;
            pm[(size_t)slot * 64 + row] = mr[r];
            pl[(size_t)slot * 64 + row] = lr[r];
        }
}

// K7b: merge 4 chunk partials -> ctx head 11 (bf16)
__global__ __launch_bounds__(256) void flash_merge(
    const float* __restrict__ pacc, const float* __restrict__ pm,
    const float* __restrict__ pl, unsigned short* __restrict__ ctxh)
{
    int bx = blockIdx.x, b = blockIdx.y;
    int tid = threadIdx.x, r = tid & 63, g = tid >> 6;
    float mc[4], mt = -1e30f;
    #pragma unroll
    for (int c = 0; c < 4; ++c) {
        mc[c] = pm[(size_t)((b * 4 + c) * 64 + bx) * 64 + r];
        mt = fmaxf(mt, mc[c]);
    }
    float fac[4], lt = 0.f;
    #pragma unroll
    for (int c = 0; c < 4; ++c) {
        fac[c] = expf(mc[c] - mt);
        lt += fac[c] * pl[(size_t)((b * 4 + c) * 64 + bx) * 64 + r];
    }
    float inv = 1.0f / lt;
    size_t obase = ((size_t)b * 4096 + (size_t)((bx << 6) + r)) * 768 + 11 * 64 + (g << 4);
    #pragma unroll
    for (int i = 0; i < 16; ++i) {
        float s = 0.f;
        #pragma unroll
        for (int c = 0; c < 4; ++c)
            s += fac[c] * pacc[(size_t)((b * 4 + c) * 64 + bx) * 4096 + (size_t)r * 64 + (g << 4) + i];
        ctxh[obase + i] = f2bf(s * inv);
    }
}

// ---------------------------------------------------------------------------
// K8: proj GEMM — plain bf16 MFMA. 128x128, BK=32, swizzled LDS, XCD swizzle.
// ---------------------------------------------------------------------------
__global__ __launch_bounds__(256, 2) void gemm_proj_mfma(
    const unsigned short* __restrict__ Xh, const unsigned short* __restrict__ Wh,
    const float* __restrict__ bias, float* __restrict__ out)
{
    __shared__ unsigned short Ah[4096], Bh[4096];
    const int tid = threadIdx.x;
    const int bid = blockIdx.x;                  // nwg=768 (%8==0)
    const int swz = (bid & 7) * 96 + (bid >> 3);
    const int brow = (swz / 6) << 7, bcol = (swz % 6) << 7;
    const int ln = tid & 63, wv = tid >> 6;
    const int wr = (wv >> 1) << 6, wc = (wv & 1) << 6;
    const int srow = tid >> 1, sc = (tid & 1) << 1;
    const size_t ag = (size_t)(brow + srow) * 768 + (sc << 3);
    const size_t bg = (size_t)(bcol + srow) * 768 + (sc << 3);
    const int fr = ln & 15, fc = ln >> 4;
    const int i0 = srow * 32 + (((sc + 0) ^ (srow & 3)) << 3);
    const int i1 = srow * 32 + (((sc + 1) ^ (srow & 3)) << 3);

    f32x4 acc[4][4] = {};
    for (int k0 = 0; k0 < 768; k0 += 32) {
        short8 xh0 = *(const short8*)(Xh + ag + k0);
        short8 xh1 = *(const short8*)(Xh + ag + k0 + 8);
        short8 wh0 = *(const short8*)(Wh + bg + k0);
        short8 wh1 = *(const short8*)(Wh + bg + k0 + 8);
        __syncthreads();
        *(short8*)&Ah[i0] = xh0; *(short8*)&Ah[i1] = xh1;
        *(short8*)&Bh[i0] = wh0; *(short8*)&Bh[i1] = wh1;
        __syncthreads();
        short8 ah[4], bh[4];
        #pragma unroll
        for (int i = 0; i < 4; ++i) {
            int ar = wr + (i << 4) + fr;
            ah[i] = *(short8*)&Ah[ar * 32 + ((fc ^ (ar & 3)) << 3)];
            int br2 = wc + (i << 4) + fr;
            bh[i] = *(short8*)&Bh[br2 * 32 + ((fc ^ (br2 & 3)) << 3)];
        }
        #pragma unroll
        for (int i = 0; i < 4; ++i)
            #pragma unroll
            for (int j = 0; j < 4; ++j)
                acc[i][j] = __builtin_amdgcn_mfma_f32_16x16x32_bf16(ah[i], bh[j], acc[i][j], 0, 0, 0);
    }
    const int fg = ln >> 4;
    #pragma unroll
    for (int j = 0; j < 4; ++j) {
        int c = bcol + wc + (j << 4) + fr;
        float bb = bias[c];
        #pragma unroll
        for (int i = 0; i < 4; ++i)
            #pragma unroll
            for (int r = 0; r < 4; ++r) {
                int row = brow + wr + (i << 4) + (fg << 2) + r;
                out[(size_t)row * 768 + c] = acc[i][j][r] + bb;
            }
    }
}

// ---------------------------------------------------------------------------
extern "C" void kernel_launch(void* const* d_in, const int* in_sizes, int n_in,
                              void* d_out, int out_size, void* d_ws, size_t ws_size,
                              hipStream_t stream)
{
    const float* x      = (const float*)d_in[0];
    const float* qkv_w  = (const float*)d_in[1];
    const float* qkv_b  = (const float*)d_in[2];
    const float* proj_w = (const float*)d_in[3];
    const float* proj_b = (const float*)d_in[4];
    float* out = (float*)d_out;

    const size_t QKV = (size_t)4 * 12 * 4096 * 64;   // 12,582,912
    unsigned short* qh = (unsigned short*)d_ws;       // 5 split arrays + ctx
    unsigned short* ql = qh + QKV;
    unsigned short* kh = ql + QKV;
    unsigned short* kl = kh + QKV;
    unsigned short* vh = kl + QKV;
    unsigned short* ctxh = vh + QKV;
    float* scm  = (float*)(ctxh + QKV);               // 6*QKV ushorts, 16B-aligned
    float* eB   = scm + 4096;
    float* den  = eB + 44 * 4096;
    float* pi_  = den + 64;
    float* Wb   = pi_ + 44 * 4096;
    float* Tb   = Wb + 44 * 4160;
    unsigned short* Whi  = (unsigned short*)(Tb + 44 * 4160);
    unsigned short* Wlo  = Whi + (size_t)2304 * 768;
    unsigned short* Pwhi = Wlo + (size_t)2304 * 768;
    unsigned short* Pwlo = Pwhi + (size_t)768 * 768;   // written, unused

    // d_out scratch: phase 1 X hi/lo (dead after gemm_qkv); phase 2 wflash
    // partials (dead after wmerge); phase 3 flash partials (dead after merge).
    unsigned short* Xhi = (unsigned short*)out;
    unsigned short* Xlo = Xhi + QKV;
    float* wacc = out;                    // 1,441,792
    float* wl   = wacc + 1441792;         // 22,528
    float* wm   = wl + 22528;             // 22,528
    float* fpacc = out;                   // 4,194,304 (after wmerge)
    float* fpm   = fpacc + 4194304;       // 65,536
    float* fpl   = fpm + 65536;           // 65,536

    preconv<<<2048, 256, 0, stream>>>(x, Xhi, Xlo, 3145728);
    preconv<<<1024, 256, 0, stream>>>(qkv_w, Whi, Wlo, 442368);
    preconv<<<512, 256, 0, stream>>>(proj_w, Pwhi, Pwlo, 147456);
    gemm_qkv_mfma<<<2304, 256, 0, stream>>>(Xhi, Xlo, Whi, Wlo, qkv_b,
                                            qh, ql, kh, kl, vh);
    wflash<<<dim3(8, 44), 256, 0, stream>>>(qh, ql, kh, kl, vh, wacc, wl, wm);
    wmerge<<<44, 256, 0, stream>>>(wacc, wl, wm, Wb, scm);
    eb_kernel<<<44, 256, 0, stream>>>(qh, ql, kh, kl, scm, eB);
    norms_kernel<<<11, 256, 0, stream>>>(eB, den);
    pinv_kernel<<<44, 256, 0, stream>>>(eB, den, pi_);
    pw_kernel<<<44, 256, 0, stream>>>(pi_, Wb, Tb);
    outp_kernel<<<dim3(64, 44), 256, 0, stream>>>(qh, ql, kh, kl, Tb, ctxh);
    flash_part<<<dim3(64, 4, 4), 256, 0, stream>>>(qh, kh, vh, fpacc, fpm, fpl);
    flash_merge<<<dim3(64, 4), 256, 0, stream>>>(fpacc, fpm, fpl, ctxh);
    gemm_proj_mfma<<<768, 256, 0, stream>>>(ctxh, Pwhi, proj_b, out);
}

// Round 9
// 456.291 us; speedup vs baseline: 13.4392x; 1.0529x over previous
//
#include <hip/hip_runtime.h>

// B=4, N=4096, C=768, H=12, D=64, M=64, PNP=11, SCALE=1/8

typedef __attribute__((ext_vector_type(8))) short short8;
typedef __attribute__((ext_vector_type(4))) float f32x4;
typedef __attribute__((ext_vector_type(4))) unsigned short ushort4v;

static __device__ __forceinline__ unsigned short f2bf(float f) {
    union { float f; unsigned u; } x; x.f = f;
    unsigned r = x.u + 0x7fffu + ((x.u >> 16) & 1u);   // RNE
    return (unsigned short)(r >> 16);
}

static __device__ __forceinline__ float b2f(unsigned short u) {
    union { unsigned u; float f; } t; t.u = (unsigned)u << 16; return t.f;
}

static __device__ __forceinline__ void bfsplit(float x, unsigned short& h, unsigned short& l) {
    unsigned short hh = f2bf(x);
    union { unsigned u; float f; } t; t.u = (unsigned)hh << 16;
    h = hh;
    l = f2bf(x - t.f);    // exact residual, RNE to bf16
}

// ---------------------------------------------------------------------------
// K0: split fp32 array into bf16 (hi, lo) pair arrays. memory-bound.
// ---------------------------------------------------------------------------
__global__ __launch_bounds__(256) void preconv(
    const float* __restrict__ in, unsigned short* __restrict__ hi,
    unsigned short* __restrict__ lo, int n4)
{
    for (int i = blockIdx.x * 256 + threadIdx.x; i < n4; i += gridDim.x * 256) {
        float4 f = *(const float4*)(in + (size_t)i * 4);
        float vs[4] = {f.x, f.y, f.z, f.w};
        ushort4v h, l;
        #pragma unroll
        for (int j = 0; j < 4; ++j) {
            unsigned short hh, ll;
            bfsplit(vs[j], hh, ll);
            h[j] = hh; l[j] = ll;
        }
        *(ushort4v*)(hi + (size_t)i * 4) = h;
        *(ushort4v*)(lo + (size_t)i * 4) = l;
    }
}

// ---------------------------------------------------------------------------
// K1a: Q,K GEMM via bf16x3-split MFMA. cols 0..1535 of qkv_w. grid 1536.
// Epilogue: q->(qh,ql)*0.125, k->(kh,kl).
// ---------------------------------------------------------------------------
__global__ __launch_bounds__(256, 2) void gemm_qk_mfma(
    const unsigned short* __restrict__ Xh, const unsigned short* __restrict__ Xl,
    const unsigned short* __restrict__ Wh, const unsigned short* __restrict__ Wl,
    const float* __restrict__ bias,
    unsigned short* __restrict__ qh, unsigned short* __restrict__ ql,
    unsigned short* __restrict__ kh, unsigned short* __restrict__ kl)
{
    __shared__ unsigned short Ah[4096], Al[4096], Bh[4096], Bl[4096]; // [128][32] swizzled
    const int tid = threadIdx.x;
    const int bid = blockIdx.x;                 // nwg=1536 (%8==0)
    const int swz = (bid & 7) * 192 + (bid >> 3);
    const int brow = (swz / 12) << 7, bcol = (swz % 12) << 7;
    const int ln = tid & 63, wv = tid >> 6;
    const int wr = (wv >> 1) << 6, wc = (wv & 1) << 6;
    const int srow = tid >> 1, sc = (tid & 1) << 1;
    const size_t ag = (size_t)(brow + srow) * 768 + (sc << 3);
    const size_t bg = (size_t)(bcol + srow) * 768 + (sc << 3);
    const int fr = ln & 15, fc = ln >> 4;
    const int i0 = srow * 32 + (((sc + 0) ^ (srow & 3)) << 3);
    const int i1 = srow * 32 + (((sc + 1) ^ (srow & 3)) << 3);

    f32x4 acc[4][4] = {};
    for (int k0 = 0; k0 < 768; k0 += 32) {
        short8 xh0 = *(const short8*)(Xh + ag + k0);
        short8 xh1 = *(const short8*)(Xh + ag + k0 + 8);
        short8 xl0 = *(const short8*)(Xl + ag + k0);
        short8 xl1 = *(const short8*)(Xl + ag + k0 + 8);
        short8 wh0 = *(const short8*)(Wh + bg + k0);
        short8 wh1 = *(const short8*)(Wh + bg + k0 + 8);
        short8 wl0 = *(const short8*)(Wl + bg + k0);
        short8 wl1 = *(const short8*)(Wl + bg + k0 + 8);
        __syncthreads();
        *(short8*)&Ah[i0] = xh0; *(short8*)&Ah[i1] = xh1;
        *(short8*)&Al[i0] = xl0; *(short8*)&Al[i1] = xl1;
        *(short8*)&Bh[i0] = wh0; *(short8*)&Bh[i1] = wh1;
        *(short8*)&Bl[i0] = wl0; *(short8*)&Bl[i1] = wl1;
        __syncthreads();
        short8 ah[4], al[4], bh[4], bl[4];
        #pragma unroll
        for (int i = 0; i < 4; ++i) {
            int ar = wr + (i << 4) + fr;
            int aidx = ar * 32 + ((fc ^ (ar & 3)) << 3);
            ah[i] = *(short8*)&Ah[aidx];
            al[i] = *(short8*)&Al[aidx];
            int br2 = wc + (i << 4) + fr;
            int bidx = br2 * 32 + ((fc ^ (br2 & 3)) << 3);
            bh[i] = *(short8*)&Bh[bidx];
            bl[i] = *(short8*)&Bl[bidx];
        }
        #pragma unroll
        for (int i = 0; i < 4; ++i)
            #pragma unroll
            for (int j = 0; j < 4; ++j) {
                acc[i][j] = __builtin_amdgcn_mfma_f32_16x16x32_bf16(ah[i], bh[j], acc[i][j], 0, 0, 0);
                acc[i][j] = __builtin_amdgcn_mfma_f32_16x16x32_bf16(ah[i], bl[j], acc[i][j], 0, 0, 0);
                acc[i][j] = __builtin_amdgcn_mfma_f32_16x16x32_bf16(al[i], bh[j], acc[i][j], 0, 0, 0);
            }
    }
    const int fg = ln >> 4;
    #pragma unroll
    for (int j = 0; j < 4; ++j) {
        int c = bcol + wc + (j << 4) + fr;
        float bb = bias[c];
        int isk = c >> 9 >= 1 ? (c >= 768) : 0;   // c in [0,1536): k iff c>=768
        int rem = c - (c >= 768 ? 768 : 0);
        int h = rem >> 6, d = rem & 63;
        #pragma unroll
        for (int i = 0; i < 4; ++i)
            #pragma unroll
            for (int r = 0; r < 4; ++r) {
                int row = brow + wr + (i << 4) + (fg << 2) + r;
                int b = row >> 12, n = row & 4095;
                float val = acc[i][j][r] + bb;
                size_t idx = (((size_t)(b * 12 + h) << 12) + n) * 64 + d;
                unsigned short hh, ll;
                if (c < 768) {
                    bfsplit(val * 0.125f, hh, ll);
                    qh[idx] = hh; ql[idx] = ll;
                } else {
                    bfsplit(val, hh, ll);
                    kh[idx] = hh; kl[idx] = ll;
                }
            }
        (void)isk;
    }
}

// ---------------------------------------------------------------------------
// K1b: V GEMM via plain bf16 MFMA. cols 1536..2303. grid 768. 16 KB LDS.
// ---------------------------------------------------------------------------
__global__ __launch_bounds__(256, 2) void gemm_v_mfma(
    const unsigned short* __restrict__ Xh, const unsigned short* __restrict__ Wh,
    const float* __restrict__ bias, unsigned short* __restrict__ vh)
{
    __shared__ unsigned short Ah[4096], Bh[4096];
    const int tid = threadIdx.x;
    const int bid = blockIdx.x;                  // nwg=768 (%8==0)
    const int swz = (bid & 7) * 96 + (bid >> 3);
    const int brow = (swz / 6) << 7, bcol = 1536 + ((swz % 6) << 7);
    const int ln = tid & 63, wv = tid >> 6;
    const int wr = (wv >> 1) << 6, wc = (wv & 1) << 6;
    const int srow = tid >> 1, sc = (tid & 1) << 1;
    const size_t ag = (size_t)(brow + srow) * 768 + (sc << 3);
    const size_t bg = (size_t)(bcol + srow) * 768 + (sc << 3);
    const int fr = ln & 15, fc = ln >> 4;
    const int i0 = srow * 32 + (((sc + 0) ^ (srow & 3)) << 3);
    const int i1 = srow * 32 + (((sc + 1) ^ (srow & 3)) << 3);

    f32x4 acc[4][4] = {};
    for (int k0 = 0; k0 < 768; k0 += 32) {
        short8 xh0 = *(const short8*)(Xh + ag + k0);
        short8 xh1 = *(const short8*)(Xh + ag + k0 + 8);
        short8 wh0 = *(const short8*)(Wh + bg + k0);
        short8 wh1 = *(const short8*)(Wh + bg + k0 + 8);
        __syncthreads();
        *(short8*)&Ah[i0] = xh0; *(short8*)&Ah[i1] = xh1;
        *(short8*)&Bh[i0] = wh0; *(short8*)&Bh[i1] = wh1;
        __syncthreads();
        short8 ah[4], bh[4];
        #pragma unroll
        for (int i = 0; i < 4; ++i) {
            int ar = wr + (i << 4) + fr;
            ah[i] = *(short8*)&Ah[ar * 32 + ((fc ^ (ar & 3)) << 3)];
            int br2 = wc + (i << 4) + fr;
            bh[i] = *(short8*)&Bh[br2 * 32 + ((fc ^ (br2 & 3)) << 3)];
        }
        #pragma unroll
        for (int i = 0; i < 4; ++i)
            #pragma unroll
            for (int j = 0; j < 4; ++j)
                acc[i][j] = __builtin_amdgcn_mfma_f32_16x16x32_bf16(ah[i], bh[j], acc[i][j], 0, 0, 0);
    }
    const int fg = ln >> 4;
    #pragma unroll
    for (int j = 0; j < 4; ++j) {
        int c = bcol + wc + (j << 4) + fr;
        float bb = bias[c];
        int rem = c - 1536;
        int h = rem >> 6, d = rem & 63;
        #pragma unroll
        for (int i = 0; i < 4; ++i)
            #pragma unroll
            for (int r = 0; r < 4; ++r) {
                int row = brow + wr + (i << 4) + (fg << 2) + r;
                int b = row >> 12, n = row & 4095;
                float val = acc[i][j][r] + bb;
                size_t idx = (((size_t)(b * 12 + h) << 12) + n) * 64 + d;
                vh[idx] = f2bf(val);
            }
    }
}

// ---------------------------------------------------------------------------
// K2: fused flash pass for SC — MFMA. S: qk x3 split; PV: P hi/lo x V bf16.
// grid (8 chunks, 44 bh).
// ---------------------------------------------------------------------------
__global__ __launch_bounds__(256) void wflash(
    const unsigned short* __restrict__ qh, const unsigned short* __restrict__ ql,
    const unsigned short* __restrict__ khg, const unsigned short* __restrict__ klg,
    const unsigned short* __restrict__ vhg,
    float* __restrict__ wacc, float* __restrict__ wl, float* __restrict__ wm)
{
    int chunk = blockIdx.x;
    int bh = blockIdx.y;
    int b = bh / 11, h = bh - b * 11;
    size_t base = ((size_t)(b * 12 + h)) << 12;   // row base
    __shared__ unsigned short kh_s[64][72], kl_s[64][72];
    __shared__ unsigned short vth[64][72];                 // V^T [d][n], bf16
    __shared__ unsigned short ph[4][16][72], pl[4][16][72];
    int tid = threadIdx.x;
    int wv = tid >> 6, ln = tid & 63;
    int rr = tid >> 2, dg = (tid & 3) << 4;
    const int arow = (wv << 4) + (ln & 15);
    const int ak0 = (ln >> 4) << 3;
    const int rg = (ln >> 4) << 2;
    short8 aqh0, aql0, aqh1, aql1;
    {
        size_t off = ((base + ((size_t)arow << 6)) << 6) + ak0;
        aqh0 = *(const short8*)(qh + off);
        aqh1 = *(const short8*)(qh + off + 32);
        aql0 = *(const short8*)(ql + off);
        aql1 = *(const short8*)(ql + off + 32);
    }
    f32x4 o_acc[4] = {};
    float mr[4] = {-1e30f, -1e30f, -1e30f, -1e30f};
    float lr[4] = {};
    for (int t = 0; t < 8; ++t) {
        int n0 = (chunk << 9) + (t << 6);
        __syncthreads();
        {
            size_t off = ((base + n0 + rr) << 6) + dg;
            *(short8*)&kh_s[rr][dg]     = *(const short8*)(khg + off);
            *(short8*)&kh_s[rr][dg + 8] = *(const short8*)(khg + off + 8);
            *(short8*)&kl_s[rr][dg]     = *(const short8*)(klg + off);
            *(short8*)&kl_s[rr][dg + 8] = *(const short8*)(klg + off + 8);
            short8 v0 = *(const short8*)(vhg + off);
            short8 v1 = *(const short8*)(vhg + off + 8);
            #pragma unroll
            for (int i = 0; i < 8; ++i) {
                vth[dg + i][rr]     = (unsigned short)v0[i];
                vth[dg + 8 + i][rr] = (unsigned short)v1[i];
            }
        }
        __syncthreads();
        f32x4 s_acc[4];
        #pragma unroll
        for (int jb = 0; jb < 4; ++jb) {
            f32x4 z = {};
            const int brow2 = (jb << 4) + (ln & 15);
            short8 bh0 = *(short8*)&kh_s[brow2][ak0];
            short8 bh1 = *(short8*)&kh_s[brow2][ak0 + 32];
            short8 bl0 = *(short8*)&kl_s[brow2][ak0];
            short8 bl1 = *(short8*)&kl_s[brow2][ak0 + 32];
            z = __builtin_amdgcn_mfma_f32_16x16x32_bf16(aqh0, bh0, z, 0, 0, 0);
            z = __builtin_amdgcn_mfma_f32_16x16x32_bf16(aqh0, bl0, z, 0, 0, 0);
            z = __builtin_amdgcn_mfma_f32_16x16x32_bf16(aql0, bh0, z, 0, 0, 0);
            z = __builtin_amdgcn_mfma_f32_16x16x32_bf16(aqh1, bh1, z, 0, 0, 0);
            z = __builtin_amdgcn_mfma_f32_16x16x32_bf16(aqh1, bl1, z, 0, 0, 0);
            z = __builtin_amdgcn_mfma_f32_16x16x32_bf16(aql1, bh1, z, 0, 0, 0);
            s_acc[jb] = z;
        }
        float mx[4];
        #pragma unroll
        for (int r = 0; r < 4; ++r)
            mx[r] = fmaxf(fmaxf(s_acc[0][r], s_acc[1][r]),
                          fmaxf(s_acc[2][r], s_acc[3][r]));
        #pragma unroll
        for (int off2 = 1; off2 < 16; off2 <<= 1)
            #pragma unroll
            for (int r = 0; r < 4; ++r)
                mx[r] = fmaxf(mx[r], __shfl_xor(mx[r], off2, 64));
        float fac[4];
        #pragma unroll
        for (int r = 0; r < 4; ++r) {
            float mn = fmaxf(mr[r], mx[r]);
            fac[r] = expf(mr[r] - mn);
            mr[r] = mn;
        }
        float rs[4] = {};
        #pragma unroll
        for (int jb = 0; jb < 4; ++jb)
            #pragma unroll
            for (int r = 0; r < 4; ++r) {
                float p = expf(s_acc[jb][r] - mr[r]);
                rs[r] += p;
                unsigned short hh, ll;
                bfsplit(p, hh, ll);
                ph[wv][rg + r][(jb << 4) + (ln & 15)] = hh;
                pl[wv][rg + r][(jb << 4) + (ln & 15)] = ll;
            }
        #pragma unroll
        for (int off2 = 1; off2 < 16; off2 <<= 1)
            #pragma unroll
            for (int r = 0; r < 4; ++r)
                rs[r] += __shfl_xor(rs[r], off2, 64);
        #pragma unroll
        for (int r = 0; r < 4; ++r) lr[r] = lr[r] * fac[r] + rs[r];
        #pragma unroll
        for (int jb = 0; jb < 4; ++jb)
            #pragma unroll
            for (int r = 0; r < 4; ++r)
                o_acc[jb][r] *= fac[r];
        short8 pah0 = *(short8*)&ph[wv][ln & 15][ak0];
        short8 pah1 = *(short8*)&ph[wv][ln & 15][ak0 + 32];
        short8 pal0 = *(short8*)&pl[wv][ln & 15][ak0];
        short8 pal1 = *(short8*)&pl[wv][ln & 15][ak0 + 32];
        #pragma unroll
        for (int jb = 0; jb < 4; ++jb) {
            const int brow2 = (jb << 4) + (ln & 15);
            short8 bv0 = *(short8*)&vth[brow2][ak0];
            short8 bv1 = *(short8*)&vth[brow2][ak0 + 32];
            f32x4 o = o_acc[jb];
            o = __builtin_amdgcn_mfma_f32_16x16x32_bf16(pah0, bv0, o, 0, 0, 0);
            o = __builtin_amdgcn_mfma_f32_16x16x32_bf16(pal0, bv0, o, 0, 0, 0);
            o = __builtin_amdgcn_mfma_f32_16x16x32_bf16(pah1, bv1, o, 0, 0, 0);
            o = __builtin_amdgcn_mfma_f32_16x16x32_bf16(pal1, bv1, o, 0, 0, 0);
            o_acc[jb] = o;
        }
    }
    int cidx = (bh << 3) + chunk;
    #pragma unroll
    for (int jb = 0; jb < 4; ++jb)
        #pragma unroll
        for (int r = 0; r < 4; ++r) {
            int row = (wv << 4) + rg + r, col = (jb << 4) + (ln & 15);
            wacc[((size_t)cidx << 12) + ((size_t)row << 6) + col] = o_acc[jb][r];
        }
    if ((ln & 15) == 0)
        #pragma unroll
        for (int r = 0; r < 4; ++r) {
            int row = (wv << 4) + rg + r;
            wl[cidx * 64 + row] = lr[r];
            wm[cidx * 64 + row] = mr[r];
        }
}

// K2b: merge chunk partials -> Wb (65 cols, col 64 = ones-column) + scm
__global__ __launch_bounds__(256) void wmerge(
    const float* __restrict__ wacc, const float* __restrict__ wl,
    const float* __restrict__ wm,
    float* __restrict__ Wb, float* __restrict__ scm)
{
    int bh = blockIdx.x;
    int tid = threadIdx.x;
    __shared__ float fcs[8][64];
    if (tid < 64) {
        float mx = -1e30f;
        #pragma unroll
        for (int c = 0; c < 8; ++c)
            mx = fmaxf(mx, wm[((bh << 3) + c) * 64 + tid]);
        scm[(bh << 6) + tid] = mx;
        #pragma unroll
        for (int c = 0; c < 8; ++c)
            fcs[c][tid] = expf(wm[((bh << 3) + c) * 64 + tid] - mx);
    }
    __syncthreads();
    for (int e = tid; e < 4096; e += 256) {
        int m = e >> 6, j = e & 63;
        float s = 0.f;
        #pragma unroll
        for (int c = 0; c < 8; ++c)
            s += fcs[c][m] * wacc[((size_t)((bh << 3) + c) << 12) + e];
        Wb[(size_t)bh * 4160 + m * 65 + j] = s;
    }
    if (tid < 64) {
        float s = 0.f;
        #pragma unroll
        for (int c = 0; c < 8; ++c)
            s += fcs[c][tid] * wl[((bh << 3) + c) * 64 + tid];
        Wb[(size_t)bh * 4160 + tid * 65 + 64] = s;
    }
}

// ---------------------------------------------------------------------------
// K3a: eB — fp32 reconstructed from (hi,lo) split arrays
// ---------------------------------------------------------------------------
__global__ __launch_bounds__(256) void eb_kernel(
    const unsigned short* __restrict__ qh, const unsigned short* __restrict__ ql,
    const unsigned short* __restrict__ kh, const unsigned short* __restrict__ kl,
    const float* __restrict__ scm, float* __restrict__ eB)
{
    int bh = blockIdx.x;
    int b = bh / 11, h = bh - b * 11;
    size_t base = ((size_t)(b * 12 + h)) << 12;
    __shared__ float qm[64][65], km[64][65];
    int tid = threadIdx.x;
    for (int e = tid; e < 4096; e += 256) {
        int mm = e >> 6, d = e & 63;
        size_t off = ((base + ((size_t)mm << 6)) << 6) + d;
        qm[mm][d] = b2f(qh[off]) + b2f(ql[off]);
        km[mm][d] = b2f(kh[off]) + b2f(kl[off]);
    }
    __syncthreads();
    int m = tid >> 2, l0 = tid & 3;
    float smax = scm[(bh << 6) + m];
    for (int l = l0; l < 64; l += 4) {
        float s = 0.f;
        #pragma unroll
        for (int d = 0; d < 64; ++d) s += qm[m][d] * km[l][d];
        eB[((size_t)bh << 12) + (m << 6) + l] = expf(fmaxf(s - smax, -88.f));
    }
}

// ---------------------------------------------------------------------------
// K3b: per-head norms
// ---------------------------------------------------------------------------
__global__ __launch_bounds__(256) void norms_kernel(
    const float* __restrict__ eB, float* __restrict__ denom)
{
    int h = blockIdx.x;
    int tid = threadIdx.x;
    int b = tid >> 6, idx = tid & 63;
    int bh = b * 11 + h;
    const float* E = eB + ((size_t)bh << 12);
    float rs = 0.f, cs = 0.f;
    #pragma unroll 4
    for (int l = 0; l < 64; ++l) rs += E[(idx << 6) + l];
    #pragma unroll 4
    for (int m = 0; m < 64; ++m) cs += E[(m << 6) + idx];
    __shared__ float r1[256], r2[256];
    r1[tid] = rs; r2[tid] = cs;
    __syncthreads();
    for (int s = 128; s > 0; s >>= 1) {
        if (tid < s) {
            r1[tid] = fmaxf(r1[tid], r1[tid + s]);
            r2[tid] = fmaxf(r2[tid], r2[tid + s]);
        }
        __syncthreads();
    }
    if (tid == 0) denom[h] = r1[0] * r2[0];
}

// ---------------------------------------------------------------------------
// K3c: pinv via 6 Newton iterations — bf16x3 MFMA matmuls, one block per bh.
// ---------------------------------------------------------------------------
__device__ __forceinline__ void mm64x3(
    const unsigned short (&Ahi)[64][72], const unsigned short (&Alo)[64][72],
    const unsigned short (&BThi)[64][72], const unsigned short (&BTlo)[64][72],
    int wr, int wc, int fr, int fk, f32x4 (&acc)[2][2])
{
    #pragma unroll
    for (int ks = 0; ks < 2; ++ks) {
        const int kb = (ks << 5) + fk;
        short8 ah[2], al[2], bh[2], bl[2];
        #pragma unroll
        for (int i = 0; i < 2; ++i) {
            ah[i] = *(const short8*)&Ahi[wr + (i << 4) + fr][kb];
            al[i] = *(const short8*)&Alo[wr + (i << 4) + fr][kb];
            bh[i] = *(const short8*)&BThi[wc + (i << 4) + fr][kb];
            bl[i] = *(const short8*)&BTlo[wc + (i << 4) + fr][kb];
        }
        #pragma unroll
        for (int i = 0; i < 2; ++i)
            #pragma unroll
            for (int j = 0; j < 2; ++j) {
                acc[i][j] = __builtin_amdgcn_mfma_f32_16x16x32_bf16(ah[i], bh[j], acc[i][j], 0, 0, 0);
                acc[i][j] = __builtin_amdgcn_mfma_f32_16x16x32_bf16(ah[i], bl[j], acc[i][j], 0, 0, 0);
                acc[i][j] = __builtin_amdgcn_mfma_f32_16x16x32_bf16(al[i], bh[j], acc[i][j], 0, 0, 0);
            }
    }
}

__global__ __launch_bounds__(256) void pinv_kernel(
    const float* __restrict__ eB, const float* __restrict__ denom,
    float* __restrict__ pi_)
{
    __shared__ unsigned short Xh[64][72],  Xl[64][72];
    __shared__ unsigned short Zh[64][72],  Zl[64][72];
    __shared__ unsigned short ZTh[64][72], ZTl[64][72];
    __shared__ unsigned short Mh[64][72],  Ml[64][72];
    __shared__ unsigned short MTh[64][72], MTl[64][72];
    __shared__ unsigned short Th[64][72],  Tbl[64][72];
    __shared__ float Zf[64][68];
    int bh = blockIdx.x;
    int h = bh % 11;
    int tid = threadIdx.x;
    float dn = denom[h];
    const int ln = tid & 63, wv = tid >> 6;
    const int wr = (wv >> 1) << 5, wc = (wv & 1) << 5;
    const int fr = ln & 15, fk = (ln >> 4) << 3;
    const int rg = (ln >> 4) << 2;

    for (int e = tid; e < 4096; e += 256) {
        int m = e >> 6, l = e & 63;
        float xv = eB[((size_t)bh << 12) + e];
        unsigned short hh, ll;
        bfsplit(xv, hh, ll);
        Xh[m][l] = hh; Xl[m][l] = ll;
        float zv = xv / dn;
        Zf[l][m] = zv;
        bfsplit(zv, hh, ll);
        Zh[l][m] = hh; Zl[l][m] = ll;
        ZTh[m][l] = hh; ZTl[m][l] = ll;
    }
    __syncthreads();

    for (int it = 0; it < 6; ++it) {
        f32x4 mm1[2][2] = {};
        mm64x3(Xh, Xl, ZTh, ZTl, wr, wc, fr, fk, mm1);
        #pragma unroll
        for (int i = 0; i < 2; ++i)
            #pragma unroll
            for (int j = 0; j < 2; ++j)
                #pragma unroll
                for (int r = 0; r < 4; ++r) {
                    int row = wr + (i << 4) + rg + r, col = wc + (j << 4) + fr;
                    unsigned short hh, ll;
                    bfsplit(mm1[i][j][r], hh, ll);
                    Mh[row][col] = hh;  Ml[row][col] = ll;
                    MTh[col][row] = hh; MTl[col][row] = ll;
                }
        __syncthreads();
        f32x4 a2[2][2] = {};
        mm64x3(Mh, Ml, MTh, MTl, wr, wc, fr, fk, a2);
        #pragma unroll
        for (int i = 0; i < 2; ++i)
            #pragma unroll
            for (int j = 0; j < 2; ++j)
                #pragma unroll
                for (int r = 0; r < 4; ++r) {
                    int row = wr + (i << 4) + rg + r, col = wc + (j << 4) + fr;
                    float val = 7.f * mm1[i][j][r] - a2[i][j][r];
                    unsigned short hh, ll;
                    bfsplit(val, hh, ll);
                    Th[col][row] = hh; Tbl[col][row] = ll;
                }
        __syncthreads();
        f32x4 a3[2][2] = {};
        mm64x3(Mh, Ml, Th, Tbl, wr, wc, fr, fk, a3);
        __syncthreads();
        #pragma unroll
        for (int i = 0; i < 2; ++i)
            #pragma unroll
            for (int j = 0; j < 2; ++j)
                #pragma unroll
                for (int r = 0; r < 4; ++r) {
                    int row = wr + (i << 4) + rg + r, col = wc + (j << 4) + fr;
                    float val = 15.f * mm1[i][j][r] - a3[i][j][r];
                    unsigned short hh, ll;
                    bfsplit(val, hh, ll);
                    Th[col][row] = hh; Tbl[col][row] = ll;
                }
        __syncthreads();
        f32x4 a4[2][2] = {};
        mm64x3(Zh, Zl, Th, Tbl, wr, wc, fr, fk, a4);
        float zn[2][2][4];
        #pragma unroll
        for (int i = 0; i < 2; ++i)
            #pragma unroll
            for (int j = 0; j < 2; ++j)
                #pragma unroll
                for (int r = 0; r < 4; ++r) {
                    int row = wr + (i << 4) + rg + r, col = wc + (j << 4) + fr;
                    zn[i][j][r] = 0.25f * (13.f * Zf[row][col] - a4[i][j][r]);
                }
        __syncthreads();
        #pragma unroll
        for (int i = 0; i < 2; ++i)
            #pragma unroll
            for (int j = 0; j < 2; ++j)
                #pragma unroll
                for (int r = 0; r < 4; ++r) {
                    int row = wr + (i << 4) + rg + r, col = wc + (j << 4) + fr;
                    float val = zn[i][j][r];
                    Zf[row][col] = val;
                    unsigned short hh, ll;
                    bfsplit(val, hh, ll);
                    Zh[row][col] = hh;  Zl[row][col] = ll;
                    ZTh[col][row] = hh; ZTl[col][row] = ll;
                }
        __syncthreads();
    }
    for (int e = tid; e < 4096; e += 256)
        pi_[((size_t)bh << 12) + e] = Zf[e >> 6][e & 63];
}

// ---------------------------------------------------------------------------
// K5: T = pi @ W  (64x64 @ 64x65)
// ---------------------------------------------------------------------------
__global__ __launch_bounds__(256) void pw_kernel(
    const float* __restrict__ pi_, const float* __restrict__ Wb,
    float* __restrict__ Tb)
{
    int bh = blockIdx.x;
    __shared__ float P[64][65];
    __shared__ float Wl[64][66];
    int tid = threadIdx.x;
    for (int e = tid; e < 4096; e += 256)
        P[e >> 6][e & 63] = pi_[((size_t)bh << 12) + e];
    for (int e = tid; e < 64 * 65; e += 256) {
        int l = e / 65, j = e - l * 65;
        Wl[l][j] = Wb[(size_t)bh * 4160 + e];
    }
    __syncthreads();
    int m = tid & 63, g = tid >> 6;
    #pragma unroll
    for (int t = 0; t < 17; ++t) {
        int j = g + (t << 2);
        if (j > 64) break;
        float s = 0.f;
        #pragma unroll
        for (int l = 0; l < 64; ++l) s += P[m][l] * Wl[l][j];
        Tb[(size_t)((bh << 6) + m) * 65 + j] = s;
    }
}

// ---------------------------------------------------------------------------
// K6: out_p — MFMA: S x3 from split q,k; eA hi/lo × T hi/lo; ctx bf16
// ---------------------------------------------------------------------------
__global__ __launch_bounds__(256) void outp_kernel(
    const unsigned short* __restrict__ qh, const unsigned short* __restrict__ ql,
    const unsigned short* __restrict__ khg, const unsigned short* __restrict__ klg,
    const float* __restrict__ Tb, unsigned short* __restrict__ ctxh)
{
    int bh = blockIdx.y;
    int b = bh / 11, h = bh - b * 11;
    int n0 = blockIdx.x << 6;
    size_t base = ((size_t)(b * 12 + h)) << 12;
    __shared__ unsigned short kmh[64][72], kml[64][72];
    __shared__ unsigned short tth[64][72], ttl[64][72];
    __shared__ unsigned short ph[4][16][72], pl[4][16][72];
    __shared__ float t64[64];
    int tid = threadIdx.x;
    int wv = tid >> 6, ln = tid & 63;
    int rr = tid >> 2, dg = (tid & 3) << 4;
    const int arow = (wv << 4) + (ln & 15);
    const int ak0 = (ln >> 4) << 3;
    const int rg = (ln >> 4) << 2;
    {
        size_t off = ((base + ((size_t)rr << 6)) << 6) + dg;
        *(short8*)&kmh[rr][dg]     = *(const short8*)(khg + off);
        *(short8*)&kmh[rr][dg + 8] = *(const short8*)(khg + off + 8);
        *(short8*)&kml[rr][dg]     = *(const short8*)(klg + off);
        *(short8*)&kml[rr][dg + 8] = *(const short8*)(klg + off + 8);
    }
    for (int e = tid; e < 4096; e += 256) {
        int m = e >> 6, j = e & 63;
        float tv = Tb[(size_t)((bh << 6) + m) * 65 + j];
        unsigned short hh, ll;
        bfsplit(tv, hh, ll);
        tth[j][m] = hh; ttl[j][m] = ll;
    }
    if (tid < 64) t64[tid] = Tb[(size_t)((bh << 6) + tid) * 65 + 64];
    short8 aqh0, aql0, aqh1, aql1;
    {
        size_t off = ((base + n0 + arow) << 6) + ak0;
        aqh0 = *(const short8*)(qh + off);
        aqh1 = *(const short8*)(qh + off + 32);
        aql0 = *(const short8*)(ql + off);
        aql1 = *(const short8*)(ql + off + 32);
    }
    __syncthreads();
    f32x4 s_acc[4];
    #pragma unroll
    for (int jb = 0; jb < 4; ++jb) {
        f32x4 z = {};
        const int brow2 = (jb << 4) + (ln & 15);
        short8 bh0 = *(short8*)&kmh[brow2][ak0];
        short8 bh1 = *(short8*)&kmh[brow2][ak0 + 32];
        short8 bl0 = *(short8*)&kml[brow2][ak0];
        short8 bl1 = *(short8*)&kml[brow2][ak0 + 32];
        z = __builtin_amdgcn_mfma_f32_16x16x32_bf16(aqh0, bh0, z, 0, 0, 0);
        z = __builtin_amdgcn_mfma_f32_16x16x32_bf16(aqh0, bl0, z, 0, 0, 0);
        z = __builtin_amdgcn_mfma_f32_16x16x32_bf16(aql0, bh0, z, 0, 0, 0);
        z = __builtin_amdgcn_mfma_f32_16x16x32_bf16(aqh1, bh1, z, 0, 0, 0);
        z = __builtin_amdgcn_mfma_f32_16x16x32_bf16(aqh1, bl1, z, 0, 0, 0);
        z = __builtin_amdgcn_mfma_f32_16x16x32_bf16(aql1, bh1, z, 0, 0, 0);
        s_acc[jb] = z;
    }
    float mx[4];
    #pragma unroll
    for (int r = 0; r < 4; ++r)
        mx[r] = fmaxf(fmaxf(s_acc[0][r], s_acc[1][r]),
                      fmaxf(s_acc[2][r], s_acc[3][r]));
    #pragma unroll
    for (int off2 = 1; off2 < 16; off2 <<= 1)
        #pragma unroll
        for (int r = 0; r < 4; ++r)
            mx[r] = fmaxf(mx[r], __shfl_xor(mx[r], off2, 64));
    float den[4] = {};
    #pragma unroll
    for (int jb = 0; jb < 4; ++jb) {
        float tj = t64[(jb << 4) + (ln & 15)];
        #pragma unroll
        for (int r = 0; r < 4; ++r) {
            float p = expf(s_acc[jb][r] - mx[r]);
            den[r] += p * tj;
            unsigned short hh, ll;
            bfsplit(p, hh, ll);
            ph[wv][rg + r][(jb << 4) + (ln & 15)] = hh;
            pl[wv][rg + r][(jb << 4) + (ln & 15)] = ll;
        }
    }
    #pragma unroll
    for (int off2 = 1; off2 < 16; off2 <<= 1)
        #pragma unroll
        for (int r = 0; r < 4; ++r)
            den[r] += __shfl_xor(den[r], off2, 64);
    short8 pah0 = *(short8*)&ph[wv][ln & 15][ak0];
    short8 pah1 = *(short8*)&ph[wv][ln & 15][ak0 + 32];
    short8 pal0 = *(short8*)&pl[wv][ln & 15][ak0];
    short8 pal1 = *(short8*)&pl[wv][ln & 15][ak0 + 32];
    f32x4 o_acc[4] = {};
    #pragma unroll
    for (int jb = 0; jb < 4; ++jb) {
        const int brow2 = (jb << 4) + (ln & 15);
        short8 bth0 = *(short8*)&tth[brow2][ak0];
        short8 bth1 = *(short8*)&tth[brow2][ak0 + 32];
        short8 btl0 = *(short8*)&ttl[brow2][ak0];
        short8 btl1 = *(short8*)&ttl[brow2][ak0 + 32];
        f32x4 o = o_acc[jb];
        o = __builtin_amdgcn_mfma_f32_16x16x32_bf16(pah0, bth0, o, 0, 0, 0);
        o = __builtin_amdgcn_mfma_f32_16x16x32_bf16(pah0, btl0, o, 0, 0, 0);
        o = __builtin_amdgcn_mfma_f32_16x16x32_bf16(pal0, bth0, o, 0, 0, 0);
        o = __builtin_amdgcn_mfma_f32_16x16x32_bf16(pah1, bth1, o, 0, 0, 0);
        o = __builtin_amdgcn_mfma_f32_16x16x32_bf16(pah1, btl1, o, 0, 0, 0);
        o = __builtin_amdgcn_mfma_f32_16x16x32_bf16(pal1, bth1, o, 0, 0, 0);
        o_acc[jb] = o;
    }
    float inv[4];
    #pragma unroll
    for (int r = 0; r < 4; ++r) inv[r] = 1.0f / fmaxf(den[r], 1e-8f);
    #pragma unroll
    for (int jb = 0; jb < 4; ++jb)
        #pragma unroll
        for (int r = 0; r < 4; ++r) {
            int row = n0 + (wv << 4) + rg + r;
            int col = (jb << 4) + (ln & 15);
            ctxh[((size_t)b * 4096 + row) * 768 + h * 64 + col] =
                f2bf(o_acc[jb][r] * inv[r]);
        }
}

// ---------------------------------------------------------------------------
// K7a: softmax head (h=11) flash partial over a 1024-KV chunk. grid (64,4,4).
// ---------------------------------------------------------------------------
__global__ __launch_bounds__(256) void flash_part(
    const unsigned short* __restrict__ qhg, const unsigned short* __restrict__ khg,
    const unsigned short* __restrict__ vhg,
    float* __restrict__ pacc, float* __restrict__ pm, float* __restrict__ pl)
{
    int bx = blockIdx.x, cy = blockIdx.y, b = blockIdx.z;
    int n0 = bx << 6;
    size_t base = ((size_t)(b * 12 + 11)) << 12;
    __shared__ unsigned short qs[64][72];
    __shared__ unsigned short ks[64][72];
    __shared__ unsigned short vts[64][72];
    __shared__ unsigned short ps[4][16][72];
    int tid = threadIdx.x;
    int wv = tid >> 6, ln = tid & 63;
    int rr = tid >> 2, dg = (tid & 3) << 4;
    {
        size_t off = ((base + n0 + rr) << 6) + dg;
        *(short8*)&qs[rr][dg]     = *(const short8*)(qhg + off);
        *(short8*)&qs[rr][dg + 8] = *(const short8*)(qhg + off + 8);
    }
    __syncthreads();
    const int arow = (wv << 4) + (ln & 15);
    const int ak0 = (ln >> 4) << 3;
    const int rg = (ln >> 4) << 2;
    short8 aq0 = *(short8*)&qs[arow][ak0];
    short8 aq1 = *(short8*)&qs[arow][ak0 + 32];
    f32x4 o_acc[4] = {};
    float mr[4] = {-1e30f, -1e30f, -1e30f, -1e30f};
    float lr[4] = {};
    for (int t = 0; t < 16; ++t) {
        int m0 = (cy << 10) + (t << 6);
        __syncthreads();
        {
            size_t off = ((base + m0 + rr) << 6) + dg;
            *(short8*)&ks[rr][dg]     = *(const short8*)(khg + off);
            *(short8*)&ks[rr][dg + 8] = *(const short8*)(khg + off + 8);
            short8 v0 = *(const short8*)(vhg + off);
            short8 v1 = *(const short8*)(vhg + off + 8);
            #pragma unroll
            for (int i = 0; i < 8; ++i) {
                vts[dg + i][rr]     = (unsigned short)v0[i];
                vts[dg + 8 + i][rr] = (unsigned short)v1[i];
            }
        }
        __syncthreads();
        f32x4 s_acc[4];
        #pragma unroll
        for (int jb = 0; jb < 4; ++jb) {
            f32x4 z = {};
            short8 bk0 = *(short8*)&ks[(jb << 4) + (ln & 15)][ak0];
            short8 bk1 = *(short8*)&ks[(jb << 4) + (ln & 15)][ak0 + 32];
            z = __builtin_amdgcn_mfma_f32_16x16x32_bf16(aq0, bk0, z, 0, 0, 0);
            z = __builtin_amdgcn_mfma_f32_16x16x32_bf16(aq1, bk1, z, 0, 0, 0);
            s_acc[jb] = z;
        }
        float mx[4];
        #pragma unroll
        for (int r = 0; r < 4; ++r)
            mx[r] = fmaxf(fmaxf(s_acc[0][r], s_acc[1][r]),
                          fmaxf(s_acc[2][r], s_acc[3][r]));
        #pragma unroll
        for (int off2 = 1; off2 < 16; off2 <<= 1)
            #pragma unroll
            for (int r = 0; r < 4; ++r)
                mx[r] = fmaxf(mx[r], __shfl_xor(mx[r], off2, 64));
        float fac[4];
        #pragma unroll
        for (int r = 0; r < 4; ++r) {
            float mn = fmaxf(mr[r], mx[r]);
            fac[r] = expf(mr[r] - mn);
            mr[r] = mn;
        }
        float rs[4] = {};
        #pragma unroll
        for (int jb = 0; jb < 4; ++jb)
            #pragma unroll
            for (int r = 0; r < 4; ++r) {
                float p = expf(s_acc[jb][r] - mr[r]);
                rs[r] += p;
                ps[wv][rg + r][(jb << 4) + (ln & 15)] = f2bf(p);
            }
        #pragma unroll
        for (int off2 = 1; off2 < 16; off2 <<= 1)
            #pragma unroll
            for (int r = 0; r < 4; ++r)
                rs[r] += __shfl_xor(rs[r], off2, 64);
        #pragma unroll
        for (int r = 0; r < 4; ++r) lr[r] = lr[r] * fac[r] + rs[r];
        #pragma unroll
        for (int jb = 0; jb < 4; ++jb)
            #pragma unroll
            for (int r = 0; r < 4; ++r)
                o_acc[jb][r] *= fac[r];
        short8 pa0 = *(short8*)&ps[wv][ln & 15][ak0];
        short8 pa1 = *(short8*)&ps[wv][ln & 15][ak0 + 32];
        #pragma unroll
        for (int jb = 0; jb < 4; ++jb) {
            short8 bv0 = *(short8*)&vts[(jb << 4) + (ln & 15)][ak0];
            short8 bv1 = *(short8*)&vts[(jb << 4) + (ln & 15)][ak0 + 32];
            f32x4 z = o_acc[jb];
            z = __builtin_amdgcn_mfma_f32_16x16x32_bf16(pa0, bv0, z, 0, 0, 0);
            z = __builtin_amdgcn_mfma_f32_16x16x32_bf16(pa1, bv1, z, 0, 0, 0);
            o_acc[jb] = z;
        }
    }
    int slot = (b * 4 + cy) * 64 + bx;
    #pragma unroll
    for (int jb = 0; jb < 4; ++jb)
        #pragma unroll
        for (int r = 0; r < 4; ++r) {
            int row = (wv << 4) + rg + r, col = (jb << 4) + (ln & 15);
            pacc[(size_t)slot * 4096 + (size_t)row * 64 + col] = o_acc[jb][r];
        }
    if ((ln & 15) == 0)
        #pragma unroll
        for (int r = 0; r < 4; ++r) {
            int row = (wv << 4) + rg + r;
            pm[(size_t)slot * 64 + row] = mr[r];
            pl[(size_t)slot * 64 + row] = lr[r];
        }
}

// K7b: merge 4 chunk partials -> ctx head 11 (bf16)
__global__ __launch_bounds__(256) void flash_merge(
    const float* __restrict__ pacc, const float* __restrict__ pm,
    const float* __restrict__ pl, unsigned short* __restrict__ ctxh)
{
    int bx = blockIdx.x, b = blockIdx.y;
    int tid = threadIdx.x, r = tid & 63, g = tid >> 6;
    float mc[4], mt = -1e30f;
    #pragma unroll
    for (int c = 0; c < 4; ++c) {
        mc[c] = pm[(size_t)((b * 4 + c) * 64 + bx) * 64 + r];
        mt = fmaxf(mt, mc[c]);
    }
    float fac[4], lt = 0.f;
    #pragma unroll
    for (int c = 0; c < 4; ++c) {
        fac[c] = expf(mc[c] - mt);
        lt += fac[c] * pl[(size_t)((b * 4 + c) * 64 + bx) * 64 + r];
    }
    float inv = 1.0f / lt;
    size_t obase = ((size_t)b * 4096 + (size_t)((bx << 6) + r)) * 768 + 11 * 64 + (g << 4);
    #pragma unroll
    for (int i = 0; i < 16; ++i) {
        float s = 0.f;
        #pragma unroll
        for (int c = 0; c < 4; ++c)
            s += fac[c] * pacc[(size_t)((b * 4 + c) * 64 + bx) * 4096 + (size_t)r * 64 + (g << 4) + i];
        ctxh[obase + i] = f2bf(s * inv);
    }
}

// ---------------------------------------------------------------------------
// K8: proj GEMM — plain bf16 MFMA. 128x128, BK=32, swizzled LDS, XCD swizzle.
// ---------------------------------------------------------------------------
__global__ __launch_bounds__(256, 2) void gemm_proj_mfma(
    const unsigned short* __restrict__ Xh, const unsigned short* __restrict__ Wh,
    const float* __restrict__ bias, float* __restrict__ out)
{
    __shared__ unsigned short Ah[4096], Bh[4096];
    const int tid = threadIdx.x;
    const int bid = blockIdx.x;                  // nwg=768 (%8==0)
    const int swz = (bid & 7) * 96 + (bid >> 3);
    const int brow = (swz / 6) << 7, bcol = (swz % 6) << 7;
    const int ln = tid & 63, wv = tid >> 6;
    const int wr = (wv >> 1) << 6, wc = (wv & 1) << 6;
    const int srow = tid >> 1, sc = (tid & 1) << 1;
    const size_t ag = (size_t)(brow + srow) * 768 + (sc << 3);
    const size_t bg = (size_t)(bcol + srow) * 768 + (sc << 3);
    const int fr = ln & 15, fc = ln >> 4;
    const int i0 = srow * 32 + (((sc + 0) ^ (srow & 3)) << 3);
    const int i1 = srow * 32 + (((sc + 1) ^ (srow & 3)) << 3);

    f32x4 acc[4][4] = {};
    for (int k0 = 0; k0 < 768; k0 += 32) {
        short8 xh0 = *(const short8*)(Xh + ag + k0);
        short8 xh1 = *(const short8*)(Xh + ag + k0 + 8);
        short8 wh0 = *(const short8*)(Wh + bg + k0);
        short8 wh1 = *(const short8*)(Wh + bg + k0 + 8);
        __syncthreads();
        *(short8*)&Ah[i0] = xh0; *(short8*)&Ah[i1] = xh1;
        *(short8*)&Bh[i0] = wh0; *(short8*)&Bh[i1] = wh1;
        __syncthreads();
        short8 ah[4], bh[4];
        #pragma unroll
        for (int i = 0; i < 4; ++i) {
            int ar = wr + (i << 4) + fr;
            ah[i] = *(short8*)&Ah[ar * 32 + ((fc ^ (ar & 3)) << 3)];
            int br2 = wc + (i << 4) + fr;
            bh[i] = *(short8*)&Bh[br2 * 32 + ((fc ^ (br2 & 3)) << 3)];
        }
        #pragma unroll
        for (int i = 0; i < 4; ++i)
            #pragma unroll
            for (int j = 0; j < 4; ++j)
                acc[i][j] = __builtin_amdgcn_mfma_f32_16x16x32_bf16(ah[i], bh[j], acc[i][j], 0, 0, 0);
    }
    const int fg = ln >> 4;
    #pragma unroll
    for (int j = 0; j < 4; ++j) {
        int c = bcol + wc + (j << 4) + fr;
        float bb = bias[c];
        #pragma unroll
        for (int i = 0; i < 4; ++i)
            #pragma unroll
            for (int r = 0; r < 4; ++r) {
                int row = brow + wr + (i << 4) + (fg << 2) + r;
                out[(size_t)row * 768 + c] = acc[i][j][r] + bb;
            }
    }
}

// ---------------------------------------------------------------------------
extern "C" void kernel_launch(void* const* d_in, const int* in_sizes, int n_in,
                              void* d_out, int out_size, void* d_ws, size_t ws_size,
                              hipStream_t stream)
{
    const float* x      = (const float*)d_in[0];
    const float* qkv_w  = (const float*)d_in[1];
    const float* qkv_b  = (const float*)d_in[2];
    const float* proj_w = (const float*)d_in[3];
    const float* proj_b = (const float*)d_in[4];
    float* out = (float*)d_out;

    const size_t QKV = (size_t)4 * 12 * 4096 * 64;   // 12,582,912
    unsigned short* qh = (unsigned short*)d_ws;
    unsigned short* ql = qh + QKV;
    unsigned short* kh = ql + QKV;
    unsigned short* kl = kh + QKV;
    unsigned short* vh = kl + QKV;
    unsigned short* ctxh = vh + QKV;
    float* scm  = (float*)(ctxh + QKV);
    float* eB   = scm + 4096;
    float* den  = eB + 44 * 4096;
    float* pi_  = den + 64;
    float* Wb   = pi_ + 44 * 4096;
    float* Tb   = Wb + 44 * 4160;
    unsigned short* Whi  = (unsigned short*)(Tb + 44 * 4160);
    unsigned short* Wlo  = Whi + (size_t)2304 * 768;
    unsigned short* Pwhi = Wlo + (size_t)2304 * 768;
    unsigned short* Pwlo = Pwhi + (size_t)768 * 768;   // written, unused

    unsigned short* Xhi = (unsigned short*)out;
    unsigned short* Xlo = Xhi + QKV;
    float* wacc = out;                    // 1,441,792
    float* wl   = wacc + 1441792;         // 22,528
    float* wm   = wl + 22528;             // 22,528
    float* fpacc = out;                   // 4,194,304 (after wmerge)
    float* fpm   = fpacc + 4194304;       // 65,536
    float* fpl   = fpm + 65536;           // 65,536

    preconv<<<2048, 256, 0, stream>>>(x, Xhi, Xlo, 3145728);
    preconv<<<1024, 256, 0, stream>>>(qkv_w, Whi, Wlo, 442368);
    preconv<<<512, 256, 0, stream>>>(proj_w, Pwhi, Pwlo, 147456);
    gemm_qk_mfma<<<1536, 256, 0, stream>>>(Xhi, Xlo, Whi, Wlo, qkv_b,
                                           qh, ql, kh, kl);
    gemm_v_mfma<<<768, 256, 0, stream>>>(Xhi, Whi, qkv_b, vh);
    wflash<<<dim3(8, 44), 256, 0, stream>>>(qh, ql, kh, kl, vh, wacc, wl, wm);
    wmerge<<<44, 256, 0, stream>>>(wacc, wl, wm, Wb, scm);
    eb_kernel<<<44, 256, 0, stream>>>(qh, ql, kh, kl, scm, eB);
    norms_kernel<<<11, 256, 0, stream>>>(eB, den);
    pinv_kernel<<<44, 256, 0, stream>>>(eB, den, pi_);
    pw_kernel<<<44, 256, 0, stream>>>(pi_, Wb, Tb);
    outp_kernel<<<dim3(64, 44), 256, 0, stream>>>(qh, ql, kh, kl, Tb, ctxh);
    flash_part<<<dim3(64, 4, 4), 256, 0, stream>>>(qh, kh, vh, fpacc, fpm, fpl);
    flash_merge<<<dim3(64, 4), 256, 0, stream>>>(fpacc, fpm, fpl, ctxh);
    gemm_proj_mfma<<<768, 256, 0, stream>>>(ctxh, Pwhi, proj_b, out);
}

// Round 10
// 436.863 us; speedup vs baseline: 14.0369x; 1.0445x over previous
//
#include <hip/hip_runtime.h>

// B=4, N=4096, C=768, H=12, D=64, M=64, PNP=11, SCALE=1/8

typedef __attribute__((ext_vector_type(8))) short short8;
typedef __attribute__((ext_vector_type(4))) float f32x4;
typedef __attribute__((ext_vector_type(4))) unsigned short ushort4v;

static __device__ __forceinline__ unsigned short f2bf(float f) {
    union { float f; unsigned u; } x; x.f = f;
    unsigned r = x.u + 0x7fffu + ((x.u >> 16) & 1u);   // RNE
    return (unsigned short)(r >> 16);
}

static __device__ __forceinline__ float b2f(unsigned short u) {
    union { unsigned u; float f; } t; t.u = (unsigned)u << 16; return t.f;
}

static __device__ __forceinline__ void bfsplit(float x, unsigned short& h, unsigned short& l) {
    unsigned short hh = f2bf(x);
    union { unsigned u; float f; } t; t.u = (unsigned)hh << 16;
    h = hh;
    l = f2bf(x - t.f);    // exact residual, RNE to bf16
}

// ---------------------------------------------------------------------------
// K0: split 3 fp32 arrays into bf16 (hi,lo) pairs, one fused launch.
// ---------------------------------------------------------------------------
__global__ __launch_bounds__(256) void preconv3(
    const float* __restrict__ a, const float* __restrict__ b,
    const float* __restrict__ c,
    unsigned short* __restrict__ ahi, unsigned short* __restrict__ alo,
    unsigned short* __restrict__ bhi, unsigned short* __restrict__ blo,
    unsigned short* __restrict__ chi, unsigned short* __restrict__ clo)
{
    const int nA = 3145728, nB = 442368, nC = 147456;
    const int total = nA + nB + nC;
    for (int i = blockIdx.x * 256 + threadIdx.x; i < total; i += gridDim.x * 256) {
        const float* src; unsigned short* hi; unsigned short* lo; int j;
        if (i < nA)           { src = a; hi = ahi; lo = alo; j = i; }
        else if (i < nA + nB) { src = b; hi = bhi; lo = blo; j = i - nA; }
        else                  { src = c; hi = chi; lo = clo; j = i - nA - nB; }
        float4 f = *(const float4*)(src + (size_t)j * 4);
        float vs[4] = {f.x, f.y, f.z, f.w};
        ushort4v h, l;
        #pragma unroll
        for (int t = 0; t < 4; ++t) {
            unsigned short hh, ll;
            bfsplit(vs[t], hh, ll);
            h[t] = hh; l[t] = ll;
        }
        *(ushort4v*)(hi + (size_t)j * 4) = h;
        *(ushort4v*)(lo + (size_t)j * 4) = l;
    }
}

// ---------------------------------------------------------------------------
// K1a: Q,K GEMM via bf16x3-split MFMA. cols 0..1535. grid 1536. (unchanged)
// ---------------------------------------------------------------------------
__global__ __launch_bounds__(256, 2) void gemm_qk_mfma(
    const unsigned short* __restrict__ Xh, const unsigned short* __restrict__ Xl,
    const unsigned short* __restrict__ Wh, const unsigned short* __restrict__ Wl,
    const float* __restrict__ bias,
    unsigned short* __restrict__ qh, unsigned short* __restrict__ ql,
    unsigned short* __restrict__ kh, unsigned short* __restrict__ kl)
{
    __shared__ unsigned short Ah[4096], Al[4096], Bh[4096], Bl[4096];
    const int tid = threadIdx.x;
    const int bid = blockIdx.x;                 // nwg=1536 (%8==0)
    const int swz = (bid & 7) * 192 + (bid >> 3);
    const int brow = (swz / 12) << 7, bcol = (swz % 12) << 7;
    const int ln = tid & 63, wv = tid >> 6;
    const int wr = (wv >> 1) << 6, wc = (wv & 1) << 6;
    const int srow = tid >> 1, sc = (tid & 1) << 1;
    const size_t ag = (size_t)(brow + srow) * 768 + (sc << 3);
    const size_t bg = (size_t)(bcol + srow) * 768 + (sc << 3);
    const int fr = ln & 15, fc = ln >> 4;
    const int i0 = srow * 32 + (((sc + 0) ^ (srow & 3)) << 3);
    const int i1 = srow * 32 + (((sc + 1) ^ (srow & 3)) << 3);

    f32x4 acc[4][4] = {};
    for (int k0 = 0; k0 < 768; k0 += 32) {
        short8 xh0 = *(const short8*)(Xh + ag + k0);
        short8 xh1 = *(const short8*)(Xh + ag + k0 + 8);
        short8 xl0 = *(const short8*)(Xl + ag + k0);
        short8 xl1 = *(const short8*)(Xl + ag + k0 + 8);
        short8 wh0 = *(const short8*)(Wh + bg + k0);
        short8 wh1 = *(const short8*)(Wh + bg + k0 + 8);
        short8 wl0 = *(const short8*)(Wl + bg + k0);
        short8 wl1 = *(const short8*)(Wl + bg + k0 + 8);
        __syncthreads();
        *(short8*)&Ah[i0] = xh0; *(short8*)&Ah[i1] = xh1;
        *(short8*)&Al[i0] = xl0; *(short8*)&Al[i1] = xl1;
        *(short8*)&Bh[i0] = wh0; *(short8*)&Bh[i1] = wh1;
        *(short8*)&Bl[i0] = wl0; *(short8*)&Bl[i1] = wl1;
        __syncthreads();
        short8 ah[4], al[4], bh[4], bl[4];
        #pragma unroll
        for (int i = 0; i < 4; ++i) {
            int ar = wr + (i << 4) + fr;
            int aidx = ar * 32 + ((fc ^ (ar & 3)) << 3);
            ah[i] = *(short8*)&Ah[aidx];
            al[i] = *(short8*)&Al[aidx];
            int br2 = wc + (i << 4) + fr;
            int bidx = br2 * 32 + ((fc ^ (br2 & 3)) << 3);
            bh[i] = *(short8*)&Bh[bidx];
            bl[i] = *(short8*)&Bl[bidx];
        }
        #pragma unroll
        for (int i = 0; i < 4; ++i)
            #pragma unroll
            for (int j = 0; j < 4; ++j) {
                acc[i][j] = __builtin_amdgcn_mfma_f32_16x16x32_bf16(ah[i], bh[j], acc[i][j], 0, 0, 0);
                acc[i][j] = __builtin_amdgcn_mfma_f32_16x16x32_bf16(ah[i], bl[j], acc[i][j], 0, 0, 0);
                acc[i][j] = __builtin_amdgcn_mfma_f32_16x16x32_bf16(al[i], bh[j], acc[i][j], 0, 0, 0);
            }
    }
    const int fg = ln >> 4;
    #pragma unroll
    for (int j = 0; j < 4; ++j) {
        int c = bcol + wc + (j << 4) + fr;
        float bb = bias[c];
        int rem = c - (c >= 768 ? 768 : 0);
        int h = rem >> 6, d = rem & 63;
        #pragma unroll
        for (int i = 0; i < 4; ++i)
            #pragma unroll
            for (int r = 0; r < 4; ++r) {
                int row = brow + wr + (i << 4) + (fg << 2) + r;
                int b = row >> 12, n = row & 4095;
                float val = acc[i][j][r] + bb;
                size_t idx = (((size_t)(b * 12 + h) << 12) + n) * 64 + d;
                unsigned short hh, ll;
                if (c < 768) {
                    bfsplit(val * 0.125f, hh, ll);
                    qh[idx] = hh; ql[idx] = ll;
                } else {
                    bfsplit(val, hh, ll);
                    kh[idx] = hh; kl[idx] = ll;
                }
            }
    }
}

// ---------------------------------------------------------------------------
// K1b: V GEMM via plain bf16 MFMA, BK=64 (half the barriers). grid 768.
// ---------------------------------------------------------------------------
__global__ __launch_bounds__(256, 2) void gemm_v_mfma(
    const unsigned short* __restrict__ Xh, const unsigned short* __restrict__ Wh,
    const float* __restrict__ bias, unsigned short* __restrict__ vh)
{
    __shared__ unsigned short Ah[8192], Bh[8192];   // [128][64] swizzled
    const int tid = threadIdx.x;
    const int bid = blockIdx.x;                  // nwg=768 (%8==0)
    const int swz = (bid & 7) * 96 + (bid >> 3);
    const int brow = (swz / 6) << 7, bcol = 1536 + ((swz % 6) << 7);
    const int ln = tid & 63, wv = tid >> 6;
    const int wr = (wv >> 1) << 6, wc = (wv & 1) << 6;
    const int srow = tid >> 1;
    const int c0 = (tid & 1) << 2;               // chunks 0-3 or 4-7
    const size_t ag = (size_t)(brow + srow) * 768;
    const size_t bg = (size_t)(bcol + srow) * 768;
    const int fr = ln & 15, fc = ln >> 4;

    f32x4 acc[4][4] = {};
    for (int k0 = 0; k0 < 768; k0 += 64) {
        short8 xa[4], wb[4];
        #pragma unroll
        for (int cc = 0; cc < 4; ++cc) {
            xa[cc] = *(const short8*)(Xh + ag + k0 + ((c0 + cc) << 3));
            wb[cc] = *(const short8*)(Wh + bg + k0 + ((c0 + cc) << 3));
        }
        __syncthreads();
        #pragma unroll
        for (int cc = 0; cc < 4; ++cc) {
            int dst = srow * 64 + (((c0 + cc) ^ (srow & 7)) << 3);
            *(short8*)&Ah[dst] = xa[cc];
            *(short8*)&Bh[dst] = wb[cc];
        }
        __syncthreads();
        #pragma unroll
        for (int ks = 0; ks < 2; ++ks) {
            const int kc = (ks << 2) + fc;
            short8 ah[4], bh[4];
            #pragma unroll
            for (int i = 0; i < 4; ++i) {
                int ar = wr + (i << 4) + fr;
                ah[i] = *(short8*)&Ah[ar * 64 + ((kc ^ (ar & 7)) << 3)];
                int br2 = wc + (i << 4) + fr;
                bh[i] = *(short8*)&Bh[br2 * 64 + ((kc ^ (br2 & 7)) << 3)];
            }
            #pragma unroll
            for (int i = 0; i < 4; ++i)
                #pragma unroll
                for (int j = 0; j < 4; ++j)
                    acc[i][j] = __builtin_amdgcn_mfma_f32_16x16x32_bf16(ah[i], bh[j], acc[i][j], 0, 0, 0);
        }
    }
    const int fg = ln >> 4;
    #pragma unroll
    for (int j = 0; j < 4; ++j) {
        int c = bcol + wc + (j << 4) + fr;
        float bb = bias[c];
        int rem = c - 1536;
        int h = rem >> 6, d = rem & 63;
        #pragma unroll
        for (int i = 0; i < 4; ++i)
            #pragma unroll
            for (int r = 0; r < 4; ++r) {
                int row = brow + wr + (i << 4) + (fg << 2) + r;
                int b = row >> 12, n = row & 4095;
                float val = acc[i][j][r] + bb;
                size_t idx = (((size_t)(b * 12 + h) << 12) + n) * 64 + d;
                vh[idx] = f2bf(val);
            }
    }
}

// ---------------------------------------------------------------------------
// K2: fused flash pass for SC — S: x3 split; PV: P hi-only × V bf16 (2 MFMA/jb).
// Denominator path (wl) stays exact fp32. grid (8 chunks, 44 bh).
// ---------------------------------------------------------------------------
__global__ __launch_bounds__(256) void wflash(
    const unsigned short* __restrict__ qh, const unsigned short* __restrict__ ql,
    const unsigned short* __restrict__ khg, const unsigned short* __restrict__ klg,
    const unsigned short* __restrict__ vhg,
    float* __restrict__ wacc, float* __restrict__ wl, float* __restrict__ wm)
{
    int chunk = blockIdx.x;
    int bh = blockIdx.y;
    int b = bh / 11, h = bh - b * 11;
    size_t base = ((size_t)(b * 12 + h)) << 12;
    __shared__ unsigned short kh_s[64][72], kl_s[64][72];
    __shared__ unsigned short vth[64][72];
    __shared__ unsigned short ph[4][16][72];
    int tid = threadIdx.x;
    int wv = tid >> 6, ln = tid & 63;
    int rr = tid >> 2, dg = (tid & 3) << 4;
    const int arow = (wv << 4) + (ln & 15);
    const int ak0 = (ln >> 4) << 3;
    const int rg = (ln >> 4) << 2;
    short8 aqh0, aql0, aqh1, aql1;
    {
        size_t off = ((base + ((size_t)arow << 6)) << 6) + ak0;
        aqh0 = *(const short8*)(qh + off);
        aqh1 = *(const short8*)(qh + off + 32);
        aql0 = *(const short8*)(ql + off);
        aql1 = *(const short8*)(ql + off + 32);
    }
    f32x4 o_acc[4] = {};
    float mr[4] = {-1e30f, -1e30f, -1e30f, -1e30f};
    float lr[4] = {};
    for (int t = 0; t < 8; ++t) {
        int n0 = (chunk << 9) + (t << 6);
        __syncthreads();
        {
            size_t off = ((base + n0 + rr) << 6) + dg;
            *(short8*)&kh_s[rr][dg]     = *(const short8*)(khg + off);
            *(short8*)&kh_s[rr][dg + 8] = *(const short8*)(khg + off + 8);
            *(short8*)&kl_s[rr][dg]     = *(const short8*)(klg + off);
            *(short8*)&kl_s[rr][dg + 8] = *(const short8*)(klg + off + 8);
            short8 v0 = *(const short8*)(vhg + off);
            short8 v1 = *(const short8*)(vhg + off + 8);
            #pragma unroll
            for (int i = 0; i < 8; ++i) {
                vth[dg + i][rr]     = (unsigned short)v0[i];
                vth[dg + 8 + i][rr] = (unsigned short)v1[i];
            }
        }
        __syncthreads();
        f32x4 s_acc[4];
        #pragma unroll
        for (int jb = 0; jb < 4; ++jb) {
            f32x4 z = {};
            const int brow2 = (jb << 4) + (ln & 15);
            short8 bh0 = *(short8*)&kh_s[brow2][ak0];
            short8 bh1 = *(short8*)&kh_s[brow2][ak0 + 32];
            short8 bl0 = *(short8*)&kl_s[brow2][ak0];
            short8 bl1 = *(short8*)&kl_s[brow2][ak0 + 32];
            z = __builtin_amdgcn_mfma_f32_16x16x32_bf16(aqh0, bh0, z, 0, 0, 0);
            z = __builtin_amdgcn_mfma_f32_16x16x32_bf16(aqh0, bl0, z, 0, 0, 0);
            z = __builtin_amdgcn_mfma_f32_16x16x32_bf16(aql0, bh0, z, 0, 0, 0);
            z = __builtin_amdgcn_mfma_f32_16x16x32_bf16(aqh1, bh1, z, 0, 0, 0);
            z = __builtin_amdgcn_mfma_f32_16x16x32_bf16(aqh1, bl1, z, 0, 0, 0);
            z = __builtin_amdgcn_mfma_f32_16x16x32_bf16(aql1, bh1, z, 0, 0, 0);
            s_acc[jb] = z;
        }
        float mx[4];
        #pragma unroll
        for (int r = 0; r < 4; ++r)
            mx[r] = fmaxf(fmaxf(s_acc[0][r], s_acc[1][r]),
                          fmaxf(s_acc[2][r], s_acc[3][r]));
        #pragma unroll
        for (int off2 = 1; off2 < 16; off2 <<= 1)
            #pragma unroll
            for (int r = 0; r < 4; ++r)
                mx[r] = fmaxf(mx[r], __shfl_xor(mx[r], off2, 64));
        float fac[4];
        #pragma unroll
        for (int r = 0; r < 4; ++r) {
            float mn = fmaxf(mr[r], mx[r]);
            fac[r] = expf(mr[r] - mn);
            mr[r] = mn;
        }
        float rs[4] = {};
        #pragma unroll
        for (int jb = 0; jb < 4; ++jb)
            #pragma unroll
            for (int r = 0; r < 4; ++r) {
                float p = expf(s_acc[jb][r] - mr[r]);
                rs[r] += p;
                ph[wv][rg + r][(jb << 4) + (ln & 15)] = f2bf(p);
            }
        #pragma unroll
        for (int off2 = 1; off2 < 16; off2 <<= 1)
            #pragma unroll
            for (int r = 0; r < 4; ++r)
                rs[r] += __shfl_xor(rs[r], off2, 64);
        #pragma unroll
        for (int r = 0; r < 4; ++r) lr[r] = lr[r] * fac[r] + rs[r];
        #pragma unroll
        for (int jb = 0; jb < 4; ++jb)
            #pragma unroll
            for (int r = 0; r < 4; ++r)
                o_acc[jb][r] *= fac[r];
        short8 pah0 = *(short8*)&ph[wv][ln & 15][ak0];
        short8 pah1 = *(short8*)&ph[wv][ln & 15][ak0 + 32];
        #pragma unroll
        for (int jb = 0; jb < 4; ++jb) {
            const int brow2 = (jb << 4) + (ln & 15);
            short8 bv0 = *(short8*)&vth[brow2][ak0];
            short8 bv1 = *(short8*)&vth[brow2][ak0 + 32];
            f32x4 o = o_acc[jb];
            o = __builtin_amdgcn_mfma_f32_16x16x32_bf16(pah0, bv0, o, 0, 0, 0);
            o = __builtin_amdgcn_mfma_f32_16x16x32_bf16(pah1, bv1, o, 0, 0, 0);
            o_acc[jb] = o;
        }
    }
    int cidx = (bh << 3) + chunk;
    #pragma unroll
    for (int jb = 0; jb < 4; ++jb)
        #pragma unroll
        for (int r = 0; r < 4; ++r) {
            int row = (wv << 4) + rg + r, col = (jb << 4) + (ln & 15);
            wacc[((size_t)cidx << 12) + ((size_t)row << 6) + col] = o_acc[jb][r];
        }
    if ((ln & 15) == 0)
        #pragma unroll
        for (int r = 0; r < 4; ++r) {
            int row = (wv << 4) + rg + r;
            wl[cidx * 64 + row] = lr[r];
            wm[cidx * 64 + row] = mr[r];
        }
}

// K2b: merge chunk partials -> Wb (col 64 = ones-column sums) + scm
__global__ __launch_bounds__(256) void wmerge(
    const float* __restrict__ wacc, const float* __restrict__ wl,
    const float* __restrict__ wm,
    float* __restrict__ Wb, float* __restrict__ scm)
{
    int bh = blockIdx.x;
    int tid = threadIdx.x;
    __shared__ float fcs[8][64];
    if (tid < 64) {
        float mx = -1e30f;
        #pragma unroll
        for (int c = 0; c < 8; ++c)
            mx = fmaxf(mx, wm[((bh << 3) + c) * 64 + tid]);
        scm[(bh << 6) + tid] = mx;
        #pragma unroll
        for (int c = 0; c < 8; ++c)
            fcs[c][tid] = expf(wm[((bh << 3) + c) * 64 + tid] - mx);
    }
    __syncthreads();
    for (int e = tid; e < 4096; e += 256) {
        int m = e >> 6, j = e & 63;
        float s = 0.f;
        #pragma unroll
        for (int c = 0; c < 8; ++c)
            s += fcs[c][m] * wacc[((size_t)((bh << 3) + c) << 12) + e];
        Wb[(size_t)bh * 4160 + m * 65 + j] = s;
    }
    if (tid < 64) {
        float s = 0.f;
        #pragma unroll
        for (int c = 0; c < 8; ++c)
            s += fcs[c][tid] * wl[((bh << 3) + c) * 64 + tid];
        Wb[(size_t)bh * 4160 + tid * 65 + 64] = s;
    }
}

// ---------------------------------------------------------------------------
// K3a: eB — fp32 reconstructed from (hi,lo) split arrays
// ---------------------------------------------------------------------------
__global__ __launch_bounds__(256) void eb_kernel(
    const unsigned short* __restrict__ qh, const unsigned short* __restrict__ ql,
    const unsigned short* __restrict__ kh, const unsigned short* __restrict__ kl,
    const float* __restrict__ scm, float* __restrict__ eB)
{
    int bh = blockIdx.x;
    int b = bh / 11, h = bh - b * 11;
    size_t base = ((size_t)(b * 12 + h)) << 12;
    __shared__ float qm[64][65], km[64][65];
    int tid = threadIdx.x;
    for (int e = tid; e < 4096; e += 256) {
        int mm = e >> 6, d = e & 63;
        size_t off = ((base + ((size_t)mm << 6)) << 6) + d;
        qm[mm][d] = b2f(qh[off]) + b2f(ql[off]);
        km[mm][d] = b2f(kh[off]) + b2f(kl[off]);
    }
    __syncthreads();
    int m = tid >> 2, l0 = tid & 3;
    float smax = scm[(bh << 6) + m];
    for (int l = l0; l < 64; l += 4) {
        float s = 0.f;
        #pragma unroll
        for (int d = 0; d < 64; ++d) s += qm[m][d] * km[l][d];
        eB[((size_t)bh << 12) + (m << 6) + l] = expf(fmaxf(s - smax, -88.f));
    }
}

// ---------------------------------------------------------------------------
// K3b: per-head norms
// ---------------------------------------------------------------------------
__global__ __launch_bounds__(256) void norms_kernel(
    const float* __restrict__ eB, float* __restrict__ denom)
{
    int h = blockIdx.x;
    int tid = threadIdx.x;
    int b = tid >> 6, idx = tid & 63;
    int bh = b * 11 + h;
    const float* E = eB + ((size_t)bh << 12);
    float rs = 0.f, cs = 0.f;
    #pragma unroll 4
    for (int l = 0; l < 64; ++l) rs += E[(idx << 6) + l];
    #pragma unroll 4
    for (int m = 0; m < 64; ++m) cs += E[(m << 6) + idx];
    __shared__ float r1[256], r2[256];
    r1[tid] = rs; r2[tid] = cs;
    __syncthreads();
    for (int s = 128; s > 0; s >>= 1) {
        if (tid < s) {
            r1[tid] = fmaxf(r1[tid], r1[tid + s]);
            r2[tid] = fmaxf(r2[tid], r2[tid + s]);
        }
        __syncthreads();
    }
    if (tid == 0) denom[h] = r1[0] * r2[0];
}

// ---------------------------------------------------------------------------
// K3c: pinv via 6 Newton iterations — bf16x3 MFMA matmuls, one block per bh.
// ---------------------------------------------------------------------------
__device__ __forceinline__ void mm64x3(
    const unsigned short (&Ahi)[64][72], const unsigned short (&Alo)[64][72],
    const unsigned short (&BThi)[64][72], const unsigned short (&BTlo)[64][72],
    int wr, int wc, int fr, int fk, f32x4 (&acc)[2][2])
{
    #pragma unroll
    for (int ks = 0; ks < 2; ++ks) {
        const int kb = (ks << 5) + fk;
        short8 ah[2], al[2], bh[2], bl[2];
        #pragma unroll
        for (int i = 0; i < 2; ++i) {
            ah[i] = *(const short8*)&Ahi[wr + (i << 4) + fr][kb];
            al[i] = *(const short8*)&Alo[wr + (i << 4) + fr][kb];
            bh[i] = *(const short8*)&BThi[wc + (i << 4) + fr][kb];
            bl[i] = *(const short8*)&BTlo[wc + (i << 4) + fr][kb];
        }
        #pragma unroll
        for (int i = 0; i < 2; ++i)
            #pragma unroll
            for (int j = 0; j < 2; ++j) {
                acc[i][j] = __builtin_amdgcn_mfma_f32_16x16x32_bf16(ah[i], bh[j], acc[i][j], 0, 0, 0);
                acc[i][j] = __builtin_amdgcn_mfma_f32_16x16x32_bf16(ah[i], bl[j], acc[i][j], 0, 0, 0);
                acc[i][j] = __builtin_amdgcn_mfma_f32_16x16x32_bf16(al[i], bh[j], acc[i][j], 0, 0, 0);
            }
    }
}

__global__ __launch_bounds__(256) void pinv_kernel(
    const float* __restrict__ eB, const float* __restrict__ denom,
    float* __restrict__ pi_)
{
    __shared__ unsigned short Xh[64][72],  Xl[64][72];
    __shared__ unsigned short Zh[64][72],  Zl[64][72];
    __shared__ unsigned short ZTh[64][72], ZTl[64][72];
    __shared__ unsigned short Mh[64][72],  Ml[64][72];
    __shared__ unsigned short MTh[64][72], MTl[64][72];
    __shared__ unsigned short Th[64][72],  Tbl[64][72];
    __shared__ float Zf[64][68];
    int bh = blockIdx.x;
    int h = bh % 11;
    int tid = threadIdx.x;
    float dn = denom[h];
    const int ln = tid & 63, wv = tid >> 6;
    const int wr = (wv >> 1) << 5, wc = (wv & 1) << 5;
    const int fr = ln & 15, fk = (ln >> 4) << 3;
    const int rg = (ln >> 4) << 2;

    for (int e = tid; e < 4096; e += 256) {
        int m = e >> 6, l = e & 63;
        float xv = eB[((size_t)bh << 12) + e];
        unsigned short hh, ll;
        bfsplit(xv, hh, ll);
        Xh[m][l] = hh; Xl[m][l] = ll;
        float zv = xv / dn;
        Zf[l][m] = zv;
        bfsplit(zv, hh, ll);
        Zh[l][m] = hh; Zl[l][m] = ll;
        ZTh[m][l] = hh; ZTl[m][l] = ll;
    }
    __syncthreads();

    for (int it = 0; it < 6; ++it) {
        f32x4 mm1[2][2] = {};
        mm64x3(Xh, Xl, ZTh, ZTl, wr, wc, fr, fk, mm1);
        #pragma unroll
        for (int i = 0; i < 2; ++i)
            #pragma unroll
            for (int j = 0; j < 2; ++j)
                #pragma unroll
                for (int r = 0; r < 4; ++r) {
                    int row = wr + (i << 4) + rg + r, col = wc + (j << 4) + fr;
                    unsigned short hh, ll;
                    bfsplit(mm1[i][j][r], hh, ll);
                    Mh[row][col] = hh;  Ml[row][col] = ll;
                    MTh[col][row] = hh; MTl[col][row] = ll;
                }
        __syncthreads();
        f32x4 a2[2][2] = {};
        mm64x3(Mh, Ml, MTh, MTl, wr, wc, fr, fk, a2);
        #pragma unroll
        for (int i = 0; i < 2; ++i)
            #pragma unroll
            for (int j = 0; j < 2; ++j)
                #pragma unroll
                for (int r = 0; r < 4; ++r) {
                    int row = wr + (i << 4) + rg + r, col = wc + (j << 4) + fr;
                    float val = 7.f * mm1[i][j][r] - a2[i][j][r];
                    unsigned short hh, ll;
                    bfsplit(val, hh, ll);
                    Th[col][row] = hh; Tbl[col][row] = ll;
                }
        __syncthreads();
        f32x4 a3[2][2] = {};
        mm64x3(Mh, Ml, Th, Tbl, wr, wc, fr, fk, a3);
        __syncthreads();
        #pragma unroll
        for (int i = 0; i < 2; ++i)
            #pragma unroll
            for (int j = 0; j < 2; ++j)
                #pragma unroll
                for (int r = 0; r < 4; ++r) {
                    int row = wr + (i << 4) + rg + r, col = wc + (j << 4) + fr;
                    float val = 15.f * mm1[i][j][r] - a3[i][j][r];
                    unsigned short hh, ll;
                    bfsplit(val, hh, ll);
                    Th[col][row] = hh; Tbl[col][row] = ll;
                }
        __syncthreads();
        f32x4 a4[2][2] = {};
        mm64x3(Zh, Zl, Th, Tbl, wr, wc, fr, fk, a4);
        float zn[2][2][4];
        #pragma unroll
        for (int i = 0; i < 2; ++i)
            #pragma unroll
            for (int j = 0; j < 2; ++j)
                #pragma unroll
                for (int r = 0; r < 4; ++r) {
                    int row = wr + (i << 4) + rg + r, col = wc + (j << 4) + fr;
                    zn[i][j][r] = 0.25f * (13.f * Zf[row][col] - a4[i][j][r]);
                }
        __syncthreads();
        #pragma unroll
        for (int i = 0; i < 2; ++i)
            #pragma unroll
            for (int j = 0; j < 2; ++j)
                #pragma unroll
                for (int r = 0; r < 4; ++r) {
                    int row = wr + (i << 4) + rg + r, col = wc + (j << 4) + fr;
                    float val = zn[i][j][r];
                    Zf[row][col] = val;
                    unsigned short hh, ll;
                    bfsplit(val, hh, ll);
                    Zh[row][col] = hh;  Zl[row][col] = ll;
                    ZTh[col][row] = hh; ZTl[col][row] = ll;
                }
        __syncthreads();
    }
    for (int e = tid; e < 4096; e += 256)
        pi_[((size_t)bh << 12) + e] = Zf[e >> 6][e & 63];
}

// ---------------------------------------------------------------------------
// K5: T = pi @ W  (64x64 @ 64x65)
// ---------------------------------------------------------------------------
__global__ __launch_bounds__(256) void pw_kernel(
    const float* __restrict__ pi_, const float* __restrict__ Wb,
    float* __restrict__ Tb)
{
    int bh = blockIdx.x;
    __shared__ float P[64][65];
    __shared__ float Wl[64][66];
    int tid = threadIdx.x;
    for (int e = tid; e < 4096; e += 256)
        P[e >> 6][e & 63] = pi_[((size_t)bh << 12) + e];
    for (int e = tid; e < 64 * 65; e += 256) {
        int l = e / 65, j = e - l * 65;
        Wl[l][j] = Wb[(size_t)bh * 4160 + e];
    }
    __syncthreads();
    int m = tid & 63, g = tid >> 6;
    #pragma unroll
    for (int t = 0; t < 17; ++t) {
        int j = g + (t << 2);
        if (j > 64) break;
        float s = 0.f;
        #pragma unroll
        for (int l = 0; l < 64; ++l) s += P[m][l] * Wl[l][j];
        Tb[(size_t)((bh << 6) + m) * 65 + j] = s;
    }
}

// ---------------------------------------------------------------------------
// K6: out_p — S x3; eA hi-only × T hi/lo (4 MFMA/jb); den exact fp32; ctx bf16
// ---------------------------------------------------------------------------
__global__ __launch_bounds__(256) void outp_kernel(
    const unsigned short* __restrict__ qh, const unsigned short* __restrict__ ql,
    const unsigned short* __restrict__ khg, const unsigned short* __restrict__ klg,
    const float* __restrict__ Tb, unsigned short* __restrict__ ctxh)
{
    int bh = blockIdx.y;
    int b = bh / 11, h = bh - b * 11;
    int n0 = blockIdx.x << 6;
    size_t base = ((size_t)(b * 12 + h)) << 12;
    __shared__ unsigned short kmh[64][72], kml[64][72];
    __shared__ unsigned short tth[64][72], ttl[64][72];
    __shared__ unsigned short ph[4][16][72];
    __shared__ float t64[64];
    int tid = threadIdx.x;
    int wv = tid >> 6, ln = tid & 63;
    int rr = tid >> 2, dg = (tid & 3) << 4;
    const int arow = (wv << 4) + (ln & 15);
    const int ak0 = (ln >> 4) << 3;
    const int rg = (ln >> 4) << 2;
    {
        size_t off = ((base + ((size_t)rr << 6)) << 6) + dg;
        *(short8*)&kmh[rr][dg]     = *(const short8*)(khg + off);
        *(short8*)&kmh[rr][dg + 8] = *(const short8*)(khg + off + 8);
        *(short8*)&kml[rr][dg]     = *(const short8*)(klg + off);
        *(short8*)&kml[rr][dg + 8] = *(const short8*)(klg + off + 8);
    }
    for (int e = tid; e < 4096; e += 256) {
        int m = e >> 6, j = e & 63;
        float tv = Tb[(size_t)((bh << 6) + m) * 65 + j];
        unsigned short hh, ll;
        bfsplit(tv, hh, ll);
        tth[j][m] = hh; ttl[j][m] = ll;
    }
    if (tid < 64) t64[tid] = Tb[(size_t)((bh << 6) + tid) * 65 + 64];
    short8 aqh0, aql0, aqh1, aql1;
    {
        size_t off = ((base + n0 + arow) << 6) + ak0;
        aqh0 = *(const short8*)(qh + off);
        aqh1 = *(const short8*)(qh + off + 32);
        aql0 = *(const short8*)(ql + off);
        aql1 = *(const short8*)(ql + off + 32);
    }
    __syncthreads();
    f32x4 s_acc[4];
    #pragma unroll
    for (int jb = 0; jb < 4; ++jb) {
        f32x4 z = {};
        const int brow2 = (jb << 4) + (ln & 15);
        short8 bh0 = *(short8*)&kmh[brow2][ak0];
        short8 bh1 = *(short8*)&kmh[brow2][ak0 + 32];
        short8 bl0 = *(short8*)&kml[brow2][ak0];
        short8 bl1 = *(short8*)&kml[brow2][ak0 + 32];
        z = __builtin_amdgcn_mfma_f32_16x16x32_bf16(aqh0, bh0, z, 0, 0, 0);
        z = __builtin_amdgcn_mfma_f32_16x16x32_bf16(aqh0, bl0, z, 0, 0, 0);
        z = __builtin_amdgcn_mfma_f32_16x16x32_bf16(aql0, bh0, z, 0, 0, 0);
        z = __builtin_amdgcn_mfma_f32_16x16x32_bf16(aqh1, bh1, z, 0, 0, 0);
        z = __builtin_amdgcn_mfma_f32_16x16x32_bf16(aqh1, bl1, z, 0, 0, 0);
        z = __builtin_amdgcn_mfma_f32_16x16x32_bf16(aql1, bh1, z, 0, 0, 0);
        s_acc[jb] = z;
    }
    float mx[4];
    #pragma unroll
    for (int r = 0; r < 4; ++r)
        mx[r] = fmaxf(fmaxf(s_acc[0][r], s_acc[1][r]),
                      fmaxf(s_acc[2][r], s_acc[3][r]));
    #pragma unroll
    for (int off2 = 1; off2 < 16; off2 <<= 1)
        #pragma unroll
        for (int r = 0; r < 4; ++r)
            mx[r] = fmaxf(mx[r], __shfl_xor(mx[r], off2, 64));
    float den[4] = {};
    #pragma unroll
    for (int jb = 0; jb < 4; ++jb) {
        float tj = t64[(jb << 4) + (ln & 15)];
        #pragma unroll
        for (int r = 0; r < 4; ++r) {
            float p = expf(s_acc[jb][r] - mx[r]);
            den[r] += p * tj;
            ph[wv][rg + r][(jb << 4) + (ln & 15)] = f2bf(p);
        }
    }
    #pragma unroll
    for (int off2 = 1; off2 < 16; off2 <<= 1)
        #pragma unroll
        for (int r = 0; r < 4; ++r)
            den[r] += __shfl_xor(den[r], off2, 64);
    short8 pah0 = *(short8*)&ph[wv][ln & 15][ak0];
    short8 pah1 = *(short8*)&ph[wv][ln & 15][ak0 + 32];
    f32x4 o_acc[4] = {};
    #pragma unroll
    for (int jb = 0; jb < 4; ++jb) {
        const int brow2 = (jb << 4) + (ln & 15);
        short8 bth0 = *(short8*)&tth[brow2][ak0];
        short8 bth1 = *(short8*)&tth[brow2][ak0 + 32];
        short8 btl0 = *(short8*)&ttl[brow2][ak0];
        short8 btl1 = *(short8*)&ttl[brow2][ak0 + 32];
        f32x4 o = o_acc[jb];
        o = __builtin_amdgcn_mfma_f32_16x16x32_bf16(pah0, bth0, o, 0, 0, 0);
        o = __builtin_amdgcn_mfma_f32_16x16x32_bf16(pah0, btl0, o, 0, 0, 0);
        o = __builtin_amdgcn_mfma_f32_16x16x32_bf16(pah1, bth1, o, 0, 0, 0);
        o = __builtin_amdgcn_mfma_f32_16x16x32_bf16(pah1, btl1, o, 0, 0, 0);
        o_acc[jb] = o;
    }
    float inv[4];
    #pragma unroll
    for (int r = 0; r < 4; ++r) inv[r] = 1.0f / fmaxf(den[r], 1e-8f);
    #pragma unroll
    for (int jb = 0; jb < 4; ++jb)
        #pragma unroll
        for (int r = 0; r < 4; ++r) {
            int row = n0 + (wv << 4) + rg + r;
            int col = (jb << 4) + (ln & 15);
            ctxh[((size_t)b * 4096 + row) * 768 + h * 64 + col] =
                f2bf(o_acc[jb][r] * inv[r]);
        }
}

// ---------------------------------------------------------------------------
// K7a: softmax head (h=11) flash partial over a 1024-KV chunk. grid (64,4,4).
// ---------------------------------------------------------------------------
__global__ __launch_bounds__(256) void flash_part(
    const unsigned short* __restrict__ qhg, const unsigned short* __restrict__ khg,
    const unsigned short* __restrict__ vhg,
    float* __restrict__ pacc, float* __restrict__ pm, float* __restrict__ pl)
{
    int bx = blockIdx.x, cy = blockIdx.y, b = blockIdx.z;
    int n0 = bx << 6;
    size_t base = ((size_t)(b * 12 + 11)) << 12;
    __shared__ unsigned short qs[64][72];
    __shared__ unsigned short ks[64][72];
    __shared__ unsigned short vts[64][72];
    __shared__ unsigned short ps[4][16][72];
    int tid = threadIdx.x;
    int wv = tid >> 6, ln = tid & 63;
    int rr = tid >> 2, dg = (tid & 3) << 4;
    {
        size_t off = ((base + n0 + rr) << 6) + dg;
        *(short8*)&qs[rr][dg]     = *(const short8*)(qhg + off);
        *(short8*)&qs[rr][dg + 8] = *(const short8*)(qhg + off + 8);
    }
    __syncthreads();
    const int arow = (wv << 4) + (ln & 15);
    const int ak0 = (ln >> 4) << 3;
    const int rg = (ln >> 4) << 2;
    short8 aq0 = *(short8*)&qs[arow][ak0];
    short8 aq1 = *(short8*)&qs[arow][ak0 + 32];
    f32x4 o_acc[4] = {};
    float mr[4] = {-1e30f, -1e30f, -1e30f, -1e30f};
    float lr[4] = {};
    for (int t = 0; t < 16; ++t) {
        int m0 = (cy << 10) + (t << 6);
        __syncthreads();
        {
            size_t off = ((base + m0 + rr) << 6) + dg;
            *(short8*)&ks[rr][dg]     = *(const short8*)(khg + off);
            *(short8*)&ks[rr][dg + 8] = *(const short8*)(khg + off + 8);
            short8 v0 = *(const short8*)(vhg + off);
            short8 v1 = *(const short8*)(vhg + off + 8);
            #pragma unroll
            for (int i = 0; i < 8; ++i) {
                vts[dg + i][rr]     = (unsigned short)v0[i];
                vts[dg + 8 + i][rr] = (unsigned short)v1[i];
            }
        }
        __syncthreads();
        f32x4 s_acc[4];
        #pragma unroll
        for (int jb = 0; jb < 4; ++jb) {
            f32x4 z = {};
            short8 bk0 = *(short8*)&ks[(jb << 4) + (ln & 15)][ak0];
            short8 bk1 = *(short8*)&ks[(jb << 4) + (ln & 15)][ak0 + 32];
            z = __builtin_amdgcn_mfma_f32_16x16x32_bf16(aq0, bk0, z, 0, 0, 0);
            z = __builtin_amdgcn_mfma_f32_16x16x32_bf16(aq1, bk1, z, 0, 0, 0);
            s_acc[jb] = z;
        }
        float mx[4];
        #pragma unroll
        for (int r = 0; r < 4; ++r)
            mx[r] = fmaxf(fmaxf(s_acc[0][r], s_acc[1][r]),
                          fmaxf(s_acc[2][r], s_acc[3][r]));
        #pragma unroll
        for (int off2 = 1; off2 < 16; off2 <<= 1)
            #pragma unroll
            for (int r = 0; r < 4; ++r)
                mx[r] = fmaxf(mx[r], __shfl_xor(mx[r], off2, 64));
        float fac[4];
        #pragma unroll
        for (int r = 0; r < 4; ++r) {
            float mn = fmaxf(mr[r], mx[r]);
            fac[r] = expf(mr[r] - mn);
            mr[r] = mn;
        }
        float rs[4] = {};
        #pragma unroll
        for (int jb = 0; jb < 4; ++jb)
            #pragma unroll
            for (int r = 0; r < 4; ++r) {
                float p = expf(s_acc[jb][r] - mr[r]);
                rs[r] += p;
                ps[wv][rg + r][(jb << 4) + (ln & 15)] = f2bf(p);
            }
        #pragma unroll
        for (int off2 = 1; off2 < 16; off2 <<= 1)
            #pragma unroll
            for (int r = 0; r < 4; ++r)
                rs[r] += __shfl_xor(rs[r], off2, 64);
        #pragma unroll
        for (int r = 0; r < 4; ++r) lr[r] = lr[r] * fac[r] + rs[r];
        #pragma unroll
        for (int jb = 0; jb < 4; ++jb)
            #pragma unroll
            for (int r = 0; r < 4; ++r)
                o_acc[jb][r] *= fac[r];
        short8 pa0 = *(short8*)&ps[wv][ln & 15][ak0];
        short8 pa1 = *(short8*)&ps[wv][ln & 15][ak0 + 32];
        #pragma unroll
        for (int jb = 0; jb < 4; ++jb) {
            short8 bv0 = *(short8*)&vts[(jb << 4) + (ln & 15)][ak0];
            short8 bv1 = *(short8*)&vts[(jb << 4) + (ln & 15)][ak0 + 32];
            f32x4 z = o_acc[jb];
            z = __builtin_amdgcn_mfma_f32_16x16x32_bf16(pa0, bv0, z, 0, 0, 0);
            z = __builtin_amdgcn_mfma_f32_16x16x32_bf16(pa1, bv1, z, 0, 0, 0);
            o_acc[jb] = z;
        }
    }
    int slot = (b * 4 + cy) * 64 + bx;
    #pragma unroll
    for (int jb = 0; jb < 4; ++jb)
        #pragma unroll
        for (int r = 0; r < 4; ++r) {
            int row = (wv << 4) + rg + r, col = (jb << 4) + (ln & 15);
            pacc[(size_t)slot * 4096 + (size_t)row * 64 + col] = o_acc[jb][r];
        }
    if ((ln & 15) == 0)
        #pragma unroll
        for (int r = 0; r < 4; ++r) {
            int row = (wv << 4) + rg + r;
            pm[(size_t)slot * 64 + row] = mr[r];
            pl[(size_t)slot * 64 + row] = lr[r];
        }
}

// K7b: merge 4 chunk partials -> ctx head 11 (bf16)
__global__ __launch_bounds__(256) void flash_merge(
    const float* __restrict__ pacc, const float* __restrict__ pm,
    const float* __restrict__ pl, unsigned short* __restrict__ ctxh)
{
    int bx = blockIdx.x, b = blockIdx.y;
    int tid = threadIdx.x, r = tid & 63, g = tid >> 6;
    float mc[4], mt = -1e30f;
    #pragma unroll
    for (int c = 0; c < 4; ++c) {
        mc[c] = pm[(size_t)((b * 4 + c) * 64 + bx) * 64 + r];
        mt = fmaxf(mt, mc[c]);
    }
    float fac[4], lt = 0.f;
    #pragma unroll
    for (int c = 0; c < 4; ++c) {
        fac[c] = expf(mc[c] - mt);
        lt += fac[c] * pl[(size_t)((b * 4 + c) * 64 + bx) * 64 + r];
    }
    float inv = 1.0f / lt;
    size_t obase = ((size_t)b * 4096 + (size_t)((bx << 6) + r)) * 768 + 11 * 64 + (g << 4);
    #pragma unroll
    for (int i = 0; i < 16; ++i) {
        float s = 0.f;
        #pragma unroll
        for (int c = 0; c < 4; ++c)
            s += fac[c] * pacc[(size_t)((b * 4 + c) * 64 + bx) * 4096 + (size_t)r * 64 + (g << 4) + i];
        ctxh[obase + i] = f2bf(s * inv);
    }
}

// ---------------------------------------------------------------------------
// K8: proj GEMM — plain bf16 MFMA, BK=64, swizzled LDS, XCD swizzle.
// ---------------------------------------------------------------------------
__global__ __launch_bounds__(256, 2) void gemm_proj_mfma(
    const unsigned short* __restrict__ Xh, const unsigned short* __restrict__ Wh,
    const float* __restrict__ bias, float* __restrict__ out)
{
    __shared__ unsigned short Ah[8192], Bh[8192];   // [128][64] swizzled
    const int tid = threadIdx.x;
    const int bid = blockIdx.x;                  // nwg=768 (%8==0)
    const int swz = (bid & 7) * 96 + (bid >> 3);
    const int brow = (swz / 6) << 7, bcol = (swz % 6) << 7;
    const int ln = tid & 63, wv = tid >> 6;
    const int wr = (wv >> 1) << 6, wc = (wv & 1) << 6;
    const int srow = tid >> 1;
    const int c0 = (tid & 1) << 2;
    const size_t ag = (size_t)(brow + srow) * 768;
    const size_t bg = (size_t)(bcol + srow) * 768;
    const int fr = ln & 15, fc = ln >> 4;

    f32x4 acc[4][4] = {};
    for (int k0 = 0; k0 < 768; k0 += 64) {
        short8 xa[4], wb[4];
        #pragma unroll
        for (int cc = 0; cc < 4; ++cc) {
            xa[cc] = *(const short8*)(Xh + ag + k0 + ((c0 + cc) << 3));
            wb[cc] = *(const short8*)(Wh + bg + k0 + ((c0 + cc) << 3));
        }
        __syncthreads();
        #pragma unroll
        for (int cc = 0; cc < 4; ++cc) {
            int dst = srow * 64 + (((c0 + cc) ^ (srow & 7)) << 3);
            *(short8*)&Ah[dst] = xa[cc];
            *(short8*)&Bh[dst] = wb[cc];
        }
        __syncthreads();
        #pragma unroll
        for (int ks = 0; ks < 2; ++ks) {
            const int kc = (ks << 2) + fc;
            short8 ah[4], bh[4];
            #pragma unroll
            for (int i = 0; i < 4; ++i) {
                int ar = wr + (i << 4) + fr;
                ah[i] = *(short8*)&Ah[ar * 64 + ((kc ^ (ar & 7)) << 3)];
                int br2 = wc + (i << 4) + fr;
                bh[i] = *(short8*)&Bh[br2 * 64 + ((kc ^ (br2 & 7)) << 3)];
            }
            #pragma unroll
            for (int i = 0; i < 4; ++i)
                #pragma unroll
                for (int j = 0; j < 4; ++j)
                    acc[i][j] = __builtin_amdgcn_mfma_f32_16x16x32_bf16(ah[i], bh[j], acc[i][j], 0, 0, 0);
        }
    }
    const int fg = ln >> 4;
    #pragma unroll
    for (int j = 0; j < 4; ++j) {
        int c = bcol + wc + (j << 4) + fr;
        float bb = bias[c];
        #pragma unroll
        for (int i = 0; i < 4; ++i)
            #pragma unroll
            for (int r = 0; r < 4; ++r) {
                int row = brow + wr + (i << 4) + (fg << 2) + r;
                out[(size_t)row * 768 + c] = acc[i][j][r] + bb;
            }
    }
}

// ---------------------------------------------------------------------------
extern "C" void kernel_launch(void* const* d_in, const int* in_sizes, int n_in,
                              void* d_out, int out_size, void* d_ws, size_t ws_size,
                              hipStream_t stream)
{
    const float* x      = (const float*)d_in[0];
    const float* qkv_w  = (const float*)d_in[1];
    const float* qkv_b  = (const float*)d_in[2];
    const float* proj_w = (const float*)d_in[3];
    const float* proj_b = (const float*)d_in[4];
    float* out = (float*)d_out;

    const size_t QKV = (size_t)4 * 12 * 4096 * 64;   // 12,582,912
    unsigned short* qh = (unsigned short*)d_ws;
    unsigned short* ql = qh + QKV;
    unsigned short* kh = ql + QKV;
    unsigned short* kl = kh + QKV;
    unsigned short* vh = kl + QKV;
    unsigned short* ctxh = vh + QKV;
    float* scm  = (float*)(ctxh + QKV);
    float* eB   = scm + 4096;
    float* den  = eB + 44 * 4096;
    float* pi_  = den + 64;
    float* Wb   = pi_ + 44 * 4096;
    float* Tb   = Wb + 44 * 4160;
    unsigned short* Whi  = (unsigned short*)(Tb + 44 * 4160);
    unsigned short* Wlo  = Whi + (size_t)2304 * 768;
    unsigned short* Pwhi = Wlo + (size_t)2304 * 768;
    unsigned short* Pwlo = Pwhi + (size_t)768 * 768;   // written, unused

    unsigned short* Xhi = (unsigned short*)out;
    unsigned short* Xlo = Xhi + QKV;
    float* wacc = out;                    // 1,441,792
    float* wl   = wacc + 1441792;         // 22,528
    float* wm   = wl + 22528;             // 22,528
    float* fpacc = out;                   // 4,194,304 (after wmerge)
    float* fpm   = fpacc + 4194304;       // 65,536
    float* fpl   = fpm + 65536;           // 65,536

    preconv3<<<2048, 256, 0, stream>>>(x, qkv_w, proj_w,
                                       Xhi, Xlo, Whi, Wlo, Pwhi, Pwlo);
    gemm_qk_mfma<<<1536, 256, 0, stream>>>(Xhi, Xlo, Whi, Wlo, qkv_b,
                                           qh, ql, kh, kl);
    gemm_v_mfma<<<768, 256, 0, stream>>>(Xhi, Whi, qkv_b, vh);
    wflash<<<dim3(8, 44), 256, 0, stream>>>(qh, ql, kh, kl, vh, wacc, wl, wm);
    wmerge<<<44, 256, 0, stream>>>(wacc, wl, wm, Wb, scm);
    eb_kernel<<<44, 256, 0, stream>>>(qh, ql, kh, kl, scm, eB);
    norms_kernel<<<11, 256, 0, stream>>>(eB, den);
    pinv_kernel<<<44, 256, 0, stream>>>(eB, den, pi_);
    pw_kernel<<<44, 256, 0, stream>>>(pi_, Wb, Tb);
    outp_kernel<<<dim3(64, 44), 256, 0, stream>>>(qh, ql, kh, kl, Tb, ctxh);
    flash_part<<<dim3(64, 4, 4), 256, 0, stream>>>(qh, kh, vh, fpacc, fpm, fpl);
    flash_merge<<<dim3(64, 4), 256, 0, stream>>>(fpacc, fpm, fpl, ctxh);
    gemm_proj_mfma<<<768, 256, 0, stream>>>(ctxh, Pwhi, proj_b, out);
}

// Round 11
// 409.496 us; speedup vs baseline: 14.9750x; 1.0668x over previous
//
#include <hip/hip_runtime.h>

// B=4, N=4096, C=768, H=12, D=64, M=64, PNP=11, SCALE=1/8

typedef __attribute__((ext_vector_type(8))) short short8;
typedef __attribute__((ext_vector_type(4))) float f32x4;
typedef __attribute__((ext_vector_type(4))) unsigned short ushort4v;

static __device__ __forceinline__ unsigned short f2bf(float f) {
    union { float f; unsigned u; } x; x.f = f;
    unsigned r = x.u + 0x7fffu + ((x.u >> 16) & 1u);   // RNE
    return (unsigned short)(r >> 16);
}

static __device__ __forceinline__ float b2f(unsigned short u) {
    union { unsigned u; float f; } t; t.u = (unsigned)u << 16; return t.f;
}

static __device__ __forceinline__ void bfsplit(float x, unsigned short& h, unsigned short& l) {
    unsigned short hh = f2bf(x);
    union { unsigned u; float f; } t; t.u = (unsigned)hh << 16;
    h = hh;
    l = f2bf(x - t.f);    // exact residual, RNE to bf16
}

// ---------------------------------------------------------------------------
// K0: split 3 fp32 arrays into bf16 (hi,lo) pairs, one fused launch.
// ---------------------------------------------------------------------------
__global__ __launch_bounds__(256) void preconv3(
    const float* __restrict__ a, const float* __restrict__ b,
    const float* __restrict__ c,
    unsigned short* __restrict__ ahi, unsigned short* __restrict__ alo,
    unsigned short* __restrict__ bhi, unsigned short* __restrict__ blo,
    unsigned short* __restrict__ chi, unsigned short* __restrict__ clo)
{
    const int nA = 3145728, nB = 442368, nC = 147456;
    const int total = nA + nB + nC;
    for (int i = blockIdx.x * 256 + threadIdx.x; i < total; i += gridDim.x * 256) {
        const float* src; unsigned short* hi; unsigned short* lo; int j;
        if (i < nA)           { src = a; hi = ahi; lo = alo; j = i; }
        else if (i < nA + nB) { src = b; hi = bhi; lo = blo; j = i - nA; }
        else                  { src = c; hi = chi; lo = clo; j = i - nA - nB; }
        float4 f = *(const float4*)(src + (size_t)j * 4);
        float vs[4] = {f.x, f.y, f.z, f.w};
        ushort4v h, l;
        #pragma unroll
        for (int t = 0; t < 4; ++t) {
            unsigned short hh, ll;
            bfsplit(vs[t], hh, ll);
            h[t] = hh; l[t] = ll;
        }
        *(ushort4v*)(hi + (size_t)j * 4) = h;
        *(ushort4v*)(lo + (size_t)j * 4) = l;
    }
}

// ---------------------------------------------------------------------------
// K1: combined QKV GEMM. blocks [0,1536): qk via bf16x3; [1536,2304): v bf16.
// Top-level disjoint bodies -> regalloc takes max, not sum (R8 lesson).
// ---------------------------------------------------------------------------
__global__ __launch_bounds__(256, 2) void gemm_qkv2(
    const unsigned short* __restrict__ Xh, const unsigned short* __restrict__ Xl,
    const unsigned short* __restrict__ Wh, const unsigned short* __restrict__ Wl,
    const float* __restrict__ bias,
    unsigned short* __restrict__ qh, unsigned short* __restrict__ ql,
    unsigned short* __restrict__ kh, unsigned short* __restrict__ kl,
    unsigned short* __restrict__ vh)
{
    __shared__ unsigned short smem[16384];   // 32 KB
    const int tid = threadIdx.x;
    const int ln = tid & 63, wv = tid >> 6;
    const int wr = (wv >> 1) << 6, wc = (wv & 1) << 6;
    const int fr = ln & 15, fc = ln >> 4;
    const int fg = ln >> 4;

    if (blockIdx.x < 1536) {
        // ----- qk body (bf16x3, BK=32) -----
        unsigned short* Ah = smem;
        unsigned short* Al = smem + 4096;
        unsigned short* Bh = smem + 8192;
        unsigned short* Bl = smem + 12288;
        const int bid = blockIdx.x;
        const int swz = (bid & 7) * 192 + (bid >> 3);
        const int brow = (swz / 12) << 7, bcol = (swz % 12) << 7;
        const int srow = tid >> 1, sc = (tid & 1) << 1;
        const size_t ag = (size_t)(brow + srow) * 768 + (sc << 3);
        const size_t bg = (size_t)(bcol + srow) * 768 + (sc << 3);
        const int i0 = srow * 32 + (((sc + 0) ^ (srow & 3)) << 3);
        const int i1 = srow * 32 + (((sc + 1) ^ (srow & 3)) << 3);

        f32x4 acc[4][4] = {};
        for (int k0 = 0; k0 < 768; k0 += 32) {
            short8 xh0 = *(const short8*)(Xh + ag + k0);
            short8 xh1 = *(const short8*)(Xh + ag + k0 + 8);
            short8 xl0 = *(const short8*)(Xl + ag + k0);
            short8 xl1 = *(const short8*)(Xl + ag + k0 + 8);
            short8 wh0 = *(const short8*)(Wh + bg + k0);
            short8 wh1 = *(const short8*)(Wh + bg + k0 + 8);
            short8 wl0 = *(const short8*)(Wl + bg + k0);
            short8 wl1 = *(const short8*)(Wl + bg + k0 + 8);
            __syncthreads();
            *(short8*)&Ah[i0] = xh0; *(short8*)&Ah[i1] = xh1;
            *(short8*)&Al[i0] = xl0; *(short8*)&Al[i1] = xl1;
            *(short8*)&Bh[i0] = wh0; *(short8*)&Bh[i1] = wh1;
            *(short8*)&Bl[i0] = wl0; *(short8*)&Bl[i1] = wl1;
            __syncthreads();
            short8 ah[4], al[4], bh[4], bl[4];
            #pragma unroll
            for (int i = 0; i < 4; ++i) {
                int ar = wr + (i << 4) + fr;
                int aidx = ar * 32 + ((fc ^ (ar & 3)) << 3);
                ah[i] = *(short8*)&Ah[aidx];
                al[i] = *(short8*)&Al[aidx];
                int br2 = wc + (i << 4) + fr;
                int bidx = br2 * 32 + ((fc ^ (br2 & 3)) << 3);
                bh[i] = *(short8*)&Bh[bidx];
                bl[i] = *(short8*)&Bl[bidx];
            }
            #pragma unroll
            for (int i = 0; i < 4; ++i)
                #pragma unroll
                for (int j = 0; j < 4; ++j) {
                    acc[i][j] = __builtin_amdgcn_mfma_f32_16x16x32_bf16(ah[i], bh[j], acc[i][j], 0, 0, 0);
                    acc[i][j] = __builtin_amdgcn_mfma_f32_16x16x32_bf16(ah[i], bl[j], acc[i][j], 0, 0, 0);
                    acc[i][j] = __builtin_amdgcn_mfma_f32_16x16x32_bf16(al[i], bh[j], acc[i][j], 0, 0, 0);
                }
        }
        #pragma unroll
        for (int j = 0; j < 4; ++j) {
            int c = bcol + wc + (j << 4) + fr;
            float bb = bias[c];
            int rem = c - (c >= 768 ? 768 : 0);
            int h = rem >> 6, d = rem & 63;
            #pragma unroll
            for (int i = 0; i < 4; ++i)
                #pragma unroll
                for (int r = 0; r < 4; ++r) {
                    int row = brow + wr + (i << 4) + (fg << 2) + r;
                    int b = row >> 12, n = row & 4095;
                    float val = acc[i][j][r] + bb;
                    size_t idx = (((size_t)(b * 12 + h) << 12) + n) * 64 + d;
                    unsigned short hh, ll;
                    if (c < 768) {
                        bfsplit(val * 0.125f, hh, ll);
                        qh[idx] = hh; ql[idx] = ll;
                    } else {
                        bfsplit(val, hh, ll);
                        kh[idx] = hh; kl[idx] = ll;
                    }
                }
        }
    } else {
        // ----- v body (bf16 x1, BK=64) -----
        unsigned short* Av = smem;            // [128][64]
        unsigned short* Bv = smem + 8192;
        const int bid = blockIdx.x - 1536;    // [0,768), %8 preserved
        const int swz = (bid & 7) * 96 + (bid >> 3);
        const int brow = (swz / 6) << 7, bcol = 1536 + ((swz % 6) << 7);
        const int srow = tid >> 1;
        const int c0 = (tid & 1) << 2;
        const size_t ag = (size_t)(brow + srow) * 768;
        const size_t bg = (size_t)(bcol + srow) * 768;

        f32x4 acc[4][4] = {};
        for (int k0 = 0; k0 < 768; k0 += 64) {
            short8 xa[4], wb[4];
            #pragma unroll
            for (int cc = 0; cc < 4; ++cc) {
                xa[cc] = *(const short8*)(Xh + ag + k0 + ((c0 + cc) << 3));
                wb[cc] = *(const short8*)(Wh + bg + k0 + ((c0 + cc) << 3));
            }
            __syncthreads();
            #pragma unroll
            for (int cc = 0; cc < 4; ++cc) {
                int dst = srow * 64 + (((c0 + cc) ^ (srow & 7)) << 3);
                *(short8*)&Av[dst] = xa[cc];
                *(short8*)&Bv[dst] = wb[cc];
            }
            __syncthreads();
            #pragma unroll
            for (int ks = 0; ks < 2; ++ks) {
                const int kc = (ks << 2) + fc;
                short8 ah[4], bh[4];
                #pragma unroll
                for (int i = 0; i < 4; ++i) {
                    int ar = wr + (i << 4) + fr;
                    ah[i] = *(short8*)&Av[ar * 64 + ((kc ^ (ar & 7)) << 3)];
                    int br2 = wc + (i << 4) + fr;
                    bh[i] = *(short8*)&Bv[br2 * 64 + ((kc ^ (br2 & 7)) << 3)];
                }
                #pragma unroll
                for (int i = 0; i < 4; ++i)
                    #pragma unroll
                    for (int j = 0; j < 4; ++j)
                        acc[i][j] = __builtin_amdgcn_mfma_f32_16x16x32_bf16(ah[i], bh[j], acc[i][j], 0, 0, 0);
            }
        }
        #pragma unroll
        for (int j = 0; j < 4; ++j) {
            int c = bcol + wc + (j << 4) + fr;
            float bb = bias[c];
            int rem = c - 1536;
            int h = rem >> 6, d = rem & 63;
            #pragma unroll
            for (int i = 0; i < 4; ++i)
                #pragma unroll
                for (int r = 0; r < 4; ++r) {
                    int row = brow + wr + (i << 4) + (fg << 2) + r;
                    int b = row >> 12, n = row & 4095;
                    float val = acc[i][j][r] + bb;
                    size_t idx = (((size_t)(b * 12 + h) << 12) + n) * 64 + d;
                    vh[idx] = f2bf(val);
                }
        }
    }
}

// ---------------------------------------------------------------------------
// K2: attn_mega — blocks [0,1024): flash_part (h=11); [1024,1376): wflash.
// Both consume only qh/ql/kh/kl/vh; disjoint top-level bodies, shared LDS.
// ---------------------------------------------------------------------------
__global__ __launch_bounds__(256) void attn_mega(
    const unsigned short* __restrict__ qh, const unsigned short* __restrict__ ql,
    const unsigned short* __restrict__ khg, const unsigned short* __restrict__ klg,
    const unsigned short* __restrict__ vhg,
    float* __restrict__ wacc, float* __restrict__ wl, float* __restrict__ wm,
    float* __restrict__ pacc, float* __restrict__ pm, float* __restrict__ pl)
{
    __shared__ unsigned short kh_s[64][72], kl_s[64][72];
    __shared__ unsigned short vth[64][72];
    __shared__ unsigned short ph[4][16][72];
    int tid = threadIdx.x;
    int wv = tid >> 6, ln = tid & 63;
    int rr = tid >> 2, dg = (tid & 3) << 4;
    const int arow = (wv << 4) + (ln & 15);
    const int ak0 = (ln >> 4) << 3;
    const int rg = (ln >> 4) << 2;

    if (blockIdx.x < 1024) {
        // ----- flash_part body (qs=kh_s, ks=kl_s, vts=vth, ps=ph) -----
        int fbid = blockIdx.x;
        int bx = fbid & 63, cy = (fbid >> 6) & 3, b = fbid >> 8;
        int n0 = bx << 6;
        size_t base = ((size_t)(b * 12 + 11)) << 12;
        {
            size_t off = ((base + n0 + rr) << 6) + dg;
            *(short8*)&kh_s[rr][dg]     = *(const short8*)(qh + off);
            *(short8*)&kh_s[rr][dg + 8] = *(const short8*)(qh + off + 8);
        }
        __syncthreads();
        short8 aq0 = *(short8*)&kh_s[arow][ak0];
        short8 aq1 = *(short8*)&kh_s[arow][ak0 + 32];
        f32x4 o_acc[4] = {};
        float mr[4] = {-1e30f, -1e30f, -1e30f, -1e30f};
        float lr[4] = {};
        for (int t = 0; t < 16; ++t) {
            int m0 = (cy << 10) + (t << 6);
            __syncthreads();
            {
                size_t off = ((base + m0 + rr) << 6) + dg;
                *(short8*)&kl_s[rr][dg]     = *(const short8*)(khg + off);
                *(short8*)&kl_s[rr][dg + 8] = *(const short8*)(khg + off + 8);
                short8 v0 = *(const short8*)(vhg + off);
                short8 v1 = *(const short8*)(vhg + off + 8);
                #pragma unroll
                for (int i = 0; i < 8; ++i) {
                    vth[dg + i][rr]     = (unsigned short)v0[i];
                    vth[dg + 8 + i][rr] = (unsigned short)v1[i];
                }
            }
            __syncthreads();
            f32x4 s_acc[4];
            #pragma unroll
            for (int jb = 0; jb < 4; ++jb) {
                f32x4 z = {};
                short8 bk0 = *(short8*)&kl_s[(jb << 4) + (ln & 15)][ak0];
                short8 bk1 = *(short8*)&kl_s[(jb << 4) + (ln & 15)][ak0 + 32];
                z = __builtin_amdgcn_mfma_f32_16x16x32_bf16(aq0, bk0, z, 0, 0, 0);
                z = __builtin_amdgcn_mfma_f32_16x16x32_bf16(aq1, bk1, z, 0, 0, 0);
                s_acc[jb] = z;
            }
            float mx[4];
            #pragma unroll
            for (int r = 0; r < 4; ++r)
                mx[r] = fmaxf(fmaxf(s_acc[0][r], s_acc[1][r]),
                              fmaxf(s_acc[2][r], s_acc[3][r]));
            #pragma unroll
            for (int off2 = 1; off2 < 16; off2 <<= 1)
                #pragma unroll
                for (int r = 0; r < 4; ++r)
                    mx[r] = fmaxf(mx[r], __shfl_xor(mx[r], off2, 64));
            float fac[4];
            #pragma unroll
            for (int r = 0; r < 4; ++r) {
                float mn = fmaxf(mr[r], mx[r]);
                fac[r] = expf(mr[r] - mn);
                mr[r] = mn;
            }
            float rs[4] = {};
            #pragma unroll
            for (int jb = 0; jb < 4; ++jb)
                #pragma unroll
                for (int r = 0; r < 4; ++r) {
                    float p = expf(s_acc[jb][r] - mr[r]);
                    rs[r] += p;
                    ph[wv][rg + r][(jb << 4) + (ln & 15)] = f2bf(p);
                }
            #pragma unroll
            for (int off2 = 1; off2 < 16; off2 <<= 1)
                #pragma unroll
                for (int r = 0; r < 4; ++r)
                    rs[r] += __shfl_xor(rs[r], off2, 64);
            #pragma unroll
            for (int r = 0; r < 4; ++r) lr[r] = lr[r] * fac[r] + rs[r];
            #pragma unroll
            for (int jb = 0; jb < 4; ++jb)
                #pragma unroll
                for (int r = 0; r < 4; ++r)
                    o_acc[jb][r] *= fac[r];
            short8 pa0 = *(short8*)&ph[wv][ln & 15][ak0];
            short8 pa1 = *(short8*)&ph[wv][ln & 15][ak0 + 32];
            #pragma unroll
            for (int jb = 0; jb < 4; ++jb) {
                short8 bv0 = *(short8*)&vth[(jb << 4) + (ln & 15)][ak0];
                short8 bv1 = *(short8*)&vth[(jb << 4) + (ln & 15)][ak0 + 32];
                f32x4 z = o_acc[jb];
                z = __builtin_amdgcn_mfma_f32_16x16x32_bf16(pa0, bv0, z, 0, 0, 0);
                z = __builtin_amdgcn_mfma_f32_16x16x32_bf16(pa1, bv1, z, 0, 0, 0);
                o_acc[jb] = z;
            }
        }
        int slot = (b * 4 + cy) * 64 + bx;
        #pragma unroll
        for (int jb = 0; jb < 4; ++jb)
            #pragma unroll
            for (int r = 0; r < 4; ++r) {
                int row = (wv << 4) + rg + r, col = (jb << 4) + (ln & 15);
                pacc[(size_t)slot * 4096 + (size_t)row * 64 + col] = o_acc[jb][r];
            }
        if ((ln & 15) == 0)
            #pragma unroll
            for (int r = 0; r < 4; ++r) {
                int row = (wv << 4) + rg + r;
                pm[(size_t)slot * 64 + row] = mr[r];
                pl[(size_t)slot * 64 + row] = lr[r];
            }
    } else {
        // ----- wflash body -----
        int wbid = blockIdx.x - 1024;
        int chunk = wbid & 7;
        int bh = wbid >> 3;
        int b = bh / 11, h = bh - b * 11;
        size_t base = ((size_t)(b * 12 + h)) << 12;
        short8 aqh0, aql0, aqh1, aql1;
        {
            size_t off = ((base + ((size_t)arow << 6)) << 6) + ak0;
            aqh0 = *(const short8*)(qh + off);
            aqh1 = *(const short8*)(qh + off + 32);
            aql0 = *(const short8*)(ql + off);
            aql1 = *(const short8*)(ql + off + 32);
        }
        f32x4 o_acc[4] = {};
        float mr[4] = {-1e30f, -1e30f, -1e30f, -1e30f};
        float lr[4] = {};
        for (int t = 0; t < 8; ++t) {
            int n0 = (chunk << 9) + (t << 6);
            __syncthreads();
            {
                size_t off = ((base + n0 + rr) << 6) + dg;
                *(short8*)&kh_s[rr][dg]     = *(const short8*)(khg + off);
                *(short8*)&kh_s[rr][dg + 8] = *(const short8*)(khg + off + 8);
                *(short8*)&kl_s[rr][dg]     = *(const short8*)(klg + off);
                *(short8*)&kl_s[rr][dg + 8] = *(const short8*)(klg + off + 8);
                short8 v0 = *(const short8*)(vhg + off);
                short8 v1 = *(const short8*)(vhg + off + 8);
                #pragma unroll
                for (int i = 0; i < 8; ++i) {
                    vth[dg + i][rr]     = (unsigned short)v0[i];
                    vth[dg + 8 + i][rr] = (unsigned short)v1[i];
                }
            }
            __syncthreads();
            f32x4 s_acc[4];
            #pragma unroll
            for (int jb = 0; jb < 4; ++jb) {
                f32x4 z = {};
                const int brow2 = (jb << 4) + (ln & 15);
                short8 bh0 = *(short8*)&kh_s[brow2][ak0];
                short8 bh1 = *(short8*)&kh_s[brow2][ak0 + 32];
                short8 bl0 = *(short8*)&kl_s[brow2][ak0];
                short8 bl1 = *(short8*)&kl_s[brow2][ak0 + 32];
                z = __builtin_amdgcn_mfma_f32_16x16x32_bf16(aqh0, bh0, z, 0, 0, 0);
                z = __builtin_amdgcn_mfma_f32_16x16x32_bf16(aqh0, bl0, z, 0, 0, 0);
                z = __builtin_amdgcn_mfma_f32_16x16x32_bf16(aql0, bh0, z, 0, 0, 0);
                z = __builtin_amdgcn_mfma_f32_16x16x32_bf16(aqh1, bh1, z, 0, 0, 0);
                z = __builtin_amdgcn_mfma_f32_16x16x32_bf16(aqh1, bl1, z, 0, 0, 0);
                z = __builtin_amdgcn_mfma_f32_16x16x32_bf16(aql1, bh1, z, 0, 0, 0);
                s_acc[jb] = z;
            }
            float mx[4];
            #pragma unroll
            for (int r = 0; r < 4; ++r)
                mx[r] = fmaxf(fmaxf(s_acc[0][r], s_acc[1][r]),
                              fmaxf(s_acc[2][r], s_acc[3][r]));
            #pragma unroll
            for (int off2 = 1; off2 < 16; off2 <<= 1)
                #pragma unroll
                for (int r = 0; r < 4; ++r)
                    mx[r] = fmaxf(mx[r], __shfl_xor(mx[r], off2, 64));
            float fac[4];
            #pragma unroll
            for (int r = 0; r < 4; ++r) {
                float mn = fmaxf(mr[r], mx[r]);
                fac[r] = expf(mr[r] - mn);
                mr[r] = mn;
            }
            float rs[4] = {};
            #pragma unroll
            for (int jb = 0; jb < 4; ++jb)
                #pragma unroll
                for (int r = 0; r < 4; ++r) {
                    float p = expf(s_acc[jb][r] - mr[r]);
                    rs[r] += p;
                    ph[wv][rg + r][(jb << 4) + (ln & 15)] = f2bf(p);
                }
            #pragma unroll
            for (int off2 = 1; off2 < 16; off2 <<= 1)
                #pragma unroll
                for (int r = 0; r < 4; ++r)
                    rs[r] += __shfl_xor(rs[r], off2, 64);
            #pragma unroll
            for (int r = 0; r < 4; ++r) lr[r] = lr[r] * fac[r] + rs[r];
            #pragma unroll
            for (int jb = 0; jb < 4; ++jb)
                #pragma unroll
                for (int r = 0; r < 4; ++r)
                    o_acc[jb][r] *= fac[r];
            short8 pah0 = *(short8*)&ph[wv][ln & 15][ak0];
            short8 pah1 = *(short8*)&ph[wv][ln & 15][ak0 + 32];
            #pragma unroll
            for (int jb = 0; jb < 4; ++jb) {
                const int brow2 = (jb << 4) + (ln & 15);
                short8 bv0 = *(short8*)&vth[brow2][ak0];
                short8 bv1 = *(short8*)&vth[brow2][ak0 + 32];
                f32x4 o = o_acc[jb];
                o = __builtin_amdgcn_mfma_f32_16x16x32_bf16(pah0, bv0, o, 0, 0, 0);
                o = __builtin_amdgcn_mfma_f32_16x16x32_bf16(pah1, bv1, o, 0, 0, 0);
                o_acc[jb] = o;
            }
        }
        int cidx = (bh << 3) + chunk;
        #pragma unroll
        for (int jb = 0; jb < 4; ++jb)
            #pragma unroll
            for (int r = 0; r < 4; ++r) {
                int row = (wv << 4) + rg + r, col = (jb << 4) + (ln & 15);
                wacc[((size_t)cidx << 12) + ((size_t)row << 6) + col] = o_acc[jb][r];
            }
        if ((ln & 15) == 0)
            #pragma unroll
            for (int r = 0; r < 4; ++r) {
                int row = (wv << 4) + rg + r;
                wl[cidx * 64 + row] = lr[r];
                wm[cidx * 64 + row] = mr[r];
            }
    }
}

// ---------------------------------------------------------------------------
// K3: fused wmerge + eB. One block per bh. scm lives in LDS only.
// ---------------------------------------------------------------------------
__global__ __launch_bounds__(256) void wmerge_eb(
    const float* __restrict__ wacc, const float* __restrict__ wl,
    const float* __restrict__ wm,
    const unsigned short* __restrict__ qh, const unsigned short* __restrict__ ql,
    const unsigned short* __restrict__ kh, const unsigned short* __restrict__ kl,
    float* __restrict__ Wb, float* __restrict__ eB)
{
    int bh = blockIdx.x;
    int b = bh / 11, h = bh - b * 11;
    size_t base = ((size_t)(b * 12 + h)) << 12;
    int tid = threadIdx.x;
    __shared__ float fcs[8][64];
    __shared__ float scms[64];
    __shared__ float qm[64][65], km[64][65];
    // stage landmark q/k (fp32 reconstructed) for the eB phase
    for (int e = tid; e < 4096; e += 256) {
        int mm = e >> 6, d = e & 63;
        size_t off = ((base + ((size_t)mm << 6)) << 6) + d;
        qm[mm][d] = b2f(qh[off]) + b2f(ql[off]);
        km[mm][d] = b2f(kh[off]) + b2f(kl[off]);
    }
    if (tid < 64) {
        float mx = -1e30f;
        #pragma unroll
        for (int c = 0; c < 8; ++c)
            mx = fmaxf(mx, wm[((bh << 3) + c) * 64 + tid]);
        scms[tid] = mx;
        #pragma unroll
        for (int c = 0; c < 8; ++c)
            fcs[c][tid] = expf(wm[((bh << 3) + c) * 64 + tid] - mx);
    }
    __syncthreads();
    // wmerge phase
    for (int e = tid; e < 4096; e += 256) {
        int m = e >> 6, j = e & 63;
        float s = 0.f;
        #pragma unroll
        for (int c = 0; c < 8; ++c)
            s += fcs[c][m] * wacc[((size_t)((bh << 3) + c) << 12) + e];
        Wb[(size_t)bh * 4160 + m * 65 + j] = s;
    }
    if (tid < 64) {
        float s = 0.f;
        #pragma unroll
        for (int c = 0; c < 8; ++c)
            s += fcs[c][tid] * wl[((bh << 3) + c) * 64 + tid];
        Wb[(size_t)bh * 4160 + tid * 65 + 64] = s;
    }
    // eB phase
    int m = tid >> 2, l0 = tid & 3;
    float smax = scms[m];
    for (int l = l0; l < 64; l += 4) {
        float s = 0.f;
        #pragma unroll
        for (int d = 0; d < 64; ++d) s += qm[m][d] * km[l][d];
        eB[((size_t)bh << 12) + (m << 6) + l] = expf(fmaxf(s - smax, -88.f));
    }
}

// ---------------------------------------------------------------------------
// K3b: per-head norms
// ---------------------------------------------------------------------------
__global__ __launch_bounds__(256) void norms_kernel(
    const float* __restrict__ eB, float* __restrict__ denom)
{
    int h = blockIdx.x;
    int tid = threadIdx.x;
    int b = tid >> 6, idx = tid & 63;
    int bh = b * 11 + h;
    const float* E = eB + ((size_t)bh << 12);
    float rs = 0.f, cs = 0.f;
    #pragma unroll 4
    for (int l = 0; l < 64; ++l) rs += E[(idx << 6) + l];
    #pragma unroll 4
    for (int m = 0; m < 64; ++m) cs += E[(m << 6) + idx];
    __shared__ float r1[256], r2[256];
    r1[tid] = rs; r2[tid] = cs;
    __syncthreads();
    for (int s = 128; s > 0; s >>= 1) {
        if (tid < s) {
            r1[tid] = fmaxf(r1[tid], r1[tid + s]);
            r2[tid] = fmaxf(r2[tid], r2[tid + s]);
        }
        __syncthreads();
    }
    if (tid == 0) denom[h] = r1[0] * r2[0];
}

// ---------------------------------------------------------------------------
// K3c: pinv via 6 Newton iterations — bf16x3 MFMA matmuls, one block per bh.
// ---------------------------------------------------------------------------
__device__ __forceinline__ void mm64x3(
    const unsigned short (&Ahi)[64][72], const unsigned short (&Alo)[64][72],
    const unsigned short (&BThi)[64][72], const unsigned short (&BTlo)[64][72],
    int wr, int wc, int fr, int fk, f32x4 (&acc)[2][2])
{
    #pragma unroll
    for (int ks = 0; ks < 2; ++ks) {
        const int kb = (ks << 5) + fk;
        short8 ah[2], al[2], bh[2], bl[2];
        #pragma unroll
        for (int i = 0; i < 2; ++i) {
            ah[i] = *(const short8*)&Ahi[wr + (i << 4) + fr][kb];
            al[i] = *(const short8*)&Alo[wr + (i << 4) + fr][kb];
            bh[i] = *(const short8*)&BThi[wc + (i << 4) + fr][kb];
            bl[i] = *(const short8*)&BTlo[wc + (i << 4) + fr][kb];
        }
        #pragma unroll
        for (int i = 0; i < 2; ++i)
            #pragma unroll
            for (int j = 0; j < 2; ++j) {
                acc[i][j] = __builtin_amdgcn_mfma_f32_16x16x32_bf16(ah[i], bh[j], acc[i][j], 0, 0, 0);
                acc[i][j] = __builtin_amdgcn_mfma_f32_16x16x32_bf16(ah[i], bl[j], acc[i][j], 0, 0, 0);
                acc[i][j] = __builtin_amdgcn_mfma_f32_16x16x32_bf16(al[i], bh[j], acc[i][j], 0, 0, 0);
            }
    }
}

__global__ __launch_bounds__(256) void pinv_kernel(
    const float* __restrict__ eB, const float* __restrict__ denom,
    float* __restrict__ pi_)
{
    __shared__ unsigned short Xh[64][72],  Xl[64][72];
    __shared__ unsigned short Zh[64][72],  Zl[64][72];
    __shared__ unsigned short ZTh[64][72], ZTl[64][72];
    __shared__ unsigned short Mh[64][72],  Ml[64][72];
    __shared__ unsigned short MTh[64][72], MTl[64][72];
    __shared__ unsigned short Th[64][72],  Tbl[64][72];
    __shared__ float Zf[64][68];
    int bh = blockIdx.x;
    int h = bh % 11;
    int tid = threadIdx.x;
    float dn = denom[h];
    const int ln = tid & 63, wv = tid >> 6;
    const int wr = (wv >> 1) << 5, wc = (wv & 1) << 5;
    const int fr = ln & 15, fk = (ln >> 4) << 3;
    const int rg = (ln >> 4) << 2;

    for (int e = tid; e < 4096; e += 256) {
        int m = e >> 6, l = e & 63;
        float xv = eB[((size_t)bh << 12) + e];
        unsigned short hh, ll;
        bfsplit(xv, hh, ll);
        Xh[m][l] = hh; Xl[m][l] = ll;
        float zv = xv / dn;
        Zf[l][m] = zv;
        bfsplit(zv, hh, ll);
        Zh[l][m] = hh; Zl[l][m] = ll;
        ZTh[m][l] = hh; ZTl[m][l] = ll;
    }
    __syncthreads();

    for (int it = 0; it < 6; ++it) {
        f32x4 mm1[2][2] = {};
        mm64x3(Xh, Xl, ZTh, ZTl, wr, wc, fr, fk, mm1);
        #pragma unroll
        for (int i = 0; i < 2; ++i)
            #pragma unroll
            for (int j = 0; j < 2; ++j)
                #pragma unroll
                for (int r = 0; r < 4; ++r) {
                    int row = wr + (i << 4) + rg + r, col = wc + (j << 4) + fr;
                    unsigned short hh, ll;
                    bfsplit(mm1[i][j][r], hh, ll);
                    Mh[row][col] = hh;  Ml[row][col] = ll;
                    MTh[col][row] = hh; MTl[col][row] = ll;
                }
        __syncthreads();
        f32x4 a2[2][2] = {};
        mm64x3(Mh, Ml, MTh, MTl, wr, wc, fr, fk, a2);
        #pragma unroll
        for (int i = 0; i < 2; ++i)
            #pragma unroll
            for (int j = 0; j < 2; ++j)
                #pragma unroll
                for (int r = 0; r < 4; ++r) {
                    int row = wr + (i << 4) + rg + r, col = wc + (j << 4) + fr;
                    float val = 7.f * mm1[i][j][r] - a2[i][j][r];
                    unsigned short hh, ll;
                    bfsplit(val, hh, ll);
                    Th[col][row] = hh; Tbl[col][row] = ll;
                }
        __syncthreads();
        f32x4 a3[2][2] = {};
        mm64x3(Mh, Ml, Th, Tbl, wr, wc, fr, fk, a3);
        __syncthreads();
        #pragma unroll
        for (int i = 0; i < 2; ++i)
            #pragma unroll
            for (int j = 0; j < 2; ++j)
                #pragma unroll
                for (int r = 0; r < 4; ++r) {
                    int row = wr + (i << 4) + rg + r, col = wc + (j << 4) + fr;
                    float val = 15.f * mm1[i][j][r] - a3[i][j][r];
                    unsigned short hh, ll;
                    bfsplit(val, hh, ll);
                    Th[col][row] = hh; Tbl[col][row] = ll;
                }
        __syncthreads();
        f32x4 a4[2][2] = {};
        mm64x3(Zh, Zl, Th, Tbl, wr, wc, fr, fk, a4);
        float zn[2][2][4];
        #pragma unroll
        for (int i = 0; i < 2; ++i)
            #pragma unroll
            for (int j = 0; j < 2; ++j)
                #pragma unroll
                for (int r = 0; r < 4; ++r) {
                    int row = wr + (i << 4) + rg + r, col = wc + (j << 4) + fr;
                    zn[i][j][r] = 0.25f * (13.f * Zf[row][col] - a4[i][j][r]);
                }
        __syncthreads();
        #pragma unroll
        for (int i = 0; i < 2; ++i)
            #pragma unroll
            for (int j = 0; j < 2; ++j)
                #pragma unroll
                for (int r = 0; r < 4; ++r) {
                    int row = wr + (i << 4) + rg + r, col = wc + (j << 4) + fr;
                    float val = zn[i][j][r];
                    Zf[row][col] = val;
                    unsigned short hh, ll;
                    bfsplit(val, hh, ll);
                    Zh[row][col] = hh;  Zl[row][col] = ll;
                    ZTh[col][row] = hh; ZTl[col][row] = ll;
                }
        __syncthreads();
    }
    for (int e = tid; e < 4096; e += 256)
        pi_[((size_t)bh << 12) + e] = Zf[e >> 6][e & 63];
}

// ---------------------------------------------------------------------------
// K5: T = pi @ W  (64x64 @ 64x65)
// ---------------------------------------------------------------------------
__global__ __launch_bounds__(256) void pw_kernel(
    const float* __restrict__ pi_, const float* __restrict__ Wb,
    float* __restrict__ Tb)
{
    int bh = blockIdx.x;
    __shared__ float P[64][65];
    __shared__ float Wl[64][66];
    int tid = threadIdx.x;
    for (int e = tid; e < 4096; e += 256)
        P[e >> 6][e & 63] = pi_[((size_t)bh << 12) + e];
    for (int e = tid; e < 64 * 65; e += 256) {
        int l = e / 65, j = e - l * 65;
        Wl[l][j] = Wb[(size_t)bh * 4160 + e];
    }
    __syncthreads();
    int m = tid & 63, g = tid >> 6;
    #pragma unroll
    for (int t = 0; t < 17; ++t) {
        int j = g + (t << 2);
        if (j > 64) break;
        float s = 0.f;
        #pragma unroll
        for (int l = 0; l < 64; ++l) s += P[m][l] * Wl[l][j];
        Tb[(size_t)((bh << 6) + m) * 65 + j] = s;
    }
}

// ---------------------------------------------------------------------------
// K6: combined out_p [0,2816) + flash_merge [2816,3072)
// ---------------------------------------------------------------------------
__global__ __launch_bounds__(256) void outp_merge(
    const unsigned short* __restrict__ qh, const unsigned short* __restrict__ ql,
    const unsigned short* __restrict__ khg, const unsigned short* __restrict__ klg,
    const float* __restrict__ Tb,
    const float* __restrict__ pacc, const float* __restrict__ pm,
    const float* __restrict__ pl,
    unsigned short* __restrict__ ctxh)
{
    int tid = threadIdx.x;
    if (blockIdx.x < 2816) {
        int bh = blockIdx.x >> 6;
        int bx = blockIdx.x & 63;
        int b = bh / 11, h = bh - b * 11;
        int n0 = bx << 6;
        size_t base = ((size_t)(b * 12 + h)) << 12;
        __shared__ unsigned short kmh[64][72], kml[64][72];
        __shared__ unsigned short tth[64][72], ttl[64][72];
        __shared__ unsigned short ph[4][16][72];
        __shared__ float t64[64];
        int wv = tid >> 6, ln = tid & 63;
        int rr = tid >> 2, dg = (tid & 3) << 4;
        const int arow = (wv << 4) + (ln & 15);
        const int ak0 = (ln >> 4) << 3;
        const int rg = (ln >> 4) << 2;
        {
            size_t off = ((base + ((size_t)rr << 6)) << 6) + dg;
            *(short8*)&kmh[rr][dg]     = *(const short8*)(khg + off);
            *(short8*)&kmh[rr][dg + 8] = *(const short8*)(khg + off + 8);
            *(short8*)&kml[rr][dg]     = *(const short8*)(klg + off);
            *(short8*)&kml[rr][dg + 8] = *(const short8*)(klg + off + 8);
        }
        for (int e = tid; e < 4096; e += 256) {
            int m = e >> 6, j = e & 63;
            float tv = Tb[(size_t)((bh << 6) + m) * 65 + j];
            unsigned short hh, ll;
            bfsplit(tv, hh, ll);
            tth[j][m] = hh; ttl[j][m] = ll;
        }
        if (tid < 64) t64[tid] = Tb[(size_t)((bh << 6) + tid) * 65 + 64];
        short8 aqh0, aql0, aqh1, aql1;
        {
            size_t off = ((base + n0 + arow) << 6) + ak0;
            aqh0 = *(const short8*)(qh + off);
            aqh1 = *(const short8*)(qh + off + 32);
            aql0 = *(const short8*)(ql + off);
            aql1 = *(const short8*)(ql + off + 32);
        }
        __syncthreads();
        f32x4 s_acc[4];
        #pragma unroll
        for (int jb = 0; jb < 4; ++jb) {
            f32x4 z = {};
            const int brow2 = (jb << 4) + (ln & 15);
            short8 bh0 = *(short8*)&kmh[brow2][ak0];
            short8 bh1 = *(short8*)&kmh[brow2][ak0 + 32];
            short8 bl0 = *(short8*)&kml[brow2][ak0];
            short8 bl1 = *(short8*)&kml[brow2][ak0 + 32];
            z = __builtin_amdgcn_mfma_f32_16x16x32_bf16(aqh0, bh0, z, 0, 0, 0);
            z = __builtin_amdgcn_mfma_f32_16x16x32_bf16(aqh0, bl0, z, 0, 0, 0);
            z = __builtin_amdgcn_mfma_f32_16x16x32_bf16(aql0, bh0, z, 0, 0, 0);
            z = __builtin_amdgcn_mfma_f32_16x16x32_bf16(aqh1, bh1, z, 0, 0, 0);
            z = __builtin_amdgcn_mfma_f32_16x16x32_bf16(aqh1, bl1, z, 0, 0, 0);
            z = __builtin_amdgcn_mfma_f32_16x16x32_bf16(aql1, bh1, z, 0, 0, 0);
            s_acc[jb] = z;
        }
        float mx[4];
        #pragma unroll
        for (int r = 0; r < 4; ++r)
            mx[r] = fmaxf(fmaxf(s_acc[0][r], s_acc[1][r]),
                          fmaxf(s_acc[2][r], s_acc[3][r]));
        #pragma unroll
        for (int off2 = 1; off2 < 16; off2 <<= 1)
            #pragma unroll
            for (int r = 0; r < 4; ++r)
                mx[r] = fmaxf(mx[r], __shfl_xor(mx[r], off2, 64));
        float den[4] = {};
        #pragma unroll
        for (int jb = 0; jb < 4; ++jb) {
            float tj = t64[(jb << 4) + (ln & 15)];
            #pragma unroll
            for (int r = 0; r < 4; ++r) {
                float p = expf(s_acc[jb][r] - mx[r]);
                den[r] += p * tj;
                ph[wv][rg + r][(jb << 4) + (ln & 15)] = f2bf(p);
            }
        }
        #pragma unroll
        for (int off2 = 1; off2 < 16; off2 <<= 1)
            #pragma unroll
            for (int r = 0; r < 4; ++r)
                den[r] += __shfl_xor(den[r], off2, 64);
        short8 pah0 = *(short8*)&ph[wv][ln & 15][ak0];
        short8 pah1 = *(short8*)&ph[wv][ln & 15][ak0 + 32];
        f32x4 o_acc[4] = {};
        #pragma unroll
        for (int jb = 0; jb < 4; ++jb) {
            const int brow2 = (jb << 4) + (ln & 15);
            short8 bth0 = *(short8*)&tth[brow2][ak0];
            short8 bth1 = *(short8*)&tth[brow2][ak0 + 32];
            short8 btl0 = *(short8*)&ttl[brow2][ak0];
            short8 btl1 = *(short8*)&ttl[brow2][ak0 + 32];
            f32x4 o = o_acc[jb];
            o = __builtin_amdgcn_mfma_f32_16x16x32_bf16(pah0, bth0, o, 0, 0, 0);
            o = __builtin_amdgcn_mfma_f32_16x16x32_bf16(pah0, btl0, o, 0, 0, 0);
            o = __builtin_amdgcn_mfma_f32_16x16x32_bf16(pah1, bth1, o, 0, 0, 0);
            o = __builtin_amdgcn_mfma_f32_16x16x32_bf16(pah1, btl1, o, 0, 0, 0);
            o_acc[jb] = o;
        }
        float inv[4];
        #pragma unroll
        for (int r = 0; r < 4; ++r) inv[r] = 1.0f / fmaxf(den[r], 1e-8f);
        #pragma unroll
        for (int jb = 0; jb < 4; ++jb)
            #pragma unroll
            for (int r = 0; r < 4; ++r) {
                int row = n0 + (wv << 4) + rg + r;
                int col = (jb << 4) + (ln & 15);
                ctxh[((size_t)b * 4096 + row) * 768 + h * 64 + col] =
                    f2bf(o_acc[jb][r] * inv[r]);
            }
    } else {
        // flash_merge body
        int fb = blockIdx.x - 2816;
        int bx = fb & 63, b = fb >> 6;
        int r = tid & 63, g = tid >> 6;
        float mc[4], mt = -1e30f;
        #pragma unroll
        for (int c = 0; c < 4; ++c) {
            mc[c] = pm[(size_t)((b * 4 + c) * 64 + bx) * 64 + r];
            mt = fmaxf(mt, mc[c]);
        }
        float fac[4], lt = 0.f;
        #pragma unroll
        for (int c = 0; c < 4; ++c) {
            fac[c] = expf(mc[c] - mt);
            lt += fac[c] * pl[(size_t)((b * 4 + c) * 64 + bx) * 64 + r];
        }
        float inv = 1.0f / lt;
        size_t obase = ((size_t)b * 4096 + (size_t)((bx << 6) + r)) * 768 + 11 * 64 + (g << 4);
        #pragma unroll
        for (int i = 0; i < 16; ++i) {
            float s = 0.f;
            #pragma unroll
            for (int c = 0; c < 4; ++c)
                s += fac[c] * pacc[(size_t)((b * 4 + c) * 64 + bx) * 4096 + (size_t)r * 64 + (g << 4) + i];
            ctxh[obase + i] = f2bf(s * inv);
        }
    }
}

// ---------------------------------------------------------------------------
// K8: proj GEMM — plain bf16 MFMA, BK=64, swizzled LDS, XCD swizzle.
// ---------------------------------------------------------------------------
__global__ __launch_bounds__(256, 2) void gemm_proj_mfma(
    const unsigned short* __restrict__ Xh, const unsigned short* __restrict__ Wh,
    const float* __restrict__ bias, float* __restrict__ out)
{
    __shared__ unsigned short Ah[8192], Bh[8192];
    const int tid = threadIdx.x;
    const int bid = blockIdx.x;
    const int swz = (bid & 7) * 96 + (bid >> 3);
    const int brow = (swz / 6) << 7, bcol = (swz % 6) << 7;
    const int ln = tid & 63, wv = tid >> 6;
    const int wr = (wv >> 1) << 6, wc = (wv & 1) << 6;
    const int srow = tid >> 1;
    const int c0 = (tid & 1) << 2;
    const size_t ag = (size_t)(brow + srow) * 768;
    const size_t bg = (size_t)(bcol + srow) * 768;
    const int fr = ln & 15, fc = ln >> 4;

    f32x4 acc[4][4] = {};
    for (int k0 = 0; k0 < 768; k0 += 64) {
        short8 xa[4], wb[4];
        #pragma unroll
        for (int cc = 0; cc < 4; ++cc) {
            xa[cc] = *(const short8*)(Xh + ag + k0 + ((c0 + cc) << 3));
            wb[cc] = *(const short8*)(Wh + bg + k0 + ((c0 + cc) << 3));
        }
        __syncthreads();
        #pragma unroll
        for (int cc = 0; cc < 4; ++cc) {
            int dst = srow * 64 + (((c0 + cc) ^ (srow & 7)) << 3);
            *(short8*)&Ah[dst] = xa[cc];
            *(short8*)&Bh[dst] = wb[cc];
        }
        __syncthreads();
        #pragma unroll
        for (int ks = 0; ks < 2; ++ks) {
            const int kc = (ks << 2) + fc;
            short8 ah[4], bh[4];
            #pragma unroll
            for (int i = 0; i < 4; ++i) {
                int ar = wr + (i << 4) + fr;
                ah[i] = *(short8*)&Ah[ar * 64 + ((kc ^ (ar & 7)) << 3)];
                int br2 = wc + (i << 4) + fr;
                bh[i] = *(short8*)&Bh[br2 * 64 + ((kc ^ (br2 & 7)) << 3)];
            }
            #pragma unroll
            for (int i = 0; i < 4; ++i)
                #pragma unroll
                for (int j = 0; j < 4; ++j)
                    acc[i][j] = __builtin_amdgcn_mfma_f32_16x16x32_bf16(ah[i], bh[j], acc[i][j], 0, 0, 0);
        }
    }
    const int fg = ln >> 4;
    #pragma unroll
    for (int j = 0; j < 4; ++j) {
        int c = bcol + wc + (j << 4) + fr;
        float bb = bias[c];
        #pragma unroll
        for (int i = 0; i < 4; ++i)
            #pragma unroll
            for (int r = 0; r < 4; ++r) {
                int row = brow + wr + (i << 4) + (fg << 2) + r;
                out[(size_t)row * 768 + c] = acc[i][j][r] + bb;
            }
    }
}

// ---------------------------------------------------------------------------
extern "C" void kernel_launch(void* const* d_in, const int* in_sizes, int n_in,
                              void* d_out, int out_size, void* d_ws, size_t ws_size,
                              hipStream_t stream)
{
    const float* x      = (const float*)d_in[0];
    const float* qkv_w  = (const float*)d_in[1];
    const float* qkv_b  = (const float*)d_in[2];
    const float* proj_w = (const float*)d_in[3];
    const float* proj_b = (const float*)d_in[4];
    float* out = (float*)d_out;

    const size_t QKV = (size_t)4 * 12 * 4096 * 64;   // 12,582,912
    unsigned short* qh = (unsigned short*)d_ws;
    unsigned short* ql = qh + QKV;
    unsigned short* kh = ql + QKV;
    unsigned short* kl = kh + QKV;
    unsigned short* vh = kl + QKV;
    unsigned short* ctxh = vh + QKV;
    float* eB   = (float*)(ctxh + QKV);
    float* den  = eB + 44 * 4096;
    float* pi_  = den + 64;
    float* Wb   = pi_ + 44 * 4096;
    float* Tb   = Wb + 44 * 4160;
    unsigned short* Whi  = (unsigned short*)(Tb + 44 * 4160);
    unsigned short* Wlo  = Whi + (size_t)2304 * 768;
    unsigned short* Pwhi = Wlo + (size_t)2304 * 768;
    unsigned short* Pwlo = Pwhi + (size_t)768 * 768;   // written, unused

    // d_out scratch: phase 1 = X hi/lo (dead after gemm_qkv2);
    // phase 2 = wflash + flash partials (disjoint ranges, both written by
    // attn_mega, consumed by wmerge_eb / outp_merge).
    unsigned short* Xhi = (unsigned short*)out;
    unsigned short* Xlo = Xhi + QKV;
    float* wacc  = out;                        // 1,441,792
    float* wl    = wacc + 1441792;             // 22,528
    float* wm    = wl + 22528;                 // 22,528   (ends 1,486,848)
    float* fpacc = wm + 22528;                 // 4,194,304
    float* fpm   = fpacc + 4194304;            // 65,536
    float* fpl   = fpm + 65536;                // 65,536   (ends 5,812,224)

    preconv3<<<2048, 256, 0, stream>>>(x, qkv_w, proj_w,
                                       Xhi, Xlo, Whi, Wlo, Pwhi, Pwlo);
    gemm_qkv2<<<2304, 256, 0, stream>>>(Xhi, Xlo, Whi, Wlo, qkv_b,
                                        qh, ql, kh, kl, vh);
    attn_mega<<<1376, 256, 0, stream>>>(qh, ql, kh, kl, vh,
                                        wacc, wl, wm, fpacc, fpm, fpl);
    wmerge_eb<<<44, 256, 0, stream>>>(wacc, wl, wm, qh, ql, kh, kl, Wb, eB);
    norms_kernel<<<11, 256, 0, stream>>>(eB, den);
    pinv_kernel<<<44, 256, 0, stream>>>(eB, den, pi_);
    pw_kernel<<<44, 256, 0, stream>>>(pi_, Wb, Tb);
    outp_merge<<<3072, 256, 0, stream>>>(qh, ql, kh, kl, Tb,
                                         fpacc, fpm, fpl, ctxh);
    gemm_proj_mfma<<<768, 256, 0, stream>>>(ctxh, Pwhi, proj_b, out);
}